// Round 1
// baseline (1707.516 us; speedup 1.0000x reference)
//
#include <hip/hip_runtime.h>
#include <math.h>

namespace {

constexpr int T   = 4096;   // B*N tokens
constexpr int C   = 512;    // dim
constexpr int NB  = 8;      // batch
constexpr int NS  = 512;    // seq
constexpr int HD  = 64;     // head dim
constexpr int KA  = 8;      // attn top-k == heads
constexpr int EA  = 24;     // attn experts
constexpr int EF  = 16;     // ffd experts
constexpr int KF  = 2;      // ffd top-k
constexpr int HID = 1024;   // mlp hidden

// ---------------- LayerNorm: one block (256 thr) per token ----------------
__global__ void ln_kernel(const float* __restrict__ in, const float* __restrict__ g,
                          const float* __restrict__ b, float* __restrict__ out) {
  int t = blockIdx.x, tid = threadIdx.x;
  const float* row = in + (size_t)t * C;
  __shared__ float red[256];
  float v0 = row[tid], v1 = row[tid + 256];
  red[tid] = v0 + v1;
  __syncthreads();
  for (int st = 128; st > 0; st >>= 1) {
    if (tid < st) red[tid] += red[tid + st];
    __syncthreads();
  }
  float mean = red[0] * (1.f / C);
  __syncthreads();
  float d0 = v0 - mean, d1 = v1 - mean;
  red[tid] = d0 * d0 + d1 * d1;
  __syncthreads();
  for (int st = 128; st > 0; st >>= 1) {
    if (tid < st) red[tid] += red[tid + st];
    __syncthreads();
  }
  float r = rsqrtf(red[0] * (1.f / C) + 1e-5f);
  out[(size_t)t * C + tid]       = d0 * r * g[tid] + b[tid];
  out[(size_t)t * C + tid + 256] = d1 * r * g[tid + 256] + b[tid + 256];
}

// ---------------- Gating: one block per token ----------------
// logits -> softmax -> top-k (lax.top_k tie-break: strict >, lowest idx wins)
template <int E, int K, int TPE>
__global__ void gating_kernel(const float* __restrict__ xn, const float* __restrict__ gate_all,
                              const int* __restrict__ task,
                              float* __restrict__ probs, float* __restrict__ lse_out,
                              float* __restrict__ gates, int* __restrict__ idxs) {
  int t = blockIdx.x, tid = threadIdx.x;
  const float* W = gate_all + (size_t)task[0] * C * E;
  __shared__ float xs[C];
  __shared__ float lg[E];
  xs[tid]       = xn[(size_t)t * C + tid];
  xs[tid + 256] = xn[(size_t)t * C + tid + 256];
  __syncthreads();
  if (tid < E * TPE) {
    int e = tid / TPE, l = tid % TPE;
    float acc = 0.f;
    for (int c = l; c < C; c += TPE) acc += xs[c] * W[(size_t)c * E + e];
    #pragma unroll
    for (int m = TPE >> 1; m > 0; m >>= 1) acc += __shfl_xor(acc, m);
    if (l == 0) lg[e] = acc;
  }
  __syncthreads();
  if (tid == 0) {
    float mx = -1e30f;
    for (int e = 0; e < E; e++) mx = fmaxf(mx, lg[e]);
    float p[E], sum = 0.f;
    for (int e = 0; e < E; e++) { p[e] = expf(lg[e] - mx); sum += p[e]; }
    float inv = 1.f / sum;
    for (int e = 0; e < E; e++) { p[e] *= inv; probs[(size_t)t * E + e] = p[e]; }
    lse_out[t] = mx + logf(sum);
    bool used[E] = {};
    float gv[K]; int gi[K]; float gsum = 0.f;
    for (int k = 0; k < K; k++) {
      float best = -1.f; int be = 0;
      for (int e = 0; e < E; e++)
        if (!used[e] && p[e] > best) { best = p[e]; be = e; }
      used[be] = true; gv[k] = best; gi[k] = be; gsum += best;
    }
    float ginv = 1.f / (gsum + 1e-6f);
    for (int k = 0; k < K; k++) {
      gates[(size_t)t * K + k] = gv[k] * ginv;
      idxs[(size_t)t * K + k]  = gi[k];
    }
  }
}

// ---------------- Q: block (512 thr) per token; wave w -> slot w ----------------
__global__ void q_kernel(const float* __restrict__ xn, const float* __restrict__ wq,
                         const int* __restrict__ idxs, float* __restrict__ q) {
  int t = blockIdx.x, tid = threadIdx.x;
  __shared__ float xs[C];
  xs[tid] = xn[(size_t)t * C + tid];
  __syncthreads();
  int k = tid >> 6, d = tid & 63;
  int e = idxs[(size_t)t * KA + k];
  const float* W = wq + (size_t)e * C * HD + d;
  float acc = 0.f;
  #pragma unroll 8
  for (int c = 0; c < C; c++) acc += xs[c] * W[(size_t)c * HD];
  q[((size_t)t * KA + k) * HD + d] = acc;
}

// ---------------- KV: block (128 thr) per token ----------------
__global__ void kv_kernel(const float* __restrict__ xn, const float* __restrict__ kv_w,
                          const float* __restrict__ kv_b, float* __restrict__ kv) {
  int t = blockIdx.x, tid = threadIdx.x;
  __shared__ float xs[C];
  for (int i = tid; i < C; i += 128) xs[i] = xn[(size_t)t * C + i];
  __syncthreads();
  float acc = kv_b[tid];
  #pragma unroll 8
  for (int c = 0; c < C; c++) acc += xs[c] * kv_w[(size_t)c * 128 + tid];
  kv[(size_t)t * 128 + tid] = acc;
}

// ---------------- Attention: block per (qtile16, head, batch) ----------------
// o may alias qin: Q tile is staged to LDS (synced) before any O write;
// blocks touch disjoint (b, row-range, h) regions.
__global__ void attn_kernel(const float* __restrict__ qin, const float* __restrict__ kv,
                            float* __restrict__ o) {
  int qt = blockIdx.x, h = blockIdx.y, b = blockIdx.z;
  int tid = threadIdx.x;
  __shared__ float Qs[16][64];
  __shared__ float P[16][513];
  int i0 = qt * 16;
  for (int idx = tid; idx < 16 * 64; idx += 256) {
    int qi = idx >> 6, d = idx & 63;
    Qs[qi][d] = qin[(((size_t)(b * NS + i0 + qi)) * KA + h) * HD + d];
  }
  __syncthreads();
  const float* Kb = kv + (size_t)b * NS * 128;
  for (int idx = tid; idx < 16 * 512; idx += 256) {
    int qi = idx >> 9, j = idx & 511;
    const float* kr = Kb + (size_t)j * 128;
    float s = 0.f;
    #pragma unroll
    for (int d = 0; d < 64; d++) s += Qs[qi][d] * kr[d];
    P[qi][j] = s * 0.125f;   // SCALE = 64^-0.5
  }
  __syncthreads();
  {
    int r = tid >> 4, l = tid & 15;
    float mx = -1e30f;
    for (int j = l; j < 512; j += 16) mx = fmaxf(mx, P[r][j]);
    #pragma unroll
    for (int m = 1; m < 16; m <<= 1) mx = fmaxf(mx, __shfl_xor(mx, m));
    float sum = 0.f;
    for (int j = l; j < 512; j += 16) { float p = expf(P[r][j] - mx); P[r][j] = p; sum += p; }
    #pragma unroll
    for (int m = 1; m < 16; m <<= 1) sum += __shfl_xor(sum, m);
    float inv = 1.f / sum;
    for (int j = l; j < 512; j += 16) P[r][j] *= inv;
  }
  __syncthreads();
  int w = tid >> 6, d = tid & 63;
  const float* Vb = kv + (size_t)b * NS * 128 + 64;
  float acc[4] = {0.f, 0.f, 0.f, 0.f};
  for (int j = 0; j < 512; j++) {
    float v = Vb[(size_t)j * 128 + d];
    #pragma unroll
    for (int r = 0; r < 4; r++) acc[r] += P[w * 4 + r][j] * v;
  }
  for (int r = 0; r < 4; r++)
    o[(((size_t)(b * NS + i0 + w * 4 + r)) * KA + h) * HD + d] = acc[r];
}

// ---------------- Attn output proj + residual: block per token ----------------
__global__ void proj_kernel(const float* __restrict__ x, const float* __restrict__ o,
                            const float* __restrict__ gates, const int* __restrict__ idxs,
                            const float* __restrict__ wo, float* __restrict__ xout) {
  int t = blockIdx.x, tid = threadIdx.x;
  __shared__ float os[KA * HD];
  __shared__ float gs[KA];
  __shared__ int es[KA];
  os[tid]       = o[(size_t)t * (KA * HD) + tid];
  os[tid + 256] = o[(size_t)t * (KA * HD) + tid + 256];
  if (tid < KA) { gs[tid] = gates[(size_t)t * KA + tid]; es[tid] = idxs[(size_t)t * KA + tid]; }
  __syncthreads();
  float acc0 = 0.f, acc1 = 0.f;
  for (int k = 0; k < KA; k++) {
    const float* W = wo + (size_t)es[k] * HD * C;
    float g = gs[k];
    float a0 = 0.f, a1 = 0.f;
    for (int d = 0; d < HD; d++) {
      float ov = os[k * HD + d];
      a0 += ov * W[(size_t)d * C + tid];
      a1 += ov * W[(size_t)d * C + tid + 256];
    }
    acc0 += g * a0; acc1 += g * a1;
  }
  xout[(size_t)t * C + tid]       = x[(size_t)t * C + tid] + acc0;
  xout[(size_t)t * C + tid + 256] = x[(size_t)t * C + tid + 256] + acc1;
}

// ---------------- MLP slot bucketing by expert ----------------
__global__ void bucket_kernel(const int* __restrict__ idx2, int* counts, int* bucket) {
  int s = blockIdx.x * 256 + threadIdx.x;
  if (s >= T * KF) return;
  int e = idx2[s];
  int pos = atomicAdd(&counts[e], 1);
  bucket[(size_t)e * T + pos] = s;
}

// ---------------- MLP GEMM1: h = gelu(x2 @ wi[e] + bi[e]) per expert group ----------------
__global__ void mlp1_kernel(const float* __restrict__ x2, const float* __restrict__ wi,
                            const float* __restrict__ bi, const int* __restrict__ counts,
                            const int* __restrict__ bucket, float* __restrict__ h) {
  int e = blockIdx.z;
  int cnt = counts[e];
  int t0 = blockIdx.y * 64;
  if (t0 >= cnt) return;
  int j0 = blockIdx.x * 64;
  int tid = threadIdx.x;
  __shared__ int slots[64];
  __shared__ float Xs[64][33];
  __shared__ float Ws[32][65];
  if (tid < 64) {
    int r = t0 + tid;
    slots[tid] = (r < cnt) ? bucket[(size_t)e * T + r] : -1;
  }
  __syncthreads();
  float acc[4][4] = {};
  const float* Wbase = wi + (size_t)e * C * HID + j0;
  for (int kc = 0; kc < C; kc += 32) {
    for (int i2 = tid; i2 < 64 * 32; i2 += 256) {
      int r = i2 >> 5, kk = i2 & 31;
      int s = slots[r];
      Xs[r][kk] = (s >= 0) ? x2[(size_t)(s >> 1) * C + kc + kk] : 0.f;
    }
    for (int i2 = tid; i2 < 32 * 64; i2 += 256) {
      int kk = i2 >> 6, jc = i2 & 63;
      Ws[kk][jc] = Wbase[(size_t)(kc + kk) * HID + jc];
    }
    __syncthreads();
    int tr = tid >> 4, tc = tid & 15;
    #pragma unroll
    for (int kk = 0; kk < 32; kk++) {
      float a[4], bv[4];
      #pragma unroll
      for (int i = 0; i < 4; i++) a[i] = Xs[tr * 4 + i][kk];
      #pragma unroll
      for (int j = 0; j < 4; j++) bv[j] = Ws[kk][tc * 4 + j];
      #pragma unroll
      for (int i = 0; i < 4; i++)
        #pragma unroll
        for (int j = 0; j < 4; j++) acc[i][j] += a[i] * bv[j];
    }
    __syncthreads();
  }
  int tr = tid >> 4, tc = tid & 15;
  for (int i = 0; i < 4; i++) {
    int s = slots[tr * 4 + i];
    if (s < 0) continue;
    for (int j = 0; j < 4; j++) {
      int jj = j0 + tc * 4 + j;
      float v = acc[i][j] + bi[(size_t)e * HID + jj];
      v = 0.5f * v * (1.f + erff(v * 0.70710678118654752f));   // exact gelu
      h[(size_t)s * HID + jj] = v;
    }
  }
}

// ---------------- MLP GEMM2: y2slot = g * (h @ wo[e] + bo[e]) ----------------
__global__ void mlp2_kernel(const float* __restrict__ h, const float* __restrict__ wo,
                            const float* __restrict__ bo, const float* __restrict__ gates2,
                            const int* __restrict__ counts, const int* __restrict__ bucket,
                            float* __restrict__ y2) {
  int e = blockIdx.z;
  int cnt = counts[e];
  int t0 = blockIdx.y * 64;
  if (t0 >= cnt) return;
  int c0 = blockIdx.x * 64;
  int tid = threadIdx.x;
  __shared__ int slots[64];
  __shared__ float Xs[64][33];
  __shared__ float Ws[32][65];
  if (tid < 64) {
    int r = t0 + tid;
    slots[tid] = (r < cnt) ? bucket[(size_t)e * T + r] : -1;
  }
  __syncthreads();
  float acc[4][4] = {};
  const float* Wbase = wo + (size_t)e * HID * C + c0;
  for (int kc = 0; kc < HID; kc += 32) {
    for (int i2 = tid; i2 < 64 * 32; i2 += 256) {
      int r = i2 >> 5, kk = i2 & 31;
      int s = slots[r];
      Xs[r][kk] = (s >= 0) ? h[(size_t)s * HID + kc + kk] : 0.f;
    }
    for (int i2 = tid; i2 < 32 * 64; i2 += 256) {
      int kk = i2 >> 6, jc = i2 & 63;
      Ws[kk][jc] = Wbase[(size_t)(kc + kk) * C + jc];
    }
    __syncthreads();
    int tr = tid >> 4, tc = tid & 15;
    #pragma unroll
    for (int kk = 0; kk < 32; kk++) {
      float a[4], bv[4];
      #pragma unroll
      for (int i = 0; i < 4; i++) a[i] = Xs[tr * 4 + i][kk];
      #pragma unroll
      for (int j = 0; j < 4; j++) bv[j] = Ws[kk][tc * 4 + j];
      #pragma unroll
      for (int i = 0; i < 4; i++)
        #pragma unroll
        for (int j = 0; j < 4; j++) acc[i][j] += a[i] * bv[j];
    }
    __syncthreads();
  }
  int tr = tid >> 4, tc = tid & 15;
  for (int i = 0; i < 4; i++) {
    int s = slots[tr * 4 + i];
    if (s < 0) continue;
    float g = gates2[s];
    for (int j = 0; j < 4; j++) {
      int cc = c0 + tc * 4 + j;
      y2[(size_t)s * C + cc] = g * (acc[i][j] + bo[(size_t)e * C + cc]);
    }
  }
}

// ---------------- Final residual add (each token has exactly 2 slots) ----------------
__global__ void final_kernel(const float* __restrict__ y2, float* __restrict__ xout) {
  int t = blockIdx.x, tid = threadIdx.x;
  for (int c = tid; c < C; c += 256) {
    xout[(size_t)t * C + c] += y2[(size_t)(t * 2) * C + c] + y2[(size_t)(t * 2 + 1) * C + c];
  }
}

// ---------------- Gating statistics reduction ----------------
template <int E, int K>
__global__ void reduce_gating(const float* __restrict__ probs, const float* __restrict__ lse,
                              const int* __restrict__ idxs, float* __restrict__ psum,
                              float* __restrict__ freq, float* __restrict__ zsum) {
  __shared__ float ps[E];
  __shared__ float fr[E];
  __shared__ float zs;
  int tid = threadIdx.x;
  if (tid < E) { ps[tid] = 0.f; fr[tid] = 0.f; }
  if (tid == 0) zs = 0.f;
  __syncthreads();
  int t = blockIdx.x * 256 + tid;   // grid 16 * 256 == T
  if (t < T) {
    for (int e = 0; e < E; e++) atomicAdd(&ps[e], probs[(size_t)t * E + e]);
    for (int k = 0; k < K; k++) atomicAdd(&fr[idxs[(size_t)t * K + k]], 1.f);
    float l = lse[t];
    atomicAdd(&zs, l * l);
  }
  __syncthreads();
  if (tid < E) { atomicAdd(&psum[tid], ps[tid]); atomicAdd(&freq[tid], fr[tid]); }
  if (tid == 0) atomicAdd(zsum, zs);
}

// acc layout: psum1[24] freq1[24] z1 psum2[16] freq2[16] z2
__global__ void loss_kernel(const float* __restrict__ acc, float* __restrict__ out) {
  const float* p1 = acc;      const float* f1 = acc + 24; float z1 = acc[48];
  const float* p2 = acc + 49; const float* f2 = acc + 65; float z2 = acc[81];
  float sp1 = 0.f, sf1 = 0.f;
  for (int e = 0; e < 24; e++) { sp1 += p1[e]; sf1 += f1[e]; }
  float sw1 = 0.f;
  for (int e = 0; e < 24; e++) sw1 += (p1[e] / sp1) * (f1[e] / sf1);
  sw1 *= 24.f;
  float sp2 = 0.f, sf2 = 0.f;
  for (int e = 0; e < 16; e++) { sp2 += p2[e]; sf2 += f2[e]; }
  float sw2 = 0.f;
  for (int e = 0; e < 16; e++) sw2 += (p2[e] / sp2) * (f2[e] / sf2);
  sw2 *= 16.f;
  out[0] = 0.01f * sw1 + 0.001f * (z1 / T) + 0.01f * sw2 + 0.001f * (z2 / T);
}

}  // namespace

extern "C" void kernel_launch(void* const* d_in, const int* in_sizes, int n_in,
                              void* d_out, int out_size, void* d_ws, size_t ws_size,
                              hipStream_t stream) {
  const float* x      = (const float*)d_in[0];
  const int*   task   = (const int*)d_in[1];
  const float* n1g    = (const float*)d_in[2];
  const float* n1b    = (const float*)d_in[3];
  const float* gate_a = (const float*)d_in[4];
  const float* wq     = (const float*)d_in[5];
  const float* wo_a   = (const float*)d_in[6];
  const float* kvw    = (const float*)d_in[7];
  const float* kvb    = (const float*)d_in[8];
  const float* n2g    = (const float*)d_in[9];
  const float* n2b    = (const float*)d_in[10];
  const float* gate_m = (const float*)d_in[11];
  const float* wi     = (const float*)d_in[12];
  const float* bi     = (const float*)d_in[13];
  const float* wo_m   = (const float*)d_in[14];
  const float* bo     = (const float*)d_in[15];
  float* out = (float*)d_out;

  float* ws = (float*)d_ws;
  float* x1     = ws; ws += (size_t)T * C;        // also reused as x2 after attention
  float* q      = ws; ws += (size_t)T * KA * HD;  // attention writes o in-place here
  float* kv     = ws; ws += (size_t)T * 2 * HD;
  float* probs1 = ws; ws += (size_t)T * EA;
  float* lse1   = ws; ws += T;
  float* gates1 = ws; ws += (size_t)T * KA;
  int*   idx1   = (int*)ws; ws += (size_t)T * KA;
  float* probs2 = ws; ws += (size_t)T * EF;
  float* lse2   = ws; ws += T;
  float* gates2 = ws; ws += (size_t)T * KF;
  int*   idx2   = (int*)ws; ws += (size_t)T * KF;
  float* hbuf   = ws; ws += (size_t)T * KF * HID;
  float* y2buf  = ws; ws += (size_t)T * KF * C;
  int*   bucket = (int*)ws; ws += (size_t)EF * T;
  int*   counts = (int*)ws; ws += 32;    // 16 used
  float* accum  = ws; ws += 128;         // 82 used (contiguous with counts)

  // zero counts + accumulators (capture-safe)
  hipMemsetAsync(counts, 0, (32 + 128) * sizeof(float), stream);

  ln_kernel<<<T, 256, 0, stream>>>(x, n1g, n1b, x1);
  gating_kernel<EA, KA, 8><<<T, 256, 0, stream>>>(x1, gate_a, task, probs1, lse1, gates1, idx1);
  q_kernel<<<T, 512, 0, stream>>>(x1, wq, idx1, q);
  kv_kernel<<<T, 128, 0, stream>>>(x1, kvw, kvb, kv);
  attn_kernel<<<dim3(NS / 16, KA, NB), 256, 0, stream>>>(q, kv, q);
  proj_kernel<<<T, 256, 0, stream>>>(x, q, gates1, idx1, wo_a, out);
  ln_kernel<<<T, 256, 0, stream>>>(out, n2g, n2b, x1);
  gating_kernel<EF, KF, 16><<<T, 256, 0, stream>>>(x1, gate_m, task, probs2, lse2, gates2, idx2);
  bucket_kernel<<<(T * KF + 255) / 256, 256, 0, stream>>>(idx2, counts, bucket);
  mlp1_kernel<<<dim3(HID / 64, T / 64, EF), 256, 0, stream>>>(x1, wi, bi, counts, bucket, hbuf);
  mlp2_kernel<<<dim3(C / 64, T / 64, EF), 256, 0, stream>>>(hbuf, wo_m, bo, gates2, counts, bucket, y2buf);
  final_kernel<<<T, 256, 0, stream>>>(y2buf, out);
  reduce_gating<EA, KA><<<16, 256, 0, stream>>>(probs1, lse1, idx1, accum, accum + 24, accum + 48);
  reduce_gating<EF, KF><<<16, 256, 0, stream>>>(probs2, lse2, idx2, accum + 49, accum + 65, accum + 81);
  loss_kernel<<<1, 1, 0, stream>>>(accum, out + (size_t)T * C);
}

// Round 2
// 1279.237 us; speedup vs baseline: 1.3348x; 1.3348x over previous
//
#include <hip/hip_runtime.h>
#include <math.h>

namespace {

constexpr int T   = 4096;   // B*N tokens
constexpr int C   = 512;    // dim
constexpr int NB  = 8;      // batch
constexpr int NS  = 512;    // seq
constexpr int HD  = 64;     // head dim
constexpr int KA  = 8;      // attn top-k == heads
constexpr int EA  = 24;     // attn experts
constexpr int EF  = 16;     // ffd experts
constexpr int KF  = 2;      // ffd top-k
constexpr int HID = 1024;   // mlp hidden

// ---------------- LayerNorm: one block (256 thr) per token ----------------
__global__ void ln_kernel(const float* __restrict__ in, const float* __restrict__ g,
                          const float* __restrict__ b, float* __restrict__ out) {
  int t = blockIdx.x, tid = threadIdx.x;
  const float* row = in + (size_t)t * C;
  __shared__ float red[256];
  float v0 = row[tid], v1 = row[tid + 256];
  red[tid] = v0 + v1;
  __syncthreads();
  for (int st = 128; st > 0; st >>= 1) {
    if (tid < st) red[tid] += red[tid + st];
    __syncthreads();
  }
  float mean = red[0] * (1.f / C);
  __syncthreads();
  float d0 = v0 - mean, d1 = v1 - mean;
  red[tid] = d0 * d0 + d1 * d1;
  __syncthreads();
  for (int st = 128; st > 0; st >>= 1) {
    if (tid < st) red[tid] += red[tid + st];
    __syncthreads();
  }
  float r = rsqrtf(red[0] * (1.f / C) + 1e-5f);
  out[(size_t)t * C + tid]       = d0 * r * g[tid] + b[tid];
  out[(size_t)t * C + tid + 256] = d1 * r * g[tid + 256] + b[tid + 256];
}

// ---------------- Gating: one block per token ----------------
template <int E, int K, int TPE>
__global__ void gating_kernel(const float* __restrict__ xn, const float* __restrict__ gate_all,
                              const int* __restrict__ task,
                              float* __restrict__ probs, float* __restrict__ lse_out,
                              float* __restrict__ gates, int* __restrict__ idxs) {
  int t = blockIdx.x, tid = threadIdx.x;
  const float* W = gate_all + (size_t)task[0] * C * E;
  __shared__ float xs[C];
  __shared__ float lg[E];
  xs[tid]       = xn[(size_t)t * C + tid];
  xs[tid + 256] = xn[(size_t)t * C + tid + 256];
  __syncthreads();
  if (tid < E * TPE) {
    int e = tid / TPE, l = tid % TPE;
    float acc = 0.f;
    for (int c = l; c < C; c += TPE) acc += xs[c] * W[(size_t)c * E + e];
    #pragma unroll
    for (int m = TPE >> 1; m > 0; m >>= 1) acc += __shfl_xor(acc, m);
    if (l == 0) lg[e] = acc;
  }
  __syncthreads();
  if (tid == 0) {
    float mx = -1e30f;
    for (int e = 0; e < E; e++) mx = fmaxf(mx, lg[e]);
    float p[E], sum = 0.f;
    for (int e = 0; e < E; e++) { p[e] = expf(lg[e] - mx); sum += p[e]; }
    float inv = 1.f / sum;
    for (int e = 0; e < E; e++) { p[e] *= inv; probs[(size_t)t * E + e] = p[e]; }
    lse_out[t] = mx + logf(sum);
    bool used[E] = {};
    float gv[K]; int gi[K]; float gsum = 0.f;
    for (int k = 0; k < K; k++) {
      float best = -1.f; int be = 0;
      for (int e = 0; e < E; e++)
        if (!used[e] && p[e] > best) { best = p[e]; be = e; }
      used[be] = true; gv[k] = best; gi[k] = be; gsum += best;
    }
    float ginv = 1.f / (gsum + 1e-6f);
    for (int k = 0; k < K; k++) {
      gates[(size_t)t * K + k] = gv[k] * ginv;
      idxs[(size_t)t * K + k]  = gi[k];
    }
  }
}

// ---------------- Generic slot bucketing by expert (bucket stride = T) ----------------
__global__ void bucket_kernel(const int* __restrict__ idx, int nslots,
                              int* counts, int* bucket) {
  int s = blockIdx.x * 256 + threadIdx.x;
  if (s >= nslots) return;
  int e = idx[s];
  int pos = atomicAdd(&counts[e], 1);
  bucket[(size_t)e * T + pos] = s;
}

// ---------------- Gathered per-expert Q GEMM: q[slot] = x1[token] @ wq[e] ----------------
// 64 slots x 64 out per block, K=512 in chunks of 32. 4x4 register tile.
__global__ void qgemm_kernel(const float* __restrict__ x1, const float* __restrict__ wq,
                             const int* __restrict__ counts, const int* __restrict__ bucket,
                             float* __restrict__ q) {
  int e = blockIdx.z;
  int cnt = counts[e];
  int t0 = blockIdx.y * 64;
  if (t0 >= cnt) return;
  int tid = threadIdx.x;
  __shared__ int slots[64];
  __shared__ __align__(16) float Xt[32][68];   // Xt[k][r]
  __shared__ __align__(16) float Ws[32][68];   // Ws[k][j]
  if (tid < 64) slots[tid] = (t0 + tid < cnt) ? bucket[(size_t)e * T + t0 + tid] : -1;
  __syncthreads();
  int tr = tid >> 4, tc = tid & 15;
  float acc[4][4] = {};
  const float* Wb = wq + (size_t)e * C * HD;
  for (int kc = 0; kc < C; kc += 32) {
    for (int i2 = tid; i2 < 64 * 32; i2 += 256) {
      int r = i2 >> 5, kk = i2 & 31;
      int s = slots[r];
      Xt[kk][r] = (s >= 0) ? x1[(size_t)(s >> 3) * C + kc + kk] : 0.f;
    }
    for (int i2 = tid; i2 < 32 * 64; i2 += 256) {
      int kk = i2 >> 6, j = i2 & 63;
      Ws[kk][j] = Wb[(size_t)(kc + kk) * HD + j];
    }
    __syncthreads();
    #pragma unroll 8
    for (int k = 0; k < 32; ++k) {
      const float4 av = *(const float4*)&Xt[k][tr * 4];
      const float4 bv = *(const float4*)&Ws[k][tc * 4];
      const float af[4] = {av.x, av.y, av.z, av.w};
      const float bf[4] = {bv.x, bv.y, bv.z, bv.w};
      #pragma unroll
      for (int i = 0; i < 4; i++)
        #pragma unroll
        for (int j = 0; j < 4; j++) acc[i][j] += af[i] * bf[j];
    }
    __syncthreads();
  }
  #pragma unroll
  for (int i = 0; i < 4; i++) {
    int s = slots[tr * 4 + i];
    if (s < 0) continue;
    float4 r4 = make_float4(acc[i][0], acc[i][1], acc[i][2], acc[i][3]);
    *(float4*)&q[(size_t)s * HD + tc * 4] = r4;
  }
}

// ---------------- Dense KV GEMM: kv = x1 @ kv_w + kv_b ----------------
__global__ void kvgemm_kernel(const float* __restrict__ x1, const float* __restrict__ kvw,
                              const float* __restrict__ kvb, float* __restrict__ kvo) {
  int t0 = blockIdx.y * 64;
  int c0 = blockIdx.x * 64;
  int tid = threadIdx.x;
  __shared__ __align__(16) float Xt[32][68];
  __shared__ __align__(16) float Ws[32][68];
  int tr = tid >> 4, tc = tid & 15;
  float acc[4][4] = {};
  for (int kc = 0; kc < C; kc += 32) {
    for (int i2 = tid; i2 < 64 * 32; i2 += 256) {
      int r = i2 >> 5, kk = i2 & 31;
      Xt[kk][r] = x1[(size_t)(t0 + r) * C + kc + kk];
    }
    for (int i2 = tid; i2 < 32 * 64; i2 += 256) {
      int kk = i2 >> 6, j = i2 & 63;
      Ws[kk][j] = kvw[(size_t)(kc + kk) * 128 + c0 + j];
    }
    __syncthreads();
    #pragma unroll 8
    for (int k = 0; k < 32; ++k) {
      const float4 av = *(const float4*)&Xt[k][tr * 4];
      const float4 bv = *(const float4*)&Ws[k][tc * 4];
      const float af[4] = {av.x, av.y, av.z, av.w};
      const float bf[4] = {bv.x, bv.y, bv.z, bv.w};
      #pragma unroll
      for (int i = 0; i < 4; i++)
        #pragma unroll
        for (int j = 0; j < 4; j++) acc[i][j] += af[i] * bf[j];
    }
    __syncthreads();
  }
  #pragma unroll
  for (int i = 0; i < 4; i++) {
    float4 r4 = make_float4(acc[i][0] + kvb[c0 + tc * 4 + 0],
                            acc[i][1] + kvb[c0 + tc * 4 + 1],
                            acc[i][2] + kvb[c0 + tc * 4 + 2],
                            acc[i][3] + kvb[c0 + tc * 4 + 3]);
    *(float4*)&kvo[(size_t)(t0 + tr * 4 + i) * 128 + c0 + tc * 4] = r4;
  }
}

// ---------------- Flash attention: block per (qtile64, head, batch) ----------------
// o aliases qin safely: block stages its own 64 Q rows to LDS first, writes the
// same disjoint region at the very end.
__global__ void attn_kernel(const float* __restrict__ qin, const float* __restrict__ kv,
                            float* __restrict__ o) {
  int qt = blockIdx.x, h = blockIdx.y, b = blockIdx.z;
  int tid = threadIdx.x;
  __shared__ __align__(16) float Qt[64][68];   // Qt[d][row], pre-scaled by 0.125
  __shared__ __align__(16) float Kt[64][68];   // Kt[d][col]
  __shared__ __align__(16) float Vs[64][64];   // Vs[j][d]
  __shared__ __align__(16) float Pt[64][68];   // Pt[j][row]
  int i0 = qt * 64;
  // stage Q transposed (scaled)
  #pragma unroll
  for (int it = 0; it < 4; ++it) {
    int fid = it * 256 + tid;            // 1024 float4s: 64 rows x 16 segs
    int row = fid >> 4, seg = fid & 15;
    const float4 v = *(const float4*)&qin[(((size_t)(b * NS + i0 + row)) * KA + h) * HD + seg * 4];
    Qt[seg * 4 + 0][row] = v.x * 0.125f;
    Qt[seg * 4 + 1][row] = v.y * 0.125f;
    Qt[seg * 4 + 2][row] = v.z * 0.125f;
    Qt[seg * 4 + 3][row] = v.w * 0.125f;
  }
  int tr = tid >> 4, tc = tid & 15;
  float acc[4][4] = {};
  float m_run[4], l_run[4], scl[4];
  #pragma unroll
  for (int i = 0; i < 4; i++) { m_run[i] = -1e30f; l_run[i] = 0.f; }
  const float* KVb = kv + (size_t)b * NS * 128;
  for (int jt = 0; jt < NS / 64; ++jt) {
    __syncthreads();   // prev PV done (Kt/Vs/Pt free); Qt visible on first iter
    #pragma unroll
    for (int it = 0; it < 8; ++it) {
      int fid = it * 256 + tid;          // 2048 float4s: 64 rows x 32 segs
      int row = fid >> 5, seg = fid & 31;
      const float4 v = *(const float4*)&KVb[(size_t)(jt * 64 + row) * 128 + seg * 4];
      if (seg < 16) {
        int d = seg * 4;
        Kt[d + 0][row] = v.x; Kt[d + 1][row] = v.y; Kt[d + 2][row] = v.z; Kt[d + 3][row] = v.w;
      } else {
        *(float4*)&Vs[row][(seg - 16) * 4] = v;
      }
    }
    __syncthreads();
    // S tile 4x4 in registers
    float s[4][4] = {};
    #pragma unroll 8
    for (int k = 0; k < 64; ++k) {
      const float4 av = *(const float4*)&Qt[k][tr * 4];
      const float4 bv = *(const float4*)&Kt[k][tc * 4];
      const float af[4] = {av.x, av.y, av.z, av.w};
      const float bf[4] = {bv.x, bv.y, bv.z, bv.w};
      #pragma unroll
      for (int i = 0; i < 4; i++)
        #pragma unroll
        for (int j = 0; j < 4; j++) s[i][j] += af[i] * bf[j];
    }
    // online softmax (rows owned by 16-lane groups sharing tr)
    #pragma unroll
    for (int i = 0; i < 4; i++) {
      float m = fmaxf(fmaxf(s[i][0], s[i][1]), fmaxf(s[i][2], s[i][3]));
      #pragma unroll
      for (int d = 1; d < 16; d <<= 1) m = fmaxf(m, __shfl_xor(m, d));
      float nm = fmaxf(m_run[i], m);
      float sc = expf(m_run[i] - nm);
      m_run[i] = nm;
      float rs = 0.f;
      #pragma unroll
      for (int j = 0; j < 4; j++) { s[i][j] = expf(s[i][j] - nm); rs += s[i][j]; }
      #pragma unroll
      for (int d = 1; d < 16; d <<= 1) rs += __shfl_xor(rs, d);
      l_run[i] = l_run[i] * sc + rs;
      scl[i] = sc;
    }
    // write P transposed: Pt[col][row]
    #pragma unroll
    for (int j = 0; j < 4; j++) {
      float4 pv = make_float4(s[0][j], s[1][j], s[2][j], s[3][j]);
      *(float4*)&Pt[tc * 4 + j][tr * 4] = pv;
    }
    __syncthreads();
    // PV: acc = acc*scale + P @ V
    #pragma unroll
    for (int i = 0; i < 4; i++) {
      acc[i][0] *= scl[i]; acc[i][1] *= scl[i]; acc[i][2] *= scl[i]; acc[i][3] *= scl[i];
    }
    #pragma unroll 8
    for (int k = 0; k < 64; ++k) {
      const float4 av = *(const float4*)&Pt[k][tr * 4];
      const float4 bv = *(const float4*)&Vs[k][tc * 4];
      const float af[4] = {av.x, av.y, av.z, av.w};
      const float bf[4] = {bv.x, bv.y, bv.z, bv.w};
      #pragma unroll
      for (int i = 0; i < 4; i++)
        #pragma unroll
        for (int j = 0; j < 4; j++) acc[i][j] += af[i] * bf[j];
    }
  }
  #pragma unroll
  for (int i = 0; i < 4; i++) {
    float inv = 1.f / l_run[i];
    float4 r4 = make_float4(acc[i][0] * inv, acc[i][1] * inv, acc[i][2] * inv, acc[i][3] * inv);
    *(float4*)&o[(((size_t)(b * NS + i0 + tr * 4 + i)) * KA + h) * HD + tc * 4] = r4;
  }
}

// ---------------- Gathered per-expert output proj: y_att[token] += g * o[slot] @ wo[e] ----------------
__global__ void oproj_kernel(const float* __restrict__ o, const float* __restrict__ wo,
                             const float* __restrict__ gates, const int* __restrict__ counts,
                             const int* __restrict__ bucket, float* __restrict__ y_att) {
  int e = blockIdx.z;
  int cnt = counts[e];
  int t0 = blockIdx.y * 64;
  if (t0 >= cnt) return;
  int c0 = blockIdx.x * 64;
  int tid = threadIdx.x;
  __shared__ int slots[64];
  __shared__ float gs[64];
  __shared__ __align__(16) float Xt[64][68];   // Xt[d][r] = o[slot r][d]
  __shared__ __align__(16) float Ws[64][68];   // Ws[d][c]
  if (tid < 64) {
    int ii = t0 + tid;
    int s = (ii < cnt) ? bucket[(size_t)e * T + ii] : -1;
    slots[tid] = s;
    gs[tid] = (s >= 0) ? gates[s] : 0.f;
  }
  __syncthreads();
  for (int i2 = tid; i2 < 64 * 64; i2 += 256) {
    int r = i2 >> 6, d = i2 & 63;
    int s = slots[r];
    Xt[d][r] = (s >= 0) ? o[(size_t)s * HD + d] : 0.f;
  }
  for (int i2 = tid; i2 < 64 * 64; i2 += 256) {
    int d = i2 >> 6, c = i2 & 63;
    Ws[d][c] = wo[(size_t)e * HD * C + (size_t)d * C + c0 + c];
  }
  __syncthreads();
  int tr = tid >> 4, tc = tid & 15;
  float acc[4][4] = {};
  #pragma unroll 8
  for (int k = 0; k < 64; ++k) {
    const float4 av = *(const float4*)&Xt[k][tr * 4];
    const float4 bv = *(const float4*)&Ws[k][tc * 4];
    const float af[4] = {av.x, av.y, av.z, av.w};
    const float bf[4] = {bv.x, bv.y, bv.z, bv.w};
    #pragma unroll
    for (int i = 0; i < 4; i++)
      #pragma unroll
      for (int j = 0; j < 4; j++) acc[i][j] += af[i] * bf[j];
  }
  #pragma unroll
  for (int i = 0; i < 4; i++) {
    int s = slots[tr * 4 + i];
    if (s < 0) continue;
    float g = gs[tr * 4 + i];
    size_t base = (size_t)(s >> 3) * C + c0 + tc * 4;
    #pragma unroll
    for (int j = 0; j < 4; j++) atomicAdd(&y_att[base + j], g * acc[i][j]);
  }
}

// ---------------- combine: out = x + y_att ----------------
__global__ void combine_kernel(const float* __restrict__ x, const float* __restrict__ y_att,
                               float* __restrict__ out) {
  size_t i = ((size_t)blockIdx.x * 256 + threadIdx.x) * 4;
  const float4 a = *(const float4*)&x[i];
  const float4 b = *(const float4*)&y_att[i];
  *(float4*)&out[i] = make_float4(a.x + b.x, a.y + b.y, a.z + b.z, a.w + b.w);
}

// ---------------- MLP GEMM1 ----------------
__global__ void mlp1_kernel(const float* __restrict__ x2, const float* __restrict__ wi,
                            const float* __restrict__ bi, const int* __restrict__ counts,
                            const int* __restrict__ bucket, float* __restrict__ h) {
  int e = blockIdx.z;
  int cnt = counts[e];
  int t0 = blockIdx.y * 64;
  if (t0 >= cnt) return;
  int j0 = blockIdx.x * 64;
  int tid = threadIdx.x;
  __shared__ int slots[64];
  __shared__ __align__(16) float Xt[32][68];
  __shared__ __align__(16) float Ws[32][68];
  if (tid < 64) slots[tid] = (t0 + tid < cnt) ? bucket[(size_t)e * T + t0 + tid] : -1;
  __syncthreads();
  int tr = tid >> 4, tc = tid & 15;
  float acc[4][4] = {};
  const float* Wbase = wi + (size_t)e * C * HID + j0;
  for (int kc = 0; kc < C; kc += 32) {
    for (int i2 = tid; i2 < 64 * 32; i2 += 256) {
      int r = i2 >> 5, kk = i2 & 31;
      int s = slots[r];
      Xt[kk][r] = (s >= 0) ? x2[(size_t)(s >> 1) * C + kc + kk] : 0.f;
    }
    for (int i2 = tid; i2 < 32 * 64; i2 += 256) {
      int kk = i2 >> 6, jc = i2 & 63;
      Ws[kk][jc] = Wbase[(size_t)(kc + kk) * HID + jc];
    }
    __syncthreads();
    #pragma unroll 8
    for (int k = 0; k < 32; ++k) {
      const float4 av = *(const float4*)&Xt[k][tr * 4];
      const float4 bv = *(const float4*)&Ws[k][tc * 4];
      const float af[4] = {av.x, av.y, av.z, av.w};
      const float bf[4] = {bv.x, bv.y, bv.z, bv.w};
      #pragma unroll
      for (int i = 0; i < 4; i++)
        #pragma unroll
        for (int j = 0; j < 4; j++) acc[i][j] += af[i] * bf[j];
    }
    __syncthreads();
  }
  for (int i = 0; i < 4; i++) {
    int s = slots[tr * 4 + i];
    if (s < 0) continue;
    for (int j = 0; j < 4; j++) {
      int jj = j0 + tc * 4 + j;
      float v = acc[i][j] + bi[(size_t)e * HID + jj];
      v = 0.5f * v * (1.f + erff(v * 0.70710678118654752f));
      h[(size_t)s * HID + jj] = v;
    }
  }
}

// ---------------- MLP GEMM2 ----------------
__global__ void mlp2_kernel(const float* __restrict__ h, const float* __restrict__ wo,
                            const float* __restrict__ bo, const float* __restrict__ gates2,
                            const int* __restrict__ counts, const int* __restrict__ bucket,
                            float* __restrict__ y2) {
  int e = blockIdx.z;
  int cnt = counts[e];
  int t0 = blockIdx.y * 64;
  if (t0 >= cnt) return;
  int c0 = blockIdx.x * 64;
  int tid = threadIdx.x;
  __shared__ int slots[64];
  __shared__ __align__(16) float Xt[32][68];
  __shared__ __align__(16) float Ws[32][68];
  if (tid < 64) slots[tid] = (t0 + tid < cnt) ? bucket[(size_t)e * T + t0 + tid] : -1;
  __syncthreads();
  int tr = tid >> 4, tc = tid & 15;
  float acc[4][4] = {};
  const float* Wbase = wo + (size_t)e * HID * C + c0;
  for (int kc = 0; kc < HID; kc += 32) {
    for (int i2 = tid; i2 < 64 * 32; i2 += 256) {
      int r = i2 >> 5, kk = i2 & 31;
      int s = slots[r];
      Xt[kk][r] = (s >= 0) ? h[(size_t)s * HID + kc + kk] : 0.f;
    }
    for (int i2 = tid; i2 < 32 * 64; i2 += 256) {
      int kk = i2 >> 6, jc = i2 & 63;
      Ws[kk][jc] = Wbase[(size_t)(kc + kk) * C + jc];
    }
    __syncthreads();
    #pragma unroll 8
    for (int k = 0; k < 32; ++k) {
      const float4 av = *(const float4*)&Xt[k][tr * 4];
      const float4 bv = *(const float4*)&Ws[k][tc * 4];
      const float af[4] = {av.x, av.y, av.z, av.w};
      const float bf[4] = {bv.x, bv.y, bv.z, bv.w};
      #pragma unroll
      for (int i = 0; i < 4; i++)
        #pragma unroll
        for (int j = 0; j < 4; j++) acc[i][j] += af[i] * bf[j];
    }
    __syncthreads();
  }
  for (int i = 0; i < 4; i++) {
    int s = slots[tr * 4 + i];
    if (s < 0) continue;
    float g = gates2[s];
    for (int j = 0; j < 4; j++) {
      int cc = c0 + tc * 4 + j;
      y2[(size_t)s * C + cc] = g * (acc[i][j] + bo[(size_t)e * C + cc]);
    }
  }
}

// ---------------- Final residual add ----------------
__global__ void final_kernel(const float* __restrict__ y2, float* __restrict__ xout) {
  int t = blockIdx.x, tid = threadIdx.x;
  for (int c = tid; c < C; c += 256) {
    xout[(size_t)t * C + c] += y2[(size_t)(t * 2) * C + c] + y2[(size_t)(t * 2 + 1) * C + c];
  }
}

// ---------------- Gating statistics reduction ----------------
template <int E, int K>
__global__ void reduce_gating(const float* __restrict__ probs, const float* __restrict__ lse,
                              const int* __restrict__ idxs, float* __restrict__ psum,
                              float* __restrict__ freq, float* __restrict__ zsum) {
  __shared__ float ps[E];
  __shared__ float fr[E];
  __shared__ float zs;
  int tid = threadIdx.x;
  if (tid < E) { ps[tid] = 0.f; fr[tid] = 0.f; }
  if (tid == 0) zs = 0.f;
  __syncthreads();
  int t = blockIdx.x * 256 + tid;
  if (t < T) {
    for (int e = 0; e < E; e++) atomicAdd(&ps[e], probs[(size_t)t * E + e]);
    for (int k = 0; k < K; k++) atomicAdd(&fr[idxs[(size_t)t * K + k]], 1.f);
    float l = lse[t];
    atomicAdd(&zs, l * l);
  }
  __syncthreads();
  if (tid < E) { atomicAdd(&psum[tid], ps[tid]); atomicAdd(&freq[tid], fr[tid]); }
  if (tid == 0) atomicAdd(zsum, zs);
}

__global__ void loss_kernel(const float* __restrict__ acc, float* __restrict__ out) {
  const float* p1 = acc;      const float* f1 = acc + 24; float z1 = acc[48];
  const float* p2 = acc + 49; const float* f2 = acc + 65; float z2 = acc[81];
  float sp1 = 0.f, sf1 = 0.f;
  for (int e = 0; e < 24; e++) { sp1 += p1[e]; sf1 += f1[e]; }
  float sw1 = 0.f;
  for (int e = 0; e < 24; e++) sw1 += (p1[e] / sp1) * (f1[e] / sf1);
  sw1 *= 24.f;
  float sp2 = 0.f, sf2 = 0.f;
  for (int e = 0; e < 16; e++) { sp2 += p2[e]; sf2 += f2[e]; }
  float sw2 = 0.f;
  for (int e = 0; e < 16; e++) sw2 += (p2[e] / sp2) * (f2[e] / sf2);
  sw2 *= 16.f;
  out[0] = 0.01f * sw1 + 0.001f * (z1 / T) + 0.01f * sw2 + 0.001f * (z2 / T);
}

}  // namespace

extern "C" void kernel_launch(void* const* d_in, const int* in_sizes, int n_in,
                              void* d_out, int out_size, void* d_ws, size_t ws_size,
                              hipStream_t stream) {
  const float* x      = (const float*)d_in[0];
  const int*   task   = (const int*)d_in[1];
  const float* n1g    = (const float*)d_in[2];
  const float* n1b    = (const float*)d_in[3];
  const float* gate_a = (const float*)d_in[4];
  const float* wq     = (const float*)d_in[5];
  const float* wo_a   = (const float*)d_in[6];
  const float* kvw    = (const float*)d_in[7];
  const float* kvb    = (const float*)d_in[8];
  const float* n2g    = (const float*)d_in[9];
  const float* n2b    = (const float*)d_in[10];
  const float* gate_m = (const float*)d_in[11];
  const float* wi     = (const float*)d_in[12];
  const float* bi     = (const float*)d_in[13];
  const float* wo_m   = (const float*)d_in[14];
  const float* bo     = (const float*)d_in[15];
  float* out = (float*)d_out;

  float* ws = (float*)d_ws;
  float* x1     = ws; ws += (size_t)T * C;        // x1 / x2
  float* q      = ws; ws += (size_t)T * KA * HD;  // attn writes o in place
  float* kvo    = ws; ws += (size_t)T * 2 * HD;
  float* y_att  = ws; ws += (size_t)T * C;
  float* probs1 = ws; ws += (size_t)T * EA;
  float* lse1   = ws; ws += T;
  float* gates1 = ws; ws += (size_t)T * KA;
  int*   idx1   = (int*)ws; ws += (size_t)T * KA;
  float* probs2 = ws; ws += (size_t)T * EF;
  float* lse2   = ws; ws += T;
  float* gates2 = ws; ws += (size_t)T * KF;
  int*   idx2   = (int*)ws; ws += (size_t)T * KF;
  float* hbuf   = ws; ws += (size_t)T * KF * HID;
  float* y2buf  = ws; ws += (size_t)T * KF * C;
  int*   bucket_a = (int*)ws; ws += (size_t)EA * T;
  int*   bucket_f = (int*)ws; ws += (size_t)EF * T;
  int*   counts_a = (int*)ws; ws += 32;
  int*   counts_f = (int*)ws; ws += 32;
  float* accum    = ws; ws += 128;   // contiguous with counts_a/counts_f

  hipMemsetAsync(counts_a, 0, (32 + 32 + 128) * sizeof(float), stream);
  hipMemsetAsync(y_att, 0, (size_t)T * C * sizeof(float), stream);

  ln_kernel<<<T, 256, 0, stream>>>(x, n1g, n1b, x1);
  gating_kernel<EA, KA, 8><<<T, 256, 0, stream>>>(x1, gate_a, task, probs1, lse1, gates1, idx1);
  bucket_kernel<<<(T * KA + 255) / 256, 256, 0, stream>>>(idx1, T * KA, counts_a, bucket_a);
  qgemm_kernel<<<dim3(1, 64, EA), 256, 0, stream>>>(x1, wq, counts_a, bucket_a, q);
  kvgemm_kernel<<<dim3(2, 64), 256, 0, stream>>>(x1, kvw, kvb, kvo);
  attn_kernel<<<dim3(NS / 64, KA, NB), 256, 0, stream>>>(q, kvo, q);
  oproj_kernel<<<dim3(C / 64, 64, EA), 256, 0, stream>>>(q, wo_a, gates1, counts_a, bucket_a, y_att);
  combine_kernel<<<(T * C) / 1024, 256, 0, stream>>>(x, y_att, out);
  ln_kernel<<<T, 256, 0, stream>>>(out, n2g, n2b, x1);
  gating_kernel<EF, KF, 16><<<T, 256, 0, stream>>>(x1, gate_m, task, probs2, lse2, gates2, idx2);
  bucket_kernel<<<(T * KF + 255) / 256, 256, 0, stream>>>(idx2, T * KF, counts_f, bucket_f);
  mlp1_kernel<<<dim3(HID / 64, 64, EF), 256, 0, stream>>>(x1, wi, bi, counts_f, bucket_f, hbuf);
  mlp2_kernel<<<dim3(C / 64, 64, EF), 256, 0, stream>>>(hbuf, wo_m, bo, gates2, counts_f, bucket_f, y2buf);
  final_kernel<<<T, 256, 0, stream>>>(y2buf, out);
  reduce_gating<EA, KA><<<16, 256, 0, stream>>>(probs1, lse1, idx1, accum, accum + 24, accum + 48);
  reduce_gating<EF, KF><<<16, 256, 0, stream>>>(probs2, lse2, idx2, accum + 49, accum + 65, accum + 81);
  loss_kernel<<<1, 1, 0, stream>>>(accum, out + (size_t)T * C);
}

// Round 3
// 963.444 us; speedup vs baseline: 1.7723x; 1.3278x over previous
//
#include <hip/hip_runtime.h>
#include <math.h>

namespace {

constexpr int T   = 4096;
constexpr int C   = 512;
constexpr int NB  = 8;
constexpr int NS  = 512;
constexpr int HD  = 64;
constexpr int KA  = 8;
constexpr int EA  = 24;
constexpr int EF  = 16;
constexpr int KF  = 2;
constexpr int HID = 1024;

typedef __attribute__((ext_vector_type(8))) short bf16x8;
typedef __attribute__((ext_vector_type(4))) float f32x4;

__device__ inline unsigned short f2bf(float f) {
  unsigned u = __float_as_uint(f);
  return (unsigned short)((u + 0x7FFFu + ((u >> 16) & 1u)) >> 16);
}

// ---------------- LayerNorm: fp32 + bf16 outputs ----------------
__global__ void ln_kernel(const float* __restrict__ in, const float* __restrict__ g,
                          const float* __restrict__ b, float* __restrict__ out,
                          unsigned short* __restrict__ outb) {
  int t = blockIdx.x, tid = threadIdx.x;
  const float* row = in + (size_t)t * C;
  __shared__ float red[256];
  float v0 = row[tid], v1 = row[tid + 256];
  red[tid] = v0 + v1;
  __syncthreads();
  for (int st = 128; st > 0; st >>= 1) {
    if (tid < st) red[tid] += red[tid + st];
    __syncthreads();
  }
  float mean = red[0] * (1.f / C);
  __syncthreads();
  float d0 = v0 - mean, d1 = v1 - mean;
  red[tid] = d0 * d0 + d1 * d1;
  __syncthreads();
  for (int st = 128; st > 0; st >>= 1) {
    if (tid < st) red[tid] += red[tid + st];
    __syncthreads();
  }
  float r = rsqrtf(red[0] * (1.f / C) + 1e-5f);
  float o0 = d0 * r * g[tid] + b[tid];
  float o1 = d1 * r * g[tid + 256] + b[tid + 256];
  out[(size_t)t * C + tid]       = o0;
  out[(size_t)t * C + tid + 256] = o1;
  outb[(size_t)t * C + tid]       = f2bf(o0);
  outb[(size_t)t * C + tid + 256] = f2bf(o1);
}

// ---------------- Gating ----------------
template <int E, int K, int TPE>
__global__ void gating_kernel(const float* __restrict__ xn, const float* __restrict__ gate_all,
                              const int* __restrict__ task,
                              float* __restrict__ probs, float* __restrict__ lse_out,
                              float* __restrict__ gates, int* __restrict__ idxs) {
  int t = blockIdx.x, tid = threadIdx.x;
  const float* W = gate_all + (size_t)task[0] * C * E;
  __shared__ float xs[C];
  __shared__ float lg[E];
  xs[tid]       = xn[(size_t)t * C + tid];
  xs[tid + 256] = xn[(size_t)t * C + tid + 256];
  __syncthreads();
  if (tid < E * TPE) {
    int e = tid / TPE, l = tid % TPE;
    float acc = 0.f;
    for (int c = l; c < C; c += TPE) acc += xs[c] * W[(size_t)c * E + e];
    #pragma unroll
    for (int m = TPE >> 1; m > 0; m >>= 1) acc += __shfl_xor(acc, m);
    if (l == 0) lg[e] = acc;
  }
  __syncthreads();
  if (tid == 0) {
    float mx = -1e30f;
    for (int e = 0; e < E; e++) mx = fmaxf(mx, lg[e]);
    float p[E], sum = 0.f;
    for (int e = 0; e < E; e++) { p[e] = expf(lg[e] - mx); sum += p[e]; }
    float inv = 1.f / sum;
    for (int e = 0; e < E; e++) { p[e] *= inv; probs[(size_t)t * E + e] = p[e]; }
    lse_out[t] = mx + logf(sum);
    bool used[E] = {};
    float gv[K]; int gi[K]; float gsum = 0.f;
    for (int k = 0; k < K; k++) {
      float best = -1.f; int be = 0;
      for (int e = 0; e < E; e++)
        if (!used[e] && p[e] > best) { best = p[e]; be = e; }
      used[be] = true; gv[k] = best; gi[k] = be; gsum += best;
    }
    float ginv = 1.f / (gsum + 1e-6f);
    for (int k = 0; k < K; k++) {
      gates[(size_t)t * K + k] = gv[k] * ginv;
      idxs[(size_t)t * K + k]  = gi[k];
    }
  }
}

// ---------------- bucket by expert ----------------
__global__ void bucket_kernel(const int* __restrict__ idx, int nslots, int stride,
                              int* counts, int* bucket) {
  int s = blockIdx.x * 256 + threadIdx.x;
  if (s >= nslots) return;
  int e = idx[s];
  int pos = atomicAdd(&counts[e], 1);
  bucket[(size_t)e * stride + pos] = s;
}

// ---------------- flat (expert, tile) maps ----------------
__global__ void build_maps_a(const int* __restrict__ counts, int* __restrict__ maps,
                             int* __restrict__ totals) {
  if (threadIdx.x != 0) return;
  int n = 0;
  for (int e = 0; e < EA; e++) { int c = counts[e]; for (int t0 = 0; t0 < c; t0 += 256) maps[n++] = (e << 16) | t0; }
  totals[0] = n;
  n = 0;
  for (int e = 0; e < EA; e++) { int c = counts[e]; for (int t0 = 0; t0 < c; t0 += 128) maps[256 + n++] = (e << 16) | t0; }
  totals[1] = n;
}
__global__ void build_maps_f(const int* __restrict__ counts, int* __restrict__ maps,
                             int* __restrict__ totals) {
  if (threadIdx.x != 0) return;
  int n = 0;
  for (int e = 0; e < EF; e++) { int c = counts[e]; for (int t0 = 0; t0 < c; t0 += 128) maps[600 + n++] = (e << 16) | t0; }
  totals[2] = n;
}

// ---------------- transpose + cvt weights: [E][K][N] f32 -> [E][N][K] bf16 ----------------
__global__ void tcvt_kernel(const float* __restrict__ src, unsigned short* __restrict__ dst,
                            int K, int N) {
  int e = blockIdx.z;
  int kt = blockIdx.y * 32, nt = blockIdx.x * 32;
  __shared__ float tile[32][33];
  int tid = threadIdx.x;
  const float* S = src + (size_t)e * K * N;
  for (int i = tid; i < 32 * 32; i += 256) {
    int r = i >> 5, c = i & 31;
    tile[r][c] = S[(size_t)(kt + r) * N + nt + c];
  }
  __syncthreads();
  unsigned short* D = dst + (size_t)e * K * N;
  for (int i = tid; i < 32 * 8; i += 256) {
    int n = i >> 3, k4 = (i & 7) * 4;
    ushort4 v;
    v.x = f2bf(tile[k4 + 0][n]); v.y = f2bf(tile[k4 + 1][n]);
    v.z = f2bf(tile[k4 + 2][n]); v.w = f2bf(tile[k4 + 3][n]);
    *(ushort4*)&D[(size_t)(nt + n) * K + kt + k4] = v;
  }
}

// ---------------- MFMA Q GEMM: 256 slots x 64 out, K=512 ----------------
__global__ __launch_bounds__(256) void qgemm_mfma(
    const unsigned short* __restrict__ xb, const unsigned short* __restrict__ wqt,
    const int* __restrict__ bucket, const int* __restrict__ counts,
    const int* __restrict__ map, const int* __restrict__ total,
    float* __restrict__ q) {
  if ((int)blockIdx.y >= *total) return;
  int ent = map[blockIdx.y];
  int e = ent >> 16, t0 = ent & 0xFFFF;
  int cnt = counts[e];
  int tid = threadIdx.x;
  __shared__ int slots[256];
  __shared__ __align__(16) unsigned short Xb[256][72];
  __shared__ __align__(16) unsigned short Wb[64][72];
  {
    int ii = t0 + tid;
    slots[tid] = (ii < cnt) ? bucket[(size_t)e * (T * KA) + ii] : -1;
  }
  __syncthreads();
  int lane = tid & 63, wid = tid >> 6;
  int lr = lane & 15, lk = (lane >> 4) * 8, rowq = (lane >> 4) * 4;
  f32x4 acc[4][4] = {};
  for (int kc = 0; kc < C; kc += 64) {
    __syncthreads();
    #pragma unroll
    for (int it = 0; it < 8; ++it) {
      int i = it * 256 + tid;
      int r = i >> 3, c8 = (i & 7) * 8;
      int s = slots[r];
      uint4 v = make_uint4(0u, 0u, 0u, 0u);
      if (s >= 0) v = *(const uint4*)&xb[(size_t)(s >> 3) * C + kc + c8];
      *(uint4*)&Xb[r][c8] = v;
    }
    #pragma unroll
    for (int it = 0; it < 2; ++it) {
      int i = it * 256 + tid;
      int r = i >> 3, c8 = (i & 7) * 8;
      *(uint4*)&Wb[r][c8] = *(const uint4*)&wqt[((size_t)e * HD + r) * C + kc + c8];
    }
    __syncthreads();
    #pragma unroll
    for (int kk = 0; kk < 64; kk += 32) {
      bf16x8 a[4], b[4];
      #pragma unroll
      for (int nf = 0; nf < 4; nf++) a[nf] = *(const bf16x8*)&Wb[nf * 16 + lr][kk + lk];
      #pragma unroll
      for (int mf = 0; mf < 4; mf++) b[mf] = *(const bf16x8*)&Xb[wid * 64 + mf * 16 + lr][kk + lk];
      #pragma unroll
      for (int nf = 0; nf < 4; nf++)
        #pragma unroll
        for (int mf = 0; mf < 4; mf++)
          acc[nf][mf] = __builtin_amdgcn_mfma_f32_16x16x32_bf16(a[nf], b[mf], acc[nf][mf], 0, 0, 0);
    }
  }
  #pragma unroll
  for (int mf = 0; mf < 4; mf++) {
    int s = slots[wid * 64 + mf * 16 + lr];
    if (s < 0) continue;
    #pragma unroll
    for (int nf = 0; nf < 4; nf++) {
      float4 v = make_float4(acc[nf][mf][0], acc[nf][mf][1], acc[nf][mf][2], acc[nf][mf][3]);
      *(float4*)&q[(size_t)s * HD + nf * 16 + rowq] = v;
    }
  }
}

// ---------------- Dense KV GEMM (fp32, unchanged) ----------------
__global__ void kvgemm_kernel(const float* __restrict__ x1, const float* __restrict__ kvw,
                              const float* __restrict__ kvb, float* __restrict__ kvo) {
  int t0 = blockIdx.y * 64;
  int c0 = blockIdx.x * 64;
  int tid = threadIdx.x;
  __shared__ __align__(16) float Xt[32][68];
  __shared__ __align__(16) float Ws[32][68];
  int tr = tid >> 4, tc = tid & 15;
  float acc[4][4] = {};
  for (int kc = 0; kc < C; kc += 32) {
    for (int i2 = tid; i2 < 64 * 32; i2 += 256) {
      int r = i2 >> 5, kk = i2 & 31;
      Xt[kk][r] = x1[(size_t)(t0 + r) * C + kc + kk];
    }
    for (int i2 = tid; i2 < 32 * 64; i2 += 256) {
      int kk = i2 >> 6, j = i2 & 63;
      Ws[kk][j] = kvw[(size_t)(kc + kk) * 128 + c0 + j];
    }
    __syncthreads();
    #pragma unroll 8
    for (int k = 0; k < 32; ++k) {
      const float4 av = *(const float4*)&Xt[k][tr * 4];
      const float4 bv = *(const float4*)&Ws[k][tc * 4];
      const float af[4] = {av.x, av.y, av.z, av.w};
      const float bf[4] = {bv.x, bv.y, bv.z, bv.w};
      #pragma unroll
      for (int i = 0; i < 4; i++)
        #pragma unroll
        for (int j = 0; j < 4; j++) acc[i][j] += af[i] * bf[j];
    }
    __syncthreads();
  }
  #pragma unroll
  for (int i = 0; i < 4; i++) {
    float4 r4 = make_float4(acc[i][0] + kvb[c0 + tc * 4 + 0],
                            acc[i][1] + kvb[c0 + tc * 4 + 1],
                            acc[i][2] + kvb[c0 + tc * 4 + 2],
                            acc[i][3] + kvb[c0 + tc * 4 + 3]);
    *(float4*)&kvo[(size_t)(t0 + tr * 4 + i) * 128 + c0 + tc * 4] = r4;
  }
}

// ---------------- Flash attention (fp32, unchanged) ----------------
__global__ void attn_kernel(const float* __restrict__ qin, const float* __restrict__ kv,
                            float* __restrict__ o) {
  int qt = blockIdx.x, h = blockIdx.y, b = blockIdx.z;
  int tid = threadIdx.x;
  __shared__ __align__(16) float Qt[64][68];
  __shared__ __align__(16) float Kt[64][68];
  __shared__ __align__(16) float Vs[64][64];
  __shared__ __align__(16) float Pt[64][68];
  int i0 = qt * 64;
  #pragma unroll
  for (int it = 0; it < 4; ++it) {
    int fid = it * 256 + tid;
    int row = fid >> 4, seg = fid & 15;
    const float4 v = *(const float4*)&qin[(((size_t)(b * NS + i0 + row)) * KA + h) * HD + seg * 4];
    Qt[seg * 4 + 0][row] = v.x * 0.125f;
    Qt[seg * 4 + 1][row] = v.y * 0.125f;
    Qt[seg * 4 + 2][row] = v.z * 0.125f;
    Qt[seg * 4 + 3][row] = v.w * 0.125f;
  }
  int tr = tid >> 4, tc = tid & 15;
  float acc[4][4] = {};
  float m_run[4], l_run[4], scl[4];
  #pragma unroll
  for (int i = 0; i < 4; i++) { m_run[i] = -1e30f; l_run[i] = 0.f; }
  const float* KVb = kv + (size_t)b * NS * 128;
  for (int jt = 0; jt < NS / 64; ++jt) {
    __syncthreads();
    #pragma unroll
    for (int it = 0; it < 8; ++it) {
      int fid = it * 256 + tid;
      int row = fid >> 5, seg = fid & 31;
      const float4 v = *(const float4*)&KVb[(size_t)(jt * 64 + row) * 128 + seg * 4];
      if (seg < 16) {
        int d = seg * 4;
        Kt[d + 0][row] = v.x; Kt[d + 1][row] = v.y; Kt[d + 2][row] = v.z; Kt[d + 3][row] = v.w;
      } else {
        *(float4*)&Vs[row][(seg - 16) * 4] = v;
      }
    }
    __syncthreads();
    float s[4][4] = {};
    #pragma unroll 8
    for (int k = 0; k < 64; ++k) {
      const float4 av = *(const float4*)&Qt[k][tr * 4];
      const float4 bv = *(const float4*)&Kt[k][tc * 4];
      const float af[4] = {av.x, av.y, av.z, av.w};
      const float bf[4] = {bv.x, bv.y, bv.z, bv.w};
      #pragma unroll
      for (int i = 0; i < 4; i++)
        #pragma unroll
        for (int j = 0; j < 4; j++) s[i][j] += af[i] * bf[j];
    }
    #pragma unroll
    for (int i = 0; i < 4; i++) {
      float m = fmaxf(fmaxf(s[i][0], s[i][1]), fmaxf(s[i][2], s[i][3]));
      #pragma unroll
      for (int d = 1; d < 16; d <<= 1) m = fmaxf(m, __shfl_xor(m, d));
      float nm = fmaxf(m_run[i], m);
      float sc = expf(m_run[i] - nm);
      m_run[i] = nm;
      float rs = 0.f;
      #pragma unroll
      for (int j = 0; j < 4; j++) { s[i][j] = expf(s[i][j] - nm); rs += s[i][j]; }
      #pragma unroll
      for (int d = 1; d < 16; d <<= 1) rs += __shfl_xor(rs, d);
      l_run[i] = l_run[i] * sc + rs;
      scl[i] = sc;
    }
    #pragma unroll
    for (int j = 0; j < 4; j++) {
      float4 pv = make_float4(s[0][j], s[1][j], s[2][j], s[3][j]);
      *(float4*)&Pt[tc * 4 + j][tr * 4] = pv;
    }
    __syncthreads();
    #pragma unroll
    for (int i = 0; i < 4; i++) {
      acc[i][0] *= scl[i]; acc[i][1] *= scl[i]; acc[i][2] *= scl[i]; acc[i][3] *= scl[i];
    }
    #pragma unroll 8
    for (int k = 0; k < 64; ++k) {
      const float4 av = *(const float4*)&Pt[k][tr * 4];
      const float4 bv = *(const float4*)&Vs[k][tc * 4];
      const float af[4] = {av.x, av.y, av.z, av.w};
      const float bf[4] = {bv.x, bv.y, bv.z, bv.w};
      #pragma unroll
      for (int i = 0; i < 4; i++)
        #pragma unroll
        for (int j = 0; j < 4; j++) acc[i][j] += af[i] * bf[j];
    }
  }
  #pragma unroll
  for (int i = 0; i < 4; i++) {
    float inv = 1.f / l_run[i];
    float4 r4 = make_float4(acc[i][0] * inv, acc[i][1] * inv, acc[i][2] * inv, acc[i][3] * inv);
    *(float4*)&o[(((size_t)(b * NS + i0 + tr * 4 + i)) * KA + h) * HD + tc * 4] = r4;
  }
}

// ---------------- MFMA output proj: 128 slots x 128 cols, K=64 ----------------
__global__ __launch_bounds__(256) void oproj_mfma(
    const float* __restrict__ o, const unsigned short* __restrict__ wot,
    const float* __restrict__ gates, const int* __restrict__ bucket,
    const int* __restrict__ counts, const int* __restrict__ map,
    const int* __restrict__ total, float* __restrict__ y_att) {
  if ((int)blockIdx.y >= *total) return;
  int ent = map[blockIdx.y];
  int e = ent >> 16, t0 = ent & 0xFFFF;
  int c0 = blockIdx.x * 128;
  int cnt = counts[e];
  int tid = threadIdx.x;
  __shared__ int slots[128];
  __shared__ float gs[128];
  __shared__ __align__(16) unsigned short Xb[128][72];
  __shared__ __align__(16) unsigned short Wb[128][72];
  if (tid < 128) {
    int ii = t0 + tid;
    int s = (ii < cnt) ? bucket[(size_t)e * (T * KA) + ii] : -1;
    slots[tid] = s;
    gs[tid] = (s >= 0) ? gates[s] : 0.f;
  }
  __syncthreads();
  #pragma unroll
  for (int it = 0; it < 4; ++it) {
    int i = it * 256 + tid;
    int r = i >> 3, c8 = (i & 7) * 8;
    int s = slots[r];
    ushort4 ua = make_ushort4(0, 0, 0, 0), ub = make_ushort4(0, 0, 0, 0);
    if (s >= 0) {
      float4 f0 = *(const float4*)&o[(size_t)s * HD + c8];
      float4 f1 = *(const float4*)&o[(size_t)s * HD + c8 + 4];
      ua = make_ushort4(f2bf(f0.x), f2bf(f0.y), f2bf(f0.z), f2bf(f0.w));
      ub = make_ushort4(f2bf(f1.x), f2bf(f1.y), f2bf(f1.z), f2bf(f1.w));
    }
    *(ushort4*)&Xb[r][c8]     = ua;
    *(ushort4*)&Xb[r][c8 + 4] = ub;
  }
  #pragma unroll
  for (int it = 0; it < 4; ++it) {
    int i = it * 256 + tid;
    int r = i >> 3, c8 = (i & 7) * 8;
    *(uint4*)&Wb[r][c8] = *(const uint4*)&wot[((size_t)e * C + c0 + r) * HD + c8];
  }
  __syncthreads();
  int lane = tid & 63, wid = tid >> 6;
  int wr = wid & 1, wc = wid >> 1;
  int lr = lane & 15, lk = (lane >> 4) * 8, rowq = (lane >> 4) * 4;
  f32x4 acc[4][4] = {};
  #pragma unroll
  for (int kk = 0; kk < 64; kk += 32) {
    bf16x8 a[4], b[4];
    #pragma unroll
    for (int nf = 0; nf < 4; nf++) a[nf] = *(const bf16x8*)&Wb[wc * 64 + nf * 16 + lr][kk + lk];
    #pragma unroll
    for (int mf = 0; mf < 4; mf++) b[mf] = *(const bf16x8*)&Xb[wr * 64 + mf * 16 + lr][kk + lk];
    #pragma unroll
    for (int nf = 0; nf < 4; nf++)
      #pragma unroll
      for (int mf = 0; mf < 4; mf++)
        acc[nf][mf] = __builtin_amdgcn_mfma_f32_16x16x32_bf16(a[nf], b[mf], acc[nf][mf], 0, 0, 0);
  }
  #pragma unroll
  for (int mf = 0; mf < 4; mf++) {
    int si = wr * 64 + mf * 16 + lr;
    int s = slots[si];
    if (s < 0) continue;
    float g = gs[si];
    size_t base = (size_t)(s >> 3) * C + c0 + wc * 64;
    #pragma unroll
    for (int nf = 0; nf < 4; nf++) {
      size_t p = base + nf * 16 + rowq;
      atomicAdd(&y_att[p + 0], g * acc[nf][mf][0]);
      atomicAdd(&y_att[p + 1], g * acc[nf][mf][1]);
      atomicAdd(&y_att[p + 2], g * acc[nf][mf][2]);
      atomicAdd(&y_att[p + 3], g * acc[nf][mf][3]);
    }
  }
}

// ---------------- combine ----------------
__global__ void combine_kernel(const float* __restrict__ x, const float* __restrict__ y_att,
                               float* __restrict__ out) {
  size_t i = ((size_t)blockIdx.x * 256 + threadIdx.x) * 4;
  const float4 a = *(const float4*)&x[i];
  const float4 b = *(const float4*)&y_att[i];
  *(float4*)&out[i] = make_float4(a.x + b.x, a.y + b.y, a.z + b.z, a.w + b.w);
}

// ---------------- MFMA MLP1: h = gelu(x2 @ wi + bi), bf16 out ----------------
__global__ __launch_bounds__(256) void mlp1_mfma(
    const unsigned short* __restrict__ xb, const unsigned short* __restrict__ wit,
    const float* __restrict__ bi, const int* __restrict__ bucket,
    const int* __restrict__ counts, const int* __restrict__ map,
    const int* __restrict__ total, unsigned short* __restrict__ h) {
  if ((int)blockIdx.y >= *total) return;
  int ent = map[blockIdx.y];
  int e = ent >> 16, t0 = ent & 0xFFFF;
  int j0 = blockIdx.x * 128;
  int cnt = counts[e];
  int tid = threadIdx.x;
  __shared__ int slots[128];
  __shared__ __align__(16) unsigned short Xb[128][72];
  __shared__ __align__(16) unsigned short Wb[128][72];
  if (tid < 128) {
    int ii = t0 + tid;
    slots[tid] = (ii < cnt) ? bucket[(size_t)e * (T * KF) + ii] : -1;
  }
  __syncthreads();
  int lane = tid & 63, wid = tid >> 6;
  int wr = wid & 1, wc = wid >> 1;
  int lr = lane & 15, lk = (lane >> 4) * 8, rowq = (lane >> 4) * 4;
  f32x4 acc[4][4] = {};
  for (int kc = 0; kc < C; kc += 64) {
    __syncthreads();
    #pragma unroll
    for (int it = 0; it < 4; ++it) {
      int i = it * 256 + tid;
      int r = i >> 3, c8 = (i & 7) * 8;
      int s = slots[r];
      uint4 v = make_uint4(0u, 0u, 0u, 0u);
      if (s >= 0) v = *(const uint4*)&xb[(size_t)(s >> 1) * C + kc + c8];
      *(uint4*)&Xb[r][c8] = v;
    }
    #pragma unroll
    for (int it = 0; it < 4; ++it) {
      int i = it * 256 + tid;
      int r = i >> 3, c8 = (i & 7) * 8;
      *(uint4*)&Wb[r][c8] = *(const uint4*)&wit[((size_t)e * HID + j0 + r) * C + kc + c8];
    }
    __syncthreads();
    #pragma unroll
    for (int kk = 0; kk < 64; kk += 32) {
      bf16x8 a[4], b[4];
      #pragma unroll
      for (int nf = 0; nf < 4; nf++) a[nf] = *(const bf16x8*)&Wb[wc * 64 + nf * 16 + lr][kk + lk];
      #pragma unroll
      for (int mf = 0; mf < 4; mf++) b[mf] = *(const bf16x8*)&Xb[wr * 64 + mf * 16 + lr][kk + lk];
      #pragma unroll
      for (int nf = 0; nf < 4; nf++)
        #pragma unroll
        for (int mf = 0; mf < 4; mf++)
          acc[nf][mf] = __builtin_amdgcn_mfma_f32_16x16x32_bf16(a[nf], b[mf], acc[nf][mf], 0, 0, 0);
    }
  }
  #pragma unroll
  for (int mf = 0; mf < 4; mf++) {
    int s = slots[wr * 64 + mf * 16 + lr];
    if (s < 0) continue;
    #pragma unroll
    for (int nf = 0; nf < 4; nf++) {
      int j = j0 + wc * 64 + nf * 16 + rowq;
      const float4 b4 = *(const float4*)&bi[(size_t)e * HID + j];
      float v0 = acc[nf][mf][0] + b4.x, v1 = acc[nf][mf][1] + b4.y;
      float v2 = acc[nf][mf][2] + b4.z, v3 = acc[nf][mf][3] + b4.w;
      v0 = 0.5f * v0 * (1.f + erff(v0 * 0.70710678118654752f));
      v1 = 0.5f * v1 * (1.f + erff(v1 * 0.70710678118654752f));
      v2 = 0.5f * v2 * (1.f + erff(v2 * 0.70710678118654752f));
      v3 = 0.5f * v3 * (1.f + erff(v3 * 0.70710678118654752f));
      *(ushort4*)&h[(size_t)s * HID + j] = make_ushort4(f2bf(v0), f2bf(v1), f2bf(v2), f2bf(v3));
    }
  }
}

// ---------------- MFMA MLP2: out[token] += g*(h @ wo + bo) ----------------
__global__ __launch_bounds__(256) void mlp2_mfma(
    const unsigned short* __restrict__ h, const unsigned short* __restrict__ wot,
    const float* __restrict__ bo, const float* __restrict__ gates2,
    const int* __restrict__ bucket, const int* __restrict__ counts,
    const int* __restrict__ map, const int* __restrict__ total,
    float* __restrict__ out) {
  if ((int)blockIdx.y >= *total) return;
  int ent = map[blockIdx.y];
  int e = ent >> 16, t0 = ent & 0xFFFF;
  int c0 = blockIdx.x * 128;
  int cnt = counts[e];
  int tid = threadIdx.x;
  __shared__ int slots[128];
  __shared__ __align__(16) unsigned short Xb[128][72];
  __shared__ __align__(16) unsigned short Wb[128][72];
  if (tid < 128) {
    int ii = t0 + tid;
    slots[tid] = (ii < cnt) ? bucket[(size_t)e * (T * KF) + ii] : -1;
  }
  __syncthreads();
  int lane = tid & 63, wid = tid >> 6;
  int wr = wid & 1, wc = wid >> 1;
  int lr = lane & 15, lk = (lane >> 4) * 8, rowq = (lane >> 4) * 4;
  f32x4 acc[4][4] = {};
  for (int kc = 0; kc < HID; kc += 64) {
    __syncthreads();
    #pragma unroll
    for (int it = 0; it < 4; ++it) {
      int i = it * 256 + tid;
      int r = i >> 3, c8 = (i & 7) * 8;
      int s = slots[r];
      uint4 v = make_uint4(0u, 0u, 0u, 0u);
      if (s >= 0) v = *(const uint4*)&h[(size_t)s * HID + kc + c8];
      *(uint4*)&Xb[r][c8] = v;
    }
    #pragma unroll
    for (int it = 0; it < 4; ++it) {
      int i = it * 256 + tid;
      int r = i >> 3, c8 = (i & 7) * 8;
      *(uint4*)&Wb[r][c8] = *(const uint4*)&wot[((size_t)e * C + c0 + r) * HID + kc + c8];
    }
    __syncthreads();
    #pragma unroll
    for (int kk = 0; kk < 64; kk += 32) {
      bf16x8 a[4], b[4];
      #pragma unroll
      for (int nf = 0; nf < 4; nf++) a[nf] = *(const bf16x8*)&Wb[wc * 64 + nf * 16 + lr][kk + lk];
      #pragma unroll
      for (int mf = 0; mf < 4; mf++) b[mf] = *(const bf16x8*)&Xb[wr * 64 + mf * 16 + lr][kk + lk];
      #pragma unroll
      for (int nf = 0; nf < 4; nf++)
        #pragma unroll
        for (int mf = 0; mf < 4; mf++)
          acc[nf][mf] = __builtin_amdgcn_mfma_f32_16x16x32_bf16(a[nf], b[mf], acc[nf][mf], 0, 0, 0);
    }
  }
  #pragma unroll
  for (int mf = 0; mf < 4; mf++) {
    int si = wr * 64 + mf * 16 + lr;
    int s = slots[si];
    if (s < 0) continue;
    float g = gates2[s];
    int t = s >> 1;
    #pragma unroll
    for (int nf = 0; nf < 4; nf++) {
      int cc = c0 + wc * 64 + nf * 16 + rowq;
      const float4 b4 = *(const float4*)&bo[(size_t)e * C + cc];
      size_t p = (size_t)t * C + cc;
      atomicAdd(&out[p + 0], g * (acc[nf][mf][0] + b4.x));
      atomicAdd(&out[p + 1], g * (acc[nf][mf][1] + b4.y));
      atomicAdd(&out[p + 2], g * (acc[nf][mf][2] + b4.z));
      atomicAdd(&out[p + 3], g * (acc[nf][mf][3] + b4.w));
    }
  }
}

// ---------------- Gating statistics reduction ----------------
template <int E, int K>
__global__ void reduce_gating(const float* __restrict__ probs, const float* __restrict__ lse,
                              const int* __restrict__ idxs, float* __restrict__ psum,
                              float* __restrict__ freq, float* __restrict__ zsum) {
  __shared__ float ps[E];
  __shared__ float fr[E];
  __shared__ float zs;
  int tid = threadIdx.x;
  if (tid < E) { ps[tid] = 0.f; fr[tid] = 0.f; }
  if (tid == 0) zs = 0.f;
  __syncthreads();
  int t = blockIdx.x * 256 + tid;
  if (t < T) {
    for (int e = 0; e < E; e++) atomicAdd(&ps[e], probs[(size_t)t * E + e]);
    for (int k = 0; k < K; k++) atomicAdd(&fr[idxs[(size_t)t * K + k]], 1.f);
    float l = lse[t];
    atomicAdd(&zs, l * l);
  }
  __syncthreads();
  if (tid < E) { atomicAdd(&psum[tid], ps[tid]); atomicAdd(&freq[tid], fr[tid]); }
  if (tid == 0) atomicAdd(zsum, zs);
}

__global__ void loss_kernel(const float* __restrict__ acc, float* __restrict__ out) {
  const float* p1 = acc;      const float* f1 = acc + 24; float z1 = acc[48];
  const float* p2 = acc + 49; const float* f2 = acc + 65; float z2 = acc[81];
  float sp1 = 0.f, sf1 = 0.f;
  for (int e = 0; e < 24; e++) { sp1 += p1[e]; sf1 += f1[e]; }
  float sw1 = 0.f;
  for (int e = 0; e < 24; e++) sw1 += (p1[e] / sp1) * (f1[e] / sf1);
  sw1 *= 24.f;
  float sp2 = 0.f, sf2 = 0.f;
  for (int e = 0; e < 16; e++) { sp2 += p2[e]; sf2 += f2[e]; }
  float sw2 = 0.f;
  for (int e = 0; e < 16; e++) sw2 += (p2[e] / sp2) * (f2[e] / sf2);
  sw2 *= 16.f;
  out[0] = 0.01f * sw1 + 0.001f * (z1 / T) + 0.01f * sw2 + 0.001f * (z2 / T);
}

}  // namespace

extern "C" void kernel_launch(void* const* d_in, const int* in_sizes, int n_in,
                              void* d_out, int out_size, void* d_ws, size_t ws_size,
                              hipStream_t stream) {
  const float* x      = (const float*)d_in[0];
  const int*   task   = (const int*)d_in[1];
  const float* n1g    = (const float*)d_in[2];
  const float* n1b    = (const float*)d_in[3];
  const float* gate_a = (const float*)d_in[4];
  const float* wq     = (const float*)d_in[5];
  const float* wo_a   = (const float*)d_in[6];
  const float* kvw    = (const float*)d_in[7];
  const float* kvb    = (const float*)d_in[8];
  const float* n2g    = (const float*)d_in[9];
  const float* n2b    = (const float*)d_in[10];
  const float* gate_m = (const float*)d_in[11];
  const float* wi     = (const float*)d_in[12];
  const float* bi     = (const float*)d_in[13];
  const float* wo_m   = (const float*)d_in[14];
  const float* bo     = (const float*)d_in[15];
  float* out = (float*)d_out;

  char* p = (char*)d_ws;
  float* x1 = (float*)p;             p += (size_t)T * C * 4;        // reused as x2
  unsigned short* x1b = (unsigned short*)p; p += (size_t)T * C * 2; // reused as x2b
  float* q = (float*)p;              p += (size_t)T * KA * HD * 4;  // attn o in place
  float* kvo = (float*)p;            p += (size_t)T * 2 * HD * 4;
  float* y_att = (float*)p;          p += (size_t)T * C * 4;
  unsigned short* h = (unsigned short*)p;    p += (size_t)T * KF * HID * 2;
  unsigned short* wqt = (unsigned short*)p;  p += (size_t)EA * C * HD * 2;
  unsigned short* woat = (unsigned short*)p; p += (size_t)EA * HD * C * 2;
  unsigned short* wit = (unsigned short*)p;  p += (size_t)EF * C * HID * 2;
  unsigned short* womt = (unsigned short*)p; p += (size_t)EF * HID * C * 2;
  float* probs1 = (float*)p;         p += (size_t)T * EA * 4;
  float* lse1 = (float*)p;           p += (size_t)T * 4;
  float* gates1 = (float*)p;         p += (size_t)T * KA * 4;
  int* idx1 = (int*)p;               p += (size_t)T * KA * 4;
  float* probs2 = (float*)p;         p += (size_t)T * EF * 4;
  float* lse2 = (float*)p;           p += (size_t)T * 4;
  float* gates2 = (float*)p;         p += (size_t)T * KF * 4;
  int* idx2 = (int*)p;               p += (size_t)T * KF * 4;
  int* bucket_a = (int*)p;           p += (size_t)EA * (T * KA) * 4;
  int* bucket_f = (int*)p;           p += (size_t)EF * (T * KF) * 4;
  int* counts_a = (int*)p;           p += 32 * 4;
  int* counts_f = (int*)p;           p += 32 * 4;
  float* accum = (float*)p;          p += 128 * 4;
  int* maps = (int*)p;               p += 768 * 4;
  int* totals = (int*)p;             p += 4 * 4;

  hipMemsetAsync(counts_a, 0, (32 + 32 + 128) * 4, stream);
  hipMemsetAsync(y_att, 0, (size_t)T * C * 4, stream);

  tcvt_kernel<<<dim3(2, 16, 24), 256, 0, stream>>>(wq, wqt, C, HD);
  tcvt_kernel<<<dim3(16, 2, 24), 256, 0, stream>>>(wo_a, woat, HD, C);
  tcvt_kernel<<<dim3(32, 16, 16), 256, 0, stream>>>(wi, wit, C, HID);
  tcvt_kernel<<<dim3(16, 32, 16), 256, 0, stream>>>(wo_m, womt, HID, C);

  ln_kernel<<<T, 256, 0, stream>>>(x, n1g, n1b, x1, x1b);
  gating_kernel<EA, KA, 8><<<T, 256, 0, stream>>>(x1, gate_a, task, probs1, lse1, gates1, idx1);
  bucket_kernel<<<(T * KA) / 256, 256, 0, stream>>>(idx1, T * KA, T * KA, counts_a, bucket_a);
  build_maps_a<<<1, 64, 0, stream>>>(counts_a, maps, totals);
  qgemm_mfma<<<dim3(1, 152), 256, 0, stream>>>(x1b, wqt, bucket_a, counts_a, maps, totals, q);
  kvgemm_kernel<<<dim3(2, 64), 256, 0, stream>>>(x1, kvw, kvb, kvo);
  attn_kernel<<<dim3(NS / 64, KA, NB), 256, 0, stream>>>(q, kvo, q);
  oproj_mfma<<<dim3(4, 280), 256, 0, stream>>>(q, woat, gates1, bucket_a, counts_a,
                                               maps + 256, totals + 1, y_att);
  combine_kernel<<<(T * C) / 1024, 256, 0, stream>>>(x, y_att, out);
  ln_kernel<<<T, 256, 0, stream>>>(out, n2g, n2b, x1, x1b);
  gating_kernel<EF, KF, 16><<<T, 256, 0, stream>>>(x1, gate_m, task, probs2, lse2, gates2, idx2);
  bucket_kernel<<<(T * KF) / 256, 256, 0, stream>>>(idx2, T * KF, T * KF, counts_f, bucket_f);
  build_maps_f<<<1, 64, 0, stream>>>(counts_f, maps, totals);
  mlp1_mfma<<<dim3(8, 80), 256, 0, stream>>>(x1b, wit, bi, bucket_f, counts_f,
                                             maps + 600, totals + 2, h);
  mlp2_mfma<<<dim3(4, 80), 256, 0, stream>>>(h, womt, bo, gates2, bucket_f, counts_f,
                                             maps + 600, totals + 2, out);
  reduce_gating<EA, KA><<<16, 256, 0, stream>>>(probs1, lse1, idx1, accum, accum + 24, accum + 48);
  reduce_gating<EF, KF><<<16, 256, 0, stream>>>(probs2, lse2, idx2, accum + 49, accum + 65, accum + 81);
  loss_kernel<<<1, 1, 0, stream>>>(accum, out + (size_t)T * C);
}

// Round 4
// 716.525 us; speedup vs baseline: 2.3831x; 1.3446x over previous
//
#include <hip/hip_runtime.h>
#include <math.h>

namespace {

constexpr int T   = 4096;
constexpr int C   = 512;
constexpr int NB  = 8;
constexpr int NS  = 512;
constexpr int HD  = 64;
constexpr int KA  = 8;
constexpr int EA  = 24;
constexpr int EF  = 16;
constexpr int KF  = 2;
constexpr int HID = 1024;

typedef __attribute__((ext_vector_type(8))) short bf16x8;
typedef __attribute__((ext_vector_type(4))) float f32x4;

__device__ inline unsigned short f2bf(float f) {
  unsigned u = __float_as_uint(f);
  return (unsigned short)((u + 0x7FFFu + ((u >> 16) & 1u)) >> 16);
}
__device__ inline float bf2f(unsigned short u) {
  return __uint_as_float((unsigned)u << 16);
}

// ---------------- LayerNorm: fp32 + bf16 outputs ----------------
__global__ void ln_kernel(const float* __restrict__ in, const float* __restrict__ g,
                          const float* __restrict__ b, float* __restrict__ out,
                          unsigned short* __restrict__ outb) {
  int t = blockIdx.x, tid = threadIdx.x;
  const float* row = in + (size_t)t * C;
  __shared__ float red[256];
  float v0 = row[tid], v1 = row[tid + 256];
  red[tid] = v0 + v1;
  __syncthreads();
  for (int st = 128; st > 0; st >>= 1) {
    if (tid < st) red[tid] += red[tid + st];
    __syncthreads();
  }
  float mean = red[0] * (1.f / C);
  __syncthreads();
  float d0 = v0 - mean, d1 = v1 - mean;
  red[tid] = d0 * d0 + d1 * d1;
  __syncthreads();
  for (int st = 128; st > 0; st >>= 1) {
    if (tid < st) red[tid] += red[tid + st];
    __syncthreads();
  }
  float r = rsqrtf(red[0] * (1.f / C) + 1e-5f);
  float o0 = d0 * r * g[tid] + b[tid];
  float o1 = d1 * r * g[tid + 256] + b[tid + 256];
  out[(size_t)t * C + tid]       = o0;
  out[(size_t)t * C + tid + 256] = o1;
  outb[(size_t)t * C + tid]       = f2bf(o0);
  outb[(size_t)t * C + tid + 256] = f2bf(o1);
}

// ---------------- Gating ----------------
template <int E, int K, int TPE>
__global__ void gating_kernel(const float* __restrict__ xn, const float* __restrict__ gate_all,
                              const int* __restrict__ task,
                              float* __restrict__ probs, float* __restrict__ lse_out,
                              float* __restrict__ gates, int* __restrict__ idxs) {
  int t = blockIdx.x, tid = threadIdx.x;
  const float* W = gate_all + (size_t)task[0] * C * E;
  __shared__ float xs[C];
  __shared__ float lg[E];
  xs[tid]       = xn[(size_t)t * C + tid];
  xs[tid + 256] = xn[(size_t)t * C + tid + 256];
  __syncthreads();
  if (tid < E * TPE) {
    int e = tid / TPE, l = tid % TPE;
    float acc = 0.f;
    for (int c = l; c < C; c += TPE) acc += xs[c] * W[(size_t)c * E + e];
    #pragma unroll
    for (int m = TPE >> 1; m > 0; m >>= 1) acc += __shfl_xor(acc, m);
    if (l == 0) lg[e] = acc;
  }
  __syncthreads();
  if (tid == 0) {
    float mx = -1e30f;
    for (int e = 0; e < E; e++) mx = fmaxf(mx, lg[e]);
    float p[E], sum = 0.f;
    for (int e = 0; e < E; e++) { p[e] = expf(lg[e] - mx); sum += p[e]; }
    float inv = 1.f / sum;
    for (int e = 0; e < E; e++) { p[e] *= inv; probs[(size_t)t * E + e] = p[e]; }
    lse_out[t] = mx + logf(sum);
    bool used[E] = {};
    float gv[K]; int gi[K]; float gsum = 0.f;
    for (int k = 0; k < K; k++) {
      float best = -1.f; int be = 0;
      for (int e = 0; e < E; e++)
        if (!used[e] && p[e] > best) { best = p[e]; be = e; }
      used[be] = true; gv[k] = best; gi[k] = be; gsum += best;
    }
    float ginv = 1.f / (gsum + 1e-6f);
    for (int k = 0; k < K; k++) {
      gates[(size_t)t * K + k] = gv[k] * ginv;
      idxs[(size_t)t * K + k]  = gi[k];
    }
  }
}

// ---------------- bucket by expert ----------------
__global__ void bucket_kernel(const int* __restrict__ idx, int nslots, int stride,
                              int* counts, int* bucket) {
  int s = blockIdx.x * 256 + threadIdx.x;
  if (s >= nslots) return;
  int e = idx[s];
  int pos = atomicAdd(&counts[e], 1);
  bucket[(size_t)e * stride + pos] = s;
}

// ---------------- flat (expert, tile) maps ----------------
__global__ void build_maps_a(const int* __restrict__ counts, int* __restrict__ maps,
                             int* __restrict__ totals) {
  if (threadIdx.x != 0) return;
  int n = 0;
  for (int e = 0; e < EA; e++) { int c = counts[e]; for (int t0 = 0; t0 < c; t0 += 256) maps[n++] = (e << 16) | t0; }
  totals[0] = n;
  n = 0;
  for (int e = 0; e < EA; e++) { int c = counts[e]; for (int t0 = 0; t0 < c; t0 += 128) maps[256 + n++] = (e << 16) | t0; }
  totals[1] = n;
}
__global__ void build_maps_f(const int* __restrict__ counts, int* __restrict__ maps,
                             int* __restrict__ totals) {
  if (threadIdx.x != 0) return;
  int n = 0;
  for (int e = 0; e < EF; e++) { int c = counts[e]; for (int t0 = 0; t0 < c; t0 += 128) maps[600 + n++] = (e << 16) | t0; }
  totals[2] = n;
}

// ---------------- transpose + cvt weights: [E][K][N] f32 -> [E][N][K] bf16 ----------------
__global__ void tcvt_kernel(const float* __restrict__ src, unsigned short* __restrict__ dst,
                            int K, int N) {
  int e = blockIdx.z;
  int kt = blockIdx.y * 32, nt = blockIdx.x * 32;
  __shared__ float tile[32][33];
  int tid = threadIdx.x;
  const float* S = src + (size_t)e * K * N;
  for (int i = tid; i < 32 * 32; i += 256) {
    int r = i >> 5, c = i & 31;
    tile[r][c] = S[(size_t)(kt + r) * N + nt + c];
  }
  __syncthreads();
  unsigned short* D = dst + (size_t)e * K * N;
  for (int i = tid; i < 32 * 8; i += 256) {
    int n = i >> 3, k4 = (i & 7) * 4;
    ushort4 v;
    v.x = f2bf(tile[k4 + 0][n]); v.y = f2bf(tile[k4 + 1][n]);
    v.z = f2bf(tile[k4 + 2][n]); v.w = f2bf(tile[k4 + 3][n]);
    *(ushort4*)&D[(size_t)(nt + n) * K + kt + k4] = v;
  }
}

// ---------------- MFMA Q GEMM: 256 slots x 64 out, K=512 ----------------
__global__ __launch_bounds__(256) void qgemm_mfma(
    const unsigned short* __restrict__ xb, const unsigned short* __restrict__ wqt,
    const int* __restrict__ bucket, const int* __restrict__ counts,
    const int* __restrict__ map, const int* __restrict__ total,
    float* __restrict__ q) {
  if ((int)blockIdx.y >= *total) return;
  int ent = map[blockIdx.y];
  int e = ent >> 16, t0 = ent & 0xFFFF;
  int cnt = counts[e];
  int tid = threadIdx.x;
  __shared__ int slots[256];
  __shared__ __align__(16) unsigned short Xb[256][72];
  __shared__ __align__(16) unsigned short Wb[64][72];
  {
    int ii = t0 + tid;
    slots[tid] = (ii < cnt) ? bucket[(size_t)e * (T * KA) + ii] : -1;
  }
  __syncthreads();
  int lane = tid & 63, wid = tid >> 6;
  int lr = lane & 15, lk = (lane >> 4) * 8, rowq = (lane >> 4) * 4;
  f32x4 acc[4][4] = {};
  for (int kc = 0; kc < C; kc += 64) {
    __syncthreads();
    #pragma unroll
    for (int it = 0; it < 8; ++it) {
      int i = it * 256 + tid;
      int r = i >> 3, c8 = (i & 7) * 8;
      int s = slots[r];
      uint4 v = make_uint4(0u, 0u, 0u, 0u);
      if (s >= 0) v = *(const uint4*)&xb[(size_t)(s >> 3) * C + kc + c8];
      *(uint4*)&Xb[r][c8] = v;
    }
    #pragma unroll
    for (int it = 0; it < 2; ++it) {
      int i = it * 256 + tid;
      int r = i >> 3, c8 = (i & 7) * 8;
      *(uint4*)&Wb[r][c8] = *(const uint4*)&wqt[((size_t)e * HD + r) * C + kc + c8];
    }
    __syncthreads();
    #pragma unroll
    for (int kk = 0; kk < 64; kk += 32) {
      bf16x8 a[4], b[4];
      #pragma unroll
      for (int nf = 0; nf < 4; nf++) a[nf] = *(const bf16x8*)&Wb[nf * 16 + lr][kk + lk];
      #pragma unroll
      for (int mf = 0; mf < 4; mf++) b[mf] = *(const bf16x8*)&Xb[wid * 64 + mf * 16 + lr][kk + lk];
      #pragma unroll
      for (int nf = 0; nf < 4; nf++)
        #pragma unroll
        for (int mf = 0; mf < 4; mf++)
          acc[nf][mf] = __builtin_amdgcn_mfma_f32_16x16x32_bf16(a[nf], b[mf], acc[nf][mf], 0, 0, 0);
    }
  }
  #pragma unroll
  for (int mf = 0; mf < 4; mf++) {
    int s = slots[wid * 64 + mf * 16 + lr];
    if (s < 0) continue;
    #pragma unroll
    for (int nf = 0; nf < 4; nf++) {
      float4 v = make_float4(acc[nf][mf][0], acc[nf][mf][1], acc[nf][mf][2], acc[nf][mf][3]);
      *(float4*)&q[(size_t)s * HD + nf * 16 + rowq] = v;
    }
  }
}

// ---------------- Dense KV GEMM (fp32) ----------------
__global__ void kvgemm_kernel(const float* __restrict__ x1, const float* __restrict__ kvw,
                              const float* __restrict__ kvb, float* __restrict__ kvo) {
  int t0 = blockIdx.y * 64;
  int c0 = blockIdx.x * 64;
  int tid = threadIdx.x;
  __shared__ __align__(16) float Xt[32][68];
  __shared__ __align__(16) float Ws[32][68];
  int tr = tid >> 4, tc = tid & 15;
  float acc[4][4] = {};
  for (int kc = 0; kc < C; kc += 32) {
    for (int i2 = tid; i2 < 64 * 32; i2 += 256) {
      int r = i2 >> 5, kk = i2 & 31;
      Xt[kk][r] = x1[(size_t)(t0 + r) * C + kc + kk];
    }
    for (int i2 = tid; i2 < 32 * 64; i2 += 256) {
      int kk = i2 >> 6, j = i2 & 63;
      Ws[kk][j] = kvw[(size_t)(kc + kk) * 128 + c0 + j];
    }
    __syncthreads();
    #pragma unroll 8
    for (int k = 0; k < 32; ++k) {
      const float4 av = *(const float4*)&Xt[k][tr * 4];
      const float4 bv = *(const float4*)&Ws[k][tc * 4];
      const float af[4] = {av.x, av.y, av.z, av.w};
      const float bf[4] = {bv.x, bv.y, bv.z, bv.w};
      #pragma unroll
      for (int i = 0; i < 4; i++)
        #pragma unroll
        for (int j = 0; j < 4; j++) acc[i][j] += af[i] * bf[j];
    }
    __syncthreads();
  }
  #pragma unroll
  for (int i = 0; i < 4; i++) {
    float4 r4 = make_float4(acc[i][0] + kvb[c0 + tc * 4 + 0],
                            acc[i][1] + kvb[c0 + tc * 4 + 1],
                            acc[i][2] + kvb[c0 + tc * 4 + 2],
                            acc[i][3] + kvb[c0 + tc * 4 + 3]);
    *(float4*)&kvo[(size_t)(t0 + tr * 4 + i) * 128 + c0 + tc * 4] = r4;
  }
}

// ---------------- Flash attention (fp32) ----------------
__global__ void attn_kernel(const float* __restrict__ qin, const float* __restrict__ kv,
                            float* __restrict__ o) {
  int qt = blockIdx.x, h = blockIdx.y, b = blockIdx.z;
  int tid = threadIdx.x;
  __shared__ __align__(16) float Qt[64][68];
  __shared__ __align__(16) float Kt[64][68];
  __shared__ __align__(16) float Vs[64][64];
  __shared__ __align__(16) float Pt[64][68];
  int i0 = qt * 64;
  #pragma unroll
  for (int it = 0; it < 4; ++it) {
    int fid = it * 256 + tid;
    int row = fid >> 4, seg = fid & 15;
    const float4 v = *(const float4*)&qin[(((size_t)(b * NS + i0 + row)) * KA + h) * HD + seg * 4];
    Qt[seg * 4 + 0][row] = v.x * 0.125f;
    Qt[seg * 4 + 1][row] = v.y * 0.125f;
    Qt[seg * 4 + 2][row] = v.z * 0.125f;
    Qt[seg * 4 + 3][row] = v.w * 0.125f;
  }
  int tr = tid >> 4, tc = tid & 15;
  float acc[4][4] = {};
  float m_run[4], l_run[4], scl[4];
  #pragma unroll
  for (int i = 0; i < 4; i++) { m_run[i] = -1e30f; l_run[i] = 0.f; }
  const float* KVb = kv + (size_t)b * NS * 128;
  for (int jt = 0; jt < NS / 64; ++jt) {
    __syncthreads();
    #pragma unroll
    for (int it = 0; it < 8; ++it) {
      int fid = it * 256 + tid;
      int row = fid >> 5, seg = fid & 31;
      const float4 v = *(const float4*)&KVb[(size_t)(jt * 64 + row) * 128 + seg * 4];
      if (seg < 16) {
        int d = seg * 4;
        Kt[d + 0][row] = v.x; Kt[d + 1][row] = v.y; Kt[d + 2][row] = v.z; Kt[d + 3][row] = v.w;
      } else {
        *(float4*)&Vs[row][(seg - 16) * 4] = v;
      }
    }
    __syncthreads();
    float s[4][4] = {};
    #pragma unroll 8
    for (int k = 0; k < 64; ++k) {
      const float4 av = *(const float4*)&Qt[k][tr * 4];
      const float4 bv = *(const float4*)&Kt[k][tc * 4];
      const float af[4] = {av.x, av.y, av.z, av.w};
      const float bf[4] = {bv.x, bv.y, bv.z, bv.w};
      #pragma unroll
      for (int i = 0; i < 4; i++)
        #pragma unroll
        for (int j = 0; j < 4; j++) s[i][j] += af[i] * bf[j];
    }
    #pragma unroll
    for (int i = 0; i < 4; i++) {
      float m = fmaxf(fmaxf(s[i][0], s[i][1]), fmaxf(s[i][2], s[i][3]));
      #pragma unroll
      for (int d = 1; d < 16; d <<= 1) m = fmaxf(m, __shfl_xor(m, d));
      float nm = fmaxf(m_run[i], m);
      float sc = expf(m_run[i] - nm);
      m_run[i] = nm;
      float rs = 0.f;
      #pragma unroll
      for (int j = 0; j < 4; j++) { s[i][j] = expf(s[i][j] - nm); rs += s[i][j]; }
      #pragma unroll
      for (int d = 1; d < 16; d <<= 1) rs += __shfl_xor(rs, d);
      l_run[i] = l_run[i] * sc + rs;
      scl[i] = sc;
    }
    #pragma unroll
    for (int j = 0; j < 4; j++) {
      float4 pv = make_float4(s[0][j], s[1][j], s[2][j], s[3][j]);
      *(float4*)&Pt[tc * 4 + j][tr * 4] = pv;
    }
    __syncthreads();
    #pragma unroll
    for (int i = 0; i < 4; i++) {
      acc[i][0] *= scl[i]; acc[i][1] *= scl[i]; acc[i][2] *= scl[i]; acc[i][3] *= scl[i];
    }
    #pragma unroll 8
    for (int k = 0; k < 64; ++k) {
      const float4 av = *(const float4*)&Pt[k][tr * 4];
      const float4 bv = *(const float4*)&Vs[k][tc * 4];
      const float af[4] = {av.x, av.y, av.z, av.w};
      const float bf[4] = {bv.x, bv.y, bv.z, bv.w};
      #pragma unroll
      for (int i = 0; i < 4; i++)
        #pragma unroll
        for (int j = 0; j < 4; j++) acc[i][j] += af[i] * bf[j];
    }
  }
  #pragma unroll
  for (int i = 0; i < 4; i++) {
    float inv = 1.f / l_run[i];
    float4 r4 = make_float4(acc[i][0] * inv, acc[i][1] * inv, acc[i][2] * inv, acc[i][3] * inv);
    *(float4*)&o[(((size_t)(b * NS + i0 + tr * 4 + i)) * KA + h) * HD + tc * 4] = r4;
  }
}

// ---------------- MFMA output proj: dense per-slot bf16 (gate folded), NO atomics ----------------
__global__ __launch_bounds__(256) void oproj_mfma(
    const float* __restrict__ o, const unsigned short* __restrict__ wot,
    const float* __restrict__ gates, const int* __restrict__ bucket,
    const int* __restrict__ counts, const int* __restrict__ map,
    const int* __restrict__ total, unsigned short* __restrict__ y_slot) {
  if ((int)blockIdx.y >= *total) return;
  int ent = map[blockIdx.y];
  int e = ent >> 16, t0 = ent & 0xFFFF;
  int c0 = blockIdx.x * 128;
  int cnt = counts[e];
  int tid = threadIdx.x;
  __shared__ int slots[128];
  __shared__ float gs[128];
  __shared__ __align__(16) unsigned short Xb[128][72];
  __shared__ __align__(16) unsigned short Wb[128][72];
  if (tid < 128) {
    int ii = t0 + tid;
    int s = (ii < cnt) ? bucket[(size_t)e * (T * KA) + ii] : -1;
    slots[tid] = s;
    gs[tid] = (s >= 0) ? gates[s] : 0.f;
  }
  __syncthreads();
  #pragma unroll
  for (int it = 0; it < 4; ++it) {
    int i = it * 256 + tid;
    int r = i >> 3, c8 = (i & 7) * 8;
    int s = slots[r];
    ushort4 ua = make_ushort4(0, 0, 0, 0), ub = make_ushort4(0, 0, 0, 0);
    if (s >= 0) {
      float g = gs[r];
      float4 f0 = *(const float4*)&o[(size_t)s * HD + c8];
      float4 f1 = *(const float4*)&o[(size_t)s * HD + c8 + 4];
      ua = make_ushort4(f2bf(g * f0.x), f2bf(g * f0.y), f2bf(g * f0.z), f2bf(g * f0.w));
      ub = make_ushort4(f2bf(g * f1.x), f2bf(g * f1.y), f2bf(g * f1.z), f2bf(g * f1.w));
    }
    *(ushort4*)&Xb[r][c8]     = ua;
    *(ushort4*)&Xb[r][c8 + 4] = ub;
  }
  #pragma unroll
  for (int it = 0; it < 4; ++it) {
    int i = it * 256 + tid;
    int r = i >> 3, c8 = (i & 7) * 8;
    *(uint4*)&Wb[r][c8] = *(const uint4*)&wot[((size_t)e * C + c0 + r) * HD + c8];
  }
  __syncthreads();
  int lane = tid & 63, wid = tid >> 6;
  int wr = wid & 1, wc = wid >> 1;
  int lr = lane & 15, lk = (lane >> 4) * 8, rowq = (lane >> 4) * 4;
  f32x4 acc[4][4] = {};
  #pragma unroll
  for (int kk = 0; kk < 64; kk += 32) {
    bf16x8 a[4], b[4];
    #pragma unroll
    for (int nf = 0; nf < 4; nf++) a[nf] = *(const bf16x8*)&Wb[wc * 64 + nf * 16 + lr][kk + lk];
    #pragma unroll
    for (int mf = 0; mf < 4; mf++) b[mf] = *(const bf16x8*)&Xb[wr * 64 + mf * 16 + lr][kk + lk];
    #pragma unroll
    for (int nf = 0; nf < 4; nf++)
      #pragma unroll
      for (int mf = 0; mf < 4; mf++)
        acc[nf][mf] = __builtin_amdgcn_mfma_f32_16x16x32_bf16(a[nf], b[mf], acc[nf][mf], 0, 0, 0);
  }
  #pragma unroll
  for (int mf = 0; mf < 4; mf++) {
    int si = wr * 64 + mf * 16 + lr;
    int s = slots[si];
    if (s < 0) continue;
    size_t base = (size_t)s * C + c0 + wc * 64;
    #pragma unroll
    for (int nf = 0; nf < 4; nf++) {
      ushort4 v = make_ushort4(f2bf(acc[nf][mf][0]), f2bf(acc[nf][mf][1]),
                               f2bf(acc[nf][mf][2]), f2bf(acc[nf][mf][3]));
      *(ushort4*)&y_slot[base + nf * 16 + rowq] = v;
    }
  }
}

// ---------------- combine: out = x + sum_k y_slot[t*8+k]  (bf16 in, fp32 out) ----------------
__global__ void combine_kernel(const float* __restrict__ x, const unsigned short* __restrict__ ys,
                               float* __restrict__ out) {
  int t = blockIdx.x, tid = threadIdx.x;
  #pragma unroll
  for (int half = 0; half < 1; ++half) {
    int c = tid * 2;
    float s0 = 0.f, s1 = 0.f;
    #pragma unroll
    for (int k = 0; k < KA; k++) {
      unsigned u = *(const unsigned*)&ys[((size_t)t * KA + k) * C + c];
      s0 += bf2f((unsigned short)(u & 0xFFFF));
      s1 += bf2f((unsigned short)(u >> 16));
    }
    out[(size_t)t * C + c]     = x[(size_t)t * C + c] + s0;
    out[(size_t)t * C + c + 1] = x[(size_t)t * C + c + 1] + s1;
  }
}

// ---------------- MFMA MLP1: h = gelu(x2 @ wi + bi), bf16 out ----------------
__global__ __launch_bounds__(256) void mlp1_mfma(
    const unsigned short* __restrict__ xb, const unsigned short* __restrict__ wit,
    const float* __restrict__ bi, const int* __restrict__ bucket,
    const int* __restrict__ counts, const int* __restrict__ map,
    const int* __restrict__ total, unsigned short* __restrict__ h) {
  if ((int)blockIdx.y >= *total) return;
  int ent = map[blockIdx.y];
  int e = ent >> 16, t0 = ent & 0xFFFF;
  int j0 = blockIdx.x * 128;
  int cnt = counts[e];
  int tid = threadIdx.x;
  __shared__ int slots[128];
  __shared__ __align__(16) unsigned short Xb[128][72];
  __shared__ __align__(16) unsigned short Wb[128][72];
  if (tid < 128) {
    int ii = t0 + tid;
    slots[tid] = (ii < cnt) ? bucket[(size_t)e * (T * KF) + ii] : -1;
  }
  __syncthreads();
  int lane = tid & 63, wid = tid >> 6;
  int wr = wid & 1, wc = wid >> 1;
  int lr = lane & 15, lk = (lane >> 4) * 8, rowq = (lane >> 4) * 4;
  f32x4 acc[4][4] = {};
  for (int kc = 0; kc < C; kc += 64) {
    __syncthreads();
    #pragma unroll
    for (int it = 0; it < 4; ++it) {
      int i = it * 256 + tid;
      int r = i >> 3, c8 = (i & 7) * 8;
      int s = slots[r];
      uint4 v = make_uint4(0u, 0u, 0u, 0u);
      if (s >= 0) v = *(const uint4*)&xb[(size_t)(s >> 1) * C + kc + c8];
      *(uint4*)&Xb[r][c8] = v;
    }
    #pragma unroll
    for (int it = 0; it < 4; ++it) {
      int i = it * 256 + tid;
      int r = i >> 3, c8 = (i & 7) * 8;
      *(uint4*)&Wb[r][c8] = *(const uint4*)&wit[((size_t)e * HID + j0 + r) * C + kc + c8];
    }
    __syncthreads();
    #pragma unroll
    for (int kk = 0; kk < 64; kk += 32) {
      bf16x8 a[4], b[4];
      #pragma unroll
      for (int nf = 0; nf < 4; nf++) a[nf] = *(const bf16x8*)&Wb[wc * 64 + nf * 16 + lr][kk + lk];
      #pragma unroll
      for (int mf = 0; mf < 4; mf++) b[mf] = *(const bf16x8*)&Xb[wr * 64 + mf * 16 + lr][kk + lk];
      #pragma unroll
      for (int nf = 0; nf < 4; nf++)
        #pragma unroll
        for (int mf = 0; mf < 4; mf++)
          acc[nf][mf] = __builtin_amdgcn_mfma_f32_16x16x32_bf16(a[nf], b[mf], acc[nf][mf], 0, 0, 0);
    }
  }
  #pragma unroll
  for (int mf = 0; mf < 4; mf++) {
    int s = slots[wr * 64 + mf * 16 + lr];
    if (s < 0) continue;
    #pragma unroll
    for (int nf = 0; nf < 4; nf++) {
      int j = j0 + wc * 64 + nf * 16 + rowq;
      const float4 b4 = *(const float4*)&bi[(size_t)e * HID + j];
      float v0 = acc[nf][mf][0] + b4.x, v1 = acc[nf][mf][1] + b4.y;
      float v2 = acc[nf][mf][2] + b4.z, v3 = acc[nf][mf][3] + b4.w;
      v0 = 0.5f * v0 * (1.f + erff(v0 * 0.70710678118654752f));
      v1 = 0.5f * v1 * (1.f + erff(v1 * 0.70710678118654752f));
      v2 = 0.5f * v2 * (1.f + erff(v2 * 0.70710678118654752f));
      v3 = 0.5f * v3 * (1.f + erff(v3 * 0.70710678118654752f));
      *(ushort4*)&h[(size_t)s * HID + j] = make_ushort4(f2bf(v0), f2bf(v1), f2bf(v2), f2bf(v3));
    }
  }
}

// ---------------- MFMA MLP2: dense per-slot bf16 (gate+bias folded), NO atomics ----------------
__global__ __launch_bounds__(256) void mlp2_mfma(
    const unsigned short* __restrict__ h, const unsigned short* __restrict__ wot,
    const float* __restrict__ bo, const float* __restrict__ gates2,
    const int* __restrict__ bucket, const int* __restrict__ counts,
    const int* __restrict__ map, const int* __restrict__ total,
    unsigned short* __restrict__ y2) {
  if ((int)blockIdx.y >= *total) return;
  int ent = map[blockIdx.y];
  int e = ent >> 16, t0 = ent & 0xFFFF;
  int c0 = blockIdx.x * 128;
  int cnt = counts[e];
  int tid = threadIdx.x;
  __shared__ int slots[128];
  __shared__ __align__(16) unsigned short Xb[128][72];
  __shared__ __align__(16) unsigned short Wb[128][72];
  if (tid < 128) {
    int ii = t0 + tid;
    slots[tid] = (ii < cnt) ? bucket[(size_t)e * (T * KF) + ii] : -1;
  }
  __syncthreads();
  int lane = tid & 63, wid = tid >> 6;
  int wr = wid & 1, wc = wid >> 1;
  int lr = lane & 15, lk = (lane >> 4) * 8, rowq = (lane >> 4) * 4;
  f32x4 acc[4][4] = {};
  for (int kc = 0; kc < HID; kc += 64) {
    __syncthreads();
    #pragma unroll
    for (int it = 0; it < 4; ++it) {
      int i = it * 256 + tid;
      int r = i >> 3, c8 = (i & 7) * 8;
      int s = slots[r];
      uint4 v = make_uint4(0u, 0u, 0u, 0u);
      if (s >= 0) v = *(const uint4*)&h[(size_t)s * HID + kc + c8];
      *(uint4*)&Xb[r][c8] = v;
    }
    #pragma unroll
    for (int it = 0; it < 4; ++it) {
      int i = it * 256 + tid;
      int r = i >> 3, c8 = (i & 7) * 8;
      *(uint4*)&Wb[r][c8] = *(const uint4*)&wot[((size_t)e * C + c0 + r) * HID + kc + c8];
    }
    __syncthreads();
    #pragma unroll
    for (int kk = 0; kk < 64; kk += 32) {
      bf16x8 a[4], b[4];
      #pragma unroll
      for (int nf = 0; nf < 4; nf++) a[nf] = *(const bf16x8*)&Wb[wc * 64 + nf * 16 + lr][kk + lk];
      #pragma unroll
      for (int mf = 0; mf < 4; mf++) b[mf] = *(const bf16x8*)&Xb[wr * 64 + mf * 16 + lr][kk + lk];
      #pragma unroll
      for (int nf = 0; nf < 4; nf++)
        #pragma unroll
        for (int mf = 0; mf < 4; mf++)
          acc[nf][mf] = __builtin_amdgcn_mfma_f32_16x16x32_bf16(a[nf], b[mf], acc[nf][mf], 0, 0, 0);
    }
  }
  #pragma unroll
  for (int mf = 0; mf < 4; mf++) {
    int si = wr * 64 + mf * 16 + lr;
    int s = slots[si];
    if (s < 0) continue;
    float g = gates2[s];
    #pragma unroll
    for (int nf = 0; nf < 4; nf++) {
      int cc = c0 + wc * 64 + nf * 16 + rowq;
      const float4 b4 = *(const float4*)&bo[(size_t)e * C + cc];
      ushort4 v = make_ushort4(f2bf(g * (acc[nf][mf][0] + b4.x)),
                               f2bf(g * (acc[nf][mf][1] + b4.y)),
                               f2bf(g * (acc[nf][mf][2] + b4.z)),
                               f2bf(g * (acc[nf][mf][3] + b4.w)));
      *(ushort4*)&y2[(size_t)s * C + cc] = v;
    }
  }
}

// ---------------- Final residual add (bf16 slots) ----------------
__global__ void final_kernel(const unsigned short* __restrict__ y2, float* __restrict__ xout) {
  int t = blockIdx.x, tid = threadIdx.x;
  int c = tid * 2;
  unsigned u0 = *(const unsigned*)&y2[(size_t)(t * 2) * C + c];
  unsigned u1 = *(const unsigned*)&y2[(size_t)(t * 2 + 1) * C + c];
  xout[(size_t)t * C + c]     += bf2f((unsigned short)(u0 & 0xFFFF)) + bf2f((unsigned short)(u1 & 0xFFFF));
  xout[(size_t)t * C + c + 1] += bf2f((unsigned short)(u0 >> 16)) + bf2f((unsigned short)(u1 >> 16));
}

// ---------------- Gating statistics reduction ----------------
template <int E, int K>
__global__ void reduce_gating(const float* __restrict__ probs, const float* __restrict__ lse,
                              const int* __restrict__ idxs, float* __restrict__ psum,
                              float* __restrict__ freq, float* __restrict__ zsum) {
  __shared__ float ps[E];
  __shared__ float fr[E];
  __shared__ float zs;
  int tid = threadIdx.x;
  if (tid < E) { ps[tid] = 0.f; fr[tid] = 0.f; }
  if (tid == 0) zs = 0.f;
  __syncthreads();
  int t = blockIdx.x * 256 + tid;
  if (t < T) {
    for (int e = 0; e < E; e++) atomicAdd(&ps[e], probs[(size_t)t * E + e]);
    for (int k = 0; k < K; k++) atomicAdd(&fr[idxs[(size_t)t * K + k]], 1.f);
    float l = lse[t];
    atomicAdd(&zs, l * l);
  }
  __syncthreads();
  if (tid < E) { atomicAdd(&psum[tid], ps[tid]); atomicAdd(&freq[tid], fr[tid]); }
  if (tid == 0) atomicAdd(zsum, zs);
}

__global__ void loss_kernel(const float* __restrict__ acc, float* __restrict__ out) {
  const float* p1 = acc;      const float* f1 = acc + 24; float z1 = acc[48];
  const float* p2 = acc + 49; const float* f2 = acc + 65; float z2 = acc[81];
  float sp1 = 0.f, sf1 = 0.f;
  for (int e = 0; e < 24; e++) { sp1 += p1[e]; sf1 += f1[e]; }
  float sw1 = 0.f;
  for (int e = 0; e < 24; e++) sw1 += (p1[e] / sp1) * (f1[e] / sf1);
  sw1 *= 24.f;
  float sp2 = 0.f, sf2 = 0.f;
  for (int e = 0; e < 16; e++) { sp2 += p2[e]; sf2 += f2[e]; }
  float sw2 = 0.f;
  for (int e = 0; e < 16; e++) sw2 += (p2[e] / sp2) * (f2[e] / sf2);
  sw2 *= 16.f;
  out[0] = 0.01f * sw1 + 0.001f * (z1 / T) + 0.01f * sw2 + 0.001f * (z2 / T);
}

}  // namespace

extern "C" void kernel_launch(void* const* d_in, const int* in_sizes, int n_in,
                              void* d_out, int out_size, void* d_ws, size_t ws_size,
                              hipStream_t stream) {
  const float* x      = (const float*)d_in[0];
  const int*   task   = (const int*)d_in[1];
  const float* n1g    = (const float*)d_in[2];
  const float* n1b    = (const float*)d_in[3];
  const float* gate_a = (const float*)d_in[4];
  const float* wq     = (const float*)d_in[5];
  const float* wo_a   = (const float*)d_in[6];
  const float* kvw    = (const float*)d_in[7];
  const float* kvb    = (const float*)d_in[8];
  const float* n2g    = (const float*)d_in[9];
  const float* n2b    = (const float*)d_in[10];
  const float* gate_m = (const float*)d_in[11];
  const float* wi     = (const float*)d_in[12];
  const float* bi     = (const float*)d_in[13];
  const float* wo_m   = (const float*)d_in[14];
  const float* bo     = (const float*)d_in[15];
  float* out = (float*)d_out;

  char* p = (char*)d_ws;
  float* x1 = (float*)p;             p += (size_t)T * C * 4;
  unsigned short* x1b = (unsigned short*)p; p += (size_t)T * C * 2;
  float* q = (float*)p;              p += (size_t)T * KA * HD * 4;  // attn o in place
  float* kvo = (float*)p;            p += (size_t)T * 2 * HD * 4;
  // union region: y_slot (33.5MB) then reused as h (16.8MB) + y2_slot (8.4MB)
  char* un = p;                      p += (size_t)T * KA * C * 2;
  unsigned short* y_slot  = (unsigned short*)un;
  unsigned short* h       = (unsigned short*)un;
  unsigned short* y2_slot = (unsigned short*)(un + (size_t)T * KF * HID * 2);
  unsigned short* wqt = (unsigned short*)p;  p += (size_t)EA * C * HD * 2;
  unsigned short* woat = (unsigned short*)p; p += (size_t)EA * HD * C * 2;
  unsigned short* wit = (unsigned short*)p;  p += (size_t)EF * C * HID * 2;
  unsigned short* womt = (unsigned short*)p; p += (size_t)EF * HID * C * 2;
  float* probs1 = (float*)p;         p += (size_t)T * EA * 4;
  float* lse1 = (float*)p;           p += (size_t)T * 4;
  float* gates1 = (float*)p;         p += (size_t)T * KA * 4;
  int* idx1 = (int*)p;               p += (size_t)T * KA * 4;
  float* probs2 = (float*)p;         p += (size_t)T * EF * 4;
  float* lse2 = (float*)p;           p += (size_t)T * 4;
  float* gates2 = (float*)p;         p += (size_t)T * KF * 4;
  int* idx2 = (int*)p;               p += (size_t)T * KF * 4;
  int* bucket_a = (int*)p;           p += (size_t)EA * (T * KA) * 4;
  int* bucket_f = (int*)p;           p += (size_t)EF * (T * KF) * 4;
  int* counts_a = (int*)p;           p += 32 * 4;
  int* counts_f = (int*)p;           p += 32 * 4;
  float* accum = (float*)p;          p += 128 * 4;
  int* maps = (int*)p;               p += 768 * 4;
  int* totals = (int*)p;             p += 4 * 4;

  hipMemsetAsync(counts_a, 0, (32 + 32 + 128) * 4, stream);

  tcvt_kernel<<<dim3(2, 16, 24), 256, 0, stream>>>(wq, wqt, C, HD);
  tcvt_kernel<<<dim3(16, 2, 24), 256, 0, stream>>>(wo_a, woat, HD, C);
  tcvt_kernel<<<dim3(32, 16, 16), 256, 0, stream>>>(wi, wit, C, HID);
  tcvt_kernel<<<dim3(16, 32, 16), 256, 0, stream>>>(wo_m, womt, HID, C);

  ln_kernel<<<T, 256, 0, stream>>>(x, n1g, n1b, x1, x1b);
  gating_kernel<EA, KA, 8><<<T, 256, 0, stream>>>(x1, gate_a, task, probs1, lse1, gates1, idx1);
  bucket_kernel<<<(T * KA) / 256, 256, 0, stream>>>(idx1, T * KA, T * KA, counts_a, bucket_a);
  build_maps_a<<<1, 64, 0, stream>>>(counts_a, maps, totals);
  qgemm_mfma<<<dim3(1, 152), 256, 0, stream>>>(x1b, wqt, bucket_a, counts_a, maps, totals, q);
  kvgemm_kernel<<<dim3(2, 64), 256, 0, stream>>>(x1, kvw, kvb, kvo);
  attn_kernel<<<dim3(NS / 64, KA, NB), 256, 0, stream>>>(q, kvo, q);
  oproj_mfma<<<dim3(4, 280), 256, 0, stream>>>(q, woat, gates1, bucket_a, counts_a,
                                               maps + 256, totals + 1, y_slot);
  combine_kernel<<<T, 256, 0, stream>>>(x, y_slot, out);
  ln_kernel<<<T, 256, 0, stream>>>(out, n2g, n2b, x1, x1b);
  gating_kernel<EF, KF, 16><<<T, 256, 0, stream>>>(x1, gate_m, task, probs2, lse2, gates2, idx2);
  bucket_kernel<<<(T * KF) / 256, 256, 0, stream>>>(idx2, T * KF, T * KF, counts_f, bucket_f);
  build_maps_f<<<1, 64, 0, stream>>>(counts_f, maps, totals);
  mlp1_mfma<<<dim3(8, 80), 256, 0, stream>>>(x1b, wit, bi, bucket_f, counts_f,
                                             maps + 600, totals + 2, h);
  mlp2_mfma<<<dim3(4, 80), 256, 0, stream>>>(h, womt, bo, gates2, bucket_f, counts_f,
                                             maps + 600, totals + 2, y2_slot);
  final_kernel<<<T, 256, 0, stream>>>(y2_slot, out);
  reduce_gating<EA, KA><<<16, 256, 0, stream>>>(probs1, lse1, idx1, accum, accum + 24, accum + 48);
  reduce_gating<EF, KF><<<16, 256, 0, stream>>>(probs2, lse2, idx2, accum + 49, accum + 65, accum + 81);
  loss_kernel<<<1, 1, 0, stream>>>(accum, out + (size_t)T * C);
}

// Round 5
// 615.294 us; speedup vs baseline: 2.7751x; 1.1645x over previous
//
#include <hip/hip_runtime.h>
#include <math.h>

namespace {

constexpr int T   = 4096;
constexpr int C   = 512;
constexpr int NB  = 8;
constexpr int NS  = 512;
constexpr int HD  = 64;
constexpr int KA  = 8;
constexpr int EA  = 24;
constexpr int EF  = 16;
constexpr int KF  = 2;
constexpr int HID = 1024;

typedef __attribute__((ext_vector_type(8))) short bf16x8;
typedef __attribute__((ext_vector_type(4))) float f32x4;

__device__ inline unsigned short f2bf(float f) {
  unsigned u = __float_as_uint(f);
  return (unsigned short)((u + 0x7FFFu + ((u >> 16) & 1u)) >> 16);
}
__device__ inline float bf2f(unsigned short u) {
  return __uint_as_float((unsigned)u << 16);
}

// ---------------- LayerNorm: fp32 + bf16 outputs ----------------
__global__ void ln_kernel(const float* __restrict__ in, const float* __restrict__ g,
                          const float* __restrict__ b, float* __restrict__ out,
                          unsigned short* __restrict__ outb) {
  int t = blockIdx.x, tid = threadIdx.x;
  const float* row = in + (size_t)t * C;
  __shared__ float red[256];
  float v0 = row[tid], v1 = row[tid + 256];
  red[tid] = v0 + v1;
  __syncthreads();
  for (int st = 128; st > 0; st >>= 1) {
    if (tid < st) red[tid] += red[tid + st];
    __syncthreads();
  }
  float mean = red[0] * (1.f / C);
  __syncthreads();
  float d0 = v0 - mean, d1 = v1 - mean;
  red[tid] = d0 * d0 + d1 * d1;
  __syncthreads();
  for (int st = 128; st > 0; st >>= 1) {
    if (tid < st) red[tid] += red[tid + st];
    __syncthreads();
  }
  float r = rsqrtf(red[0] * (1.f / C) + 1e-5f);
  float o0 = d0 * r * g[tid] + b[tid];
  float o1 = d1 * r * g[tid + 256] + b[tid + 256];
  out[(size_t)t * C + tid]       = o0;
  out[(size_t)t * C + tid + 256] = o1;
  outb[(size_t)t * C + tid]       = f2bf(o0);
  outb[(size_t)t * C + tid + 256] = f2bf(o1);
}

// ---------------- Gating: logits via waves, softmax+topk via one wave ----------------
template <int E, int K, int TPE>
__global__ void gating_kernel(const float* __restrict__ xn, const float* __restrict__ gate_all,
                              const int* __restrict__ task,
                              float* __restrict__ probs, float* __restrict__ lse_out,
                              float* __restrict__ gates, int* __restrict__ idxs) {
  int t = blockIdx.x, tid = threadIdx.x;
  const float* W = gate_all + (size_t)task[0] * C * E;
  __shared__ float xs[C];
  __shared__ float lg[E];
  xs[tid]       = xn[(size_t)t * C + tid];
  xs[tid + 256] = xn[(size_t)t * C + tid + 256];
  __syncthreads();
  if (tid < E * TPE) {
    int e = tid / TPE, l = tid % TPE;
    float acc = 0.f;
    for (int c = l; c < C; c += TPE) acc += xs[c] * W[(size_t)c * E + e];
    #pragma unroll
    for (int m = TPE >> 1; m > 0; m >>= 1) acc += __shfl_xor(acc, m);
    if (l == 0) lg[e] = acc;
  }
  __syncthreads();
  if (tid < 64) {
    float lgv = (tid < E) ? lg[tid] : -3.0e38f;
    float mx = lgv;
    #pragma unroll
    for (int m = 1; m < 64; m <<= 1) mx = fmaxf(mx, __shfl_xor(mx, m));
    float pe = (tid < E) ? expf(lgv - mx) : 0.f;
    float sum = pe;
    #pragma unroll
    for (int m = 1; m < 64; m <<= 1) sum += __shfl_xor(sum, m);
    float inv = 1.f / sum;
    float prob = pe * inv;
    if (tid < E) probs[(size_t)t * E + tid] = prob;
    if (tid == 0) lse_out[t] = mx + logf(sum);
    // iterative top-K with lax.top_k tie-break (strict >, lowest index wins)
    float pv = (tid < E) ? prob : -1.f;
    float gsum = 0.f, myv = 0.f; int myi = 0;
    for (int k = 0; k < K; k++) {
      float bv = pv; int bi_ = tid;
      #pragma unroll
      for (int m = 1; m < 64; m <<= 1) {
        float ov = __shfl_xor(bv, m); int oi = __shfl_xor(bi_, m);
        if (ov > bv || (ov == bv && oi < bi_)) { bv = ov; bi_ = oi; }
      }
      gsum += bv;
      if (tid == k) { myv = bv; myi = bi_; }
      if (tid == bi_) pv = -1.f;
    }
    if (tid < K) {
      float ginv = 1.f / (gsum + 1e-6f);
      gates[(size_t)t * K + tid] = myv * ginv;
      idxs[(size_t)t * K + tid]  = myi;
    }
  }
}

// ---------------- bucket by expert ----------------
__global__ void bucket_kernel(const int* __restrict__ idx, int nslots, int stride,
                              int* counts, int* bucket) {
  int s = blockIdx.x * 256 + threadIdx.x;
  if (s >= nslots) return;
  int e = idx[s];
  int pos = atomicAdd(&counts[e], 1);
  bucket[(size_t)e * stride + pos] = s;
}

// ---------------- flat (expert, tile) maps ----------------
__global__ void build_maps_a(const int* __restrict__ counts, int* __restrict__ maps,
                             int* __restrict__ totals) {
  if (threadIdx.x != 0) return;
  int n = 0;
  for (int e = 0; e < EA; e++) { int c = counts[e]; for (int t0 = 0; t0 < c; t0 += 256) maps[n++] = (e << 16) | t0; }
  totals[0] = n;
  n = 0;
  for (int e = 0; e < EA; e++) { int c = counts[e]; for (int t0 = 0; t0 < c; t0 += 128) maps[256 + n++] = (e << 16) | t0; }
  totals[1] = n;
}
__global__ void build_maps_f(const int* __restrict__ counts, int* __restrict__ maps,
                             int* __restrict__ totals) {
  if (threadIdx.x != 0) return;
  int n = 0;
  for (int e = 0; e < EF; e++) { int c = counts[e]; for (int t0 = 0; t0 < c; t0 += 128) maps[600 + n++] = (e << 16) | t0; }
  totals[2] = n;
}

// ---------------- transpose + cvt weights: [E][K][N] f32 -> [E][N][K] bf16 ----------------
__global__ void tcvt_kernel(const float* __restrict__ src, unsigned short* __restrict__ dst,
                            int K, int N) {
  int e = blockIdx.z;
  int kt = blockIdx.y * 32, nt = blockIdx.x * 32;
  __shared__ float tile[32][33];
  int tid = threadIdx.x;
  const float* S = src + (size_t)e * K * N;
  for (int i = tid; i < 32 * 32; i += 256) {
    int r = i >> 5, c = i & 31;
    tile[r][c] = S[(size_t)(kt + r) * N + nt + c];
  }
  __syncthreads();
  unsigned short* D = dst + (size_t)e * K * N;
  for (int i = tid; i < 32 * 8; i += 256) {
    int n = i >> 3, k4 = (i & 7) * 4;
    ushort4 v;
    v.x = f2bf(tile[k4 + 0][n]); v.y = f2bf(tile[k4 + 1][n]);
    v.z = f2bf(tile[k4 + 2][n]); v.w = f2bf(tile[k4 + 3][n]);
    *(ushort4*)&D[(size_t)(nt + n) * K + kt + k4] = v;
  }
}

// ---------------- MFMA Q GEMM: 256 slots x 64 out, K=512 -> bf16 q (pre-scaled) ----------------
__global__ __launch_bounds__(256) void qgemm_mfma(
    const unsigned short* __restrict__ xb, const unsigned short* __restrict__ wqt,
    const int* __restrict__ bucket, const int* __restrict__ counts,
    const int* __restrict__ map, const int* __restrict__ total,
    unsigned short* __restrict__ qb) {
  if ((int)blockIdx.y >= *total) return;
  int ent = map[blockIdx.y];
  int e = ent >> 16, t0 = ent & 0xFFFF;
  int cnt = counts[e];
  int tid = threadIdx.x;
  __shared__ int slots[256];
  __shared__ __align__(16) unsigned short Xb[256][72];
  __shared__ __align__(16) unsigned short Wb[64][72];
  {
    int ii = t0 + tid;
    slots[tid] = (ii < cnt) ? bucket[(size_t)e * (T * KA) + ii] : -1;
  }
  __syncthreads();
  int lane = tid & 63, wid = tid >> 6;
  int lr = lane & 15, lk = (lane >> 4) * 8, rowq = (lane >> 4) * 4;
  f32x4 acc[4][4] = {};
  for (int kc = 0; kc < C; kc += 64) {
    __syncthreads();
    #pragma unroll
    for (int it = 0; it < 8; ++it) {
      int i = it * 256 + tid;
      int r = i >> 3, c8 = (i & 7) * 8;
      int s = slots[r];
      uint4 v = make_uint4(0u, 0u, 0u, 0u);
      if (s >= 0) v = *(const uint4*)&xb[(size_t)(s >> 3) * C + kc + c8];
      *(uint4*)&Xb[r][c8] = v;
    }
    #pragma unroll
    for (int it = 0; it < 2; ++it) {
      int i = it * 256 + tid;
      int r = i >> 3, c8 = (i & 7) * 8;
      *(uint4*)&Wb[r][c8] = *(const uint4*)&wqt[((size_t)e * HD + r) * C + kc + c8];
    }
    __syncthreads();
    #pragma unroll
    for (int kk = 0; kk < 64; kk += 32) {
      bf16x8 a[4], b[4];
      #pragma unroll
      for (int nf = 0; nf < 4; nf++) a[nf] = *(const bf16x8*)&Wb[nf * 16 + lr][kk + lk];
      #pragma unroll
      for (int mf = 0; mf < 4; mf++) b[mf] = *(const bf16x8*)&Xb[wid * 64 + mf * 16 + lr][kk + lk];
      #pragma unroll
      for (int nf = 0; nf < 4; nf++)
        #pragma unroll
        for (int mf = 0; mf < 4; mf++)
          acc[nf][mf] = __builtin_amdgcn_mfma_f32_16x16x32_bf16(a[nf], b[mf], acc[nf][mf], 0, 0, 0);
    }
  }
  #pragma unroll
  for (int mf = 0; mf < 4; mf++) {
    int s = slots[wid * 64 + mf * 16 + lr];
    if (s < 0) continue;
    #pragma unroll
    for (int nf = 0; nf < 4; nf++) {
      ushort4 v = make_ushort4(f2bf(0.125f * acc[nf][mf][0]), f2bf(0.125f * acc[nf][mf][1]),
                               f2bf(0.125f * acc[nf][mf][2]), f2bf(0.125f * acc[nf][mf][3]));
      *(ushort4*)&qb[(size_t)s * HD + nf * 16 + rowq] = v;
    }
  }
}

// ---------------- Dense KV GEMM (fp32 math) -> bf16 K [b][j][64] + bf16 V^T [b][d][512] ----------------
__global__ void kvgemm_kernel(const float* __restrict__ x1, const float* __restrict__ kvw,
                              const float* __restrict__ kvb, unsigned short* __restrict__ Kb,
                              unsigned short* __restrict__ Vt) {
  int t0 = blockIdx.y * 64;
  int c0 = blockIdx.x * 64;
  int tid = threadIdx.x;
  __shared__ __align__(16) float Xt[32][68];
  __shared__ __align__(16) float Ws[32][68];
  int tr = tid >> 4, tc = tid & 15;
  float acc[4][4] = {};
  for (int kc = 0; kc < C; kc += 32) {
    for (int i2 = tid; i2 < 64 * 32; i2 += 256) {
      int r = i2 >> 5, kk = i2 & 31;
      Xt[kk][r] = x1[(size_t)(t0 + r) * C + kc + kk];
    }
    for (int i2 = tid; i2 < 32 * 64; i2 += 256) {
      int kk = i2 >> 6, j = i2 & 63;
      Ws[kk][j] = kvw[(size_t)(kc + kk) * 128 + c0 + j];
    }
    __syncthreads();
    #pragma unroll 8
    for (int k = 0; k < 32; ++k) {
      const float4 av = *(const float4*)&Xt[k][tr * 4];
      const float4 bv = *(const float4*)&Ws[k][tc * 4];
      const float af[4] = {av.x, av.y, av.z, av.w};
      const float bf[4] = {bv.x, bv.y, bv.z, bv.w};
      #pragma unroll
      for (int i = 0; i < 4; i++)
        #pragma unroll
        for (int j = 0; j < 4; j++) acc[i][j] += af[i] * bf[j];
    }
    __syncthreads();
  }
  if (c0 == 0) {
    #pragma unroll
    for (int i = 0; i < 4; i++) {
      int t = t0 + tr * 4 + i;
      ushort4 v = make_ushort4(f2bf(acc[i][0] + kvb[tc * 4 + 0]),
                               f2bf(acc[i][1] + kvb[tc * 4 + 1]),
                               f2bf(acc[i][2] + kvb[tc * 4 + 2]),
                               f2bf(acc[i][3] + kvb[tc * 4 + 3]));
      *(ushort4*)&Kb[(size_t)t * HD + tc * 4] = v;
    }
  } else {
    int bb = t0 >> 9;
    #pragma unroll
    for (int i = 0; i < 4; i++) {
      int n = (t0 + tr * 4 + i) & (NS - 1);
      #pragma unroll
      for (int j = 0; j < 4; j++) {
        int d = tc * 4 + j;
        Vt[((size_t)bb * HD + d) * NS + n] = f2bf(acc[i][j] + kvb[64 + d]);
      }
    }
  }
}

// ---------------- MFMA flash attention: block per (qtile64, head, batch) ----------------
// Per wave: 16 q rows. S = mfma(K,Q) -> col=q,row=k (softmax mostly lane-local).
// P -> LDS bf16 [q][k]; PV = mfma(V^T, P) -> col=q,row=d.
__global__ __launch_bounds__(256) void attn_mfma(
    const unsigned short* __restrict__ qb, const unsigned short* __restrict__ Kb,
    const unsigned short* __restrict__ Vt, unsigned short* __restrict__ ob) {
  int qt = blockIdx.x, h = blockIdx.y, b = blockIdx.z;
  int tid = threadIdx.x;
  __shared__ __align__(16) unsigned short Qs[64][72];
  __shared__ __align__(16) unsigned short Ks[64][72];
  __shared__ __align__(16) unsigned short Vs[64][72];
  __shared__ __align__(16) unsigned short Ps[64][72];
  int i0 = qt * 64;
  #pragma unroll
  for (int it = 0; it < 2; ++it) {
    int i = it * 256 + tid;
    int r = i >> 3, c8 = (i & 7) * 8;
    *(uint4*)&Qs[r][c8] = *(const uint4*)&qb[(((size_t)(b * NS + i0 + r)) * KA + h) * HD + c8];
  }
  int lane = tid & 63, w = tid >> 6;
  int lr = lane & 15, lk = (lane >> 4) * 8, rowq = (lane >> 4) * 4;
  f32x4 acc_o[4] = {};
  float m_run = -3.0e38f, l_run = 0.f;
  for (int jt = 0; jt < NS / 64; ++jt) {
    __syncthreads();   // prev PV done; Q staged (first iter)
    #pragma unroll
    for (int it = 0; it < 2; ++it) {
      int i = it * 256 + tid;
      int r = i >> 3, c8 = (i & 7) * 8;
      *(uint4*)&Ks[r][c8] = *(const uint4*)&Kb[((size_t)(b * NS + jt * 64 + r)) * HD + c8];
      *(uint4*)&Vs[r][c8] = *(const uint4*)&Vt[((size_t)b * HD + r) * NS + jt * 64 + c8];
    }
    __syncthreads();
    // S tile: 4 k-frags x 1 q-frag per wave
    f32x4 acc_s[4] = {};
    #pragma unroll
    for (int kk = 0; kk < 64; kk += 32) {
      bf16x8 qf = *(const bf16x8*)&Qs[w * 16 + lr][kk + lk];
      #pragma unroll
      for (int kf = 0; kf < 4; kf++) {
        bf16x8 kr = *(const bf16x8*)&Ks[kf * 16 + lr][kk + lk];
        acc_s[kf] = __builtin_amdgcn_mfma_f32_16x16x32_bf16(kr, qf, acc_s[kf], 0, 0, 0);
      }
    }
    // online softmax: each lane holds 16 k-values for one q column
    float pmax = acc_s[0][0];
    #pragma unroll
    for (int kf = 0; kf < 4; kf++)
      #pragma unroll
      for (int r = 0; r < 4; r++) pmax = fmaxf(pmax, acc_s[kf][r]);
    pmax = fmaxf(pmax, __shfl_xor(pmax, 16));
    pmax = fmaxf(pmax, __shfl_xor(pmax, 32));
    float m_new = fmaxf(m_run, pmax);
    float scl = expf(m_run - m_new);
    float rs = 0.f;
    #pragma unroll
    for (int kf = 0; kf < 4; kf++)
      #pragma unroll
      for (int r = 0; r < 4; r++) {
        float pv = expf(acc_s[kf][r] - m_new);
        rs += pv;
        Ps[w * 16 + lr][kf * 16 + rowq + r] = f2bf(pv);
      }
    rs += __shfl_xor(rs, 16);
    rs += __shfl_xor(rs, 32);
    l_run = l_run * scl + rs;
    m_run = m_new;
    __syncthreads();   // Ps visible (cross-lane within wave via LDS)
    #pragma unroll
    for (int df = 0; df < 4; df++) {
      acc_o[df][0] *= scl; acc_o[df][1] *= scl;
      acc_o[df][2] *= scl; acc_o[df][3] *= scl;
    }
    #pragma unroll
    for (int kk = 0; kk < 64; kk += 32) {
      bf16x8 pf = *(const bf16x8*)&Ps[w * 16 + lr][kk + lk];
      #pragma unroll
      for (int df = 0; df < 4; df++) {
        bf16x8 vf = *(const bf16x8*)&Vs[df * 16 + lr][kk + lk];
        acc_o[df] = __builtin_amdgcn_mfma_f32_16x16x32_bf16(vf, pf, acc_o[df], 0, 0, 0);
      }
    }
  }
  float inv = 1.f / l_run;
  int token = b * NS + i0 + w * 16 + lr;   // col = lane&15 = q
  #pragma unroll
  for (int df = 0; df < 4; df++) {
    ushort4 v = make_ushort4(f2bf(acc_o[df][0] * inv), f2bf(acc_o[df][1] * inv),
                             f2bf(acc_o[df][2] * inv), f2bf(acc_o[df][3] * inv));
    *(ushort4*)&ob[((size_t)token * KA + h) * HD + df * 16 + rowq] = v;
  }
}

// ---------------- MFMA output proj: dense per-slot bf16 (gate folded), NO atomics ----------------
__global__ __launch_bounds__(256) void oproj_mfma(
    const unsigned short* __restrict__ ob, const unsigned short* __restrict__ wot,
    const float* __restrict__ gates, const int* __restrict__ bucket,
    const int* __restrict__ counts, const int* __restrict__ map,
    const int* __restrict__ total, unsigned short* __restrict__ y_slot) {
  if ((int)blockIdx.y >= *total) return;
  int ent = map[blockIdx.y];
  int e = ent >> 16, t0 = ent & 0xFFFF;
  int c0 = blockIdx.x * 128;
  int cnt = counts[e];
  int tid = threadIdx.x;
  __shared__ int slots[128];
  __shared__ float gs[128];
  __shared__ __align__(16) unsigned short Xb[128][72];
  __shared__ __align__(16) unsigned short Wb[128][72];
  if (tid < 128) {
    int ii = t0 + tid;
    int s = (ii < cnt) ? bucket[(size_t)e * (T * KA) + ii] : -1;
    slots[tid] = s;
    gs[tid] = (s >= 0) ? gates[s] : 0.f;
  }
  __syncthreads();
  #pragma unroll
  for (int it = 0; it < 4; ++it) {
    int i = it * 256 + tid;
    int r = i >> 3, c8 = (i & 7) * 8;
    int s = slots[r];
    uint4 vo = make_uint4(0u, 0u, 0u, 0u);
    if (s >= 0) {
      float g = gs[r];
      uint4 u = *(const uint4*)&ob[(size_t)s * HD + c8];
      const unsigned short* us = (const unsigned short*)&u;
      unsigned short* vs = (unsigned short*)&vo;
      #pragma unroll
      for (int k = 0; k < 8; k++) vs[k] = f2bf(g * bf2f(us[k]));
    }
    *(uint4*)&Xb[r][c8] = vo;
  }
  #pragma unroll
  for (int it = 0; it < 4; ++it) {
    int i = it * 256 + tid;
    int r = i >> 3, c8 = (i & 7) * 8;
    *(uint4*)&Wb[r][c8] = *(const uint4*)&wot[((size_t)e * C + c0 + r) * HD + c8];
  }
  __syncthreads();
  int lane = tid & 63, wid = tid >> 6;
  int wr = wid & 1, wc = wid >> 1;
  int lr = lane & 15, lk = (lane >> 4) * 8, rowq = (lane >> 4) * 4;
  f32x4 acc[4][4] = {};
  #pragma unroll
  for (int kk = 0; kk < 64; kk += 32) {
    bf16x8 a[4], b[4];
    #pragma unroll
    for (int nf = 0; nf < 4; nf++) a[nf] = *(const bf16x8*)&Wb[wc * 64 + nf * 16 + lr][kk + lk];
    #pragma unroll
    for (int mf = 0; mf < 4; mf++) b[mf] = *(const bf16x8*)&Xb[wr * 64 + mf * 16 + lr][kk + lk];
    #pragma unroll
    for (int nf = 0; nf < 4; nf++)
      #pragma unroll
      for (int mf = 0; mf < 4; mf++)
        acc[nf][mf] = __builtin_amdgcn_mfma_f32_16x16x32_bf16(a[nf], b[mf], acc[nf][mf], 0, 0, 0);
  }
  #pragma unroll
  for (int mf = 0; mf < 4; mf++) {
    int si = wr * 64 + mf * 16 + lr;
    int s = slots[si];
    if (s < 0) continue;
    size_t base = (size_t)s * C + c0 + wc * 64;
    #pragma unroll
    for (int nf = 0; nf < 4; nf++) {
      ushort4 v = make_ushort4(f2bf(acc[nf][mf][0]), f2bf(acc[nf][mf][1]),
                               f2bf(acc[nf][mf][2]), f2bf(acc[nf][mf][3]));
      *(ushort4*)&y_slot[base + nf * 16 + rowq] = v;
    }
  }
}

// ---------------- combine: out = x + sum_k y_slot[t*8+k] ----------------
__global__ void combine_kernel(const float* __restrict__ x, const unsigned short* __restrict__ ys,
                               float* __restrict__ out) {
  int t = blockIdx.x, tid = threadIdx.x;
  int c = tid * 2;
  float s0 = 0.f, s1 = 0.f;
  #pragma unroll
  for (int k = 0; k < KA; k++) {
    unsigned u = *(const unsigned*)&ys[((size_t)t * KA + k) * C + c];
    s0 += bf2f((unsigned short)(u & 0xFFFF));
    s1 += bf2f((unsigned short)(u >> 16));
  }
  out[(size_t)t * C + c]     = x[(size_t)t * C + c] + s0;
  out[(size_t)t * C + c + 1] = x[(size_t)t * C + c + 1] + s1;
}

// ---------------- MFMA MLP1: h = gelu(x2 @ wi + bi), bf16 out ----------------
__global__ __launch_bounds__(256) void mlp1_mfma(
    const unsigned short* __restrict__ xb, const unsigned short* __restrict__ wit,
    const float* __restrict__ bi, const int* __restrict__ bucket,
    const int* __restrict__ counts, const int* __restrict__ map,
    const int* __restrict__ total, unsigned short* __restrict__ h) {
  if ((int)blockIdx.y >= *total) return;
  int ent = map[blockIdx.y];
  int e = ent >> 16, t0 = ent & 0xFFFF;
  int j0 = blockIdx.x * 128;
  int cnt = counts[e];
  int tid = threadIdx.x;
  __shared__ int slots[128];
  __shared__ __align__(16) unsigned short Xb[128][72];
  __shared__ __align__(16) unsigned short Wb[128][72];
  if (tid < 128) {
    int ii = t0 + tid;
    slots[tid] = (ii < cnt) ? bucket[(size_t)e * (T * KF) + ii] : -1;
  }
  __syncthreads();
  int lane = tid & 63, wid = tid >> 6;
  int wr = wid & 1, wc = wid >> 1;
  int lr = lane & 15, lk = (lane >> 4) * 8, rowq = (lane >> 4) * 4;
  f32x4 acc[4][4] = {};
  for (int kc = 0; kc < C; kc += 64) {
    __syncthreads();
    #pragma unroll
    for (int it = 0; it < 4; ++it) {
      int i = it * 256 + tid;
      int r = i >> 3, c8 = (i & 7) * 8;
      int s = slots[r];
      uint4 v = make_uint4(0u, 0u, 0u, 0u);
      if (s >= 0) v = *(const uint4*)&xb[(size_t)(s >> 1) * C + kc + c8];
      *(uint4*)&Xb[r][c8] = v;
    }
    #pragma unroll
    for (int it = 0; it < 4; ++it) {
      int i = it * 256 + tid;
      int r = i >> 3, c8 = (i & 7) * 8;
      *(uint4*)&Wb[r][c8] = *(const uint4*)&wit[((size_t)e * HID + j0 + r) * C + kc + c8];
    }
    __syncthreads();
    #pragma unroll
    for (int kk = 0; kk < 64; kk += 32) {
      bf16x8 a[4], b[4];
      #pragma unroll
      for (int nf = 0; nf < 4; nf++) a[nf] = *(const bf16x8*)&Wb[wc * 64 + nf * 16 + lr][kk + lk];
      #pragma unroll
      for (int mf = 0; mf < 4; mf++) b[mf] = *(const bf16x8*)&Xb[wr * 64 + mf * 16 + lr][kk + lk];
      #pragma unroll
      for (int nf = 0; nf < 4; nf++)
        #pragma unroll
        for (int mf = 0; mf < 4; mf++)
          acc[nf][mf] = __builtin_amdgcn_mfma_f32_16x16x32_bf16(a[nf], b[mf], acc[nf][mf], 0, 0, 0);
    }
  }
  #pragma unroll
  for (int mf = 0; mf < 4; mf++) {
    int s = slots[wr * 64 + mf * 16 + lr];
    if (s < 0) continue;
    #pragma unroll
    for (int nf = 0; nf < 4; nf++) {
      int j = j0 + wc * 64 + nf * 16 + rowq;
      const float4 b4 = *(const float4*)&bi[(size_t)e * HID + j];
      float v0 = acc[nf][mf][0] + b4.x, v1 = acc[nf][mf][1] + b4.y;
      float v2 = acc[nf][mf][2] + b4.z, v3 = acc[nf][mf][3] + b4.w;
      v0 = 0.5f * v0 * (1.f + erff(v0 * 0.70710678118654752f));
      v1 = 0.5f * v1 * (1.f + erff(v1 * 0.70710678118654752f));
      v2 = 0.5f * v2 * (1.f + erff(v2 * 0.70710678118654752f));
      v3 = 0.5f * v3 * (1.f + erff(v3 * 0.70710678118654752f));
      *(ushort4*)&h[(size_t)s * HID + j] = make_ushort4(f2bf(v0), f2bf(v1), f2bf(v2), f2bf(v3));
    }
  }
}

// ---------------- MFMA MLP2: dense per-slot bf16 (gate+bias folded), NO atomics ----------------
__global__ __launch_bounds__(256) void mlp2_mfma(
    const unsigned short* __restrict__ h, const unsigned short* __restrict__ wot,
    const float* __restrict__ bo, const float* __restrict__ gates2,
    const int* __restrict__ bucket, const int* __restrict__ counts,
    const int* __restrict__ map, const int* __restrict__ total,
    unsigned short* __restrict__ y2) {
  if ((int)blockIdx.y >= *total) return;
  int ent = map[blockIdx.y];
  int e = ent >> 16, t0 = ent & 0xFFFF;
  int c0 = blockIdx.x * 128;
  int cnt = counts[e];
  int tid = threadIdx.x;
  __shared__ int slots[128];
  __shared__ __align__(16) unsigned short Xb[128][72];
  __shared__ __align__(16) unsigned short Wb[128][72];
  if (tid < 128) {
    int ii = t0 + tid;
    slots[tid] = (ii < cnt) ? bucket[(size_t)e * (T * KF) + ii] : -1;
  }
  __syncthreads();
  int lane = tid & 63, wid = tid >> 6;
  int wr = wid & 1, wc = wid >> 1;
  int lr = lane & 15, lk = (lane >> 4) * 8, rowq = (lane >> 4) * 4;
  f32x4 acc[4][4] = {};
  for (int kc = 0; kc < HID; kc += 64) {
    __syncthreads();
    #pragma unroll
    for (int it = 0; it < 4; ++it) {
      int i = it * 256 + tid;
      int r = i >> 3, c8 = (i & 7) * 8;
      int s = slots[r];
      uint4 v = make_uint4(0u, 0u, 0u, 0u);
      if (s >= 0) v = *(const uint4*)&h[(size_t)s * HID + kc + c8];
      *(uint4*)&Xb[r][c8] = v;
    }
    #pragma unroll
    for (int it = 0; it < 4; ++it) {
      int i = it * 256 + tid;
      int r = i >> 3, c8 = (i & 7) * 8;
      *(uint4*)&Wb[r][c8] = *(const uint4*)&wot[((size_t)e * C + c0 + r) * HID + kc + c8];
    }
    __syncthreads();
    #pragma unroll
    for (int kk = 0; kk < 64; kk += 32) {
      bf16x8 a[4], b[4];
      #pragma unroll
      for (int nf = 0; nf < 4; nf++) a[nf] = *(const bf16x8*)&Wb[wc * 64 + nf * 16 + lr][kk + lk];
      #pragma unroll
      for (int mf = 0; mf < 4; mf++) b[mf] = *(const bf16x8*)&Xb[wr * 64 + mf * 16 + lr][kk + lk];
      #pragma unroll
      for (int nf = 0; nf < 4; nf++)
        #pragma unroll
        for (int mf = 0; mf < 4; mf++)
          acc[nf][mf] = __builtin_amdgcn_mfma_f32_16x16x32_bf16(a[nf], b[mf], acc[nf][mf], 0, 0, 0);
    }
  }
  #pragma unroll
  for (int mf = 0; mf < 4; mf++) {
    int si = wr * 64 + mf * 16 + lr;
    int s = slots[si];
    if (s < 0) continue;
    float g = gates2[s];
    #pragma unroll
    for (int nf = 0; nf < 4; nf++) {
      int cc = c0 + wc * 64 + nf * 16 + rowq;
      const float4 b4 = *(const float4*)&bo[(size_t)e * C + cc];
      ushort4 v = make_ushort4(f2bf(g * (acc[nf][mf][0] + b4.x)),
                               f2bf(g * (acc[nf][mf][1] + b4.y)),
                               f2bf(g * (acc[nf][mf][2] + b4.z)),
                               f2bf(g * (acc[nf][mf][3] + b4.w)));
      *(ushort4*)&y2[(size_t)s * C + cc] = v;
    }
  }
}

// ---------------- Final residual add (bf16 slots) ----------------
__global__ void final_kernel(const unsigned short* __restrict__ y2, float* __restrict__ xout) {
  int t = blockIdx.x, tid = threadIdx.x;
  int c = tid * 2;
  unsigned u0 = *(const unsigned*)&y2[(size_t)(t * 2) * C + c];
  unsigned u1 = *(const unsigned*)&y2[(size_t)(t * 2 + 1) * C + c];
  xout[(size_t)t * C + c]     += bf2f((unsigned short)(u0 & 0xFFFF)) + bf2f((unsigned short)(u1 & 0xFFFF));
  xout[(size_t)t * C + c + 1] += bf2f((unsigned short)(u0 >> 16)) + bf2f((unsigned short)(u1 >> 16));
}

// ---------------- Gating statistics reduction ----------------
template <int E, int K>
__global__ void reduce_gating(const float* __restrict__ probs, const float* __restrict__ lse,
                              const int* __restrict__ idxs, float* __restrict__ psum,
                              float* __restrict__ freq, float* __restrict__ zsum) {
  __shared__ float ps[E];
  __shared__ float fr[E];
  __shared__ float zs;
  int tid = threadIdx.x;
  if (tid < E) { ps[tid] = 0.f; fr[tid] = 0.f; }
  if (tid == 0) zs = 0.f;
  __syncthreads();
  int t = blockIdx.x * 256 + tid;
  if (t < T) {
    for (int e = 0; e < E; e++) atomicAdd(&ps[e], probs[(size_t)t * E + e]);
    for (int k = 0; k < K; k++) atomicAdd(&fr[idxs[(size_t)t * K + k]], 1.f);
    float l = lse[t];
    atomicAdd(&zs, l * l);
  }
  __syncthreads();
  if (tid < E) { atomicAdd(&psum[tid], ps[tid]); atomicAdd(&freq[tid], fr[tid]); }
  if (tid == 0) atomicAdd(zsum, zs);
}

__global__ void loss_kernel(const float* __restrict__ acc, float* __restrict__ out) {
  const float* p1 = acc;      const float* f1 = acc + 24; float z1 = acc[48];
  const float* p2 = acc + 49; const float* f2 = acc + 65; float z2 = acc[81];
  float sp1 = 0.f, sf1 = 0.f;
  for (int e = 0; e < 24; e++) { sp1 += p1[e]; sf1 += f1[e]; }
  float sw1 = 0.f;
  for (int e = 0; e < 24; e++) sw1 += (p1[e] / sp1) * (f1[e] / sf1);
  sw1 *= 24.f;
  float sp2 = 0.f, sf2 = 0.f;
  for (int e = 0; e < 16; e++) { sp2 += p2[e]; sf2 += f2[e]; }
  float sw2 = 0.f;
  for (int e = 0; e < 16; e++) sw2 += (p2[e] / sp2) * (f2[e] / sf2);
  sw2 *= 16.f;
  out[0] = 0.01f * sw1 + 0.001f * (z1 / T) + 0.01f * sw2 + 0.001f * (z2 / T);
}

}  // namespace

extern "C" void kernel_launch(void* const* d_in, const int* in_sizes, int n_in,
                              void* d_out, int out_size, void* d_ws, size_t ws_size,
                              hipStream_t stream) {
  const float* x      = (const float*)d_in[0];
  const int*   task   = (const int*)d_in[1];
  const float* n1g    = (const float*)d_in[2];
  const float* n1b    = (const float*)d_in[3];
  const float* gate_a = (const float*)d_in[4];
  const float* wq     = (const float*)d_in[5];
  const float* wo_a   = (const float*)d_in[6];
  const float* kvw    = (const float*)d_in[7];
  const float* kvb    = (const float*)d_in[8];
  const float* n2g    = (const float*)d_in[9];
  const float* n2b    = (const float*)d_in[10];
  const float* gate_m = (const float*)d_in[11];
  const float* wi     = (const float*)d_in[12];
  const float* bi     = (const float*)d_in[13];
  const float* wo_m   = (const float*)d_in[14];
  const float* bo     = (const float*)d_in[15];
  float* out = (float*)d_out;

  char* p = (char*)d_ws;
  float* x1 = (float*)p;             p += (size_t)T * C * 4;
  unsigned short* x1b = (unsigned short*)p; p += (size_t)T * C * 2;
  unsigned short* qb = (unsigned short*)p;  p += (size_t)T * KA * HD * 2;
  unsigned short* ob = (unsigned short*)p;  p += (size_t)T * KA * HD * 2;
  unsigned short* Kb = (unsigned short*)p;  p += (size_t)T * HD * 2;
  unsigned short* Vt = (unsigned short*)p;  p += (size_t)T * HD * 2;
  // union region: y_slot (33.5MB) then reused as h (16.8MB) + y2_slot (8.4MB)
  char* un = p;                      p += (size_t)T * KA * C * 2;
  unsigned short* y_slot  = (unsigned short*)un;
  unsigned short* h       = (unsigned short*)un;
  unsigned short* y2_slot = (unsigned short*)(un + (size_t)T * KF * HID * 2);
  unsigned short* wqt = (unsigned short*)p;  p += (size_t)EA * C * HD * 2;
  unsigned short* woat = (unsigned short*)p; p += (size_t)EA * HD * C * 2;
  unsigned short* wit = (unsigned short*)p;  p += (size_t)EF * C * HID * 2;
  unsigned short* womt = (unsigned short*)p; p += (size_t)EF * HID * C * 2;
  float* probs1 = (float*)p;         p += (size_t)T * EA * 4;
  float* lse1 = (float*)p;           p += (size_t)T * 4;
  float* gates1 = (float*)p;         p += (size_t)T * KA * 4;
  int* idx1 = (int*)p;               p += (size_t)T * KA * 4;
  float* probs2 = (float*)p;         p += (size_t)T * EF * 4;
  float* lse2 = (float*)p;           p += (size_t)T * 4;
  float* gates2 = (float*)p;         p += (size_t)T * KF * 4;
  int* idx2 = (int*)p;               p += (size_t)T * KF * 4;
  int* bucket_a = (int*)p;           p += (size_t)EA * (T * KA) * 4;
  int* bucket_f = (int*)p;           p += (size_t)EF * (T * KF) * 4;
  int* counts_a = (int*)p;           p += 32 * 4;
  int* counts_f = (int*)p;           p += 32 * 4;
  float* accum = (float*)p;          p += 128 * 4;
  int* maps = (int*)p;               p += 768 * 4;
  int* totals = (int*)p;             p += 4 * 4;

  hipMemsetAsync(counts_a, 0, (32 + 32 + 128) * 4, stream);

  tcvt_kernel<<<dim3(2, 16, 24), 256, 0, stream>>>(wq, wqt, C, HD);
  tcvt_kernel<<<dim3(16, 2, 24), 256, 0, stream>>>(wo_a, woat, HD, C);
  tcvt_kernel<<<dim3(32, 16, 16), 256, 0, stream>>>(wi, wit, C, HID);
  tcvt_kernel<<<dim3(16, 32, 16), 256, 0, stream>>>(wo_m, womt, HID, C);

  ln_kernel<<<T, 256, 0, stream>>>(x, n1g, n1b, x1, x1b);
  gating_kernel<EA, KA, 8><<<T, 256, 0, stream>>>(x1, gate_a, task, probs1, lse1, gates1, idx1);
  bucket_kernel<<<(T * KA) / 256, 256, 0, stream>>>(idx1, T * KA, T * KA, counts_a, bucket_a);
  build_maps_a<<<1, 64, 0, stream>>>(counts_a, maps, totals);
  qgemm_mfma<<<dim3(1, 152), 256, 0, stream>>>(x1b, wqt, bucket_a, counts_a, maps, totals, qb);
  kvgemm_kernel<<<dim3(2, 64), 256, 0, stream>>>(x1, kvw, kvb, Kb, Vt);
  attn_mfma<<<dim3(NS / 64, KA, NB), 256, 0, stream>>>(qb, Kb, Vt, ob);
  oproj_mfma<<<dim3(4, 280), 256, 0, stream>>>(ob, woat, gates1, bucket_a, counts_a,
                                               maps + 256, totals + 1, y_slot);
  combine_kernel<<<T, 256, 0, stream>>>(x, y_slot, out);
  ln_kernel<<<T, 256, 0, stream>>>(out, n2g, n2b, x1, x1b);
  gating_kernel<EF, KF, 16><<<T, 256, 0, stream>>>(x1, gate_m, task, probs2, lse2, gates2, idx2);
  bucket_kernel<<<(T * KF) / 256, 256, 0, stream>>>(idx2, T * KF, T * KF, counts_f, bucket_f);
  build_maps_f<<<1, 64, 0, stream>>>(counts_f, maps, totals);
  mlp1_mfma<<<dim3(8, 80), 256, 0, stream>>>(x1b, wit, bi, bucket_f, counts_f,
                                             maps + 600, totals + 2, h);
  mlp2_mfma<<<dim3(4, 80), 256, 0, stream>>>(h, womt, bo, gates2, bucket_f, counts_f,
                                             maps + 600, totals + 2, y2_slot);
  final_kernel<<<T, 256, 0, stream>>>(y2_slot, out);
  reduce_gating<EA, KA><<<16, 256, 0, stream>>>(probs1, lse1, idx1, accum, accum + 24, accum + 48);
  reduce_gating<EF, KF><<<16, 256, 0, stream>>>(probs2, lse2, idx2, accum + 49, accum + 65, accum + 81);
  loss_kernel<<<1, 1, 0, stream>>>(accum, out + (size_t)T * C);
}

// Round 6
// 531.415 us; speedup vs baseline: 3.2131x; 1.1578x over previous
//
#include <hip/hip_runtime.h>
#include <math.h>

namespace {

constexpr int T   = 4096;
constexpr int C   = 512;
constexpr int NB  = 8;
constexpr int NS  = 512;
constexpr int HD  = 64;
constexpr int KA  = 8;
constexpr int EA  = 24;
constexpr int EF  = 16;
constexpr int KF  = 2;
constexpr int HID = 1024;

typedef __attribute__((ext_vector_type(8))) short bf16x8;
typedef __attribute__((ext_vector_type(4))) float f32x4;

__device__ inline unsigned short f2bf(float f) {
  unsigned u = __float_as_uint(f);
  return (unsigned short)((u + 0x7FFFu + ((u >> 16) & 1u)) >> 16);
}
__device__ inline float bf2f(unsigned short u) {
  return __uint_as_float((unsigned)u << 16);
}

// ---------------- LayerNorm: fp32 + bf16 outputs ----------------
__global__ void ln_kernel(const float* __restrict__ in, const float* __restrict__ g,
                          const float* __restrict__ b, float* __restrict__ out,
                          unsigned short* __restrict__ outb) {
  int t = blockIdx.x, tid = threadIdx.x;
  const float* row = in + (size_t)t * C;
  __shared__ float red[256];
  float v0 = row[tid], v1 = row[tid + 256];
  red[tid] = v0 + v1;
  __syncthreads();
  for (int st = 128; st > 0; st >>= 1) {
    if (tid < st) red[tid] += red[tid + st];
    __syncthreads();
  }
  float mean = red[0] * (1.f / C);
  __syncthreads();
  float d0 = v0 - mean, d1 = v1 - mean;
  red[tid] = d0 * d0 + d1 * d1;
  __syncthreads();
  for (int st = 128; st > 0; st >>= 1) {
    if (tid < st) red[tid] += red[tid + st];
    __syncthreads();
  }
  float r = rsqrtf(red[0] * (1.f / C) + 1e-5f);
  float o0 = d0 * r * g[tid] + b[tid];
  float o1 = d1 * r * g[tid + 256] + b[tid + 256];
  out[(size_t)t * C + tid]       = o0;
  out[(size_t)t * C + tid + 256] = o1;
  outb[(size_t)t * C + tid]       = f2bf(o0);
  outb[(size_t)t * C + tid + 256] = f2bf(o1);
}

// ---------------- Gating: logits via waves, softmax+topk via one wave ----------------
template <int E, int K, int TPE>
__global__ void gating_kernel(const float* __restrict__ xn, const float* __restrict__ gate_all,
                              const int* __restrict__ task,
                              float* __restrict__ probs, float* __restrict__ lse_out,
                              float* __restrict__ gates, int* __restrict__ idxs) {
  int t = blockIdx.x, tid = threadIdx.x;
  const float* W = gate_all + (size_t)task[0] * C * E;
  __shared__ float xs[C];
  __shared__ float lg[E];
  xs[tid]       = xn[(size_t)t * C + tid];
  xs[tid + 256] = xn[(size_t)t * C + tid + 256];
  __syncthreads();
  if (tid < E * TPE) {
    int e = tid / TPE, l = tid % TPE;
    float acc = 0.f;
    for (int c = l; c < C; c += TPE) acc += xs[c] * W[(size_t)c * E + e];
    #pragma unroll
    for (int m = TPE >> 1; m > 0; m >>= 1) acc += __shfl_xor(acc, m);
    if (l == 0) lg[e] = acc;
  }
  __syncthreads();
  if (tid < 64) {
    float lgv = (tid < E) ? lg[tid] : -3.0e38f;
    float mx = lgv;
    #pragma unroll
    for (int m = 1; m < 64; m <<= 1) mx = fmaxf(mx, __shfl_xor(mx, m));
    float pe = (tid < E) ? expf(lgv - mx) : 0.f;
    float sum = pe;
    #pragma unroll
    for (int m = 1; m < 64; m <<= 1) sum += __shfl_xor(sum, m);
    float inv = 1.f / sum;
    float prob = pe * inv;
    if (tid < E) probs[(size_t)t * E + tid] = prob;
    if (tid == 0) lse_out[t] = mx + logf(sum);
    float pv = (tid < E) ? prob : -1.f;
    float gsum = 0.f, myv = 0.f; int myi = 0;
    for (int k = 0; k < K; k++) {
      float bv = pv; int bi_ = tid;
      #pragma unroll
      for (int m = 1; m < 64; m <<= 1) {
        float ov = __shfl_xor(bv, m); int oi = __shfl_xor(bi_, m);
        if (ov > bv || (ov == bv && oi < bi_)) { bv = ov; bi_ = oi; }
      }
      gsum += bv;
      if (tid == k) { myv = bv; myi = bi_; }
      if (tid == bi_) pv = -1.f;
    }
    if (tid < K) {
      float ginv = 1.f / (gsum + 1e-6f);
      gates[(size_t)t * K + tid] = myv * ginv;
      idxs[(size_t)t * K + tid]  = myi;
    }
  }
}

// ---------------- bucket by expert ----------------
__global__ void bucket_kernel(const int* __restrict__ idx, int nslots, int stride,
                              int* counts, int* bucket) {
  int s = blockIdx.x * 256 + threadIdx.x;
  if (s >= nslots) return;
  int e = idx[s];
  int pos = atomicAdd(&counts[e], 1);
  bucket[(size_t)e * stride + pos] = s;
}

// ---------------- flat (expert, tile) maps ----------------
__global__ void build_maps_a(const int* __restrict__ counts, int* __restrict__ maps,
                             int* __restrict__ totals) {
  if (threadIdx.x != 0) return;
  int n = 0;
  for (int e = 0; e < EA; e++) { int c = counts[e]; for (int t0 = 0; t0 < c; t0 += 256) maps[n++] = (e << 16) | t0; }
  totals[0] = n;
  n = 0;
  for (int e = 0; e < EA; e++) { int c = counts[e]; for (int t0 = 0; t0 < c; t0 += 128) maps[256 + n++] = (e << 16) | t0; }
  totals[1] = n;
}
__global__ void build_maps_f(const int* __restrict__ counts, int* __restrict__ maps,
                             int* __restrict__ totals) {
  if (threadIdx.x != 0) return;
  int n = 0;
  for (int e = 0; e < EF; e++) { int c = counts[e]; for (int t0 = 0; t0 < c; t0 += 128) maps[600 + n++] = (e << 16) | t0; }
  totals[2] = n;
}

// ---------------- transpose + cvt weights: [E][K][N] f32 -> [E][N][K] bf16 ----------------
__global__ void tcvt_kernel(const float* __restrict__ src, unsigned short* __restrict__ dst,
                            int K, int N) {
  int e = blockIdx.z;
  int kt = blockIdx.y * 32, nt = blockIdx.x * 32;
  __shared__ float tile[32][33];
  int tid = threadIdx.x;
  const float* S = src + (size_t)e * K * N;
  for (int i = tid; i < 32 * 32; i += 256) {
    int r = i >> 5, c = i & 31;
    tile[r][c] = S[(size_t)(kt + r) * N + nt + c];
  }
  __syncthreads();
  unsigned short* D = dst + (size_t)e * K * N;
  for (int i = tid; i < 32 * 8; i += 256) {
    int n = i >> 3, k4 = (i & 7) * 4;
    ushort4 v;
    v.x = f2bf(tile[k4 + 0][n]); v.y = f2bf(tile[k4 + 1][n]);
    v.z = f2bf(tile[k4 + 2][n]); v.w = f2bf(tile[k4 + 3][n]);
    *(ushort4*)&D[(size_t)(nt + n) * K + kt + k4] = v;
  }
}

// ---------------- MFMA Q GEMM: 256 slots x 64 out, K=512 -> bf16 q (pre-scaled) ----------------
__global__ __launch_bounds__(256) void qgemm_mfma(
    const unsigned short* __restrict__ xb, const unsigned short* __restrict__ wqt,
    const int* __restrict__ bucket, const int* __restrict__ counts,
    const int* __restrict__ map, const int* __restrict__ total,
    unsigned short* __restrict__ qb) {
  if ((int)blockIdx.y >= *total) return;
  int ent = map[blockIdx.y];
  int e = ent >> 16, t0 = ent & 0xFFFF;
  int cnt = counts[e];
  int tid = threadIdx.x;
  __shared__ int slots[256];
  __shared__ __align__(16) unsigned short Xb[256][72];
  __shared__ __align__(16) unsigned short Wb[64][72];
  {
    int ii = t0 + tid;
    slots[tid] = (ii < cnt) ? bucket[(size_t)e * (T * KA) + ii] : -1;
  }
  __syncthreads();
  int lane = tid & 63, wid = tid >> 6;
  int lr = lane & 15, lk = (lane >> 4) * 8, rowq = (lane >> 4) * 4;
  f32x4 acc[4][4] = {};
  for (int kc = 0; kc < C; kc += 64) {
    __syncthreads();
    #pragma unroll
    for (int it = 0; it < 8; ++it) {
      int i = it * 256 + tid;
      int r = i >> 3, c8 = (i & 7) * 8;
      int s = slots[r];
      uint4 v = make_uint4(0u, 0u, 0u, 0u);
      if (s >= 0) v = *(const uint4*)&xb[(size_t)(s >> 3) * C + kc + c8];
      *(uint4*)&Xb[r][c8] = v;
    }
    #pragma unroll
    for (int it = 0; it < 2; ++it) {
      int i = it * 256 + tid;
      int r = i >> 3, c8 = (i & 7) * 8;
      *(uint4*)&Wb[r][c8] = *(const uint4*)&wqt[((size_t)e * HD + r) * C + kc + c8];
    }
    __syncthreads();
    #pragma unroll
    for (int kk = 0; kk < 64; kk += 32) {
      bf16x8 a[4], b[4];
      #pragma unroll
      for (int nf = 0; nf < 4; nf++) a[nf] = *(const bf16x8*)&Wb[nf * 16 + lr][kk + lk];
      #pragma unroll
      for (int mf = 0; mf < 4; mf++) b[mf] = *(const bf16x8*)&Xb[wid * 64 + mf * 16 + lr][kk + lk];
      #pragma unroll
      for (int nf = 0; nf < 4; nf++)
        #pragma unroll
        for (int mf = 0; mf < 4; mf++)
          acc[nf][mf] = __builtin_amdgcn_mfma_f32_16x16x32_bf16(a[nf], b[mf], acc[nf][mf], 0, 0, 0);
    }
  }
  #pragma unroll
  for (int mf = 0; mf < 4; mf++) {
    int s = slots[wid * 64 + mf * 16 + lr];
    if (s < 0) continue;
    #pragma unroll
    for (int nf = 0; nf < 4; nf++) {
      ushort4 v = make_ushort4(f2bf(0.125f * acc[nf][mf][0]), f2bf(0.125f * acc[nf][mf][1]),
                               f2bf(0.125f * acc[nf][mf][2]), f2bf(0.125f * acc[nf][mf][3]));
      *(ushort4*)&qb[(size_t)s * HD + nf * 16 + rowq] = v;
    }
  }
}

// ---------------- MFMA KV GEMM: 16 tokens x 128 cols per block, 256 blocks ----------------
// bf16 in (x1b, kvwt[128][512]); writes bf16 K [b][j][64] + V^T [b][d][512].
__global__ __launch_bounds__(256) void kv_mfma(
    const unsigned short* __restrict__ xb, const unsigned short* __restrict__ kvwt,
    const float* __restrict__ kvb, unsigned short* __restrict__ Kb,
    unsigned short* __restrict__ Vt) {
  int t0 = blockIdx.x * 16;
  int tid = threadIdx.x;
  __shared__ __align__(16) unsigned short Xs[16][72];
  __shared__ __align__(16) unsigned short Ws[128][72];
  int lane = tid & 63, w = tid >> 6;
  int lr = lane & 15, lk = (lane >> 4) * 8, rowq = (lane >> 4) * 4;
  f32x4 acc[2] = {};
  for (int kc = 0; kc < C; kc += 64) {
    __syncthreads();
    if (tid < 128) {
      int r = tid >> 3, c8 = (tid & 7) * 8;
      *(uint4*)&Xs[r][c8] = *(const uint4*)&xb[(size_t)(t0 + r) * C + kc + c8];
    }
    #pragma unroll
    for (int it = 0; it < 4; ++it) {
      int i = it * 256 + tid;
      int r = i >> 3, c8 = (i & 7) * 8;
      *(uint4*)&Ws[r][c8] = *(const uint4*)&kvwt[(size_t)r * C + kc + c8];
    }
    __syncthreads();
    #pragma unroll
    for (int kk = 0; kk < 64; kk += 32) {
      bf16x8 xf = *(const bf16x8*)&Xs[lr][kk + lk];
      #pragma unroll
      for (int cf = 0; cf < 2; cf++) {
        bf16x8 wf = *(const bf16x8*)&Ws[w * 32 + cf * 16 + lr][kk + lk];
        acc[cf] = __builtin_amdgcn_mfma_f32_16x16x32_bf16(wf, xf, acc[cf], 0, 0, 0);
      }
    }
  }
  // D: col(lane&15)=token, row(rowq+reg)=kv-dim within frag
  int t = t0 + lr;
  int bb = t >> 9, n = t & (NS - 1);
  #pragma unroll
  for (int cf = 0; cf < 2; cf++) {
    #pragma unroll
    for (int r2 = 0; r2 < 4; r2++) {
      int c = w * 32 + cf * 16 + rowq + r2;
      float v = acc[cf][r2] + kvb[c];
      if (c < HD) Kb[(size_t)t * HD + c] = f2bf(v);
      else        Vt[((size_t)bb * HD + (c - HD)) * NS + n] = f2bf(v);
    }
  }
}

// ---------------- MFMA flash attention: block per (qtile64, head, batch) ----------------
__global__ __launch_bounds__(256) void attn_mfma(
    const unsigned short* __restrict__ qb, const unsigned short* __restrict__ Kb,
    const unsigned short* __restrict__ Vt, unsigned short* __restrict__ ob) {
  int qt = blockIdx.x, h = blockIdx.y, b = blockIdx.z;
  int tid = threadIdx.x;
  __shared__ __align__(16) unsigned short Qs[64][72];
  __shared__ __align__(16) unsigned short Ks[64][72];
  __shared__ __align__(16) unsigned short Vs[64][72];
  __shared__ __align__(16) unsigned short Ps[64][72];
  int i0 = qt * 64;
  #pragma unroll
  for (int it = 0; it < 2; ++it) {
    int i = it * 256 + tid;
    int r = i >> 3, c8 = (i & 7) * 8;
    *(uint4*)&Qs[r][c8] = *(const uint4*)&qb[(((size_t)(b * NS + i0 + r)) * KA + h) * HD + c8];
  }
  int lane = tid & 63, w = tid >> 6;
  int lr = lane & 15, lk = (lane >> 4) * 8, rowq = (lane >> 4) * 4;
  f32x4 acc_o[4] = {};
  float m_run = -3.0e38f, l_run = 0.f;
  for (int jt = 0; jt < NS / 64; ++jt) {
    __syncthreads();
    #pragma unroll
    for (int it = 0; it < 2; ++it) {
      int i = it * 256 + tid;
      int r = i >> 3, c8 = (i & 7) * 8;
      *(uint4*)&Ks[r][c8] = *(const uint4*)&Kb[((size_t)(b * NS + jt * 64 + r)) * HD + c8];
      *(uint4*)&Vs[r][c8] = *(const uint4*)&Vt[((size_t)b * HD + r) * NS + jt * 64 + c8];
    }
    __syncthreads();
    f32x4 acc_s[4] = {};
    #pragma unroll
    for (int kk = 0; kk < 64; kk += 32) {
      bf16x8 qf = *(const bf16x8*)&Qs[w * 16 + lr][kk + lk];
      #pragma unroll
      for (int kf = 0; kf < 4; kf++) {
        bf16x8 kr = *(const bf16x8*)&Ks[kf * 16 + lr][kk + lk];
        acc_s[kf] = __builtin_amdgcn_mfma_f32_16x16x32_bf16(kr, qf, acc_s[kf], 0, 0, 0);
      }
    }
    float pmax = acc_s[0][0];
    #pragma unroll
    for (int kf = 0; kf < 4; kf++)
      #pragma unroll
      for (int r = 0; r < 4; r++) pmax = fmaxf(pmax, acc_s[kf][r]);
    pmax = fmaxf(pmax, __shfl_xor(pmax, 16));
    pmax = fmaxf(pmax, __shfl_xor(pmax, 32));
    float m_new = fmaxf(m_run, pmax);
    float scl = expf(m_run - m_new);
    float rs = 0.f;
    #pragma unroll
    for (int kf = 0; kf < 4; kf++)
      #pragma unroll
      for (int r = 0; r < 4; r++) {
        float pv = expf(acc_s[kf][r] - m_new);
        rs += pv;
        Ps[w * 16 + lr][kf * 16 + rowq + r] = f2bf(pv);
      }
    rs += __shfl_xor(rs, 16);
    rs += __shfl_xor(rs, 32);
    l_run = l_run * scl + rs;
    m_run = m_new;
    __syncthreads();
    #pragma unroll
    for (int df = 0; df < 4; df++) {
      acc_o[df][0] *= scl; acc_o[df][1] *= scl;
      acc_o[df][2] *= scl; acc_o[df][3] *= scl;
    }
    #pragma unroll
    for (int kk = 0; kk < 64; kk += 32) {
      bf16x8 pf = *(const bf16x8*)&Ps[w * 16 + lr][kk + lk];
      #pragma unroll
      for (int df = 0; df < 4; df++) {
        bf16x8 vf = *(const bf16x8*)&Vs[df * 16 + lr][kk + lk];
        acc_o[df] = __builtin_amdgcn_mfma_f32_16x16x32_bf16(vf, pf, acc_o[df], 0, 0, 0);
      }
    }
  }
  float inv = 1.f / l_run;
  int token = b * NS + i0 + w * 16 + lr;
  #pragma unroll
  for (int df = 0; df < 4; df++) {
    ushort4 v = make_ushort4(f2bf(acc_o[df][0] * inv), f2bf(acc_o[df][1] * inv),
                             f2bf(acc_o[df][2] * inv), f2bf(acc_o[df][3] * inv));
    *(ushort4*)&ob[((size_t)token * KA + h) * HD + df * 16 + rowq] = v;
  }
}

// ---------------- MFMA output proj: dense per-slot bf16 (gate folded), NO atomics ----------------
__global__ __launch_bounds__(256) void oproj_mfma(
    const unsigned short* __restrict__ ob, const unsigned short* __restrict__ wot,
    const float* __restrict__ gates, const int* __restrict__ bucket,
    const int* __restrict__ counts, const int* __restrict__ map,
    const int* __restrict__ total, unsigned short* __restrict__ y_slot) {
  if ((int)blockIdx.y >= *total) return;
  int ent = map[blockIdx.y];
  int e = ent >> 16, t0 = ent & 0xFFFF;
  int c0 = blockIdx.x * 128;
  int cnt = counts[e];
  int tid = threadIdx.x;
  __shared__ int slots[128];
  __shared__ float gs[128];
  __shared__ __align__(16) unsigned short Xb[128][72];
  __shared__ __align__(16) unsigned short Wb[128][72];
  if (tid < 128) {
    int ii = t0 + tid;
    int s = (ii < cnt) ? bucket[(size_t)e * (T * KA) + ii] : -1;
    slots[tid] = s;
    gs[tid] = (s >= 0) ? gates[s] : 0.f;
  }
  __syncthreads();
  #pragma unroll
  for (int it = 0; it < 4; ++it) {
    int i = it * 256 + tid;
    int r = i >> 3, c8 = (i & 7) * 8;
    int s = slots[r];
    uint4 vo = make_uint4(0u, 0u, 0u, 0u);
    if (s >= 0) {
      float g = gs[r];
      uint4 u = *(const uint4*)&ob[(size_t)s * HD + c8];
      const unsigned short* us = (const unsigned short*)&u;
      unsigned short* vs = (unsigned short*)&vo;
      #pragma unroll
      for (int k = 0; k < 8; k++) vs[k] = f2bf(g * bf2f(us[k]));
    }
    *(uint4*)&Xb[r][c8] = vo;
  }
  #pragma unroll
  for (int it = 0; it < 4; ++it) {
    int i = it * 256 + tid;
    int r = i >> 3, c8 = (i & 7) * 8;
    *(uint4*)&Wb[r][c8] = *(const uint4*)&wot[((size_t)e * C + c0 + r) * HD + c8];
  }
  __syncthreads();
  int lane = tid & 63, wid = tid >> 6;
  int wr = wid & 1, wc = wid >> 1;
  int lr = lane & 15, lk = (lane >> 4) * 8, rowq = (lane >> 4) * 4;
  f32x4 acc[4][4] = {};
  #pragma unroll
  for (int kk = 0; kk < 64; kk += 32) {
    bf16x8 a[4], b[4];
    #pragma unroll
    for (int nf = 0; nf < 4; nf++) a[nf] = *(const bf16x8*)&Wb[wc * 64 + nf * 16 + lr][kk + lk];
    #pragma unroll
    for (int mf = 0; mf < 4; mf++) b[mf] = *(const bf16x8*)&Xb[wr * 64 + mf * 16 + lr][kk + lk];
    #pragma unroll
    for (int nf = 0; nf < 4; nf++)
      #pragma unroll
      for (int mf = 0; mf < 4; mf++)
        acc[nf][mf] = __builtin_amdgcn_mfma_f32_16x16x32_bf16(a[nf], b[mf], acc[nf][mf], 0, 0, 0);
  }
  #pragma unroll
  for (int mf = 0; mf < 4; mf++) {
    int si = wr * 64 + mf * 16 + lr;
    int s = slots[si];
    if (s < 0) continue;
    size_t base = (size_t)s * C + c0 + wc * 64;
    #pragma unroll
    for (int nf = 0; nf < 4; nf++) {
      ushort4 v = make_ushort4(f2bf(acc[nf][mf][0]), f2bf(acc[nf][mf][1]),
                               f2bf(acc[nf][mf][2]), f2bf(acc[nf][mf][3]));
      *(ushort4*)&y_slot[base + nf * 16 + rowq] = v;
    }
  }
}

// ---------------- combine: out = x + sum_k y_slot[t*8+k] ----------------
__global__ void combine_kernel(const float* __restrict__ x, const unsigned short* __restrict__ ys,
                               float* __restrict__ out) {
  int t = blockIdx.x, tid = threadIdx.x;
  int c = tid * 2;
  float s0 = 0.f, s1 = 0.f;
  #pragma unroll
  for (int k = 0; k < KA; k++) {
    unsigned u = *(const unsigned*)&ys[((size_t)t * KA + k) * C + c];
    s0 += bf2f((unsigned short)(u & 0xFFFF));
    s1 += bf2f((unsigned short)(u >> 16));
  }
  out[(size_t)t * C + c]     = x[(size_t)t * C + c] + s0;
  out[(size_t)t * C + c + 1] = x[(size_t)t * C + c + 1] + s1;
}

// ---------------- MFMA MLP1: h = gelu(x2 @ wi + bi), bf16 out ----------------
__global__ __launch_bounds__(256) void mlp1_mfma(
    const unsigned short* __restrict__ xb, const unsigned short* __restrict__ wit,
    const float* __restrict__ bi, const int* __restrict__ bucket,
    const int* __restrict__ counts, const int* __restrict__ map,
    const int* __restrict__ total, unsigned short* __restrict__ h) {
  if ((int)blockIdx.y >= *total) return;
  int ent = map[blockIdx.y];
  int e = ent >> 16, t0 = ent & 0xFFFF;
  int j0 = blockIdx.x * 128;
  int cnt = counts[e];
  int tid = threadIdx.x;
  __shared__ int slots[128];
  __shared__ __align__(16) unsigned short Xb[128][72];
  __shared__ __align__(16) unsigned short Wb[128][72];
  if (tid < 128) {
    int ii = t0 + tid;
    slots[tid] = (ii < cnt) ? bucket[(size_t)e * (T * KF) + ii] : -1;
  }
  __syncthreads();
  int lane = tid & 63, wid = tid >> 6;
  int wr = wid & 1, wc = wid >> 1;
  int lr = lane & 15, lk = (lane >> 4) * 8, rowq = (lane >> 4) * 4;
  f32x4 acc[4][4] = {};
  for (int kc = 0; kc < C; kc += 64) {
    __syncthreads();
    #pragma unroll
    for (int it = 0; it < 4; ++it) {
      int i = it * 256 + tid;
      int r = i >> 3, c8 = (i & 7) * 8;
      int s = slots[r];
      uint4 v = make_uint4(0u, 0u, 0u, 0u);
      if (s >= 0) v = *(const uint4*)&xb[(size_t)(s >> 1) * C + kc + c8];
      *(uint4*)&Xb[r][c8] = v;
    }
    #pragma unroll
    for (int it = 0; it < 4; ++it) {
      int i = it * 256 + tid;
      int r = i >> 3, c8 = (i & 7) * 8;
      *(uint4*)&Wb[r][c8] = *(const uint4*)&wit[((size_t)e * HID + j0 + r) * C + kc + c8];
    }
    __syncthreads();
    #pragma unroll
    for (int kk = 0; kk < 64; kk += 32) {
      bf16x8 a[4], b[4];
      #pragma unroll
      for (int nf = 0; nf < 4; nf++) a[nf] = *(const bf16x8*)&Wb[wc * 64 + nf * 16 + lr][kk + lk];
      #pragma unroll
      for (int mf = 0; mf < 4; mf++) b[mf] = *(const bf16x8*)&Xb[wr * 64 + mf * 16 + lr][kk + lk];
      #pragma unroll
      for (int nf = 0; nf < 4; nf++)
        #pragma unroll
        for (int mf = 0; mf < 4; mf++)
          acc[nf][mf] = __builtin_amdgcn_mfma_f32_16x16x32_bf16(a[nf], b[mf], acc[nf][mf], 0, 0, 0);
    }
  }
  #pragma unroll
  for (int mf = 0; mf < 4; mf++) {
    int s = slots[wr * 64 + mf * 16 + lr];
    if (s < 0) continue;
    #pragma unroll
    for (int nf = 0; nf < 4; nf++) {
      int j = j0 + wc * 64 + nf * 16 + rowq;
      const float4 b4 = *(const float4*)&bi[(size_t)e * HID + j];
      float v0 = acc[nf][mf][0] + b4.x, v1 = acc[nf][mf][1] + b4.y;
      float v2 = acc[nf][mf][2] + b4.z, v3 = acc[nf][mf][3] + b4.w;
      v0 = 0.5f * v0 * (1.f + erff(v0 * 0.70710678118654752f));
      v1 = 0.5f * v1 * (1.f + erff(v1 * 0.70710678118654752f));
      v2 = 0.5f * v2 * (1.f + erff(v2 * 0.70710678118654752f));
      v3 = 0.5f * v3 * (1.f + erff(v3 * 0.70710678118654752f));
      *(ushort4*)&h[(size_t)s * HID + j] = make_ushort4(f2bf(v0), f2bf(v1), f2bf(v2), f2bf(v3));
    }
  }
}

// ---------------- MFMA MLP2: dense per-slot bf16 (gate+bias folded), NO atomics ----------------
__global__ __launch_bounds__(256) void mlp2_mfma(
    const unsigned short* __restrict__ h, const unsigned short* __restrict__ wot,
    const float* __restrict__ bo, const float* __restrict__ gates2,
    const int* __restrict__ bucket, const int* __restrict__ counts,
    const int* __restrict__ map, const int* __restrict__ total,
    unsigned short* __restrict__ y2) {
  if ((int)blockIdx.y >= *total) return;
  int ent = map[blockIdx.y];
  int e = ent >> 16, t0 = ent & 0xFFFF;
  int c0 = blockIdx.x * 128;
  int cnt = counts[e];
  int tid = threadIdx.x;
  __shared__ int slots[128];
  __shared__ __align__(16) unsigned short Xb[128][72];
  __shared__ __align__(16) unsigned short Wb[128][72];
  if (tid < 128) {
    int ii = t0 + tid;
    slots[tid] = (ii < cnt) ? bucket[(size_t)e * (T * KF) + ii] : -1;
  }
  __syncthreads();
  int lane = tid & 63, wid = tid >> 6;
  int wr = wid & 1, wc = wid >> 1;
  int lr = lane & 15, lk = (lane >> 4) * 8, rowq = (lane >> 4) * 4;
  f32x4 acc[4][4] = {};
  for (int kc = 0; kc < HID; kc += 64) {
    __syncthreads();
    #pragma unroll
    for (int it = 0; it < 4; ++it) {
      int i = it * 256 + tid;
      int r = i >> 3, c8 = (i & 7) * 8;
      int s = slots[r];
      uint4 v = make_uint4(0u, 0u, 0u, 0u);
      if (s >= 0) v = *(const uint4*)&h[(size_t)s * HID + kc + c8];
      *(uint4*)&Xb[r][c8] = v;
    }
    #pragma unroll
    for (int it = 0; it < 4; ++it) {
      int i = it * 256 + tid;
      int r = i >> 3, c8 = (i & 7) * 8;
      *(uint4*)&Wb[r][c8] = *(const uint4*)&wot[((size_t)e * C + c0 + r) * HID + kc + c8];
    }
    __syncthreads();
    #pragma unroll
    for (int kk = 0; kk < 64; kk += 32) {
      bf16x8 a[4], b[4];
      #pragma unroll
      for (int nf = 0; nf < 4; nf++) a[nf] = *(const bf16x8*)&Wb[wc * 64 + nf * 16 + lr][kk + lk];
      #pragma unroll
      for (int mf = 0; mf < 4; mf++) b[mf] = *(const bf16x8*)&Xb[wr * 64 + mf * 16 + lr][kk + lk];
      #pragma unroll
      for (int nf = 0; nf < 4; nf++)
        #pragma unroll
        for (int mf = 0; mf < 4; mf++)
          acc[nf][mf] = __builtin_amdgcn_mfma_f32_16x16x32_bf16(a[nf], b[mf], acc[nf][mf], 0, 0, 0);
    }
  }
  #pragma unroll
  for (int mf = 0; mf < 4; mf++) {
    int si = wr * 64 + mf * 16 + lr;
    int s = slots[si];
    if (s < 0) continue;
    float g = gates2[s];
    #pragma unroll
    for (int nf = 0; nf < 4; nf++) {
      int cc = c0 + wc * 64 + nf * 16 + rowq;
      const float4 b4 = *(const float4*)&bo[(size_t)e * C + cc];
      ushort4 v = make_ushort4(f2bf(g * (acc[nf][mf][0] + b4.x)),
                               f2bf(g * (acc[nf][mf][1] + b4.y)),
                               f2bf(g * (acc[nf][mf][2] + b4.z)),
                               f2bf(g * (acc[nf][mf][3] + b4.w)));
      *(ushort4*)&y2[(size_t)s * C + cc] = v;
    }
  }
}

// ---------------- Final residual add (bf16 slots) ----------------
__global__ void final_kernel(const unsigned short* __restrict__ y2, float* __restrict__ xout) {
  int t = blockIdx.x, tid = threadIdx.x;
  int c = tid * 2;
  unsigned u0 = *(const unsigned*)&y2[(size_t)(t * 2) * C + c];
  unsigned u1 = *(const unsigned*)&y2[(size_t)(t * 2 + 1) * C + c];
  xout[(size_t)t * C + c]     += bf2f((unsigned short)(u0 & 0xFFFF)) + bf2f((unsigned short)(u1 & 0xFFFF));
  xout[(size_t)t * C + c + 1] += bf2f((unsigned short)(u0 >> 16)) + bf2f((unsigned short)(u1 >> 16));
}

// ---------------- Gating statistics reduction ----------------
template <int E, int K>
__global__ void reduce_gating(const float* __restrict__ probs, const float* __restrict__ lse,
                              const int* __restrict__ idxs, float* __restrict__ psum,
                              float* __restrict__ freq, float* __restrict__ zsum) {
  __shared__ float ps[E];
  __shared__ float fr[E];
  __shared__ float zs;
  int tid = threadIdx.x;
  if (tid < E) { ps[tid] = 0.f; fr[tid] = 0.f; }
  if (tid == 0) zs = 0.f;
  __syncthreads();
  int t = blockIdx.x * 256 + tid;
  if (t < T) {
    for (int e = 0; e < E; e++) atomicAdd(&ps[e], probs[(size_t)t * E + e]);
    for (int k = 0; k < K; k++) atomicAdd(&fr[idxs[(size_t)t * K + k]], 1.f);
    float l = lse[t];
    atomicAdd(&zs, l * l);
  }
  __syncthreads();
  if (tid < E) { atomicAdd(&psum[tid], ps[tid]); atomicAdd(&freq[tid], fr[tid]); }
  if (tid == 0) atomicAdd(zsum, zs);
}

__global__ void loss_kernel(const float* __restrict__ acc, float* __restrict__ out) {
  const float* p1 = acc;      const float* f1 = acc + 24; float z1 = acc[48];
  const float* p2 = acc + 49; const float* f2 = acc + 65; float z2 = acc[81];
  float sp1 = 0.f, sf1 = 0.f;
  for (int e = 0; e < 24; e++) { sp1 += p1[e]; sf1 += f1[e]; }
  float sw1 = 0.f;
  for (int e = 0; e < 24; e++) sw1 += (p1[e] / sp1) * (f1[e] / sf1);
  sw1 *= 24.f;
  float sp2 = 0.f, sf2 = 0.f;
  for (int e = 0; e < 16; e++) { sp2 += p2[e]; sf2 += f2[e]; }
  float sw2 = 0.f;
  for (int e = 0; e < 16; e++) sw2 += (p2[e] / sp2) * (f2[e] / sf2);
  sw2 *= 16.f;
  out[0] = 0.01f * sw1 + 0.001f * (z1 / T) + 0.01f * sw2 + 0.001f * (z2 / T);
}

}  // namespace

extern "C" void kernel_launch(void* const* d_in, const int* in_sizes, int n_in,
                              void* d_out, int out_size, void* d_ws, size_t ws_size,
                              hipStream_t stream) {
  const float* x      = (const float*)d_in[0];
  const int*   task   = (const int*)d_in[1];
  const float* n1g    = (const float*)d_in[2];
  const float* n1b    = (const float*)d_in[3];
  const float* gate_a = (const float*)d_in[4];
  const float* wq     = (const float*)d_in[5];
  const float* wo_a   = (const float*)d_in[6];
  const float* kvw    = (const float*)d_in[7];
  const float* kvb    = (const float*)d_in[8];
  const float* n2g    = (const float*)d_in[9];
  const float* n2b    = (const float*)d_in[10];
  const float* gate_m = (const float*)d_in[11];
  const float* wi     = (const float*)d_in[12];
  const float* bi     = (const float*)d_in[13];
  const float* wo_m   = (const float*)d_in[14];
  const float* bo     = (const float*)d_in[15];
  float* out = (float*)d_out;

  char* p = (char*)d_ws;
  float* x1 = (float*)p;             p += (size_t)T * C * 4;
  unsigned short* x1b = (unsigned short*)p; p += (size_t)T * C * 2;
  unsigned short* qb = (unsigned short*)p;  p += (size_t)T * KA * HD * 2;
  unsigned short* ob = (unsigned short*)p;  p += (size_t)T * KA * HD * 2;
  unsigned short* Kb = (unsigned short*)p;  p += (size_t)T * HD * 2;
  unsigned short* Vt = (unsigned short*)p;  p += (size_t)T * HD * 2;
  // union region: y_slot (33.5MB) then reused as h (16.8MB) + y2_slot (8.4MB)
  char* un = p;                      p += (size_t)T * KA * C * 2;
  unsigned short* y_slot  = (unsigned short*)un;
  unsigned short* h       = (unsigned short*)un;
  unsigned short* y2_slot = (unsigned short*)(un + (size_t)T * KF * HID * 2);
  unsigned short* wqt = (unsigned short*)p;  p += (size_t)EA * C * HD * 2;
  unsigned short* woat = (unsigned short*)p; p += (size_t)EA * HD * C * 2;
  unsigned short* wit = (unsigned short*)p;  p += (size_t)EF * C * HID * 2;
  unsigned short* womt = (unsigned short*)p; p += (size_t)EF * HID * C * 2;
  unsigned short* kvwt = (unsigned short*)p; p += (size_t)(2 * HD) * C * 2;
  float* probs1 = (float*)p;         p += (size_t)T * EA * 4;
  float* lse1 = (float*)p;           p += (size_t)T * 4;
  float* gates1 = (float*)p;         p += (size_t)T * KA * 4;
  int* idx1 = (int*)p;               p += (size_t)T * KA * 4;
  float* probs2 = (float*)p;         p += (size_t)T * EF * 4;
  float* lse2 = (float*)p;           p += (size_t)T * 4;
  float* gates2 = (float*)p;         p += (size_t)T * KF * 4;
  int* idx2 = (int*)p;               p += (size_t)T * KF * 4;
  int* bucket_a = (int*)p;           p += (size_t)EA * (T * KA) * 4;
  int* bucket_f = (int*)p;           p += (size_t)EF * (T * KF) * 4;
  int* counts_a = (int*)p;           p += 32 * 4;
  int* counts_f = (int*)p;           p += 32 * 4;
  float* accum = (float*)p;          p += 128 * 4;
  int* maps = (int*)p;               p += 768 * 4;
  int* totals = (int*)p;             p += 4 * 4;

  hipMemsetAsync(counts_a, 0, (32 + 32 + 128) * 4, stream);

  tcvt_kernel<<<dim3(2, 16, 24), 256, 0, stream>>>(wq, wqt, C, HD);
  tcvt_kernel<<<dim3(16, 2, 24), 256, 0, stream>>>(wo_a, woat, HD, C);
  tcvt_kernel<<<dim3(32, 16, 16), 256, 0, stream>>>(wi, wit, C, HID);
  tcvt_kernel<<<dim3(16, 32, 16), 256, 0, stream>>>(wo_m, womt, HID, C);
  tcvt_kernel<<<dim3(4, 16, 1), 256, 0, stream>>>(kvw, kvwt, C, 2 * HD);

  ln_kernel<<<T, 256, 0, stream>>>(x, n1g, n1b, x1, x1b);
  gating_kernel<EA, KA, 8><<<T, 256, 0, stream>>>(x1, gate_a, task, probs1, lse1, gates1, idx1);
  bucket_kernel<<<(T * KA) / 256, 256, 0, stream>>>(idx1, T * KA, T * KA, counts_a, bucket_a);
  build_maps_a<<<1, 64, 0, stream>>>(counts_a, maps, totals);
  qgemm_mfma<<<dim3(1, 152), 256, 0, stream>>>(x1b, wqt, bucket_a, counts_a, maps, totals, qb);
  kv_mfma<<<T / 16, 256, 0, stream>>>(x1b, kvwt, kvb, Kb, Vt);
  attn_mfma<<<dim3(NS / 64, KA, NB), 256, 0, stream>>>(qb, Kb, Vt, ob);
  oproj_mfma<<<dim3(4, 280), 256, 0, stream>>>(ob, woat, gates1, bucket_a, counts_a,
                                               maps + 256, totals + 1, y_slot);
  combine_kernel<<<T, 256, 0, stream>>>(x, y_slot, out);
  ln_kernel<<<T, 256, 0, stream>>>(out, n2g, n2b, x1, x1b);
  gating_kernel<EF, KF, 16><<<T, 256, 0, stream>>>(x1, gate_m, task, probs2, lse2, gates2, idx2);
  bucket_kernel<<<(T * KF) / 256, 256, 0, stream>>>(idx2, T * KF, T * KF, counts_f, bucket_f);
  build_maps_f<<<1, 64, 0, stream>>>(counts_f, maps, totals);
  mlp1_mfma<<<dim3(8, 80), 256, 0, stream>>>(x1b, wit, bi, bucket_f, counts_f,
                                             maps + 600, totals + 2, h);
  mlp2_mfma<<<dim3(4, 80), 256, 0, stream>>>(h, womt, bo, gates2, bucket_f, counts_f,
                                             maps + 600, totals + 2, y2_slot);
  final_kernel<<<T, 256, 0, stream>>>(y2_slot, out);
  reduce_gating<EA, KA><<<16, 256, 0, stream>>>(probs1, lse1, idx1, accum, accum + 24, accum + 48);
  reduce_gating<EF, KF><<<16, 256, 0, stream>>>(probs2, lse2, idx2, accum + 49, accum + 65, accum + 81);
  loss_kernel<<<1, 1, 0, stream>>>(accum, out + (size_t)T * C);
}

// Round 7
// 439.245 us; speedup vs baseline: 3.8874x; 1.2098x over previous
//
#include <hip/hip_runtime.h>
#include <math.h>

namespace {

constexpr int T   = 4096;
constexpr int C   = 512;
constexpr int NB  = 8;
constexpr int NS  = 512;
constexpr int HD  = 64;
constexpr int KA  = 8;
constexpr int EA  = 24;
constexpr int EF  = 16;
constexpr int KF  = 2;
constexpr int HID = 1024;

typedef __attribute__((ext_vector_type(8))) short bf16x8;
typedef __attribute__((ext_vector_type(4))) float f32x4;

__device__ inline unsigned short f2bf(float f) {
  unsigned u = __float_as_uint(f);
  return (unsigned short)((u + 0x7FFFu + ((u >> 16) & 1u)) >> 16);
}
__device__ inline float bf2f(unsigned short u) {
  return __uint_as_float((unsigned)u << 16);
}

// ---------------- Fused LayerNorm + Gating: one block (256 thr) per token ----------------
// LN result stays in LDS; bf16 LN output written for the GEMMs; fp32 x1 buffer eliminated.
template <int E, int K, int TPE>
__global__ void ln_gate_kernel(const float* __restrict__ in, const float* __restrict__ g,
                               const float* __restrict__ b, const float* __restrict__ gate_all,
                               const int* __restrict__ task, unsigned short* __restrict__ outb,
                               float* __restrict__ probs, float* __restrict__ lse_out,
                               float* __restrict__ gates, int* __restrict__ idxs) {
  int t = blockIdx.x, tid = threadIdx.x;
  const float* row = in + (size_t)t * C;
  __shared__ float xs[C];
  __shared__ float red[256];
  __shared__ float lg[E];
  float v0 = row[tid], v1 = row[tid + 256];
  red[tid] = v0 + v1;
  __syncthreads();
  for (int st = 128; st > 0; st >>= 1) {
    if (tid < st) red[tid] += red[tid + st];
    __syncthreads();
  }
  float mean = red[0] * (1.f / C);
  __syncthreads();
  float d0 = v0 - mean, d1 = v1 - mean;
  red[tid] = d0 * d0 + d1 * d1;
  __syncthreads();
  for (int st = 128; st > 0; st >>= 1) {
    if (tid < st) red[tid] += red[tid + st];
    __syncthreads();
  }
  float r = rsqrtf(red[0] * (1.f / C) + 1e-5f);
  float o0 = d0 * r * g[tid] + b[tid];
  float o1 = d1 * r * g[tid + 256] + b[tid + 256];
  outb[(size_t)t * C + tid]       = f2bf(o0);
  outb[(size_t)t * C + tid + 256] = f2bf(o1);
  xs[tid] = o0;
  xs[tid + 256] = o1;
  __syncthreads();
  // gating logits
  const float* W = gate_all + (size_t)task[0] * C * E;
  if (tid < E * TPE) {
    int e = tid / TPE, l = tid % TPE;
    float acc = 0.f;
    for (int c = l; c < C; c += TPE) acc += xs[c] * W[(size_t)c * E + e];
    #pragma unroll
    for (int m = TPE >> 1; m > 0; m >>= 1) acc += __shfl_xor(acc, m);
    if (l == 0) lg[e] = acc;
  }
  __syncthreads();
  if (tid < 64) {
    float lgv = (tid < E) ? lg[tid] : -3.0e38f;
    float mx = lgv;
    #pragma unroll
    for (int m = 1; m < 64; m <<= 1) mx = fmaxf(mx, __shfl_xor(mx, m));
    float pe = (tid < E) ? expf(lgv - mx) : 0.f;
    float sum = pe;
    #pragma unroll
    for (int m = 1; m < 64; m <<= 1) sum += __shfl_xor(sum, m);
    float inv = 1.f / sum;
    float prob = pe * inv;
    if (tid < E) probs[(size_t)t * E + tid] = prob;
    if (tid == 0) lse_out[t] = mx + logf(sum);
    // iterative top-K, lax.top_k tie-break (strict >, lowest index wins)
    float pv = (tid < E) ? prob : -1.f;
    float gsum = 0.f, myv = 0.f; int myi = 0;
    for (int k = 0; k < K; k++) {
      float bv = pv; int bi_ = tid;
      #pragma unroll
      for (int m = 1; m < 64; m <<= 1) {
        float ov = __shfl_xor(bv, m); int oi = __shfl_xor(bi_, m);
        if (ov > bv || (ov == bv && oi < bi_)) { bv = ov; bi_ = oi; }
      }
      gsum += bv;
      if (tid == k) { myv = bv; myi = bi_; }
      if (tid == bi_) pv = -1.f;
    }
    if (tid < K) {
      float ginv = 1.f / (gsum + 1e-6f);
      gates[(size_t)t * K + tid] = myv * ginv;
      idxs[(size_t)t * K + tid]  = myi;
    }
  }
}

// ---------------- bucket by expert: LDS-aggregated, ~E global atomics per block ----------------
template <int E>
__global__ __launch_bounds__(512) void bucket_kernel(const int* __restrict__ idx, int nslots,
                                                     int stride, int* counts, int* bucket) {
  __shared__ int lcount[E];
  __shared__ int lbase[E];
  int tid = threadIdx.x;
  if (tid < E) lcount[tid] = 0;
  __syncthreads();
  int s = blockIdx.x * 512 + tid;
  int e = 0, lpos = 0;
  bool valid = (s < nslots);
  if (valid) {
    e = idx[s];
    lpos = atomicAdd(&lcount[e], 1);
  }
  __syncthreads();
  if (tid < E) lbase[tid] = lcount[tid] ? atomicAdd(&counts[tid], lcount[tid]) : 0;
  __syncthreads();
  if (valid) bucket[(size_t)e * stride + lbase[e] + lpos] = s;
}

// ---------------- flat (expert, tile) maps ----------------
__global__ void build_maps_a(const int* __restrict__ counts, int* __restrict__ maps,
                             int* __restrict__ totals) {
  if (threadIdx.x != 0) return;
  int n = 0;
  for (int e = 0; e < EA; e++) { int c = counts[e]; for (int t0 = 0; t0 < c; t0 += 256) maps[n++] = (e << 16) | t0; }
  totals[0] = n;
  n = 0;
  for (int e = 0; e < EA; e++) { int c = counts[e]; for (int t0 = 0; t0 < c; t0 += 128) maps[256 + n++] = (e << 16) | t0; }
  totals[1] = n;
}
__global__ void build_maps_f(const int* __restrict__ counts, int* __restrict__ maps,
                             int* __restrict__ totals) {
  if (threadIdx.x != 0) return;
  int n = 0;
  for (int e = 0; e < EF; e++) { int c = counts[e]; for (int t0 = 0; t0 < c; t0 += 128) maps[600 + n++] = (e << 16) | t0; }
  totals[2] = n;
}

// ---------------- transpose + cvt weights: [E][K][N] f32 -> [E][N][K] bf16 ----------------
__global__ void tcvt_kernel(const float* __restrict__ src, unsigned short* __restrict__ dst,
                            int K, int N) {
  int e = blockIdx.z;
  int kt = blockIdx.y * 32, nt = blockIdx.x * 32;
  __shared__ float tile[32][33];
  int tid = threadIdx.x;
  const float* S = src + (size_t)e * K * N;
  for (int i = tid; i < 32 * 32; i += 256) {
    int r = i >> 5, c = i & 31;
    tile[r][c] = S[(size_t)(kt + r) * N + nt + c];
  }
  __syncthreads();
  unsigned short* D = dst + (size_t)e * K * N;
  for (int i = tid; i < 32 * 8; i += 256) {
    int n = i >> 3, k4 = (i & 7) * 4;
    ushort4 v;
    v.x = f2bf(tile[k4 + 0][n]); v.y = f2bf(tile[k4 + 1][n]);
    v.z = f2bf(tile[k4 + 2][n]); v.w = f2bf(tile[k4 + 3][n]);
    *(ushort4*)&D[(size_t)(nt + n) * K + kt + k4] = v;
  }
}

// ---------------- MFMA Q GEMM: 256 slots x 64 out, K=512 -> bf16 q (pre-scaled) ----------------
__global__ __launch_bounds__(256) void qgemm_mfma(
    const unsigned short* __restrict__ xb, const unsigned short* __restrict__ wqt,
    const int* __restrict__ bucket, const int* __restrict__ counts,
    const int* __restrict__ map, const int* __restrict__ total,
    unsigned short* __restrict__ qb) {
  if ((int)blockIdx.y >= *total) return;
  int ent = map[blockIdx.y];
  int e = ent >> 16, t0 = ent & 0xFFFF;
  int cnt = counts[e];
  int tid = threadIdx.x;
  __shared__ int slots[256];
  __shared__ __align__(16) unsigned short Xb[256][72];
  __shared__ __align__(16) unsigned short Wb[64][72];
  {
    int ii = t0 + tid;
    slots[tid] = (ii < cnt) ? bucket[(size_t)e * (T * KA) + ii] : -1;
  }
  __syncthreads();
  int lane = tid & 63, wid = tid >> 6;
  int lr = lane & 15, lk = (lane >> 4) * 8, rowq = (lane >> 4) * 4;
  f32x4 acc[4][4] = {};
  for (int kc = 0; kc < C; kc += 64) {
    __syncthreads();
    #pragma unroll
    for (int it = 0; it < 8; ++it) {
      int i = it * 256 + tid;
      int r = i >> 3, c8 = (i & 7) * 8;
      int s = slots[r];
      uint4 v = make_uint4(0u, 0u, 0u, 0u);
      if (s >= 0) v = *(const uint4*)&xb[(size_t)(s >> 3) * C + kc + c8];
      *(uint4*)&Xb[r][c8] = v;
    }
    #pragma unroll
    for (int it = 0; it < 2; ++it) {
      int i = it * 256 + tid;
      int r = i >> 3, c8 = (i & 7) * 8;
      *(uint4*)&Wb[r][c8] = *(const uint4*)&wqt[((size_t)e * HD + r) * C + kc + c8];
    }
    __syncthreads();
    #pragma unroll
    for (int kk = 0; kk < 64; kk += 32) {
      bf16x8 a[4], b[4];
      #pragma unroll
      for (int nf = 0; nf < 4; nf++) a[nf] = *(const bf16x8*)&Wb[nf * 16 + lr][kk + lk];
      #pragma unroll
      for (int mf = 0; mf < 4; mf++) b[mf] = *(const bf16x8*)&Xb[wid * 64 + mf * 16 + lr][kk + lk];
      #pragma unroll
      for (int nf = 0; nf < 4; nf++)
        #pragma unroll
        for (int mf = 0; mf < 4; mf++)
          acc[nf][mf] = __builtin_amdgcn_mfma_f32_16x16x32_bf16(a[nf], b[mf], acc[nf][mf], 0, 0, 0);
    }
  }
  #pragma unroll
  for (int mf = 0; mf < 4; mf++) {
    int s = slots[wid * 64 + mf * 16 + lr];
    if (s < 0) continue;
    #pragma unroll
    for (int nf = 0; nf < 4; nf++) {
      ushort4 v = make_ushort4(f2bf(0.125f * acc[nf][mf][0]), f2bf(0.125f * acc[nf][mf][1]),
                               f2bf(0.125f * acc[nf][mf][2]), f2bf(0.125f * acc[nf][mf][3]));
      *(ushort4*)&qb[(size_t)s * HD + nf * 16 + rowq] = v;
    }
  }
}

// ---------------- MFMA KV GEMM: 16 tokens x 128 cols per block, 256 blocks ----------------
__global__ __launch_bounds__(256) void kv_mfma(
    const unsigned short* __restrict__ xb, const unsigned short* __restrict__ kvwt,
    const float* __restrict__ kvb, unsigned short* __restrict__ Kb,
    unsigned short* __restrict__ Vt) {
  int t0 = blockIdx.x * 16;
  int tid = threadIdx.x;
  __shared__ __align__(16) unsigned short Xs[16][72];
  __shared__ __align__(16) unsigned short Ws[128][72];
  int lane = tid & 63, w = tid >> 6;
  int lr = lane & 15, lk = (lane >> 4) * 8, rowq = (lane >> 4) * 4;
  f32x4 acc[2] = {};
  for (int kc = 0; kc < C; kc += 64) {
    __syncthreads();
    if (tid < 128) {
      int r = tid >> 3, c8 = (tid & 7) * 8;
      *(uint4*)&Xs[r][c8] = *(const uint4*)&xb[(size_t)(t0 + r) * C + kc + c8];
    }
    #pragma unroll
    for (int it = 0; it < 4; ++it) {
      int i = it * 256 + tid;
      int r = i >> 3, c8 = (i & 7) * 8;
      *(uint4*)&Ws[r][c8] = *(const uint4*)&kvwt[(size_t)r * C + kc + c8];
    }
    __syncthreads();
    #pragma unroll
    for (int kk = 0; kk < 64; kk += 32) {
      bf16x8 xf = *(const bf16x8*)&Xs[lr][kk + lk];
      #pragma unroll
      for (int cf = 0; cf < 2; cf++) {
        bf16x8 wf = *(const bf16x8*)&Ws[w * 32 + cf * 16 + lr][kk + lk];
        acc[cf] = __builtin_amdgcn_mfma_f32_16x16x32_bf16(wf, xf, acc[cf], 0, 0, 0);
      }
    }
  }
  int t = t0 + lr;
  int bb = t >> 9, n = t & (NS - 1);
  #pragma unroll
  for (int cf = 0; cf < 2; cf++) {
    #pragma unroll
    for (int r2 = 0; r2 < 4; r2++) {
      int c = w * 32 + cf * 16 + rowq + r2;
      float v = acc[cf][r2] + kvb[c];
      if (c < HD) Kb[(size_t)t * HD + c] = f2bf(v);
      else        Vt[((size_t)bb * HD + (c - HD)) * NS + n] = f2bf(v);
    }
  }
}

// ---------------- MFMA flash attention: block per (qtile64, head, batch) ----------------
__global__ __launch_bounds__(256) void attn_mfma(
    const unsigned short* __restrict__ qb, const unsigned short* __restrict__ Kb,
    const unsigned short* __restrict__ Vt, unsigned short* __restrict__ ob) {
  int qt = blockIdx.x, h = blockIdx.y, b = blockIdx.z;
  int tid = threadIdx.x;
  __shared__ __align__(16) unsigned short Qs[64][72];
  __shared__ __align__(16) unsigned short Ks[64][72];
  __shared__ __align__(16) unsigned short Vs[64][72];
  __shared__ __align__(16) unsigned short Ps[64][72];
  int i0 = qt * 64;
  #pragma unroll
  for (int it = 0; it < 2; ++it) {
    int i = it * 256 + tid;
    int r = i >> 3, c8 = (i & 7) * 8;
    *(uint4*)&Qs[r][c8] = *(const uint4*)&qb[(((size_t)(b * NS + i0 + r)) * KA + h) * HD + c8];
  }
  int lane = tid & 63, w = tid >> 6;
  int lr = lane & 15, lk = (lane >> 4) * 8, rowq = (lane >> 4) * 4;
  f32x4 acc_o[4] = {};
  float m_run = -3.0e38f, l_run = 0.f;
  for (int jt = 0; jt < NS / 64; ++jt) {
    __syncthreads();
    #pragma unroll
    for (int it = 0; it < 2; ++it) {
      int i = it * 256 + tid;
      int r = i >> 3, c8 = (i & 7) * 8;
      *(uint4*)&Ks[r][c8] = *(const uint4*)&Kb[((size_t)(b * NS + jt * 64 + r)) * HD + c8];
      *(uint4*)&Vs[r][c8] = *(const uint4*)&Vt[((size_t)b * HD + r) * NS + jt * 64 + c8];
    }
    __syncthreads();
    f32x4 acc_s[4] = {};
    #pragma unroll
    for (int kk = 0; kk < 64; kk += 32) {
      bf16x8 qf = *(const bf16x8*)&Qs[w * 16 + lr][kk + lk];
      #pragma unroll
      for (int kf = 0; kf < 4; kf++) {
        bf16x8 kr = *(const bf16x8*)&Ks[kf * 16 + lr][kk + lk];
        acc_s[kf] = __builtin_amdgcn_mfma_f32_16x16x32_bf16(kr, qf, acc_s[kf], 0, 0, 0);
      }
    }
    float pmax = acc_s[0][0];
    #pragma unroll
    for (int kf = 0; kf < 4; kf++)
      #pragma unroll
      for (int r = 0; r < 4; r++) pmax = fmaxf(pmax, acc_s[kf][r]);
    pmax = fmaxf(pmax, __shfl_xor(pmax, 16));
    pmax = fmaxf(pmax, __shfl_xor(pmax, 32));
    float m_new = fmaxf(m_run, pmax);
    float scl = expf(m_run - m_new);
    float rs = 0.f;
    #pragma unroll
    for (int kf = 0; kf < 4; kf++)
      #pragma unroll
      for (int r = 0; r < 4; r++) {
        float pv = expf(acc_s[kf][r] - m_new);
        rs += pv;
        Ps[w * 16 + lr][kf * 16 + rowq + r] = f2bf(pv);
      }
    rs += __shfl_xor(rs, 16);
    rs += __shfl_xor(rs, 32);
    l_run = l_run * scl + rs;
    m_run = m_new;
    __syncthreads();
    #pragma unroll
    for (int df = 0; df < 4; df++) {
      acc_o[df][0] *= scl; acc_o[df][1] *= scl;
      acc_o[df][2] *= scl; acc_o[df][3] *= scl;
    }
    #pragma unroll
    for (int kk = 0; kk < 64; kk += 32) {
      bf16x8 pf = *(const bf16x8*)&Ps[w * 16 + lr][kk + lk];
      #pragma unroll
      for (int df = 0; df < 4; df++) {
        bf16x8 vf = *(const bf16x8*)&Vs[df * 16 + lr][kk + lk];
        acc_o[df] = __builtin_amdgcn_mfma_f32_16x16x32_bf16(vf, pf, acc_o[df], 0, 0, 0);
      }
    }
  }
  float inv = 1.f / l_run;
  int token = b * NS + i0 + w * 16 + lr;
  #pragma unroll
  for (int df = 0; df < 4; df++) {
    ushort4 v = make_ushort4(f2bf(acc_o[df][0] * inv), f2bf(acc_o[df][1] * inv),
                             f2bf(acc_o[df][2] * inv), f2bf(acc_o[df][3] * inv));
    *(ushort4*)&ob[((size_t)token * KA + h) * HD + df * 16 + rowq] = v;
  }
}

// ---------------- MFMA output proj: dense per-slot bf16 (gate folded), NO atomics ----------------
__global__ __launch_bounds__(256) void oproj_mfma(
    const unsigned short* __restrict__ ob, const unsigned short* __restrict__ wot,
    const float* __restrict__ gates, const int* __restrict__ bucket,
    const int* __restrict__ counts, const int* __restrict__ map,
    const int* __restrict__ total, unsigned short* __restrict__ y_slot) {
  if ((int)blockIdx.y >= *total) return;
  int ent = map[blockIdx.y];
  int e = ent >> 16, t0 = ent & 0xFFFF;
  int c0 = blockIdx.x * 128;
  int cnt = counts[e];
  int tid = threadIdx.x;
  __shared__ int slots[128];
  __shared__ float gs[128];
  __shared__ __align__(16) unsigned short Xb[128][72];
  __shared__ __align__(16) unsigned short Wb[128][72];
  if (tid < 128) {
    int ii = t0 + tid;
    int s = (ii < cnt) ? bucket[(size_t)e * (T * KA) + ii] : -1;
    slots[tid] = s;
    gs[tid] = (s >= 0) ? gates[s] : 0.f;
  }
  __syncthreads();
  #pragma unroll
  for (int it = 0; it < 4; ++it) {
    int i = it * 256 + tid;
    int r = i >> 3, c8 = (i & 7) * 8;
    int s = slots[r];
    uint4 vo = make_uint4(0u, 0u, 0u, 0u);
    if (s >= 0) {
      float g = gs[r];
      uint4 u = *(const uint4*)&ob[(size_t)s * HD + c8];
      const unsigned short* us = (const unsigned short*)&u;
      unsigned short* vs = (unsigned short*)&vo;
      #pragma unroll
      for (int k = 0; k < 8; k++) vs[k] = f2bf(g * bf2f(us[k]));
    }
    *(uint4*)&Xb[r][c8] = vo;
  }
  #pragma unroll
  for (int it = 0; it < 4; ++it) {
    int i = it * 256 + tid;
    int r = i >> 3, c8 = (i & 7) * 8;
    *(uint4*)&Wb[r][c8] = *(const uint4*)&wot[((size_t)e * C + c0 + r) * HD + c8];
  }
  __syncthreads();
  int lane = tid & 63, wid = tid >> 6;
  int wr = wid & 1, wc = wid >> 1;
  int lr = lane & 15, lk = (lane >> 4) * 8, rowq = (lane >> 4) * 4;
  f32x4 acc[4][4] = {};
  #pragma unroll
  for (int kk = 0; kk < 64; kk += 32) {
    bf16x8 a[4], b[4];
    #pragma unroll
    for (int nf = 0; nf < 4; nf++) a[nf] = *(const bf16x8*)&Wb[wc * 64 + nf * 16 + lr][kk + lk];
    #pragma unroll
    for (int mf = 0; mf < 4; mf++) b[mf] = *(const bf16x8*)&Xb[wr * 64 + mf * 16 + lr][kk + lk];
    #pragma unroll
    for (int nf = 0; nf < 4; nf++)
      #pragma unroll
      for (int mf = 0; mf < 4; mf++)
        acc[nf][mf] = __builtin_amdgcn_mfma_f32_16x16x32_bf16(a[nf], b[mf], acc[nf][mf], 0, 0, 0);
  }
  #pragma unroll
  for (int mf = 0; mf < 4; mf++) {
    int si = wr * 64 + mf * 16 + lr;
    int s = slots[si];
    if (s < 0) continue;
    size_t base = (size_t)s * C + c0 + wc * 64;
    #pragma unroll
    for (int nf = 0; nf < 4; nf++) {
      ushort4 v = make_ushort4(f2bf(acc[nf][mf][0]), f2bf(acc[nf][mf][1]),
                               f2bf(acc[nf][mf][2]), f2bf(acc[nf][mf][3]));
      *(ushort4*)&y_slot[base + nf * 16 + rowq] = v;
    }
  }
}

// ---------------- combine: out = x + sum_k y_slot[t*8+k] ----------------
__global__ void combine_kernel(const float* __restrict__ x, const unsigned short* __restrict__ ys,
                               float* __restrict__ out) {
  int t = blockIdx.x, tid = threadIdx.x;
  int c = tid * 2;
  float s0 = 0.f, s1 = 0.f;
  #pragma unroll
  for (int k = 0; k < KA; k++) {
    unsigned u = *(const unsigned*)&ys[((size_t)t * KA + k) * C + c];
    s0 += bf2f((unsigned short)(u & 0xFFFF));
    s1 += bf2f((unsigned short)(u >> 16));
  }
  out[(size_t)t * C + c]     = x[(size_t)t * C + c] + s0;
  out[(size_t)t * C + c + 1] = x[(size_t)t * C + c + 1] + s1;
}

// ---------------- MFMA MLP1: h = gelu(x2 @ wi + bi), bf16 out ----------------
__global__ __launch_bounds__(256) void mlp1_mfma(
    const unsigned short* __restrict__ xb, const unsigned short* __restrict__ wit,
    const float* __restrict__ bi, const int* __restrict__ bucket,
    const int* __restrict__ counts, const int* __restrict__ map,
    const int* __restrict__ total, unsigned short* __restrict__ h) {
  if ((int)blockIdx.y >= *total) return;
  int ent = map[blockIdx.y];
  int e = ent >> 16, t0 = ent & 0xFFFF;
  int j0 = blockIdx.x * 128;
  int cnt = counts[e];
  int tid = threadIdx.x;
  __shared__ int slots[128];
  __shared__ __align__(16) unsigned short Xb[128][72];
  __shared__ __align__(16) unsigned short Wb[128][72];
  if (tid < 128) {
    int ii = t0 + tid;
    slots[tid] = (ii < cnt) ? bucket[(size_t)e * (T * KF) + ii] : -1;
  }
  __syncthreads();
  int lane = tid & 63, wid = tid >> 6;
  int wr = wid & 1, wc = wid >> 1;
  int lr = lane & 15, lk = (lane >> 4) * 8, rowq = (lane >> 4) * 4;
  f32x4 acc[4][4] = {};
  for (int kc = 0; kc < C; kc += 64) {
    __syncthreads();
    #pragma unroll
    for (int it = 0; it < 4; ++it) {
      int i = it * 256 + tid;
      int r = i >> 3, c8 = (i & 7) * 8;
      int s = slots[r];
      uint4 v = make_uint4(0u, 0u, 0u, 0u);
      if (s >= 0) v = *(const uint4*)&xb[(size_t)(s >> 1) * C + kc + c8];
      *(uint4*)&Xb[r][c8] = v;
    }
    #pragma unroll
    for (int it = 0; it < 4; ++it) {
      int i = it * 256 + tid;
      int r = i >> 3, c8 = (i & 7) * 8;
      *(uint4*)&Wb[r][c8] = *(const uint4*)&wit[((size_t)e * HID + j0 + r) * C + kc + c8];
    }
    __syncthreads();
    #pragma unroll
    for (int kk = 0; kk < 64; kk += 32) {
      bf16x8 a[4], b[4];
      #pragma unroll
      for (int nf = 0; nf < 4; nf++) a[nf] = *(const bf16x8*)&Wb[wc * 64 + nf * 16 + lr][kk + lk];
      #pragma unroll
      for (int mf = 0; mf < 4; mf++) b[mf] = *(const bf16x8*)&Xb[wr * 64 + mf * 16 + lr][kk + lk];
      #pragma unroll
      for (int nf = 0; nf < 4; nf++)
        #pragma unroll
        for (int mf = 0; mf < 4; mf++)
          acc[nf][mf] = __builtin_amdgcn_mfma_f32_16x16x32_bf16(a[nf], b[mf], acc[nf][mf], 0, 0, 0);
    }
  }
  #pragma unroll
  for (int mf = 0; mf < 4; mf++) {
    int s = slots[wr * 64 + mf * 16 + lr];
    if (s < 0) continue;
    #pragma unroll
    for (int nf = 0; nf < 4; nf++) {
      int j = j0 + wc * 64 + nf * 16 + rowq;
      const float4 b4 = *(const float4*)&bi[(size_t)e * HID + j];
      float v0 = acc[nf][mf][0] + b4.x, v1 = acc[nf][mf][1] + b4.y;
      float v2 = acc[nf][mf][2] + b4.z, v3 = acc[nf][mf][3] + b4.w;
      v0 = 0.5f * v0 * (1.f + erff(v0 * 0.70710678118654752f));
      v1 = 0.5f * v1 * (1.f + erff(v1 * 0.70710678118654752f));
      v2 = 0.5f * v2 * (1.f + erff(v2 * 0.70710678118654752f));
      v3 = 0.5f * v3 * (1.f + erff(v3 * 0.70710678118654752f));
      *(ushort4*)&h[(size_t)s * HID + j] = make_ushort4(f2bf(v0), f2bf(v1), f2bf(v2), f2bf(v3));
    }
  }
}

// ---------------- MFMA MLP2: dense per-slot bf16 (gate+bias folded), NO atomics ----------------
__global__ __launch_bounds__(256) void mlp2_mfma(
    const unsigned short* __restrict__ h, const unsigned short* __restrict__ wot,
    const float* __restrict__ bo, const float* __restrict__ gates2,
    const int* __restrict__ bucket, const int* __restrict__ counts,
    const int* __restrict__ map, const int* __restrict__ total,
    unsigned short* __restrict__ y2) {
  if ((int)blockIdx.y >= *total) return;
  int ent = map[blockIdx.y];
  int e = ent >> 16, t0 = ent & 0xFFFF;
  int c0 = blockIdx.x * 128;
  int cnt = counts[e];
  int tid = threadIdx.x;
  __shared__ int slots[128];
  __shared__ __align__(16) unsigned short Xb[128][72];
  __shared__ __align__(16) unsigned short Wb[128][72];
  if (tid < 128) {
    int ii = t0 + tid;
    slots[tid] = (ii < cnt) ? bucket[(size_t)e * (T * KF) + ii] : -1;
  }
  __syncthreads();
  int lane = tid & 63, wid = tid >> 6;
  int wr = wid & 1, wc = wid >> 1;
  int lr = lane & 15, lk = (lane >> 4) * 8, rowq = (lane >> 4) * 4;
  f32x4 acc[4][4] = {};
  for (int kc = 0; kc < HID; kc += 64) {
    __syncthreads();
    #pragma unroll
    for (int it = 0; it < 4; ++it) {
      int i = it * 256 + tid;
      int r = i >> 3, c8 = (i & 7) * 8;
      int s = slots[r];
      uint4 v = make_uint4(0u, 0u, 0u, 0u);
      if (s >= 0) v = *(const uint4*)&h[(size_t)s * HID + kc + c8];
      *(uint4*)&Xb[r][c8] = v;
    }
    #pragma unroll
    for (int it = 0; it < 4; ++it) {
      int i = it * 256 + tid;
      int r = i >> 3, c8 = (i & 7) * 8;
      *(uint4*)&Wb[r][c8] = *(const uint4*)&wot[((size_t)e * C + c0 + r) * HID + kc + c8];
    }
    __syncthreads();
    #pragma unroll
    for (int kk = 0; kk < 64; kk += 32) {
      bf16x8 a[4], b[4];
      #pragma unroll
      for (int nf = 0; nf < 4; nf++) a[nf] = *(const bf16x8*)&Wb[wc * 64 + nf * 16 + lr][kk + lk];
      #pragma unroll
      for (int mf = 0; mf < 4; mf++) b[mf] = *(const bf16x8*)&Xb[wr * 64 + mf * 16 + lr][kk + lk];
      #pragma unroll
      for (int nf = 0; nf < 4; nf++)
        #pragma unroll
        for (int mf = 0; mf < 4; mf++)
          acc[nf][mf] = __builtin_amdgcn_mfma_f32_16x16x32_bf16(a[nf], b[mf], acc[nf][mf], 0, 0, 0);
    }
  }
  #pragma unroll
  for (int mf = 0; mf < 4; mf++) {
    int si = wr * 64 + mf * 16 + lr;
    int s = slots[si];
    if (s < 0) continue;
    float g = gates2[s];
    #pragma unroll
    for (int nf = 0; nf < 4; nf++) {
      int cc = c0 + wc * 64 + nf * 16 + rowq;
      const float4 b4 = *(const float4*)&bo[(size_t)e * C + cc];
      ushort4 v = make_ushort4(f2bf(g * (acc[nf][mf][0] + b4.x)),
                               f2bf(g * (acc[nf][mf][1] + b4.y)),
                               f2bf(g * (acc[nf][mf][2] + b4.z)),
                               f2bf(g * (acc[nf][mf][3] + b4.w)));
      *(ushort4*)&y2[(size_t)s * C + cc] = v;
    }
  }
}

// ---------------- Final residual add (bf16 slots) ----------------
__global__ void final_kernel(const unsigned short* __restrict__ y2, float* __restrict__ xout) {
  int t = blockIdx.x, tid = threadIdx.x;
  int c = tid * 2;
  unsigned u0 = *(const unsigned*)&y2[(size_t)(t * 2) * C + c];
  unsigned u1 = *(const unsigned*)&y2[(size_t)(t * 2 + 1) * C + c];
  xout[(size_t)t * C + c]     += bf2f((unsigned short)(u0 & 0xFFFF)) + bf2f((unsigned short)(u1 & 0xFFFF));
  xout[(size_t)t * C + c + 1] += bf2f((unsigned short)(u0 >> 16)) + bf2f((unsigned short)(u1 >> 16));
}

// ---------------- Gating statistics reduction ----------------
template <int E, int K>
__global__ void reduce_gating(const float* __restrict__ probs, const float* __restrict__ lse,
                              const int* __restrict__ idxs, float* __restrict__ psum,
                              float* __restrict__ freq, float* __restrict__ zsum) {
  __shared__ float ps[E];
  __shared__ float fr[E];
  __shared__ float zs;
  int tid = threadIdx.x;
  if (tid < E) { ps[tid] = 0.f; fr[tid] = 0.f; }
  if (tid == 0) zs = 0.f;
  __syncthreads();
  int t = blockIdx.x * 256 + tid;
  if (t < T) {
    for (int e = 0; e < E; e++) atomicAdd(&ps[e], probs[(size_t)t * E + e]);
    for (int k = 0; k < K; k++) atomicAdd(&fr[idxs[(size_t)t * K + k]], 1.f);
    float l = lse[t];
    atomicAdd(&zs, l * l);
  }
  __syncthreads();
  if (tid < E) { atomicAdd(&psum[tid], ps[tid]); atomicAdd(&freq[tid], fr[tid]); }
  if (tid == 0) atomicAdd(zsum, zs);
}

__global__ void loss_kernel(const float* __restrict__ acc, float* __restrict__ out) {
  const float* p1 = acc;      const float* f1 = acc + 24; float z1 = acc[48];
  const float* p2 = acc + 49; const float* f2 = acc + 65; float z2 = acc[81];
  float sp1 = 0.f, sf1 = 0.f;
  for (int e = 0; e < 24; e++) { sp1 += p1[e]; sf1 += f1[e]; }
  float sw1 = 0.f;
  for (int e = 0; e < 24; e++) sw1 += (p1[e] / sp1) * (f1[e] / sf1);
  sw1 *= 24.f;
  float sp2 = 0.f, sf2 = 0.f;
  for (int e = 0; e < 16; e++) { sp2 += p2[e]; sf2 += f2[e]; }
  float sw2 = 0.f;
  for (int e = 0; e < 16; e++) sw2 += (p2[e] / sp2) * (f2[e] / sf2);
  sw2 *= 16.f;
  out[0] = 0.01f * sw1 + 0.001f * (z1 / T) + 0.01f * sw2 + 0.001f * (z2 / T);
}

}  // namespace

extern "C" void kernel_launch(void* const* d_in, const int* in_sizes, int n_in,
                              void* d_out, int out_size, void* d_ws, size_t ws_size,
                              hipStream_t stream) {
  const float* x      = (const float*)d_in[0];
  const int*   task   = (const int*)d_in[1];
  const float* n1g    = (const float*)d_in[2];
  const float* n1b    = (const float*)d_in[3];
  const float* gate_a = (const float*)d_in[4];
  const float* wq     = (const float*)d_in[5];
  const float* wo_a   = (const float*)d_in[6];
  const float* kvw    = (const float*)d_in[7];
  const float* kvb    = (const float*)d_in[8];
  const float* n2g    = (const float*)d_in[9];
  const float* n2b    = (const float*)d_in[10];
  const float* gate_m = (const float*)d_in[11];
  const float* wi     = (const float*)d_in[12];
  const float* bi     = (const float*)d_in[13];
  const float* wo_m   = (const float*)d_in[14];
  const float* bo     = (const float*)d_in[15];
  float* out = (float*)d_out;

  char* p = (char*)d_ws;
  unsigned short* x1b = (unsigned short*)p; p += (size_t)T * C * 2;
  unsigned short* qb = (unsigned short*)p;  p += (size_t)T * KA * HD * 2;
  unsigned short* ob = (unsigned short*)p;  p += (size_t)T * KA * HD * 2;
  unsigned short* Kb = (unsigned short*)p;  p += (size_t)T * HD * 2;
  unsigned short* Vt = (unsigned short*)p;  p += (size_t)T * HD * 2;
  // union region: y_slot (33.5MB) then reused as h (16.8MB) + y2_slot (8.4MB)
  char* un = p;                      p += (size_t)T * KA * C * 2;
  unsigned short* y_slot  = (unsigned short*)un;
  unsigned short* h       = (unsigned short*)un;
  unsigned short* y2_slot = (unsigned short*)(un + (size_t)T * KF * HID * 2);
  unsigned short* wqt = (unsigned short*)p;  p += (size_t)EA * C * HD * 2;
  unsigned short* woat = (unsigned short*)p; p += (size_t)EA * HD * C * 2;
  unsigned short* wit = (unsigned short*)p;  p += (size_t)EF * C * HID * 2;
  unsigned short* womt = (unsigned short*)p; p += (size_t)EF * HID * C * 2;
  unsigned short* kvwt = (unsigned short*)p; p += (size_t)(2 * HD) * C * 2;
  float* probs1 = (float*)p;         p += (size_t)T * EA * 4;
  float* lse1 = (float*)p;           p += (size_t)T * 4;
  float* gates1 = (float*)p;         p += (size_t)T * KA * 4;
  int* idx1 = (int*)p;               p += (size_t)T * KA * 4;
  float* probs2 = (float*)p;         p += (size_t)T * EF * 4;
  float* lse2 = (float*)p;           p += (size_t)T * 4;
  float* gates2 = (float*)p;         p += (size_t)T * KF * 4;
  int* idx2 = (int*)p;               p += (size_t)T * KF * 4;
  int* bucket_a = (int*)p;           p += (size_t)EA * (T * KA) * 4;
  int* bucket_f = (int*)p;           p += (size_t)EF * (T * KF) * 4;
  int* counts_a = (int*)p;           p += 32 * 4;
  int* counts_f = (int*)p;           p += 32 * 4;
  float* accum = (float*)p;          p += 128 * 4;
  int* maps = (int*)p;               p += 768 * 4;
  int* totals = (int*)p;             p += 4 * 4;

  hipMemsetAsync(counts_a, 0, (32 + 32 + 128) * 4, stream);

  tcvt_kernel<<<dim3(2, 16, 24), 256, 0, stream>>>(wq, wqt, C, HD);
  tcvt_kernel<<<dim3(16, 2, 24), 256, 0, stream>>>(wo_a, woat, HD, C);
  tcvt_kernel<<<dim3(32, 16, 16), 256, 0, stream>>>(wi, wit, C, HID);
  tcvt_kernel<<<dim3(16, 32, 16), 256, 0, stream>>>(wo_m, womt, HID, C);
  tcvt_kernel<<<dim3(4, 16, 1), 256, 0, stream>>>(kvw, kvwt, C, 2 * HD);

  ln_gate_kernel<EA, KA, 8><<<T, 256, 0, stream>>>(x, n1g, n1b, gate_a, task, x1b,
                                                   probs1, lse1, gates1, idx1);
  bucket_kernel<EA><<<(T * KA + 511) / 512, 512, 0, stream>>>(idx1, T * KA, T * KA,
                                                              counts_a, bucket_a);
  build_maps_a<<<1, 64, 0, stream>>>(counts_a, maps, totals);
  qgemm_mfma<<<dim3(1, 152), 256, 0, stream>>>(x1b, wqt, bucket_a, counts_a, maps, totals, qb);
  kv_mfma<<<T / 16, 256, 0, stream>>>(x1b, kvwt, kvb, Kb, Vt);
  attn_mfma<<<dim3(NS / 64, KA, NB), 256, 0, stream>>>(qb, Kb, Vt, ob);
  oproj_mfma<<<dim3(4, 280), 256, 0, stream>>>(ob, woat, gates1, bucket_a, counts_a,
                                               maps + 256, totals + 1, y_slot);
  combine_kernel<<<T, 256, 0, stream>>>(x, y_slot, out);
  ln_gate_kernel<EF, KF, 16><<<T, 256, 0, stream>>>(out, n2g, n2b, gate_m, task, x1b,
                                                    probs2, lse2, gates2, idx2);
  bucket_kernel<EF><<<(T * KF + 511) / 512, 512, 0, stream>>>(idx2, T * KF, T * KF,
                                                              counts_f, bucket_f);
  build_maps_f<<<1, 64, 0, stream>>>(counts_f, maps, totals);
  mlp1_mfma<<<dim3(8, 80), 256, 0, stream>>>(x1b, wit, bi, bucket_f, counts_f,
                                             maps + 600, totals + 2, h);
  mlp2_mfma<<<dim3(4, 80), 256, 0, stream>>>(h, womt, bo, gates2, bucket_f, counts_f,
                                             maps + 600, totals + 2, y2_slot);
  final_kernel<<<T, 256, 0, stream>>>(y2_slot, out);
  reduce_gating<EA, KA><<<16, 256, 0, stream>>>(probs1, lse1, idx1, accum, accum + 24, accum + 48);
  reduce_gating<EF, KF><<<16, 256, 0, stream>>>(probs2, lse2, idx2, accum + 49, accum + 65, accum + 81);
  loss_kernel<<<1, 1, 0, stream>>>(accum, out + (size_t)T * C);
}

// Round 8
// 411.144 us; speedup vs baseline: 4.1531x; 1.0683x over previous
//
#include <hip/hip_runtime.h>
#include <math.h>

namespace {

constexpr int T   = 4096;
constexpr int C   = 512;
constexpr int NB  = 8;
constexpr int NS  = 512;
constexpr int HD  = 64;
constexpr int KA  = 8;
constexpr int EA  = 24;
constexpr int EF  = 16;
constexpr int KF  = 2;
constexpr int HID = 1024;

typedef __attribute__((ext_vector_type(8))) short bf16x8;
typedef __attribute__((ext_vector_type(4))) float f32x4;

__device__ inline unsigned short f2bf(float f) {
  unsigned u = __float_as_uint(f);
  return (unsigned short)((u + 0x7FFFu + ((u >> 16) & 1u)) >> 16);
}
__device__ inline float bf2f(unsigned short u) {
  return __uint_as_float((unsigned)u << 16);
}

// ---------------- Fused LayerNorm + Gating: one block (256 thr) per token ----------------
// Gate matrix staged in LDS (fp32, bit-identical math); wave-shuffle LN reduction.
template <int E, int K, int TPE>
__global__ __launch_bounds__(256) void ln_gate_kernel(
    const float* __restrict__ in, const float* __restrict__ g,
    const float* __restrict__ b, const float* __restrict__ gate_all,
    const int* __restrict__ task, unsigned short* __restrict__ outb,
    float* __restrict__ probs, float* __restrict__ lse_out,
    float* __restrict__ gates, int* __restrict__ idxs) {
  int t = blockIdx.x, tid = threadIdx.x;
  int lane = tid & 63, wv = tid >> 6;
  const float* row = in + (size_t)t * C;
  __shared__ float xs[C];
  __shared__ float red[8];
  __shared__ float lg[E];
  __shared__ __align__(16) float Ws[C * E];
  // stage gate matrix (task-indexed) into LDS, float4-coalesced
  const float* W = gate_all + (size_t)task[0] * C * E;
  #pragma unroll
  for (int i = tid; i < C * E / 4; i += 256) {
    *(float4*)&Ws[i * 4] = *(const float4*)&W[(size_t)i * 4];
  }
  // LN: wave-shuffle reductions (2 barriers total)
  float v0 = row[tid], v1 = row[tid + 256];
  float s = v0 + v1;
  #pragma unroll
  for (int m = 1; m < 64; m <<= 1) s += __shfl_xor(s, m);
  if (lane == 0) red[wv] = s;
  __syncthreads();
  float mean = (red[0] + red[1] + red[2] + red[3]) * (1.f / C);
  float d0 = v0 - mean, d1 = v1 - mean;
  float vv = d0 * d0 + d1 * d1;
  #pragma unroll
  for (int m = 1; m < 64; m <<= 1) vv += __shfl_xor(vv, m);
  if (lane == 0) red[4 + wv] = vv;
  __syncthreads();
  float r = rsqrtf((red[4] + red[5] + red[6] + red[7]) * (1.f / C) + 1e-5f);
  float o0 = d0 * r * g[tid] + b[tid];
  float o1 = d1 * r * g[tid + 256] + b[tid + 256];
  outb[(size_t)t * C + tid]       = f2bf(o0);
  outb[(size_t)t * C + tid + 256] = f2bf(o1);
  xs[tid] = o0;
  xs[tid + 256] = o1;
  __syncthreads();
  // gating logits from LDS (4 split accumulators to break fmac chain)
  if (tid < E * TPE) {
    int e = tid / TPE, l = tid % TPE;
    float a0 = 0.f, a1 = 0.f, a2 = 0.f, a3 = 0.f;
    #pragma unroll 4
    for (int c = l; c < C; c += 4 * TPE) {
      a0 += xs[c] * Ws[c * E + e];
      a1 += xs[c + TPE] * Ws[(c + TPE) * E + e];
      a2 += xs[c + 2 * TPE] * Ws[(c + 2 * TPE) * E + e];
      a3 += xs[c + 3 * TPE] * Ws[(c + 3 * TPE) * E + e];
    }
    float acc = (a0 + a1) + (a2 + a3);
    #pragma unroll
    for (int m = TPE >> 1; m > 0; m >>= 1) acc += __shfl_xor(acc, m);
    if (l == 0) lg[e] = acc;
  }
  __syncthreads();
  if (tid < 64) {
    float lgv = (tid < E) ? lg[tid] : -3.0e38f;
    float mx = lgv;
    #pragma unroll
    for (int m = 1; m < 64; m <<= 1) mx = fmaxf(mx, __shfl_xor(mx, m));
    float pe = (tid < E) ? expf(lgv - mx) : 0.f;
    float sum = pe;
    #pragma unroll
    for (int m = 1; m < 64; m <<= 1) sum += __shfl_xor(sum, m);
    float inv = 1.f / sum;
    float prob = pe * inv;
    if (tid < E) probs[(size_t)t * E + tid] = prob;
    if (tid == 0) lse_out[t] = mx + logf(sum);
    // iterative top-K, lax.top_k tie-break (strict >, lowest index wins)
    float pv = (tid < E) ? prob : -1.f;
    float gsum = 0.f, myv = 0.f; int myi = 0;
    for (int k = 0; k < K; k++) {
      float bv = pv; int bi_ = tid;
      #pragma unroll
      for (int m = 1; m < 64; m <<= 1) {
        float ov = __shfl_xor(bv, m); int oi = __shfl_xor(bi_, m);
        if (ov > bv || (ov == bv && oi < bi_)) { bv = ov; bi_ = oi; }
      }
      gsum += bv;
      if (tid == k) { myv = bv; myi = bi_; }
      if (tid == bi_) pv = -1.f;
    }
    if (tid < K) {
      float ginv = 1.f / (gsum + 1e-6f);
      gates[(size_t)t * K + tid] = myv * ginv;
      idxs[(size_t)t * K + tid]  = myi;
    }
  }
}

// ---------------- bucket by expert: LDS-aggregated, ~E global atomics per block ----------------
template <int E>
__global__ __launch_bounds__(512) void bucket_kernel(const int* __restrict__ idx, int nslots,
                                                     int stride, int* counts, int* bucket) {
  __shared__ int lcount[E];
  __shared__ int lbase[E];
  int tid = threadIdx.x;
  if (tid < E) lcount[tid] = 0;
  __syncthreads();
  int s = blockIdx.x * 512 + tid;
  int e = 0, lpos = 0;
  bool valid = (s < nslots);
  if (valid) {
    e = idx[s];
    lpos = atomicAdd(&lcount[e], 1);
  }
  __syncthreads();
  if (tid < E) lbase[tid] = lcount[tid] ? atomicAdd(&counts[tid], lcount[tid]) : 0;
  __syncthreads();
  if (valid) bucket[(size_t)e * stride + lbase[e] + lpos] = s;
}

// ---------------- flat (expert, tile) maps ----------------
__global__ void build_maps_a(const int* __restrict__ counts, int* __restrict__ maps,
                             int* __restrict__ totals) {
  if (threadIdx.x != 0) return;
  int n = 0;
  for (int e = 0; e < EA; e++) { int c = counts[e]; for (int t0 = 0; t0 < c; t0 += 256) maps[n++] = (e << 16) | t0; }
  totals[0] = n;
  n = 0;
  for (int e = 0; e < EA; e++) { int c = counts[e]; for (int t0 = 0; t0 < c; t0 += 128) maps[256 + n++] = (e << 16) | t0; }
  totals[1] = n;
}
__global__ void build_maps_f(const int* __restrict__ counts, int* __restrict__ maps,
                             int* __restrict__ totals) {
  if (threadIdx.x != 0) return;
  int n = 0;
  for (int e = 0; e < EF; e++) { int c = counts[e]; for (int t0 = 0; t0 < c; t0 += 128) maps[600 + n++] = (e << 16) | t0; }
  totals[2] = n;
}

// ---------------- transpose + cvt weights: [E][K][N] f32 -> [E][N][K] bf16 ----------------
__global__ void tcvt_kernel(const float* __restrict__ src, unsigned short* __restrict__ dst,
                            int K, int N) {
  int e = blockIdx.z;
  int kt = blockIdx.y * 32, nt = blockIdx.x * 32;
  __shared__ float tile[32][33];
  int tid = threadIdx.x;
  const float* S = src + (size_t)e * K * N;
  for (int i = tid; i < 32 * 32; i += 256) {
    int r = i >> 5, c = i & 31;
    tile[r][c] = S[(size_t)(kt + r) * N + nt + c];
  }
  __syncthreads();
  unsigned short* D = dst + (size_t)e * K * N;
  for (int i = tid; i < 32 * 8; i += 256) {
    int n = i >> 3, k4 = (i & 7) * 4;
    ushort4 v;
    v.x = f2bf(tile[k4 + 0][n]); v.y = f2bf(tile[k4 + 1][n]);
    v.z = f2bf(tile[k4 + 2][n]); v.w = f2bf(tile[k4 + 3][n]);
    *(ushort4*)&D[(size_t)(nt + n) * K + kt + k4] = v;
  }
}

// ---------------- MFMA Q GEMM: 256 slots x 64 out, K=512 -> bf16 q (pre-scaled) ----------------
__global__ __launch_bounds__(256) void qgemm_mfma(
    const unsigned short* __restrict__ xb, const unsigned short* __restrict__ wqt,
    const int* __restrict__ bucket, const int* __restrict__ counts,
    const int* __restrict__ map, const int* __restrict__ total,
    unsigned short* __restrict__ qb) {
  if ((int)blockIdx.y >= *total) return;
  int ent = map[blockIdx.y];
  int e = ent >> 16, t0 = ent & 0xFFFF;
  int cnt = counts[e];
  int tid = threadIdx.x;
  __shared__ int slots[256];
  __shared__ __align__(16) unsigned short Xb[256][72];
  __shared__ __align__(16) unsigned short Wb[64][72];
  {
    int ii = t0 + tid;
    slots[tid] = (ii < cnt) ? bucket[(size_t)e * (T * KA) + ii] : -1;
  }
  __syncthreads();
  int lane = tid & 63, wid = tid >> 6;
  int lr = lane & 15, lk = (lane >> 4) * 8, rowq = (lane >> 4) * 4;
  f32x4 acc[4][4] = {};
  for (int kc = 0; kc < C; kc += 64) {
    __syncthreads();
    #pragma unroll
    for (int it = 0; it < 8; ++it) {
      int i = it * 256 + tid;
      int r = i >> 3, c8 = (i & 7) * 8;
      int s = slots[r];
      uint4 v = make_uint4(0u, 0u, 0u, 0u);
      if (s >= 0) v = *(const uint4*)&xb[(size_t)(s >> 3) * C + kc + c8];
      *(uint4*)&Xb[r][c8] = v;
    }
    #pragma unroll
    for (int it = 0; it < 2; ++it) {
      int i = it * 256 + tid;
      int r = i >> 3, c8 = (i & 7) * 8;
      *(uint4*)&Wb[r][c8] = *(const uint4*)&wqt[((size_t)e * HD + r) * C + kc + c8];
    }
    __syncthreads();
    #pragma unroll
    for (int kk = 0; kk < 64; kk += 32) {
      bf16x8 a[4], b[4];
      #pragma unroll
      for (int nf = 0; nf < 4; nf++) a[nf] = *(const bf16x8*)&Wb[nf * 16 + lr][kk + lk];
      #pragma unroll
      for (int mf = 0; mf < 4; mf++) b[mf] = *(const bf16x8*)&Xb[wid * 64 + mf * 16 + lr][kk + lk];
      #pragma unroll
      for (int nf = 0; nf < 4; nf++)
        #pragma unroll
        for (int mf = 0; mf < 4; mf++)
          acc[nf][mf] = __builtin_amdgcn_mfma_f32_16x16x32_bf16(a[nf], b[mf], acc[nf][mf], 0, 0, 0);
    }
  }
  #pragma unroll
  for (int mf = 0; mf < 4; mf++) {
    int s = slots[wid * 64 + mf * 16 + lr];
    if (s < 0) continue;
    #pragma unroll
    for (int nf = 0; nf < 4; nf++) {
      ushort4 v = make_ushort4(f2bf(0.125f * acc[nf][mf][0]), f2bf(0.125f * acc[nf][mf][1]),
                               f2bf(0.125f * acc[nf][mf][2]), f2bf(0.125f * acc[nf][mf][3]));
      *(ushort4*)&qb[(size_t)s * HD + nf * 16 + rowq] = v;
    }
  }
}

// ---------------- MFMA KV GEMM: 16 tokens x 128 cols per block, 256 blocks ----------------
__global__ __launch_bounds__(256) void kv_mfma(
    const unsigned short* __restrict__ xb, const unsigned short* __restrict__ kvwt,
    const float* __restrict__ kvb, unsigned short* __restrict__ Kb,
    unsigned short* __restrict__ Vt) {
  int t0 = blockIdx.x * 16;
  int tid = threadIdx.x;
  __shared__ __align__(16) unsigned short Xs[16][72];
  __shared__ __align__(16) unsigned short Ws[128][72];
  int lane = tid & 63, w = tid >> 6;
  int lr = lane & 15, lk = (lane >> 4) * 8, rowq = (lane >> 4) * 4;
  f32x4 acc[2] = {};
  for (int kc = 0; kc < C; kc += 64) {
    __syncthreads();
    if (tid < 128) {
      int r = tid >> 3, c8 = (tid & 7) * 8;
      *(uint4*)&Xs[r][c8] = *(const uint4*)&xb[(size_t)(t0 + r) * C + kc + c8];
    }
    #pragma unroll
    for (int it = 0; it < 4; ++it) {
      int i = it * 256 + tid;
      int r = i >> 3, c8 = (i & 7) * 8;
      *(uint4*)&Ws[r][c8] = *(const uint4*)&kvwt[(size_t)r * C + kc + c8];
    }
    __syncthreads();
    #pragma unroll
    for (int kk = 0; kk < 64; kk += 32) {
      bf16x8 xf = *(const bf16x8*)&Xs[lr][kk + lk];
      #pragma unroll
      for (int cf = 0; cf < 2; cf++) {
        bf16x8 wf = *(const bf16x8*)&Ws[w * 32 + cf * 16 + lr][kk + lk];
        acc[cf] = __builtin_amdgcn_mfma_f32_16x16x32_bf16(wf, xf, acc[cf], 0, 0, 0);
      }
    }
  }
  int t = t0 + lr;
  int bb = t >> 9, n = t & (NS - 1);
  #pragma unroll
  for (int cf = 0; cf < 2; cf++) {
    #pragma unroll
    for (int r2 = 0; r2 < 4; r2++) {
      int c = w * 32 + cf * 16 + rowq + r2;
      float v = acc[cf][r2] + kvb[c];
      if (c < HD) Kb[(size_t)t * HD + c] = f2bf(v);
      else        Vt[((size_t)bb * HD + (c - HD)) * NS + n] = f2bf(v);
    }
  }
}

// ---------------- MFMA flash attention: block per (qtile64, head, batch) ----------------
__global__ __launch_bounds__(256) void attn_mfma(
    const unsigned short* __restrict__ qb, const unsigned short* __restrict__ Kb,
    const unsigned short* __restrict__ Vt, unsigned short* __restrict__ ob) {
  int qt = blockIdx.x, h = blockIdx.y, b = blockIdx.z;
  int tid = threadIdx.x;
  __shared__ __align__(16) unsigned short Qs[64][72];
  __shared__ __align__(16) unsigned short Ks[64][72];
  __shared__ __align__(16) unsigned short Vs[64][72];
  __shared__ __align__(16) unsigned short Ps[64][72];
  int i0 = qt * 64;
  #pragma unroll
  for (int it = 0; it < 2; ++it) {
    int i = it * 256 + tid;
    int r = i >> 3, c8 = (i & 7) * 8;
    *(uint4*)&Qs[r][c8] = *(const uint4*)&qb[(((size_t)(b * NS + i0 + r)) * KA + h) * HD + c8];
  }
  int lane = tid & 63, w = tid >> 6;
  int lr = lane & 15, lk = (lane >> 4) * 8, rowq = (lane >> 4) * 4;
  f32x4 acc_o[4] = {};
  float m_run = -3.0e38f, l_run = 0.f;
  for (int jt = 0; jt < NS / 64; ++jt) {
    __syncthreads();
    #pragma unroll
    for (int it = 0; it < 2; ++it) {
      int i = it * 256 + tid;
      int r = i >> 3, c8 = (i & 7) * 8;
      *(uint4*)&Ks[r][c8] = *(const uint4*)&Kb[((size_t)(b * NS + jt * 64 + r)) * HD + c8];
      *(uint4*)&Vs[r][c8] = *(const uint4*)&Vt[((size_t)b * HD + r) * NS + jt * 64 + c8];
    }
    __syncthreads();
    f32x4 acc_s[4] = {};
    #pragma unroll
    for (int kk = 0; kk < 64; kk += 32) {
      bf16x8 qf = *(const bf16x8*)&Qs[w * 16 + lr][kk + lk];
      #pragma unroll
      for (int kf = 0; kf < 4; kf++) {
        bf16x8 kr = *(const bf16x8*)&Ks[kf * 16 + lr][kk + lk];
        acc_s[kf] = __builtin_amdgcn_mfma_f32_16x16x32_bf16(kr, qf, acc_s[kf], 0, 0, 0);
      }
    }
    float pmax = acc_s[0][0];
    #pragma unroll
    for (int kf = 0; kf < 4; kf++)
      #pragma unroll
      for (int r = 0; r < 4; r++) pmax = fmaxf(pmax, acc_s[kf][r]);
    pmax = fmaxf(pmax, __shfl_xor(pmax, 16));
    pmax = fmaxf(pmax, __shfl_xor(pmax, 32));
    float m_new = fmaxf(m_run, pmax);
    float scl = expf(m_run - m_new);
    float rs = 0.f;
    #pragma unroll
    for (int kf = 0; kf < 4; kf++)
      #pragma unroll
      for (int r = 0; r < 4; r++) {
        float pv = expf(acc_s[kf][r] - m_new);
        rs += pv;
        Ps[w * 16 + lr][kf * 16 + rowq + r] = f2bf(pv);
      }
    rs += __shfl_xor(rs, 16);
    rs += __shfl_xor(rs, 32);
    l_run = l_run * scl + rs;
    m_run = m_new;
    __syncthreads();
    #pragma unroll
    for (int df = 0; df < 4; df++) {
      acc_o[df][0] *= scl; acc_o[df][1] *= scl;
      acc_o[df][2] *= scl; acc_o[df][3] *= scl;
    }
    #pragma unroll
    for (int kk = 0; kk < 64; kk += 32) {
      bf16x8 pf = *(const bf16x8*)&Ps[w * 16 + lr][kk + lk];
      #pragma unroll
      for (int df = 0; df < 4; df++) {
        bf16x8 vf = *(const bf16x8*)&Vs[df * 16 + lr][kk + lk];
        acc_o[df] = __builtin_amdgcn_mfma_f32_16x16x32_bf16(vf, pf, acc_o[df], 0, 0, 0);
      }
    }
  }
  float inv = 1.f / l_run;
  int token = b * NS + i0 + w * 16 + lr;
  #pragma unroll
  for (int df = 0; df < 4; df++) {
    ushort4 v = make_ushort4(f2bf(acc_o[df][0] * inv), f2bf(acc_o[df][1] * inv),
                             f2bf(acc_o[df][2] * inv), f2bf(acc_o[df][3] * inv));
    *(ushort4*)&ob[((size_t)token * KA + h) * HD + df * 16 + rowq] = v;
  }
}

// ---------------- MFMA output proj: dense per-slot bf16 (gate folded), NO atomics ----------------
__global__ __launch_bounds__(256) void oproj_mfma(
    const unsigned short* __restrict__ ob, const unsigned short* __restrict__ wot,
    const float* __restrict__ gates, const int* __restrict__ bucket,
    const int* __restrict__ counts, const int* __restrict__ map,
    const int* __restrict__ total, unsigned short* __restrict__ y_slot) {
  if ((int)blockIdx.y >= *total) return;
  int ent = map[blockIdx.y];
  int e = ent >> 16, t0 = ent & 0xFFFF;
  int c0 = blockIdx.x * 128;
  int cnt = counts[e];
  int tid = threadIdx.x;
  __shared__ int slots[128];
  __shared__ float gs[128];
  __shared__ __align__(16) unsigned short Xb[128][72];
  __shared__ __align__(16) unsigned short Wb[128][72];
  if (tid < 128) {
    int ii = t0 + tid;
    int s = (ii < cnt) ? bucket[(size_t)e * (T * KA) + ii] : -1;
    slots[tid] = s;
    gs[tid] = (s >= 0) ? gates[s] : 0.f;
  }
  __syncthreads();
  #pragma unroll
  for (int it = 0; it < 4; ++it) {
    int i = it * 256 + tid;
    int r = i >> 3, c8 = (i & 7) * 8;
    int s = slots[r];
    uint4 vo = make_uint4(0u, 0u, 0u, 0u);
    if (s >= 0) {
      float g = gs[r];
      uint4 u = *(const uint4*)&ob[(size_t)s * HD + c8];
      const unsigned short* us = (const unsigned short*)&u;
      unsigned short* vs = (unsigned short*)&vo;
      #pragma unroll
      for (int k = 0; k < 8; k++) vs[k] = f2bf(g * bf2f(us[k]));
    }
    *(uint4*)&Xb[r][c8] = vo;
  }
  #pragma unroll
  for (int it = 0; it < 4; ++it) {
    int i = it * 256 + tid;
    int r = i >> 3, c8 = (i & 7) * 8;
    *(uint4*)&Wb[r][c8] = *(const uint4*)&wot[((size_t)e * C + c0 + r) * HD + c8];
  }
  __syncthreads();
  int lane = tid & 63, wid = tid >> 6;
  int wr = wid & 1, wc = wid >> 1;
  int lr = lane & 15, lk = (lane >> 4) * 8, rowq = (lane >> 4) * 4;
  f32x4 acc[4][4] = {};
  #pragma unroll
  for (int kk = 0; kk < 64; kk += 32) {
    bf16x8 a[4], b[4];
    #pragma unroll
    for (int nf = 0; nf < 4; nf++) a[nf] = *(const bf16x8*)&Wb[wc * 64 + nf * 16 + lr][kk + lk];
    #pragma unroll
    for (int mf = 0; mf < 4; mf++) b[mf] = *(const bf16x8*)&Xb[wr * 64 + mf * 16 + lr][kk + lk];
    #pragma unroll
    for (int nf = 0; nf < 4; nf++)
      #pragma unroll
      for (int mf = 0; mf < 4; mf++)
        acc[nf][mf] = __builtin_amdgcn_mfma_f32_16x16x32_bf16(a[nf], b[mf], acc[nf][mf], 0, 0, 0);
  }
  #pragma unroll
  for (int mf = 0; mf < 4; mf++) {
    int si = wr * 64 + mf * 16 + lr;
    int s = slots[si];
    if (s < 0) continue;
    size_t base = (size_t)s * C + c0 + wc * 64;
    #pragma unroll
    for (int nf = 0; nf < 4; nf++) {
      ushort4 v = make_ushort4(f2bf(acc[nf][mf][0]), f2bf(acc[nf][mf][1]),
                               f2bf(acc[nf][mf][2]), f2bf(acc[nf][mf][3]));
      *(ushort4*)&y_slot[base + nf * 16 + rowq] = v;
    }
  }
}

// ---------------- combine: out = x + sum_k y_slot[t*8+k] ----------------
__global__ void combine_kernel(const float* __restrict__ x, const unsigned short* __restrict__ ys,
                               float* __restrict__ out) {
  int t = blockIdx.x, tid = threadIdx.x;
  int c = tid * 2;
  float s0 = 0.f, s1 = 0.f;
  #pragma unroll
  for (int k = 0; k < KA; k++) {
    unsigned u = *(const unsigned*)&ys[((size_t)t * KA + k) * C + c];
    s0 += bf2f((unsigned short)(u & 0xFFFF));
    s1 += bf2f((unsigned short)(u >> 16));
  }
  out[(size_t)t * C + c]     = x[(size_t)t * C + c] + s0;
  out[(size_t)t * C + c + 1] = x[(size_t)t * C + c + 1] + s1;
}

// ---------------- MFMA MLP1: h = gelu(x2 @ wi + bi), bf16 out ----------------
__global__ __launch_bounds__(256) void mlp1_mfma(
    const unsigned short* __restrict__ xb, const unsigned short* __restrict__ wit,
    const float* __restrict__ bi, const int* __restrict__ bucket,
    const int* __restrict__ counts, const int* __restrict__ map,
    const int* __restrict__ total, unsigned short* __restrict__ h) {
  if ((int)blockIdx.y >= *total) return;
  int ent = map[blockIdx.y];
  int e = ent >> 16, t0 = ent & 0xFFFF;
  int j0 = blockIdx.x * 128;
  int cnt = counts[e];
  int tid = threadIdx.x;
  __shared__ int slots[128];
  __shared__ __align__(16) unsigned short Xb[128][72];
  __shared__ __align__(16) unsigned short Wb[128][72];
  if (tid < 128) {
    int ii = t0 + tid;
    slots[tid] = (ii < cnt) ? bucket[(size_t)e * (T * KF) + ii] : -1;
  }
  __syncthreads();
  int lane = tid & 63, wid = tid >> 6;
  int wr = wid & 1, wc = wid >> 1;
  int lr = lane & 15, lk = (lane >> 4) * 8, rowq = (lane >> 4) * 4;
  f32x4 acc[4][4] = {};
  for (int kc = 0; kc < C; kc += 64) {
    __syncthreads();
    #pragma unroll
    for (int it = 0; it < 4; ++it) {
      int i = it * 256 + tid;
      int r = i >> 3, c8 = (i & 7) * 8;
      int s = slots[r];
      uint4 v = make_uint4(0u, 0u, 0u, 0u);
      if (s >= 0) v = *(const uint4*)&xb[(size_t)(s >> 1) * C + kc + c8];
      *(uint4*)&Xb[r][c8] = v;
    }
    #pragma unroll
    for (int it = 0; it < 4; ++it) {
      int i = it * 256 + tid;
      int r = i >> 3, c8 = (i & 7) * 8;
      *(uint4*)&Wb[r][c8] = *(const uint4*)&wit[((size_t)e * HID + j0 + r) * C + kc + c8];
    }
    __syncthreads();
    #pragma unroll
    for (int kk = 0; kk < 64; kk += 32) {
      bf16x8 a[4], b[4];
      #pragma unroll
      for (int nf = 0; nf < 4; nf++) a[nf] = *(const bf16x8*)&Wb[wc * 64 + nf * 16 + lr][kk + lk];
      #pragma unroll
      for (int mf = 0; mf < 4; mf++) b[mf] = *(const bf16x8*)&Xb[wr * 64 + mf * 16 + lr][kk + lk];
      #pragma unroll
      for (int nf = 0; nf < 4; nf++)
        #pragma unroll
        for (int mf = 0; mf < 4; mf++)
          acc[nf][mf] = __builtin_amdgcn_mfma_f32_16x16x32_bf16(a[nf], b[mf], acc[nf][mf], 0, 0, 0);
    }
  }
  #pragma unroll
  for (int mf = 0; mf < 4; mf++) {
    int s = slots[wr * 64 + mf * 16 + lr];
    if (s < 0) continue;
    #pragma unroll
    for (int nf = 0; nf < 4; nf++) {
      int j = j0 + wc * 64 + nf * 16 + rowq;
      const float4 b4 = *(const float4*)&bi[(size_t)e * HID + j];
      float v0 = acc[nf][mf][0] + b4.x, v1 = acc[nf][mf][1] + b4.y;
      float v2 = acc[nf][mf][2] + b4.z, v3 = acc[nf][mf][3] + b4.w;
      v0 = 0.5f * v0 * (1.f + erff(v0 * 0.70710678118654752f));
      v1 = 0.5f * v1 * (1.f + erff(v1 * 0.70710678118654752f));
      v2 = 0.5f * v2 * (1.f + erff(v2 * 0.70710678118654752f));
      v3 = 0.5f * v3 * (1.f + erff(v3 * 0.70710678118654752f));
      *(ushort4*)&h[(size_t)s * HID + j] = make_ushort4(f2bf(v0), f2bf(v1), f2bf(v2), f2bf(v3));
    }
  }
}

// ---------------- MFMA MLP2: dense per-slot bf16 (gate+bias folded), NO atomics ----------------
__global__ __launch_bounds__(256) void mlp2_mfma(
    const unsigned short* __restrict__ h, const unsigned short* __restrict__ wot,
    const float* __restrict__ bo, const float* __restrict__ gates2,
    const int* __restrict__ bucket, const int* __restrict__ counts,
    const int* __restrict__ map, const int* __restrict__ total,
    unsigned short* __restrict__ y2) {
  if ((int)blockIdx.y >= *total) return;
  int ent = map[blockIdx.y];
  int e = ent >> 16, t0 = ent & 0xFFFF;
  int c0 = blockIdx.x * 128;
  int cnt = counts[e];
  int tid = threadIdx.x;
  __shared__ int slots[128];
  __shared__ __align__(16) unsigned short Xb[128][72];
  __shared__ __align__(16) unsigned short Wb[128][72];
  if (tid < 128) {
    int ii = t0 + tid;
    slots[tid] = (ii < cnt) ? bucket[(size_t)e * (T * KF) + ii] : -1;
  }
  __syncthreads();
  int lane = tid & 63, wid = tid >> 6;
  int wr = wid & 1, wc = wid >> 1;
  int lr = lane & 15, lk = (lane >> 4) * 8, rowq = (lane >> 4) * 4;
  f32x4 acc[4][4] = {};
  for (int kc = 0; kc < HID; kc += 64) {
    __syncthreads();
    #pragma unroll
    for (int it = 0; it < 4; ++it) {
      int i = it * 256 + tid;
      int r = i >> 3, c8 = (i & 7) * 8;
      int s = slots[r];
      uint4 v = make_uint4(0u, 0u, 0u, 0u);
      if (s >= 0) v = *(const uint4*)&h[(size_t)s * HID + kc + c8];
      *(uint4*)&Xb[r][c8] = v;
    }
    #pragma unroll
    for (int it = 0; it < 4; ++it) {
      int i = it * 256 + tid;
      int r = i >> 3, c8 = (i & 7) * 8;
      *(uint4*)&Wb[r][c8] = *(const uint4*)&wot[((size_t)e * C + c0 + r) * HID + kc + c8];
    }
    __syncthreads();
    #pragma unroll
    for (int kk = 0; kk < 64; kk += 32) {
      bf16x8 a[4], b[4];
      #pragma unroll
      for (int nf = 0; nf < 4; nf++) a[nf] = *(const bf16x8*)&Wb[wc * 64 + nf * 16 + lr][kk + lk];
      #pragma unroll
      for (int mf = 0; mf < 4; mf++) b[mf] = *(const bf16x8*)&Xb[wr * 64 + mf * 16 + lr][kk + lk];
      #pragma unroll
      for (int nf = 0; nf < 4; nf++)
        #pragma unroll
        for (int mf = 0; mf < 4; mf++)
          acc[nf][mf] = __builtin_amdgcn_mfma_f32_16x16x32_bf16(a[nf], b[mf], acc[nf][mf], 0, 0, 0);
    }
  }
  #pragma unroll
  for (int mf = 0; mf < 4; mf++) {
    int si = wr * 64 + mf * 16 + lr;
    int s = slots[si];
    if (s < 0) continue;
    float g = gates2[s];
    #pragma unroll
    for (int nf = 0; nf < 4; nf++) {
      int cc = c0 + wc * 64 + nf * 16 + rowq;
      const float4 b4 = *(const float4*)&bo[(size_t)e * C + cc];
      ushort4 v = make_ushort4(f2bf(g * (acc[nf][mf][0] + b4.x)),
                               f2bf(g * (acc[nf][mf][1] + b4.y)),
                               f2bf(g * (acc[nf][mf][2] + b4.z)),
                               f2bf(g * (acc[nf][mf][3] + b4.w)));
      *(ushort4*)&y2[(size_t)s * C + cc] = v;
    }
  }
}

// ---------------- Final residual add (bf16 slots) ----------------
__global__ void final_kernel(const unsigned short* __restrict__ y2, float* __restrict__ xout) {
  int t = blockIdx.x, tid = threadIdx.x;
  int c = tid * 2;
  unsigned u0 = *(const unsigned*)&y2[(size_t)(t * 2) * C + c];
  unsigned u1 = *(const unsigned*)&y2[(size_t)(t * 2 + 1) * C + c];
  xout[(size_t)t * C + c]     += bf2f((unsigned short)(u0 & 0xFFFF)) + bf2f((unsigned short)(u1 & 0xFFFF));
  xout[(size_t)t * C + c + 1] += bf2f((unsigned short)(u0 >> 16)) + bf2f((unsigned short)(u1 >> 16));
}

// ---------------- Gating statistics reduction ----------------
template <int E, int K>
__global__ void reduce_gating(const float* __restrict__ probs, const float* __restrict__ lse,
                              const int* __restrict__ idxs, float* __restrict__ psum,
                              float* __restrict__ freq, float* __restrict__ zsum) {
  __shared__ float ps[E];
  __shared__ float fr[E];
  __shared__ float zs;
  int tid = threadIdx.x;
  if (tid < E) { ps[tid] = 0.f; fr[tid] = 0.f; }
  if (tid == 0) zs = 0.f;
  __syncthreads();
  int t = blockIdx.x * 256 + tid;
  if (t < T) {
    for (int e = 0; e < E; e++) atomicAdd(&ps[e], probs[(size_t)t * E + e]);
    for (int k = 0; k < K; k++) atomicAdd(&fr[idxs[(size_t)t * K + k]], 1.f);
    float l = lse[t];
    atomicAdd(&zs, l * l);
  }
  __syncthreads();
  if (tid < E) { atomicAdd(&psum[tid], ps[tid]); atomicAdd(&freq[tid], fr[tid]); }
  if (tid == 0) atomicAdd(zsum, zs);
}

__global__ void loss_kernel(const float* __restrict__ acc, float* __restrict__ out) {
  const float* p1 = acc;      const float* f1 = acc + 24; float z1 = acc[48];
  const float* p2 = acc + 49; const float* f2 = acc + 65; float z2 = acc[81];
  float sp1 = 0.f, sf1 = 0.f;
  for (int e = 0; e < 24; e++) { sp1 += p1[e]; sf1 += f1[e]; }
  float sw1 = 0.f;
  for (int e = 0; e < 24; e++) sw1 += (p1[e] / sp1) * (f1[e] / sf1);
  sw1 *= 24.f;
  float sp2 = 0.f, sf2 = 0.f;
  for (int e = 0; e < 16; e++) { sp2 += p2[e]; sf2 += f2[e]; }
  float sw2 = 0.f;
  for (int e = 0; e < 16; e++) sw2 += (p2[e] / sp2) * (f2[e] / sf2);
  sw2 *= 16.f;
  out[0] = 0.01f * sw1 + 0.001f * (z1 / T) + 0.01f * sw2 + 0.001f * (z2 / T);
}

}  // namespace

extern "C" void kernel_launch(void* const* d_in, const int* in_sizes, int n_in,
                              void* d_out, int out_size, void* d_ws, size_t ws_size,
                              hipStream_t stream) {
  const float* x      = (const float*)d_in[0];
  const int*   task   = (const int*)d_in[1];
  const float* n1g    = (const float*)d_in[2];
  const float* n1b    = (const float*)d_in[3];
  const float* gate_a = (const float*)d_in[4];
  const float* wq     = (const float*)d_in[5];
  const float* wo_a   = (const float*)d_in[6];
  const float* kvw    = (const float*)d_in[7];
  const float* kvb    = (const float*)d_in[8];
  const float* n2g    = (const float*)d_in[9];
  const float* n2b    = (const float*)d_in[10];
  const float* gate_m = (const float*)d_in[11];
  const float* wi     = (const float*)d_in[12];
  const float* bi     = (const float*)d_in[13];
  const float* wo_m   = (const float*)d_in[14];
  const float* bo     = (const float*)d_in[15];
  float* out = (float*)d_out;

  char* p = (char*)d_ws;
  unsigned short* x1b = (unsigned short*)p; p += (size_t)T * C * 2;
  unsigned short* qb = (unsigned short*)p;  p += (size_t)T * KA * HD * 2;
  unsigned short* ob = (unsigned short*)p;  p += (size_t)T * KA * HD * 2;
  unsigned short* Kb = (unsigned short*)p;  p += (size_t)T * HD * 2;
  unsigned short* Vt = (unsigned short*)p;  p += (size_t)T * HD * 2;
  // union region: y_slot (33.5MB) then reused as h (16.8MB) + y2_slot (8.4MB)
  char* un = p;                      p += (size_t)T * KA * C * 2;
  unsigned short* y_slot  = (unsigned short*)un;
  unsigned short* h       = (unsigned short*)un;
  unsigned short* y2_slot = (unsigned short*)(un + (size_t)T * KF * HID * 2);
  unsigned short* wqt = (unsigned short*)p;  p += (size_t)EA * C * HD * 2;
  unsigned short* woat = (unsigned short*)p; p += (size_t)EA * HD * C * 2;
  unsigned short* wit = (unsigned short*)p;  p += (size_t)EF * C * HID * 2;
  unsigned short* womt = (unsigned short*)p; p += (size_t)EF * HID * C * 2;
  unsigned short* kvwt = (unsigned short*)p; p += (size_t)(2 * HD) * C * 2;
  float* probs1 = (float*)p;         p += (size_t)T * EA * 4;
  float* lse1 = (float*)p;           p += (size_t)T * 4;
  float* gates1 = (float*)p;         p += (size_t)T * KA * 4;
  int* idx1 = (int*)p;               p += (size_t)T * KA * 4;
  float* probs2 = (float*)p;         p += (size_t)T * EF * 4;
  float* lse2 = (float*)p;           p += (size_t)T * 4;
  float* gates2 = (float*)p;         p += (size_t)T * KF * 4;
  int* idx2 = (int*)p;               p += (size_t)T * KF * 4;
  int* bucket_a = (int*)p;           p += (size_t)EA * (T * KA) * 4;
  int* bucket_f = (int*)p;           p += (size_t)EF * (T * KF) * 4;
  int* counts_a = (int*)p;           p += 32 * 4;
  int* counts_f = (int*)p;           p += 32 * 4;
  float* accum = (float*)p;          p += 128 * 4;
  int* maps = (int*)p;               p += 768 * 4;
  int* totals = (int*)p;             p += 4 * 4;

  hipMemsetAsync(counts_a, 0, (32 + 32 + 128) * 4, stream);

  tcvt_kernel<<<dim3(2, 16, 24), 256, 0, stream>>>(wq, wqt, C, HD);
  tcvt_kernel<<<dim3(16, 2, 24), 256, 0, stream>>>(wo_a, woat, HD, C);
  tcvt_kernel<<<dim3(32, 16, 16), 256, 0, stream>>>(wi, wit, C, HID);
  tcvt_kernel<<<dim3(16, 32, 16), 256, 0, stream>>>(wo_m, womt, HID, C);
  tcvt_kernel<<<dim3(4, 16, 1), 256, 0, stream>>>(kvw, kvwt, C, 2 * HD);

  ln_gate_kernel<EA, KA, 8><<<T, 256, 0, stream>>>(x, n1g, n1b, gate_a, task, x1b,
                                                   probs1, lse1, gates1, idx1);
  bucket_kernel<EA><<<(T * KA + 511) / 512, 512, 0, stream>>>(idx1, T * KA, T * KA,
                                                              counts_a, bucket_a);
  build_maps_a<<<1, 64, 0, stream>>>(counts_a, maps, totals);
  qgemm_mfma<<<dim3(1, 152), 256, 0, stream>>>(x1b, wqt, bucket_a, counts_a, maps, totals, qb);
  kv_mfma<<<T / 16, 256, 0, stream>>>(x1b, kvwt, kvb, Kb, Vt);
  attn_mfma<<<dim3(NS / 64, KA, NB), 256, 0, stream>>>(qb, Kb, Vt, ob);
  oproj_mfma<<<dim3(4, 280), 256, 0, stream>>>(ob, woat, gates1, bucket_a, counts_a,
                                               maps + 256, totals + 1, y_slot);
  combine_kernel<<<T, 256, 0, stream>>>(x, y_slot, out);
  ln_gate_kernel<EF, KF, 16><<<T, 256, 0, stream>>>(out, n2g, n2b, gate_m, task, x1b,
                                                    probs2, lse2, gates2, idx2);
  bucket_kernel<EF><<<(T * KF + 511) / 512, 512, 0, stream>>>(idx2, T * KF, T * KF,
                                                              counts_f, bucket_f);
  build_maps_f<<<1, 64, 0, stream>>>(counts_f, maps, totals);
  mlp1_mfma<<<dim3(8, 80), 256, 0, stream>>>(x1b, wit, bi, bucket_f, counts_f,
                                             maps + 600, totals + 2, h);
  mlp2_mfma<<<dim3(4, 80), 256, 0, stream>>>(h, womt, bo, gates2, bucket_f, counts_f,
                                             maps + 600, totals + 2, y2_slot);
  final_kernel<<<T, 256, 0, stream>>>(y2_slot, out);
  reduce_gating<EA, KA><<<16, 256, 0, stream>>>(probs1, lse1, idx1, accum, accum + 24, accum + 48);
  reduce_gating<EF, KF><<<16, 256, 0, stream>>>(probs2, lse2, idx2, accum + 49, accum + 65, accum + 81);
  loss_kernel<<<1, 1, 0, stream>>>(accum, out + (size_t)T * C);
}

// Round 9
// 376.148 us; speedup vs baseline: 4.5395x; 1.0930x over previous
//
#include <hip/hip_runtime.h>
#include <math.h>

namespace {

constexpr int T   = 4096;
constexpr int C   = 512;
constexpr int NB  = 8;
constexpr int NS  = 512;
constexpr int HD  = 64;
constexpr int KA  = 8;
constexpr int EA  = 24;
constexpr int EF  = 16;
constexpr int KF  = 2;
constexpr int HID = 1024;

typedef __attribute__((ext_vector_type(8))) short bf16x8;
typedef __attribute__((ext_vector_type(4))) float f32x4;

__device__ inline unsigned short f2bf(float f) {
  unsigned u = __float_as_uint(f);
  return (unsigned short)((u + 0x7FFFu + ((u >> 16) & 1u)) >> 16);
}
__device__ inline float bf2f(unsigned short u) {
  return __uint_as_float((unsigned)u << 16);
}

// ---------------- Fused LayerNorm + Gating: 16 tokens per block ----------------
// W staged once per block (amortized over 16 tokens); LN fully in-wave (no barriers);
// logits = 384/256 thread-parallel fp32 dots from LDS; softmax+topk one wave/token.
template <int E, int K>
__global__ __launch_bounds__(256) void ln_gate_kernel(
    const float* __restrict__ in, const float* __restrict__ g,
    const float* __restrict__ b, const float* __restrict__ gate_all,
    const int* __restrict__ task, unsigned short* __restrict__ outb,
    float* __restrict__ probs, float* __restrict__ lse_out,
    float* __restrict__ gates, int* __restrict__ idxs) {
  constexpr int TPB = 16;   // tokens per block
  constexpr int XSS = 516;  // padded xs stride (516%32=4 -> tt-lanes hit distinct banks)
  int tid = threadIdx.x, lane = tid & 63, wv = tid >> 6;
  int tb = blockIdx.x * TPB;
  __shared__ float xs[TPB][XSS];
  __shared__ float lg[TPB][E];
  __shared__ __align__(16) float Ws[C * E];
  // stage gate matrix once per block (float4-coalesced from L2)
  const float* W = gate_all + (size_t)task[0] * C * E;
  for (int i = tid; i < C * E / 4; i += 256)
    *(float4*)&Ws[i * 4] = *(const float4*)&W[(size_t)i * 4];
  // LN: wave wv handles tokens wv*4..wv*4+3, lane covers cols lane*8..+7
  int c0 = lane * 8;
  const float4 g0 = *(const float4*)&g[c0], g1 = *(const float4*)&g[c0 + 4];
  const float4 b0 = *(const float4*)&b[c0], b1 = *(const float4*)&b[c0 + 4];
  #pragma unroll
  for (int i = 0; i < 4; i++) {
    int tt = wv * 4 + i;
    int t = tb + tt;
    const float* row = in + (size_t)t * C + c0;
    const float4 v0 = *(const float4*)&row[0];
    const float4 v1 = *(const float4*)&row[4];
    float s = (v0.x + v0.y) + (v0.z + v0.w) + (v1.x + v1.y) + (v1.z + v1.w);
    #pragma unroll
    for (int m = 1; m < 64; m <<= 1) s += __shfl_xor(s, m);
    float mean = s * (1.f / C);
    float d[8] = {v0.x - mean, v0.y - mean, v0.z - mean, v0.w - mean,
                  v1.x - mean, v1.y - mean, v1.z - mean, v1.w - mean};
    float vv = 0.f;
    #pragma unroll
    for (int j = 0; j < 8; j++) vv += d[j] * d[j];
    #pragma unroll
    for (int m = 1; m < 64; m <<= 1) vv += __shfl_xor(vv, m);
    float r = rsqrtf(vv * (1.f / C) + 1e-5f);
    float o[8];
    o[0] = d[0] * r * g0.x + b0.x; o[1] = d[1] * r * g0.y + b0.y;
    o[2] = d[2] * r * g0.z + b0.z; o[3] = d[3] * r * g0.w + b0.w;
    o[4] = d[4] * r * g1.x + b1.x; o[5] = d[5] * r * g1.y + b1.y;
    o[6] = d[6] * r * g1.z + b1.z; o[7] = d[7] * r * g1.w + b1.w;
    *(ushort4*)&outb[(size_t)t * C + c0] =
        make_ushort4(f2bf(o[0]), f2bf(o[1]), f2bf(o[2]), f2bf(o[3]));
    *(ushort4*)&outb[(size_t)t * C + c0 + 4] =
        make_ushort4(f2bf(o[4]), f2bf(o[5]), f2bf(o[6]), f2bf(o[7]));
    #pragma unroll
    for (int j = 0; j < 8; j++) xs[tt][c0 + j] = o[j];
  }
  __syncthreads();
  // logits: thread per (token, expert) pair, fp32 dot from LDS
  for (int p = tid; p < TPB * E; p += 256) {
    int e = p % E, tt = p / E;
    float a0 = 0.f, a1 = 0.f, a2 = 0.f, a3 = 0.f;
    #pragma unroll 8
    for (int c = 0; c < C; c += 4) {
      a0 += xs[tt][c + 0] * Ws[(c + 0) * E + e];
      a1 += xs[tt][c + 1] * Ws[(c + 1) * E + e];
      a2 += xs[tt][c + 2] * Ws[(c + 2) * E + e];
      a3 += xs[tt][c + 3] * Ws[(c + 3) * E + e];
    }
    lg[tt][e] = (a0 + a1) + (a2 + a3);
  }
  __syncthreads();
  // softmax + top-k: one wave per token, 4 tokens serial per wave
  #pragma unroll
  for (int i = 0; i < 4; i++) {
    int tt = wv * 4 + i;
    int t = tb + tt;
    float lgv = (lane < E) ? lg[tt][lane] : -3.0e38f;
    float mx = lgv;
    #pragma unroll
    for (int m = 1; m < 64; m <<= 1) mx = fmaxf(mx, __shfl_xor(mx, m));
    float pe = (lane < E) ? expf(lgv - mx) : 0.f;
    float sum = pe;
    #pragma unroll
    for (int m = 1; m < 64; m <<= 1) sum += __shfl_xor(sum, m);
    float inv = 1.f / sum;
    float prob = pe * inv;
    if (lane < E) probs[(size_t)t * E + lane] = prob;
    if (lane == 0) lse_out[t] = mx + logf(sum);
    // iterative top-K, lax.top_k tie-break (strict >, lowest index wins)
    float pv = (lane < E) ? prob : -1.f;
    float gsum = 0.f, myv = 0.f; int myi = 0;
    for (int k = 0; k < K; k++) {
      float bv = pv; int bi_ = lane;
      #pragma unroll
      for (int m = 1; m < 64; m <<= 1) {
        float ov = __shfl_xor(bv, m); int oi = __shfl_xor(bi_, m);
        if (ov > bv || (ov == bv && oi < bi_)) { bv = ov; bi_ = oi; }
      }
      gsum += bv;
      if (lane == k) { myv = bv; myi = bi_; }
      if (lane == bi_) pv = -1.f;
    }
    if (lane < K) {
      float ginv = 1.f / (gsum + 1e-6f);
      gates[(size_t)t * K + lane] = myv * ginv;
      idxs[(size_t)t * K + lane]  = myi;
    }
  }
}

// ---------------- bucket by expert: LDS-aggregated, ~E global atomics per block ----------------
template <int E>
__global__ __launch_bounds__(512) void bucket_kernel(const int* __restrict__ idx, int nslots,
                                                     int stride, int* counts, int* bucket) {
  __shared__ int lcount[E];
  __shared__ int lbase[E];
  int tid = threadIdx.x;
  if (tid < E) lcount[tid] = 0;
  __syncthreads();
  int s = blockIdx.x * 512 + tid;
  int e = 0, lpos = 0;
  bool valid = (s < nslots);
  if (valid) {
    e = idx[s];
    lpos = atomicAdd(&lcount[e], 1);
  }
  __syncthreads();
  if (tid < E) lbase[tid] = lcount[tid] ? atomicAdd(&counts[tid], lcount[tid]) : 0;
  __syncthreads();
  if (valid) bucket[(size_t)e * stride + lbase[e] + lpos] = s;
}

// ---------------- flat (expert, tile) maps ----------------
__global__ void build_maps_a(const int* __restrict__ counts, int* __restrict__ maps,
                             int* __restrict__ totals) {
  if (threadIdx.x != 0) return;
  int n = 0;
  for (int e = 0; e < EA; e++) { int c = counts[e]; for (int t0 = 0; t0 < c; t0 += 256) maps[n++] = (e << 16) | t0; }
  totals[0] = n;
  n = 0;
  for (int e = 0; e < EA; e++) { int c = counts[e]; for (int t0 = 0; t0 < c; t0 += 128) maps[256 + n++] = (e << 16) | t0; }
  totals[1] = n;
}
__global__ void build_maps_f(const int* __restrict__ counts, int* __restrict__ maps,
                             int* __restrict__ totals) {
  if (threadIdx.x != 0) return;
  int n = 0;
  for (int e = 0; e < EF; e++) { int c = counts[e]; for (int t0 = 0; t0 < c; t0 += 128) maps[600 + n++] = (e << 16) | t0; }
  totals[2] = n;
}

// ---------------- transpose + cvt weights: [E][K][N] f32 -> [E][N][K] bf16 ----------------
__global__ void tcvt_kernel(const float* __restrict__ src, unsigned short* __restrict__ dst,
                            int K, int N) {
  int e = blockIdx.z;
  int kt = blockIdx.y * 32, nt = blockIdx.x * 32;
  __shared__ float tile[32][33];
  int tid = threadIdx.x;
  const float* S = src + (size_t)e * K * N;
  for (int i = tid; i < 32 * 32; i += 256) {
    int r = i >> 5, c = i & 31;
    tile[r][c] = S[(size_t)(kt + r) * N + nt + c];
  }
  __syncthreads();
  unsigned short* D = dst + (size_t)e * K * N;
  for (int i = tid; i < 32 * 8; i += 256) {
    int n = i >> 3, k4 = (i & 7) * 4;
    ushort4 v;
    v.x = f2bf(tile[k4 + 0][n]); v.y = f2bf(tile[k4 + 1][n]);
    v.z = f2bf(tile[k4 + 2][n]); v.w = f2bf(tile[k4 + 3][n]);
    *(ushort4*)&D[(size_t)(nt + n) * K + kt + k4] = v;
  }
}

// ---------------- MFMA Q GEMM: 256 slots x 64 out, K=512 -> bf16 q (pre-scaled) ----------------
__global__ __launch_bounds__(256) void qgemm_mfma(
    const unsigned short* __restrict__ xb, const unsigned short* __restrict__ wqt,
    const int* __restrict__ bucket, const int* __restrict__ counts,
    const int* __restrict__ map, const int* __restrict__ total,
    unsigned short* __restrict__ qb) {
  if ((int)blockIdx.y >= *total) return;
  int ent = map[blockIdx.y];
  int e = ent >> 16, t0 = ent & 0xFFFF;
  int cnt = counts[e];
  int tid = threadIdx.x;
  __shared__ int slots[256];
  __shared__ __align__(16) unsigned short Xb[256][72];
  __shared__ __align__(16) unsigned short Wb[64][72];
  {
    int ii = t0 + tid;
    slots[tid] = (ii < cnt) ? bucket[(size_t)e * (T * KA) + ii] : -1;
  }
  __syncthreads();
  int lane = tid & 63, wid = tid >> 6;
  int lr = lane & 15, lk = (lane >> 4) * 8, rowq = (lane >> 4) * 4;
  f32x4 acc[4][4] = {};
  for (int kc = 0; kc < C; kc += 64) {
    __syncthreads();
    #pragma unroll
    for (int it = 0; it < 8; ++it) {
      int i = it * 256 + tid;
      int r = i >> 3, c8 = (i & 7) * 8;
      int s = slots[r];
      uint4 v = make_uint4(0u, 0u, 0u, 0u);
      if (s >= 0) v = *(const uint4*)&xb[(size_t)(s >> 3) * C + kc + c8];
      *(uint4*)&Xb[r][c8] = v;
    }
    #pragma unroll
    for (int it = 0; it < 2; ++it) {
      int i = it * 256 + tid;
      int r = i >> 3, c8 = (i & 7) * 8;
      *(uint4*)&Wb[r][c8] = *(const uint4*)&wqt[((size_t)e * HD + r) * C + kc + c8];
    }
    __syncthreads();
    #pragma unroll
    for (int kk = 0; kk < 64; kk += 32) {
      bf16x8 a[4], b[4];
      #pragma unroll
      for (int nf = 0; nf < 4; nf++) a[nf] = *(const bf16x8*)&Wb[nf * 16 + lr][kk + lk];
      #pragma unroll
      for (int mf = 0; mf < 4; mf++) b[mf] = *(const bf16x8*)&Xb[wid * 64 + mf * 16 + lr][kk + lk];
      #pragma unroll
      for (int nf = 0; nf < 4; nf++)
        #pragma unroll
        for (int mf = 0; mf < 4; mf++)
          acc[nf][mf] = __builtin_amdgcn_mfma_f32_16x16x32_bf16(a[nf], b[mf], acc[nf][mf], 0, 0, 0);
    }
  }
  #pragma unroll
  for (int mf = 0; mf < 4; mf++) {
    int s = slots[wid * 64 + mf * 16 + lr];
    if (s < 0) continue;
    #pragma unroll
    for (int nf = 0; nf < 4; nf++) {
      ushort4 v = make_ushort4(f2bf(0.125f * acc[nf][mf][0]), f2bf(0.125f * acc[nf][mf][1]),
                               f2bf(0.125f * acc[nf][mf][2]), f2bf(0.125f * acc[nf][mf][3]));
      *(ushort4*)&qb[(size_t)s * HD + nf * 16 + rowq] = v;
    }
  }
}

// ---------------- MFMA KV GEMM: 16 tokens x 128 cols per block, 256 blocks ----------------
__global__ __launch_bounds__(256) void kv_mfma(
    const unsigned short* __restrict__ xb, const unsigned short* __restrict__ kvwt,
    const float* __restrict__ kvb, unsigned short* __restrict__ Kb,
    unsigned short* __restrict__ Vt) {
  int t0 = blockIdx.x * 16;
  int tid = threadIdx.x;
  __shared__ __align__(16) unsigned short Xs[16][72];
  __shared__ __align__(16) unsigned short Ws[128][72];
  int lane = tid & 63, w = tid >> 6;
  int lr = lane & 15, lk = (lane >> 4) * 8, rowq = (lane >> 4) * 4;
  f32x4 acc[2] = {};
  for (int kc = 0; kc < C; kc += 64) {
    __syncthreads();
    if (tid < 128) {
      int r = tid >> 3, c8 = (tid & 7) * 8;
      *(uint4*)&Xs[r][c8] = *(const uint4*)&xb[(size_t)(t0 + r) * C + kc + c8];
    }
    #pragma unroll
    for (int it = 0; it < 4; ++it) {
      int i = it * 256 + tid;
      int r = i >> 3, c8 = (i & 7) * 8;
      *(uint4*)&Ws[r][c8] = *(const uint4*)&kvwt[(size_t)r * C + kc + c8];
    }
    __syncthreads();
    #pragma unroll
    for (int kk = 0; kk < 64; kk += 32) {
      bf16x8 xf = *(const bf16x8*)&Xs[lr][kk + lk];
      #pragma unroll
      for (int cf = 0; cf < 2; cf++) {
        bf16x8 wf = *(const bf16x8*)&Ws[w * 32 + cf * 16 + lr][kk + lk];
        acc[cf] = __builtin_amdgcn_mfma_f32_16x16x32_bf16(wf, xf, acc[cf], 0, 0, 0);
      }
    }
  }
  int t = t0 + lr;
  int bb = t >> 9, n = t & (NS - 1);
  #pragma unroll
  for (int cf = 0; cf < 2; cf++) {
    #pragma unroll
    for (int r2 = 0; r2 < 4; r2++) {
      int c = w * 32 + cf * 16 + rowq + r2;
      float v = acc[cf][r2] + kvb[c];
      if (c < HD) Kb[(size_t)t * HD + c] = f2bf(v);
      else        Vt[((size_t)bb * HD + (c - HD)) * NS + n] = f2bf(v);
    }
  }
}

// ---------------- MFMA flash attention: block per (qtile64, head, batch) ----------------
__global__ __launch_bounds__(256) void attn_mfma(
    const unsigned short* __restrict__ qb, const unsigned short* __restrict__ Kb,
    const unsigned short* __restrict__ Vt, unsigned short* __restrict__ ob) {
  int qt = blockIdx.x, h = blockIdx.y, b = blockIdx.z;
  int tid = threadIdx.x;
  __shared__ __align__(16) unsigned short Qs[64][72];
  __shared__ __align__(16) unsigned short Ks[64][72];
  __shared__ __align__(16) unsigned short Vs[64][72];
  __shared__ __align__(16) unsigned short Ps[64][72];
  int i0 = qt * 64;
  #pragma unroll
  for (int it = 0; it < 2; ++it) {
    int i = it * 256 + tid;
    int r = i >> 3, c8 = (i & 7) * 8;
    *(uint4*)&Qs[r][c8] = *(const uint4*)&qb[(((size_t)(b * NS + i0 + r)) * KA + h) * HD + c8];
  }
  int lane = tid & 63, w = tid >> 6;
  int lr = lane & 15, lk = (lane >> 4) * 8, rowq = (lane >> 4) * 4;
  f32x4 acc_o[4] = {};
  float m_run = -3.0e38f, l_run = 0.f;
  for (int jt = 0; jt < NS / 64; ++jt) {
    __syncthreads();
    #pragma unroll
    for (int it = 0; it < 2; ++it) {
      int i = it * 256 + tid;
      int r = i >> 3, c8 = (i & 7) * 8;
      *(uint4*)&Ks[r][c8] = *(const uint4*)&Kb[((size_t)(b * NS + jt * 64 + r)) * HD + c8];
      *(uint4*)&Vs[r][c8] = *(const uint4*)&Vt[((size_t)b * HD + r) * NS + jt * 64 + c8];
    }
    __syncthreads();
    f32x4 acc_s[4] = {};
    #pragma unroll
    for (int kk = 0; kk < 64; kk += 32) {
      bf16x8 qf = *(const bf16x8*)&Qs[w * 16 + lr][kk + lk];
      #pragma unroll
      for (int kf = 0; kf < 4; kf++) {
        bf16x8 kr = *(const bf16x8*)&Ks[kf * 16 + lr][kk + lk];
        acc_s[kf] = __builtin_amdgcn_mfma_f32_16x16x32_bf16(kr, qf, acc_s[kf], 0, 0, 0);
      }
    }
    float pmax = acc_s[0][0];
    #pragma unroll
    for (int kf = 0; kf < 4; kf++)
      #pragma unroll
      for (int r = 0; r < 4; r++) pmax = fmaxf(pmax, acc_s[kf][r]);
    pmax = fmaxf(pmax, __shfl_xor(pmax, 16));
    pmax = fmaxf(pmax, __shfl_xor(pmax, 32));
    float m_new = fmaxf(m_run, pmax);
    float scl = expf(m_run - m_new);
    float rs = 0.f;
    #pragma unroll
    for (int kf = 0; kf < 4; kf++)
      #pragma unroll
      for (int r = 0; r < 4; r++) {
        float pv = expf(acc_s[kf][r] - m_new);
        rs += pv;
        Ps[w * 16 + lr][kf * 16 + rowq + r] = f2bf(pv);
      }
    rs += __shfl_xor(rs, 16);
    rs += __shfl_xor(rs, 32);
    l_run = l_run * scl + rs;
    m_run = m_new;
    __syncthreads();
    #pragma unroll
    for (int df = 0; df < 4; df++) {
      acc_o[df][0] *= scl; acc_o[df][1] *= scl;
      acc_o[df][2] *= scl; acc_o[df][3] *= scl;
    }
    #pragma unroll
    for (int kk = 0; kk < 64; kk += 32) {
      bf16x8 pf = *(const bf16x8*)&Ps[w * 16 + lr][kk + lk];
      #pragma unroll
      for (int df = 0; df < 4; df++) {
        bf16x8 vf = *(const bf16x8*)&Vs[df * 16 + lr][kk + lk];
        acc_o[df] = __builtin_amdgcn_mfma_f32_16x16x32_bf16(vf, pf, acc_o[df], 0, 0, 0);
      }
    }
  }
  float inv = 1.f / l_run;
  int token = b * NS + i0 + w * 16 + lr;
  #pragma unroll
  for (int df = 0; df < 4; df++) {
    ushort4 v = make_ushort4(f2bf(acc_o[df][0] * inv), f2bf(acc_o[df][1] * inv),
                             f2bf(acc_o[df][2] * inv), f2bf(acc_o[df][3] * inv));
    *(ushort4*)&ob[((size_t)token * KA + h) * HD + df * 16 + rowq] = v;
  }
}

// ---------------- MFMA output proj: dense per-slot bf16 (gate folded), NO atomics ----------------
__global__ __launch_bounds__(256) void oproj_mfma(
    const unsigned short* __restrict__ ob, const unsigned short* __restrict__ wot,
    const float* __restrict__ gates, const int* __restrict__ bucket,
    const int* __restrict__ counts, const int* __restrict__ map,
    const int* __restrict__ total, unsigned short* __restrict__ y_slot) {
  if ((int)blockIdx.y >= *total) return;
  int ent = map[blockIdx.y];
  int e = ent >> 16, t0 = ent & 0xFFFF;
  int c0 = blockIdx.x * 128;
  int cnt = counts[e];
  int tid = threadIdx.x;
  __shared__ int slots[128];
  __shared__ float gs[128];
  __shared__ __align__(16) unsigned short Xb[128][72];
  __shared__ __align__(16) unsigned short Wb[128][72];
  if (tid < 128) {
    int ii = t0 + tid;
    int s = (ii < cnt) ? bucket[(size_t)e * (T * KA) + ii] : -1;
    slots[tid] = s;
    gs[tid] = (s >= 0) ? gates[s] : 0.f;
  }
  __syncthreads();
  #pragma unroll
  for (int it = 0; it < 4; ++it) {
    int i = it * 256 + tid;
    int r = i >> 3, c8 = (i & 7) * 8;
    int s = slots[r];
    uint4 vo = make_uint4(0u, 0u, 0u, 0u);
    if (s >= 0) {
      float g = gs[r];
      uint4 u = *(const uint4*)&ob[(size_t)s * HD + c8];
      const unsigned short* us = (const unsigned short*)&u;
      unsigned short* vs = (unsigned short*)&vo;
      #pragma unroll
      for (int k = 0; k < 8; k++) vs[k] = f2bf(g * bf2f(us[k]));
    }
    *(uint4*)&Xb[r][c8] = vo;
  }
  #pragma unroll
  for (int it = 0; it < 4; ++it) {
    int i = it * 256 + tid;
    int r = i >> 3, c8 = (i & 7) * 8;
    *(uint4*)&Wb[r][c8] = *(const uint4*)&wot[((size_t)e * C + c0 + r) * HD + c8];
  }
  __syncthreads();
  int lane = tid & 63, wid = tid >> 6;
  int wr = wid & 1, wc = wid >> 1;
  int lr = lane & 15, lk = (lane >> 4) * 8, rowq = (lane >> 4) * 4;
  f32x4 acc[4][4] = {};
  #pragma unroll
  for (int kk = 0; kk < 64; kk += 32) {
    bf16x8 a[4], b[4];
    #pragma unroll
    for (int nf = 0; nf < 4; nf++) a[nf] = *(const bf16x8*)&Wb[wc * 64 + nf * 16 + lr][kk + lk];
    #pragma unroll
    for (int mf = 0; mf < 4; mf++) b[mf] = *(const bf16x8*)&Xb[wr * 64 + mf * 16 + lr][kk + lk];
    #pragma unroll
    for (int nf = 0; nf < 4; nf++)
      #pragma unroll
      for (int mf = 0; mf < 4; mf++)
        acc[nf][mf] = __builtin_amdgcn_mfma_f32_16x16x32_bf16(a[nf], b[mf], acc[nf][mf], 0, 0, 0);
  }
  #pragma unroll
  for (int mf = 0; mf < 4; mf++) {
    int si = wr * 64 + mf * 16 + lr;
    int s = slots[si];
    if (s < 0) continue;
    size_t base = (size_t)s * C + c0 + wc * 64;
    #pragma unroll
    for (int nf = 0; nf < 4; nf++) {
      ushort4 v = make_ushort4(f2bf(acc[nf][mf][0]), f2bf(acc[nf][mf][1]),
                               f2bf(acc[nf][mf][2]), f2bf(acc[nf][mf][3]));
      *(ushort4*)&y_slot[base + nf * 16 + rowq] = v;
    }
  }
}

// ---------------- combine: out = x + sum_k y_slot[t*8+k] ----------------
__global__ void combine_kernel(const float* __restrict__ x, const unsigned short* __restrict__ ys,
                               float* __restrict__ out) {
  int t = blockIdx.x, tid = threadIdx.x;
  int c = tid * 2;
  float s0 = 0.f, s1 = 0.f;
  #pragma unroll
  for (int k = 0; k < KA; k++) {
    unsigned u = *(const unsigned*)&ys[((size_t)t * KA + k) * C + c];
    s0 += bf2f((unsigned short)(u & 0xFFFF));
    s1 += bf2f((unsigned short)(u >> 16));
  }
  out[(size_t)t * C + c]     = x[(size_t)t * C + c] + s0;
  out[(size_t)t * C + c + 1] = x[(size_t)t * C + c + 1] + s1;
}

// ---------------- MFMA MLP1: h = gelu(x2 @ wi + bi), bf16 out ----------------
__global__ __launch_bounds__(256) void mlp1_mfma(
    const unsigned short* __restrict__ xb, const unsigned short* __restrict__ wit,
    const float* __restrict__ bi, const int* __restrict__ bucket,
    const int* __restrict__ counts, const int* __restrict__ map,
    const int* __restrict__ total, unsigned short* __restrict__ h) {
  if ((int)blockIdx.y >= *total) return;
  int ent = map[blockIdx.y];
  int e = ent >> 16, t0 = ent & 0xFFFF;
  int j0 = blockIdx.x * 128;
  int cnt = counts[e];
  int tid = threadIdx.x;
  __shared__ int slots[128];
  __shared__ __align__(16) unsigned short Xb[128][72];
  __shared__ __align__(16) unsigned short Wb[128][72];
  if (tid < 128) {
    int ii = t0 + tid;
    slots[tid] = (ii < cnt) ? bucket[(size_t)e * (T * KF) + ii] : -1;
  }
  __syncthreads();
  int lane = tid & 63, wid = tid >> 6;
  int wr = wid & 1, wc = wid >> 1;
  int lr = lane & 15, lk = (lane >> 4) * 8, rowq = (lane >> 4) * 4;
  f32x4 acc[4][4] = {};
  for (int kc = 0; kc < C; kc += 64) {
    __syncthreads();
    #pragma unroll
    for (int it = 0; it < 4; ++it) {
      int i = it * 256 + tid;
      int r = i >> 3, c8 = (i & 7) * 8;
      int s = slots[r];
      uint4 v = make_uint4(0u, 0u, 0u, 0u);
      if (s >= 0) v = *(const uint4*)&xb[(size_t)(s >> 1) * C + kc + c8];
      *(uint4*)&Xb[r][c8] = v;
    }
    #pragma unroll
    for (int it = 0; it < 4; ++it) {
      int i = it * 256 + tid;
      int r = i >> 3, c8 = (i & 7) * 8;
      *(uint4*)&Wb[r][c8] = *(const uint4*)&wit[((size_t)e * HID + j0 + r) * C + kc + c8];
    }
    __syncthreads();
    #pragma unroll
    for (int kk = 0; kk < 64; kk += 32) {
      bf16x8 a[4], b[4];
      #pragma unroll
      for (int nf = 0; nf < 4; nf++) a[nf] = *(const bf16x8*)&Wb[wc * 64 + nf * 16 + lr][kk + lk];
      #pragma unroll
      for (int mf = 0; mf < 4; mf++) b[mf] = *(const bf16x8*)&Xb[wr * 64 + mf * 16 + lr][kk + lk];
      #pragma unroll
      for (int nf = 0; nf < 4; nf++)
        #pragma unroll
        for (int mf = 0; mf < 4; mf++)
          acc[nf][mf] = __builtin_amdgcn_mfma_f32_16x16x32_bf16(a[nf], b[mf], acc[nf][mf], 0, 0, 0);
    }
  }
  #pragma unroll
  for (int mf = 0; mf < 4; mf++) {
    int s = slots[wr * 64 + mf * 16 + lr];
    if (s < 0) continue;
    #pragma unroll
    for (int nf = 0; nf < 4; nf++) {
      int j = j0 + wc * 64 + nf * 16 + rowq;
      const float4 b4 = *(const float4*)&bi[(size_t)e * HID + j];
      float v0 = acc[nf][mf][0] + b4.x, v1 = acc[nf][mf][1] + b4.y;
      float v2 = acc[nf][mf][2] + b4.z, v3 = acc[nf][mf][3] + b4.w;
      v0 = 0.5f * v0 * (1.f + erff(v0 * 0.70710678118654752f));
      v1 = 0.5f * v1 * (1.f + erff(v1 * 0.70710678118654752f));
      v2 = 0.5f * v2 * (1.f + erff(v2 * 0.70710678118654752f));
      v3 = 0.5f * v3 * (1.f + erff(v3 * 0.70710678118654752f));
      *(ushort4*)&h[(size_t)s * HID + j] = make_ushort4(f2bf(v0), f2bf(v1), f2bf(v2), f2bf(v3));
    }
  }
}

// ---------------- MFMA MLP2: dense per-slot bf16 (gate+bias folded), NO atomics ----------------
__global__ __launch_bounds__(256) void mlp2_mfma(
    const unsigned short* __restrict__ h, const unsigned short* __restrict__ wot,
    const float* __restrict__ bo, const float* __restrict__ gates2,
    const int* __restrict__ bucket, const int* __restrict__ counts,
    const int* __restrict__ map, const int* __restrict__ total,
    unsigned short* __restrict__ y2) {
  if ((int)blockIdx.y >= *total) return;
  int ent = map[blockIdx.y];
  int e = ent >> 16, t0 = ent & 0xFFFF;
  int c0 = blockIdx.x * 128;
  int cnt = counts[e];
  int tid = threadIdx.x;
  __shared__ int slots[128];
  __shared__ __align__(16) unsigned short Xb[128][72];
  __shared__ __align__(16) unsigned short Wb[128][72];
  if (tid < 128) {
    int ii = t0 + tid;
    slots[tid] = (ii < cnt) ? bucket[(size_t)e * (T * KF) + ii] : -1;
  }
  __syncthreads();
  int lane = tid & 63, wid = tid >> 6;
  int wr = wid & 1, wc = wid >> 1;
  int lr = lane & 15, lk = (lane >> 4) * 8, rowq = (lane >> 4) * 4;
  f32x4 acc[4][4] = {};
  for (int kc = 0; kc < HID; kc += 64) {
    __syncthreads();
    #pragma unroll
    for (int it = 0; it < 4; ++it) {
      int i = it * 256 + tid;
      int r = i >> 3, c8 = (i & 7) * 8;
      int s = slots[r];
      uint4 v = make_uint4(0u, 0u, 0u, 0u);
      if (s >= 0) v = *(const uint4*)&h[(size_t)s * HID + kc + c8];
      *(uint4*)&Xb[r][c8] = v;
    }
    #pragma unroll
    for (int it = 0; it < 4; ++it) {
      int i = it * 256 + tid;
      int r = i >> 3, c8 = (i & 7) * 8;
      *(uint4*)&Wb[r][c8] = *(const uint4*)&wot[((size_t)e * C + c0 + r) * HID + kc + c8];
    }
    __syncthreads();
    #pragma unroll
    for (int kk = 0; kk < 64; kk += 32) {
      bf16x8 a[4], b[4];
      #pragma unroll
      for (int nf = 0; nf < 4; nf++) a[nf] = *(const bf16x8*)&Wb[wc * 64 + nf * 16 + lr][kk + lk];
      #pragma unroll
      for (int mf = 0; mf < 4; mf++) b[mf] = *(const bf16x8*)&Xb[wr * 64 + mf * 16 + lr][kk + lk];
      #pragma unroll
      for (int nf = 0; nf < 4; nf++)
        #pragma unroll
        for (int mf = 0; mf < 4; mf++)
          acc[nf][mf] = __builtin_amdgcn_mfma_f32_16x16x32_bf16(a[nf], b[mf], acc[nf][mf], 0, 0, 0);
    }
  }
  #pragma unroll
  for (int mf = 0; mf < 4; mf++) {
    int si = wr * 64 + mf * 16 + lr;
    int s = slots[si];
    if (s < 0) continue;
    float g = gates2[s];
    #pragma unroll
    for (int nf = 0; nf < 4; nf++) {
      int cc = c0 + wc * 64 + nf * 16 + rowq;
      const float4 b4 = *(const float4*)&bo[(size_t)e * C + cc];
      ushort4 v = make_ushort4(f2bf(g * (acc[nf][mf][0] + b4.x)),
                               f2bf(g * (acc[nf][mf][1] + b4.y)),
                               f2bf(g * (acc[nf][mf][2] + b4.z)),
                               f2bf(g * (acc[nf][mf][3] + b4.w)));
      *(ushort4*)&y2[(size_t)s * C + cc] = v;
    }
  }
}

// ---------------- Final residual add (bf16 slots) ----------------
__global__ void final_kernel(const unsigned short* __restrict__ y2, float* __restrict__ xout) {
  int t = blockIdx.x, tid = threadIdx.x;
  int c = tid * 2;
  unsigned u0 = *(const unsigned*)&y2[(size_t)(t * 2) * C + c];
  unsigned u1 = *(const unsigned*)&y2[(size_t)(t * 2 + 1) * C + c];
  xout[(size_t)t * C + c]     += bf2f((unsigned short)(u0 & 0xFFFF)) + bf2f((unsigned short)(u1 & 0xFFFF));
  xout[(size_t)t * C + c + 1] += bf2f((unsigned short)(u0 >> 16)) + bf2f((unsigned short)(u1 >> 16));
}

// ---------------- Gating statistics reduction ----------------
template <int E, int K>
__global__ void reduce_gating(const float* __restrict__ probs, const float* __restrict__ lse,
                              const int* __restrict__ idxs, float* __restrict__ psum,
                              float* __restrict__ freq, float* __restrict__ zsum) {
  __shared__ float ps[E];
  __shared__ float fr[E];
  __shared__ float zs;
  int tid = threadIdx.x;
  if (tid < E) { ps[tid] = 0.f; fr[tid] = 0.f; }
  if (tid == 0) zs = 0.f;
  __syncthreads();
  int t = blockIdx.x * 256 + tid;
  if (t < T) {
    for (int e = 0; e < E; e++) atomicAdd(&ps[e], probs[(size_t)t * E + e]);
    for (int k = 0; k < K; k++) atomicAdd(&fr[idxs[(size_t)t * K + k]], 1.f);
    float l = lse[t];
    atomicAdd(&zs, l * l);
  }
  __syncthreads();
  if (tid < E) { atomicAdd(&psum[tid], ps[tid]); atomicAdd(&freq[tid], fr[tid]); }
  if (tid == 0) atomicAdd(zsum, zs);
}

__global__ void loss_kernel(const float* __restrict__ acc, float* __restrict__ out) {
  const float* p1 = acc;      const float* f1 = acc + 24; float z1 = acc[48];
  const float* p2 = acc + 49; const float* f2 = acc + 65; float z2 = acc[81];
  float sp1 = 0.f, sf1 = 0.f;
  for (int e = 0; e < 24; e++) { sp1 += p1[e]; sf1 += f1[e]; }
  float sw1 = 0.f;
  for (int e = 0; e < 24; e++) sw1 += (p1[e] / sp1) * (f1[e] / sf1);
  sw1 *= 24.f;
  float sp2 = 0.f, sf2 = 0.f;
  for (int e = 0; e < 16; e++) { sp2 += p2[e]; sf2 += f2[e]; }
  float sw2 = 0.f;
  for (int e = 0; e < 16; e++) sw2 += (p2[e] / sp2) * (f2[e] / sf2);
  sw2 *= 16.f;
  out[0] = 0.01f * sw1 + 0.001f * (z1 / T) + 0.01f * sw2 + 0.001f * (z2 / T);
}

}  // namespace

extern "C" void kernel_launch(void* const* d_in, const int* in_sizes, int n_in,
                              void* d_out, int out_size, void* d_ws, size_t ws_size,
                              hipStream_t stream) {
  const float* x      = (const float*)d_in[0];
  const int*   task   = (const int*)d_in[1];
  const float* n1g    = (const float*)d_in[2];
  const float* n1b    = (const float*)d_in[3];
  const float* gate_a = (const float*)d_in[4];
  const float* wq     = (const float*)d_in[5];
  const float* wo_a   = (const float*)d_in[6];
  const float* kvw    = (const float*)d_in[7];
  const float* kvb    = (const float*)d_in[8];
  const float* n2g    = (const float*)d_in[9];
  const float* n2b    = (const float*)d_in[10];
  const float* gate_m = (const float*)d_in[11];
  const float* wi     = (const float*)d_in[12];
  const float* bi     = (const float*)d_in[13];
  const float* wo_m   = (const float*)d_in[14];
  const float* bo     = (const float*)d_in[15];
  float* out = (float*)d_out;

  char* p = (char*)d_ws;
  unsigned short* x1b = (unsigned short*)p; p += (size_t)T * C * 2;
  unsigned short* qb = (unsigned short*)p;  p += (size_t)T * KA * HD * 2;
  unsigned short* ob = (unsigned short*)p;  p += (size_t)T * KA * HD * 2;
  unsigned short* Kb = (unsigned short*)p;  p += (size_t)T * HD * 2;
  unsigned short* Vt = (unsigned short*)p;  p += (size_t)T * HD * 2;
  // union region: y_slot (33.5MB) then reused as h (16.8MB) + y2_slot (8.4MB)
  char* un = p;                      p += (size_t)T * KA * C * 2;
  unsigned short* y_slot  = (unsigned short*)un;
  unsigned short* h       = (unsigned short*)un;
  unsigned short* y2_slot = (unsigned short*)(un + (size_t)T * KF * HID * 2);
  unsigned short* wqt = (unsigned short*)p;  p += (size_t)EA * C * HD * 2;
  unsigned short* woat = (unsigned short*)p; p += (size_t)EA * HD * C * 2;
  unsigned short* wit = (unsigned short*)p;  p += (size_t)EF * C * HID * 2;
  unsigned short* womt = (unsigned short*)p; p += (size_t)EF * HID * C * 2;
  unsigned short* kvwt = (unsigned short*)p; p += (size_t)(2 * HD) * C * 2;
  float* probs1 = (float*)p;         p += (size_t)T * EA * 4;
  float* lse1 = (float*)p;           p += (size_t)T * 4;
  float* gates1 = (float*)p;         p += (size_t)T * KA * 4;
  int* idx1 = (int*)p;               p += (size_t)T * KA * 4;
  float* probs2 = (float*)p;         p += (size_t)T * EF * 4;
  float* lse2 = (float*)p;           p += (size_t)T * 4;
  float* gates2 = (float*)p;         p += (size_t)T * KF * 4;
  int* idx2 = (int*)p;               p += (size_t)T * KF * 4;
  int* bucket_a = (int*)p;           p += (size_t)EA * (T * KA) * 4;
  int* bucket_f = (int*)p;           p += (size_t)EF * (T * KF) * 4;
  int* counts_a = (int*)p;           p += 32 * 4;
  int* counts_f = (int*)p;           p += 32 * 4;
  float* accum = (float*)p;          p += 128 * 4;
  int* maps = (int*)p;               p += 768 * 4;
  int* totals = (int*)p;             p += 4 * 4;

  hipMemsetAsync(counts_a, 0, (32 + 32 + 128) * 4, stream);

  tcvt_kernel<<<dim3(2, 16, 24), 256, 0, stream>>>(wq, wqt, C, HD);
  tcvt_kernel<<<dim3(16, 2, 24), 256, 0, stream>>>(wo_a, woat, HD, C);
  tcvt_kernel<<<dim3(32, 16, 16), 256, 0, stream>>>(wi, wit, C, HID);
  tcvt_kernel<<<dim3(16, 32, 16), 256, 0, stream>>>(wo_m, womt, HID, C);
  tcvt_kernel<<<dim3(4, 16, 1), 256, 0, stream>>>(kvw, kvwt, C, 2 * HD);

  ln_gate_kernel<EA, KA><<<T / 16, 256, 0, stream>>>(x, n1g, n1b, gate_a, task, x1b,
                                                     probs1, lse1, gates1, idx1);
  bucket_kernel<EA><<<(T * KA + 511) / 512, 512, 0, stream>>>(idx1, T * KA, T * KA,
                                                              counts_a, bucket_a);
  build_maps_a<<<1, 64, 0, stream>>>(counts_a, maps, totals);
  qgemm_mfma<<<dim3(1, 152), 256, 0, stream>>>(x1b, wqt, bucket_a, counts_a, maps, totals, qb);
  kv_mfma<<<T / 16, 256, 0, stream>>>(x1b, kvwt, kvb, Kb, Vt);
  attn_mfma<<<dim3(NS / 64, KA, NB), 256, 0, stream>>>(qb, Kb, Vt, ob);
  oproj_mfma<<<dim3(4, 280), 256, 0, stream>>>(ob, woat, gates1, bucket_a, counts_a,
                                               maps + 256, totals + 1, y_slot);
  combine_kernel<<<T, 256, 0, stream>>>(x, y_slot, out);
  ln_gate_kernel<EF, KF><<<T / 16, 256, 0, stream>>>(out, n2g, n2b, gate_m, task, x1b,
                                                     probs2, lse2, gates2, idx2);
  bucket_kernel<EF><<<(T * KF + 511) / 512, 512, 0, stream>>>(idx2, T * KF, T * KF,
                                                              counts_f, bucket_f);
  build_maps_f<<<1, 64, 0, stream>>>(counts_f, maps, totals);
  mlp1_mfma<<<dim3(8, 80), 256, 0, stream>>>(x1b, wit, bi, bucket_f, counts_f,
                                             maps + 600, totals + 2, h);
  mlp2_mfma<<<dim3(4, 80), 256, 0, stream>>>(h, womt, bo, gates2, bucket_f, counts_f,
                                             maps + 600, totals + 2, y2_slot);
  final_kernel<<<T, 256, 0, stream>>>(y2_slot, out);
  reduce_gating<EA, KA><<<16, 256, 0, stream>>>(probs1, lse1, idx1, accum, accum + 24, accum + 48);
  reduce_gating<EF, KF><<<16, 256, 0, stream>>>(probs2, lse2, idx2, accum + 49, accum + 65, accum + 81);
  loss_kernel<<<1, 1, 0, stream>>>(accum, out + (size_t)T * C);
}

// Round 10
// 294.370 us; speedup vs baseline: 5.8006x; 1.2778x over previous
//
#include <hip/hip_runtime.h>
#include <math.h>

namespace {

constexpr int T   = 4096;
constexpr int C   = 512;
constexpr int NB  = 8;
constexpr int NS  = 512;
constexpr int HD  = 64;
constexpr int KA  = 8;
constexpr int EA  = 24;
constexpr int EF  = 16;
constexpr int KF  = 2;
constexpr int HID = 1024;

typedef __attribute__((ext_vector_type(8))) short bf16x8;
typedef __attribute__((ext_vector_type(4))) float f32x4;

__device__ inline unsigned short f2bf(float f) {
  unsigned u = __float_as_uint(f);
  return (unsigned short)((u + 0x7FFFu + ((u >> 16) & 1u)) >> 16);
}
__device__ inline float bf2f(unsigned short u) {
  return __uint_as_float((unsigned)u << 16);
}

// ---------------- Fused LayerNorm + Gating: 16 tokens per block ----------------
template <int E, int K>
__global__ __launch_bounds__(256) void ln_gate_kernel(
    const float* __restrict__ in, const float* __restrict__ g,
    const float* __restrict__ b, const float* __restrict__ gate_all,
    const int* __restrict__ task, unsigned short* __restrict__ outb,
    float* __restrict__ probs, float* __restrict__ lse_out,
    float* __restrict__ gates, int* __restrict__ idxs) {
  constexpr int TPB = 16;
  constexpr int XSS = 516;
  int tid = threadIdx.x, lane = tid & 63, wv = tid >> 6;
  int tb = blockIdx.x * TPB;
  __shared__ float xs[TPB][XSS];
  __shared__ float lg[TPB][E];
  __shared__ __align__(16) float Ws[C * E];
  const float* W = gate_all + (size_t)task[0] * C * E;
  for (int i = tid; i < C * E / 4; i += 256)
    *(float4*)&Ws[i * 4] = *(const float4*)&W[(size_t)i * 4];
  int c0 = lane * 8;
  const float4 g0 = *(const float4*)&g[c0], g1 = *(const float4*)&g[c0 + 4];
  const float4 b0 = *(const float4*)&b[c0], b1 = *(const float4*)&b[c0 + 4];
  #pragma unroll
  for (int i = 0; i < 4; i++) {
    int tt = wv * 4 + i;
    int t = tb + tt;
    const float* row = in + (size_t)t * C + c0;
    const float4 v0 = *(const float4*)&row[0];
    const float4 v1 = *(const float4*)&row[4];
    float s = (v0.x + v0.y) + (v0.z + v0.w) + (v1.x + v1.y) + (v1.z + v1.w);
    #pragma unroll
    for (int m = 1; m < 64; m <<= 1) s += __shfl_xor(s, m);
    float mean = s * (1.f / C);
    float d[8] = {v0.x - mean, v0.y - mean, v0.z - mean, v0.w - mean,
                  v1.x - mean, v1.y - mean, v1.z - mean, v1.w - mean};
    float vv = 0.f;
    #pragma unroll
    for (int j = 0; j < 8; j++) vv += d[j] * d[j];
    #pragma unroll
    for (int m = 1; m < 64; m <<= 1) vv += __shfl_xor(vv, m);
    float r = rsqrtf(vv * (1.f / C) + 1e-5f);
    float o[8];
    o[0] = d[0] * r * g0.x + b0.x; o[1] = d[1] * r * g0.y + b0.y;
    o[2] = d[2] * r * g0.z + b0.z; o[3] = d[3] * r * g0.w + b0.w;
    o[4] = d[4] * r * g1.x + b1.x; o[5] = d[5] * r * g1.y + b1.y;
    o[6] = d[6] * r * g1.z + b1.z; o[7] = d[7] * r * g1.w + b1.w;
    *(ushort4*)&outb[(size_t)t * C + c0] =
        make_ushort4(f2bf(o[0]), f2bf(o[1]), f2bf(o[2]), f2bf(o[3]));
    *(ushort4*)&outb[(size_t)t * C + c0 + 4] =
        make_ushort4(f2bf(o[4]), f2bf(o[5]), f2bf(o[6]), f2bf(o[7]));
    #pragma unroll
    for (int j = 0; j < 8; j++) xs[tt][c0 + j] = o[j];
  }
  __syncthreads();
  for (int p = tid; p < TPB * E; p += 256) {
    int e = p % E, tt = p / E;
    float a0 = 0.f, a1 = 0.f, a2 = 0.f, a3 = 0.f;
    #pragma unroll 8
    for (int c = 0; c < C; c += 4) {
      a0 += xs[tt][c + 0] * Ws[(c + 0) * E + e];
      a1 += xs[tt][c + 1] * Ws[(c + 1) * E + e];
      a2 += xs[tt][c + 2] * Ws[(c + 2) * E + e];
      a3 += xs[tt][c + 3] * Ws[(c + 3) * E + e];
    }
    lg[tt][e] = (a0 + a1) + (a2 + a3);
  }
  __syncthreads();
  #pragma unroll
  for (int i = 0; i < 4; i++) {
    int tt = wv * 4 + i;
    int t = tb + tt;
    float lgv = (lane < E) ? lg[tt][lane] : -3.0e38f;
    float mx = lgv;
    #pragma unroll
    for (int m = 1; m < 64; m <<= 1) mx = fmaxf(mx, __shfl_xor(mx, m));
    float pe = (lane < E) ? expf(lgv - mx) : 0.f;
    float sum = pe;
    #pragma unroll
    for (int m = 1; m < 64; m <<= 1) sum += __shfl_xor(sum, m);
    float inv = 1.f / sum;
    float prob = pe * inv;
    if (lane < E) probs[(size_t)t * E + lane] = prob;
    if (lane == 0) lse_out[t] = mx + logf(sum);
    float pv = (lane < E) ? prob : -1.f;
    float gsum = 0.f, myv = 0.f; int myi = 0;
    for (int k = 0; k < K; k++) {
      float bv = pv; int bi_ = lane;
      #pragma unroll
      for (int m = 1; m < 64; m <<= 1) {
        float ov = __shfl_xor(bv, m); int oi = __shfl_xor(bi_, m);
        if (ov > bv || (ov == bv && oi < bi_)) { bv = ov; bi_ = oi; }
      }
      gsum += bv;
      if (lane == k) { myv = bv; myi = bi_; }
      if (lane == bi_) pv = -1.f;
    }
    if (lane < K) {
      float ginv = 1.f / (gsum + 1e-6f);
      gates[(size_t)t * K + lane] = myv * ginv;
      idxs[(size_t)t * K + lane]  = myi;
    }
  }
}

// ---------------- bucket by expert: LDS-aggregated, ~E global atomics per block ----------------
template <int E>
__global__ __launch_bounds__(512) void bucket_kernel(const int* __restrict__ idx, int nslots,
                                                     int stride, int* counts, int* bucket) {
  __shared__ int lcount[E];
  __shared__ int lbase[E];
  int tid = threadIdx.x;
  if (tid < E) lcount[tid] = 0;
  __syncthreads();
  int s = blockIdx.x * 512 + tid;
  int e = 0, lpos = 0;
  bool valid = (s < nslots);
  if (valid) {
    e = idx[s];
    lpos = atomicAdd(&lcount[e], 1);
  }
  __syncthreads();
  if (tid < E) lbase[tid] = lcount[tid] ? atomicAdd(&counts[tid], lcount[tid]) : 0;
  __syncthreads();
  if (valid) bucket[(size_t)e * stride + lbase[e] + lpos] = s;
}

// ---------------- flat (expert, tile) maps ----------------
__global__ void build_maps_a(const int* __restrict__ counts, int* __restrict__ maps,
                             int* __restrict__ totals) {
  if (threadIdx.x != 0) return;
  int n = 0;
  for (int e = 0; e < EA; e++) { int c = counts[e]; for (int t0 = 0; t0 < c; t0 += 256) maps[n++] = (e << 16) | t0; }
  totals[0] = n;
  n = 0;
  for (int e = 0; e < EA; e++) { int c = counts[e]; for (int t0 = 0; t0 < c; t0 += 128) maps[256 + n++] = (e << 16) | t0; }
  totals[1] = n;
}
__global__ void build_maps_f(const int* __restrict__ counts, int* __restrict__ maps,
                             int* __restrict__ totals) {
  if (threadIdx.x != 0) return;
  int n = 0;
  for (int e = 0; e < EF; e++) { int c = counts[e]; for (int t0 = 0; t0 < c; t0 += 128) maps[600 + n++] = (e << 16) | t0; }
  totals[2] = n;
}

// ---------------- transpose + cvt weights: [E][K][N] f32 -> [E][N][K] bf16 ----------------
__global__ void tcvt_kernel(const float* __restrict__ src, unsigned short* __restrict__ dst,
                            int K, int N) {
  int e = blockIdx.z;
  int kt = blockIdx.y * 32, nt = blockIdx.x * 32;
  __shared__ float tile[32][33];
  int tid = threadIdx.x;
  const float* S = src + (size_t)e * K * N;
  for (int i = tid; i < 32 * 32; i += 256) {
    int r = i >> 5, c = i & 31;
    tile[r][c] = S[(size_t)(kt + r) * N + nt + c];
  }
  __syncthreads();
  unsigned short* D = dst + (size_t)e * K * N;
  for (int i = tid; i < 32 * 8; i += 256) {
    int n = i >> 3, k4 = (i & 7) * 4;
    ushort4 v;
    v.x = f2bf(tile[k4 + 0][n]); v.y = f2bf(tile[k4 + 1][n]);
    v.z = f2bf(tile[k4 + 2][n]); v.w = f2bf(tile[k4 + 3][n]);
    *(ushort4*)&D[(size_t)(nt + n) * K + kt + k4] = v;
  }
}

// ---------------- MFMA Q GEMM: 256 slots x 64 out, K=512 -> bf16 q (pre-scaled) ----------------
__global__ __launch_bounds__(256) void qgemm_mfma(
    const unsigned short* __restrict__ xb, const unsigned short* __restrict__ wqt,
    const int* __restrict__ bucket, const int* __restrict__ counts,
    const int* __restrict__ map, const int* __restrict__ total,
    unsigned short* __restrict__ qb) {
  if ((int)blockIdx.y >= *total) return;
  int ent = map[blockIdx.y];
  int e = ent >> 16, t0 = ent & 0xFFFF;
  int cnt = counts[e];
  int tid = threadIdx.x;
  __shared__ int slots[256];
  __shared__ __align__(16) unsigned short Xb[256][72];
  __shared__ __align__(16) unsigned short Wb[64][72];
  {
    int ii = t0 + tid;
    slots[tid] = (ii < cnt) ? bucket[(size_t)e * (T * KA) + ii] : -1;
  }
  __syncthreads();
  int lane = tid & 63, wid = tid >> 6;
  int lr = lane & 15, lk = (lane >> 4) * 8, rowq = (lane >> 4) * 4;
  f32x4 acc[4][4] = {};
  for (int kc = 0; kc < C; kc += 64) {
    __syncthreads();
    #pragma unroll
    for (int it = 0; it < 8; ++it) {
      int i = it * 256 + tid;
      int r = i >> 3, c8 = (i & 7) * 8;
      int s = slots[r];
      uint4 v = make_uint4(0u, 0u, 0u, 0u);
      if (s >= 0) v = *(const uint4*)&xb[(size_t)(s >> 3) * C + kc + c8];
      *(uint4*)&Xb[r][c8] = v;
    }
    #pragma unroll
    for (int it = 0; it < 2; ++it) {
      int i = it * 256 + tid;
      int r = i >> 3, c8 = (i & 7) * 8;
      *(uint4*)&Wb[r][c8] = *(const uint4*)&wqt[((size_t)e * HD + r) * C + kc + c8];
    }
    __syncthreads();
    #pragma unroll
    for (int kk = 0; kk < 64; kk += 32) {
      bf16x8 a[4], b[4];
      #pragma unroll
      for (int nf = 0; nf < 4; nf++) a[nf] = *(const bf16x8*)&Wb[nf * 16 + lr][kk + lk];
      #pragma unroll
      for (int mf = 0; mf < 4; mf++) b[mf] = *(const bf16x8*)&Xb[wid * 64 + mf * 16 + lr][kk + lk];
      #pragma unroll
      for (int nf = 0; nf < 4; nf++)
        #pragma unroll
        for (int mf = 0; mf < 4; mf++)
          acc[nf][mf] = __builtin_amdgcn_mfma_f32_16x16x32_bf16(a[nf], b[mf], acc[nf][mf], 0, 0, 0);
    }
  }
  #pragma unroll
  for (int mf = 0; mf < 4; mf++) {
    int s = slots[wid * 64 + mf * 16 + lr];
    if (s < 0) continue;
    #pragma unroll
    for (int nf = 0; nf < 4; nf++) {
      ushort4 v = make_ushort4(f2bf(0.125f * acc[nf][mf][0]), f2bf(0.125f * acc[nf][mf][1]),
                               f2bf(0.125f * acc[nf][mf][2]), f2bf(0.125f * acc[nf][mf][3]));
      *(ushort4*)&qb[(size_t)s * HD + nf * 16 + rowq] = v;
    }
  }
}

// ---------------- MFMA KV GEMM: 16 tokens x 128 cols per block, 256 blocks ----------------
__global__ __launch_bounds__(256) void kv_mfma(
    const unsigned short* __restrict__ xb, const unsigned short* __restrict__ kvwt,
    const float* __restrict__ kvb, unsigned short* __restrict__ Kb,
    unsigned short* __restrict__ Vt) {
  int t0 = blockIdx.x * 16;
  int tid = threadIdx.x;
  __shared__ __align__(16) unsigned short Xs[16][72];
  __shared__ __align__(16) unsigned short Ws[128][72];
  int lane = tid & 63, w = tid >> 6;
  int lr = lane & 15, lk = (lane >> 4) * 8, rowq = (lane >> 4) * 4;
  f32x4 acc[2] = {};
  for (int kc = 0; kc < C; kc += 64) {
    __syncthreads();
    if (tid < 128) {
      int r = tid >> 3, c8 = (tid & 7) * 8;
      *(uint4*)&Xs[r][c8] = *(const uint4*)&xb[(size_t)(t0 + r) * C + kc + c8];
    }
    #pragma unroll
    for (int it = 0; it < 4; ++it) {
      int i = it * 256 + tid;
      int r = i >> 3, c8 = (i & 7) * 8;
      *(uint4*)&Ws[r][c8] = *(const uint4*)&kvwt[(size_t)r * C + kc + c8];
    }
    __syncthreads();
    #pragma unroll
    for (int kk = 0; kk < 64; kk += 32) {
      bf16x8 xf = *(const bf16x8*)&Xs[lr][kk + lk];
      #pragma unroll
      for (int cf = 0; cf < 2; cf++) {
        bf16x8 wf = *(const bf16x8*)&Ws[w * 32 + cf * 16 + lr][kk + lk];
        acc[cf] = __builtin_amdgcn_mfma_f32_16x16x32_bf16(wf, xf, acc[cf], 0, 0, 0);
      }
    }
  }
  int t = t0 + lr;
  int bb = t >> 9, n = t & (NS - 1);
  #pragma unroll
  for (int cf = 0; cf < 2; cf++) {
    #pragma unroll
    for (int r2 = 0; r2 < 4; r2++) {
      int c = w * 32 + cf * 16 + rowq + r2;
      float v = acc[cf][r2] + kvb[c];
      if (c < HD) Kb[(size_t)t * HD + c] = f2bf(v);
      else        Vt[((size_t)bb * HD + (c - HD)) * NS + n] = f2bf(v);
    }
  }
}

// ---------------- MFMA flash attention: block per (qtile64, head, batch) ----------------
__global__ __launch_bounds__(256) void attn_mfma(
    const unsigned short* __restrict__ qb, const unsigned short* __restrict__ Kb,
    const unsigned short* __restrict__ Vt, unsigned short* __restrict__ ob) {
  int qt = blockIdx.x, h = blockIdx.y, b = blockIdx.z;
  int tid = threadIdx.x;
  __shared__ __align__(16) unsigned short Qs[64][72];
  __shared__ __align__(16) unsigned short Ks[64][72];
  __shared__ __align__(16) unsigned short Vs[64][72];
  __shared__ __align__(16) unsigned short Ps[64][72];
  int i0 = qt * 64;
  #pragma unroll
  for (int it = 0; it < 2; ++it) {
    int i = it * 256 + tid;
    int r = i >> 3, c8 = (i & 7) * 8;
    *(uint4*)&Qs[r][c8] = *(const uint4*)&qb[(((size_t)(b * NS + i0 + r)) * KA + h) * HD + c8];
  }
  int lane = tid & 63, w = tid >> 6;
  int lr = lane & 15, lk = (lane >> 4) * 8, rowq = (lane >> 4) * 4;
  f32x4 acc_o[4] = {};
  float m_run = -3.0e38f, l_run = 0.f;
  for (int jt = 0; jt < NS / 64; ++jt) {
    __syncthreads();
    #pragma unroll
    for (int it = 0; it < 2; ++it) {
      int i = it * 256 + tid;
      int r = i >> 3, c8 = (i & 7) * 8;
      *(uint4*)&Ks[r][c8] = *(const uint4*)&Kb[((size_t)(b * NS + jt * 64 + r)) * HD + c8];
      *(uint4*)&Vs[r][c8] = *(const uint4*)&Vt[((size_t)b * HD + r) * NS + jt * 64 + c8];
    }
    __syncthreads();
    f32x4 acc_s[4] = {};
    #pragma unroll
    for (int kk = 0; kk < 64; kk += 32) {
      bf16x8 qf = *(const bf16x8*)&Qs[w * 16 + lr][kk + lk];
      #pragma unroll
      for (int kf = 0; kf < 4; kf++) {
        bf16x8 kr = *(const bf16x8*)&Ks[kf * 16 + lr][kk + lk];
        acc_s[kf] = __builtin_amdgcn_mfma_f32_16x16x32_bf16(kr, qf, acc_s[kf], 0, 0, 0);
      }
    }
    float pmax = acc_s[0][0];
    #pragma unroll
    for (int kf = 0; kf < 4; kf++)
      #pragma unroll
      for (int r = 0; r < 4; r++) pmax = fmaxf(pmax, acc_s[kf][r]);
    pmax = fmaxf(pmax, __shfl_xor(pmax, 16));
    pmax = fmaxf(pmax, __shfl_xor(pmax, 32));
    float m_new = fmaxf(m_run, pmax);
    float scl = expf(m_run - m_new);
    float rs = 0.f;
    #pragma unroll
    for (int kf = 0; kf < 4; kf++)
      #pragma unroll
      for (int r = 0; r < 4; r++) {
        float pv = expf(acc_s[kf][r] - m_new);
        rs += pv;
        Ps[w * 16 + lr][kf * 16 + rowq + r] = f2bf(pv);
      }
    rs += __shfl_xor(rs, 16);
    rs += __shfl_xor(rs, 32);
    l_run = l_run * scl + rs;
    m_run = m_new;
    __syncthreads();
    #pragma unroll
    for (int df = 0; df < 4; df++) {
      acc_o[df][0] *= scl; acc_o[df][1] *= scl;
      acc_o[df][2] *= scl; acc_o[df][3] *= scl;
    }
    #pragma unroll
    for (int kk = 0; kk < 64; kk += 32) {
      bf16x8 pf = *(const bf16x8*)&Ps[w * 16 + lr][kk + lk];
      #pragma unroll
      for (int df = 0; df < 4; df++) {
        bf16x8 vf = *(const bf16x8*)&Vs[df * 16 + lr][kk + lk];
        acc_o[df] = __builtin_amdgcn_mfma_f32_16x16x32_bf16(vf, pf, acc_o[df], 0, 0, 0);
      }
    }
  }
  float inv = 1.f / l_run;
  int token = b * NS + i0 + w * 16 + lr;
  #pragma unroll
  for (int df = 0; df < 4; df++) {
    ushort4 v = make_ushort4(f2bf(acc_o[df][0] * inv), f2bf(acc_o[df][1] * inv),
                             f2bf(acc_o[df][2] * inv), f2bf(acc_o[df][3] * inv));
    *(ushort4*)&ob[((size_t)token * KA + h) * HD + df * 16 + rowq] = v;
  }
}

// ---------------- MFMA output proj: dense per-slot bf16 (gate folded), NO atomics ----------------
__global__ __launch_bounds__(256) void oproj_mfma(
    const unsigned short* __restrict__ ob, const unsigned short* __restrict__ wot,
    const float* __restrict__ gates, const int* __restrict__ bucket,
    const int* __restrict__ counts, const int* __restrict__ map,
    const int* __restrict__ total, unsigned short* __restrict__ y_slot) {
  if ((int)blockIdx.y >= *total) return;
  int ent = map[blockIdx.y];
  int e = ent >> 16, t0 = ent & 0xFFFF;
  int c0 = blockIdx.x * 128;
  int cnt = counts[e];
  int tid = threadIdx.x;
  __shared__ int slots[128];
  __shared__ float gs[128];
  __shared__ __align__(16) unsigned short Xb[128][72];
  __shared__ __align__(16) unsigned short Wb[128][72];
  if (tid < 128) {
    int ii = t0 + tid;
    int s = (ii < cnt) ? bucket[(size_t)e * (T * KA) + ii] : -1;
    slots[tid] = s;
    gs[tid] = (s >= 0) ? gates[s] : 0.f;
  }
  __syncthreads();
  #pragma unroll
  for (int it = 0; it < 4; ++it) {
    int i = it * 256 + tid;
    int r = i >> 3, c8 = (i & 7) * 8;
    int s = slots[r];
    uint4 vo = make_uint4(0u, 0u, 0u, 0u);
    if (s >= 0) {
      float g = gs[r];
      uint4 u = *(const uint4*)&ob[(size_t)s * HD + c8];
      const unsigned short* us = (const unsigned short*)&u;
      unsigned short* vs = (unsigned short*)&vo;
      #pragma unroll
      for (int k = 0; k < 8; k++) vs[k] = f2bf(g * bf2f(us[k]));
    }
    *(uint4*)&Xb[r][c8] = vo;
  }
  #pragma unroll
  for (int it = 0; it < 4; ++it) {
    int i = it * 256 + tid;
    int r = i >> 3, c8 = (i & 7) * 8;
    *(uint4*)&Wb[r][c8] = *(const uint4*)&wot[((size_t)e * C + c0 + r) * HD + c8];
  }
  __syncthreads();
  int lane = tid & 63, wid = tid >> 6;
  int wr = wid & 1, wc = wid >> 1;
  int lr = lane & 15, lk = (lane >> 4) * 8, rowq = (lane >> 4) * 4;
  f32x4 acc[4][4] = {};
  #pragma unroll
  for (int kk = 0; kk < 64; kk += 32) {
    bf16x8 a[4], b[4];
    #pragma unroll
    for (int nf = 0; nf < 4; nf++) a[nf] = *(const bf16x8*)&Wb[wc * 64 + nf * 16 + lr][kk + lk];
    #pragma unroll
    for (int mf = 0; mf < 4; mf++) b[mf] = *(const bf16x8*)&Xb[wr * 64 + mf * 16 + lr][kk + lk];
    #pragma unroll
    for (int nf = 0; nf < 4; nf++)
      #pragma unroll
      for (int mf = 0; mf < 4; mf++)
        acc[nf][mf] = __builtin_amdgcn_mfma_f32_16x16x32_bf16(a[nf], b[mf], acc[nf][mf], 0, 0, 0);
  }
  #pragma unroll
  for (int mf = 0; mf < 4; mf++) {
    int si = wr * 64 + mf * 16 + lr;
    int s = slots[si];
    if (s < 0) continue;
    size_t base = (size_t)s * C + c0 + wc * 64;
    #pragma unroll
    for (int nf = 0; nf < 4; nf++) {
      ushort4 v = make_ushort4(f2bf(acc[nf][mf][0]), f2bf(acc[nf][mf][1]),
                               f2bf(acc[nf][mf][2]), f2bf(acc[nf][mf][3]));
      *(ushort4*)&y_slot[base + nf * 16 + rowq] = v;
    }
  }
}

// ---------------- combine: out = x + sum_k y_slot[t*8+k] ----------------
__global__ void combine_kernel(const float* __restrict__ x, const unsigned short* __restrict__ ys,
                               float* __restrict__ out) {
  int t = blockIdx.x, tid = threadIdx.x;
  int c = tid * 2;
  float s0 = 0.f, s1 = 0.f;
  #pragma unroll
  for (int k = 0; k < KA; k++) {
    unsigned u = *(const unsigned*)&ys[((size_t)t * KA + k) * C + c];
    s0 += bf2f((unsigned short)(u & 0xFFFF));
    s1 += bf2f((unsigned short)(u >> 16));
  }
  out[(size_t)t * C + c]     = x[(size_t)t * C + c] + s0;
  out[(size_t)t * C + c + 1] = x[(size_t)t * C + c + 1] + s1;
}

// ---------------- MFMA MLP1: h = gelu(x2 @ wi + bi), bf16 out ----------------
__global__ __launch_bounds__(256) void mlp1_mfma(
    const unsigned short* __restrict__ xb, const unsigned short* __restrict__ wit,
    const float* __restrict__ bi, const int* __restrict__ bucket,
    const int* __restrict__ counts, const int* __restrict__ map,
    const int* __restrict__ total, unsigned short* __restrict__ h) {
  if ((int)blockIdx.y >= *total) return;
  int ent = map[blockIdx.y];
  int e = ent >> 16, t0 = ent & 0xFFFF;
  int j0 = blockIdx.x * 128;
  int cnt = counts[e];
  int tid = threadIdx.x;
  __shared__ int slots[128];
  __shared__ __align__(16) unsigned short Xb[128][72];
  __shared__ __align__(16) unsigned short Wb[128][72];
  if (tid < 128) {
    int ii = t0 + tid;
    slots[tid] = (ii < cnt) ? bucket[(size_t)e * (T * KF) + ii] : -1;
  }
  __syncthreads();
  int lane = tid & 63, wid = tid >> 6;
  int wr = wid & 1, wc = wid >> 1;
  int lr = lane & 15, lk = (lane >> 4) * 8, rowq = (lane >> 4) * 4;
  f32x4 acc[4][4] = {};
  for (int kc = 0; kc < C; kc += 64) {
    __syncthreads();
    #pragma unroll
    for (int it = 0; it < 4; ++it) {
      int i = it * 256 + tid;
      int r = i >> 3, c8 = (i & 7) * 8;
      int s = slots[r];
      uint4 v = make_uint4(0u, 0u, 0u, 0u);
      if (s >= 0) v = *(const uint4*)&xb[(size_t)(s >> 1) * C + kc + c8];
      *(uint4*)&Xb[r][c8] = v;
    }
    #pragma unroll
    for (int it = 0; it < 4; ++it) {
      int i = it * 256 + tid;
      int r = i >> 3, c8 = (i & 7) * 8;
      *(uint4*)&Wb[r][c8] = *(const uint4*)&wit[((size_t)e * HID + j0 + r) * C + kc + c8];
    }
    __syncthreads();
    #pragma unroll
    for (int kk = 0; kk < 64; kk += 32) {
      bf16x8 a[4], b[4];
      #pragma unroll
      for (int nf = 0; nf < 4; nf++) a[nf] = *(const bf16x8*)&Wb[wc * 64 + nf * 16 + lr][kk + lk];
      #pragma unroll
      for (int mf = 0; mf < 4; mf++) b[mf] = *(const bf16x8*)&Xb[wr * 64 + mf * 16 + lr][kk + lk];
      #pragma unroll
      for (int nf = 0; nf < 4; nf++)
        #pragma unroll
        for (int mf = 0; mf < 4; mf++)
          acc[nf][mf] = __builtin_amdgcn_mfma_f32_16x16x32_bf16(a[nf], b[mf], acc[nf][mf], 0, 0, 0);
    }
  }
  #pragma unroll
  for (int mf = 0; mf < 4; mf++) {
    int s = slots[wr * 64 + mf * 16 + lr];
    if (s < 0) continue;
    #pragma unroll
    for (int nf = 0; nf < 4; nf++) {
      int j = j0 + wc * 64 + nf * 16 + rowq;
      const float4 b4 = *(const float4*)&bi[(size_t)e * HID + j];
      float v0 = acc[nf][mf][0] + b4.x, v1 = acc[nf][mf][1] + b4.y;
      float v2 = acc[nf][mf][2] + b4.z, v3 = acc[nf][mf][3] + b4.w;
      v0 = 0.5f * v0 * (1.f + erff(v0 * 0.70710678118654752f));
      v1 = 0.5f * v1 * (1.f + erff(v1 * 0.70710678118654752f));
      v2 = 0.5f * v2 * (1.f + erff(v2 * 0.70710678118654752f));
      v3 = 0.5f * v3 * (1.f + erff(v3 * 0.70710678118654752f));
      *(ushort4*)&h[(size_t)s * HID + j] = make_ushort4(f2bf(v0), f2bf(v1), f2bf(v2), f2bf(v3));
    }
  }
}

// ---------------- MFMA MLP2: dense per-slot bf16 (gate+bias folded), NO atomics ----------------
__global__ __launch_bounds__(256) void mlp2_mfma(
    const unsigned short* __restrict__ h, const unsigned short* __restrict__ wot,
    const float* __restrict__ bo, const float* __restrict__ gates2,
    const int* __restrict__ bucket, const int* __restrict__ counts,
    const int* __restrict__ map, const int* __restrict__ total,
    unsigned short* __restrict__ y2) {
  if ((int)blockIdx.y >= *total) return;
  int ent = map[blockIdx.y];
  int e = ent >> 16, t0 = ent & 0xFFFF;
  int c0 = blockIdx.x * 128;
  int cnt = counts[e];
  int tid = threadIdx.x;
  __shared__ int slots[128];
  __shared__ __align__(16) unsigned short Xb[128][72];
  __shared__ __align__(16) unsigned short Wb[128][72];
  if (tid < 128) {
    int ii = t0 + tid;
    slots[tid] = (ii < cnt) ? bucket[(size_t)e * (T * KF) + ii] : -1;
  }
  __syncthreads();
  int lane = tid & 63, wid = tid >> 6;
  int wr = wid & 1, wc = wid >> 1;
  int lr = lane & 15, lk = (lane >> 4) * 8, rowq = (lane >> 4) * 4;
  f32x4 acc[4][4] = {};
  for (int kc = 0; kc < HID; kc += 64) {
    __syncthreads();
    #pragma unroll
    for (int it = 0; it < 4; ++it) {
      int i = it * 256 + tid;
      int r = i >> 3, c8 = (i & 7) * 8;
      int s = slots[r];
      uint4 v = make_uint4(0u, 0u, 0u, 0u);
      if (s >= 0) v = *(const uint4*)&h[(size_t)s * HID + kc + c8];
      *(uint4*)&Xb[r][c8] = v;
    }
    #pragma unroll
    for (int it = 0; it < 4; ++it) {
      int i = it * 256 + tid;
      int r = i >> 3, c8 = (i & 7) * 8;
      *(uint4*)&Wb[r][c8] = *(const uint4*)&wot[((size_t)e * C + c0 + r) * HID + kc + c8];
    }
    __syncthreads();
    #pragma unroll
    for (int kk = 0; kk < 64; kk += 32) {
      bf16x8 a[4], b[4];
      #pragma unroll
      for (int nf = 0; nf < 4; nf++) a[nf] = *(const bf16x8*)&Wb[wc * 64 + nf * 16 + lr][kk + lk];
      #pragma unroll
      for (int mf = 0; mf < 4; mf++) b[mf] = *(const bf16x8*)&Xb[wr * 64 + mf * 16 + lr][kk + lk];
      #pragma unroll
      for (int nf = 0; nf < 4; nf++)
        #pragma unroll
        for (int mf = 0; mf < 4; mf++)
          acc[nf][mf] = __builtin_amdgcn_mfma_f32_16x16x32_bf16(a[nf], b[mf], acc[nf][mf], 0, 0, 0);
    }
  }
  #pragma unroll
  for (int mf = 0; mf < 4; mf++) {
    int si = wr * 64 + mf * 16 + lr;
    int s = slots[si];
    if (s < 0) continue;
    float g = gates2[s];
    #pragma unroll
    for (int nf = 0; nf < 4; nf++) {
      int cc = c0 + wc * 64 + nf * 16 + rowq;
      const float4 b4 = *(const float4*)&bo[(size_t)e * C + cc];
      ushort4 v = make_ushort4(f2bf(g * (acc[nf][mf][0] + b4.x)),
                               f2bf(g * (acc[nf][mf][1] + b4.y)),
                               f2bf(g * (acc[nf][mf][2] + b4.z)),
                               f2bf(g * (acc[nf][mf][3] + b4.w)));
      *(ushort4*)&y2[(size_t)s * C + cc] = v;
    }
  }
}

// ---------------- Final residual add (bf16 slots) ----------------
__global__ void final_kernel(const unsigned short* __restrict__ y2, float* __restrict__ xout) {
  int t = blockIdx.x, tid = threadIdx.x;
  int c = tid * 2;
  unsigned u0 = *(const unsigned*)&y2[(size_t)(t * 2) * C + c];
  unsigned u1 = *(const unsigned*)&y2[(size_t)(t * 2 + 1) * C + c];
  xout[(size_t)t * C + c]     += bf2f((unsigned short)(u0 & 0xFFFF)) + bf2f((unsigned short)(u1 & 0xFFFF));
  xout[(size_t)t * C + c + 1] += bf2f((unsigned short)(u0 >> 16)) + bf2f((unsigned short)(u1 >> 16));
}

// ---------------- Gating statistics reduction: lane==expert, NO per-element atomics ----------------
// Each wave owns TPW tokens: probs accumulated in register (lane<E), freq via compare,
// z via lane-strided square-sum. Cross-wave combine in LDS; one global atomic per (block,expert).
template <int E, int K, int TPB>
__global__ __launch_bounds__(256) void reduce_gating(
    const float* __restrict__ probs, const float* __restrict__ lse,
    const int* __restrict__ idxs, float* __restrict__ psum,
    float* __restrict__ freq, float* __restrict__ zsum) {
  constexpr int TPW = TPB / 4;
  int tid = threadIdx.x, lane = tid & 63, wv = tid >> 6;
  int t0 = blockIdx.x * TPB + wv * TPW;
  float ps = 0.f, fr = 0.f;
  if (lane < E) {
    for (int i = 0; i < TPW; i++) {
      int t = t0 + i;
      ps += probs[(size_t)t * E + lane];
      #pragma unroll
      for (int k = 0; k < K; k++)
        fr += (idxs[(size_t)t * K + k] == lane) ? 1.f : 0.f;
    }
  }
  float z = 0.f;
  for (int i = lane; i < TPW; i += 64) {
    float l = lse[t0 + i];
    z += l * l;
  }
  #pragma unroll
  for (int m = 1; m < 64; m <<= 1) z += __shfl_xor(z, m);
  __shared__ float sps[4][E];
  __shared__ float sfr[4][E];
  __shared__ float sz[4];
  if (lane < E) { sps[wv][lane] = ps; sfr[wv][lane] = fr; }
  if (lane == 0) sz[wv] = z;
  __syncthreads();
  if (tid < E) {
    atomicAdd(&psum[tid], sps[0][tid] + sps[1][tid] + sps[2][tid] + sps[3][tid]);
    atomicAdd(&freq[tid], sfr[0][tid] + sfr[1][tid] + sfr[2][tid] + sfr[3][tid]);
  }
  if (tid == 255) atomicAdd(zsum, sz[0] + sz[1] + sz[2] + sz[3]);
}

__global__ void loss_kernel(const float* __restrict__ acc, float* __restrict__ out) {
  const float* p1 = acc;      const float* f1 = acc + 24; float z1 = acc[48];
  const float* p2 = acc + 49; const float* f2 = acc + 65; float z2 = acc[81];
  float sp1 = 0.f, sf1 = 0.f;
  for (int e = 0; e < 24; e++) { sp1 += p1[e]; sf1 += f1[e]; }
  float sw1 = 0.f;
  for (int e = 0; e < 24; e++) sw1 += (p1[e] / sp1) * (f1[e] / sf1);
  sw1 *= 24.f;
  float sp2 = 0.f, sf2 = 0.f;
  for (int e = 0; e < 16; e++) { sp2 += p2[e]; sf2 += f2[e]; }
  float sw2 = 0.f;
  for (int e = 0; e < 16; e++) sw2 += (p2[e] / sp2) * (f2[e] / sf2);
  sw2 *= 16.f;
  out[0] = 0.01f * sw1 + 0.001f * (z1 / T) + 0.01f * sw2 + 0.001f * (z2 / T);
}

}  // namespace

extern "C" void kernel_launch(void* const* d_in, const int* in_sizes, int n_in,
                              void* d_out, int out_size, void* d_ws, size_t ws_size,
                              hipStream_t stream) {
  const float* x      = (const float*)d_in[0];
  const int*   task   = (const int*)d_in[1];
  const float* n1g    = (const float*)d_in[2];
  const float* n1b    = (const float*)d_in[3];
  const float* gate_a = (const float*)d_in[4];
  const float* wq     = (const float*)d_in[5];
  const float* wo_a   = (const float*)d_in[6];
  const float* kvw    = (const float*)d_in[7];
  const float* kvb    = (const float*)d_in[8];
  const float* n2g    = (const float*)d_in[9];
  const float* n2b    = (const float*)d_in[10];
  const float* gate_m = (const float*)d_in[11];
  const float* wi     = (const float*)d_in[12];
  const float* bi     = (const float*)d_in[13];
  const float* wo_m   = (const float*)d_in[14];
  const float* bo     = (const float*)d_in[15];
  float* out = (float*)d_out;

  char* p = (char*)d_ws;
  unsigned short* x1b = (unsigned short*)p; p += (size_t)T * C * 2;
  unsigned short* qb = (unsigned short*)p;  p += (size_t)T * KA * HD * 2;
  unsigned short* ob = (unsigned short*)p;  p += (size_t)T * KA * HD * 2;
  unsigned short* Kb = (unsigned short*)p;  p += (size_t)T * HD * 2;
  unsigned short* Vt = (unsigned short*)p;  p += (size_t)T * HD * 2;
  // union region: y_slot (33.5MB) then reused as h (16.8MB) + y2_slot (8.4MB)
  char* un = p;                      p += (size_t)T * KA * C * 2;
  unsigned short* y_slot  = (unsigned short*)un;
  unsigned short* h       = (unsigned short*)un;
  unsigned short* y2_slot = (unsigned short*)(un + (size_t)T * KF * HID * 2);
  unsigned short* wqt = (unsigned short*)p;  p += (size_t)EA * C * HD * 2;
  unsigned short* woat = (unsigned short*)p; p += (size_t)EA * HD * C * 2;
  unsigned short* wit = (unsigned short*)p;  p += (size_t)EF * C * HID * 2;
  unsigned short* womt = (unsigned short*)p; p += (size_t)EF * HID * C * 2;
  unsigned short* kvwt = (unsigned short*)p; p += (size_t)(2 * HD) * C * 2;
  float* probs1 = (float*)p;         p += (size_t)T * EA * 4;
  float* lse1 = (float*)p;           p += (size_t)T * 4;
  float* gates1 = (float*)p;         p += (size_t)T * KA * 4;
  int* idx1 = (int*)p;               p += (size_t)T * KA * 4;
  float* probs2 = (float*)p;         p += (size_t)T * EF * 4;
  float* lse2 = (float*)p;           p += (size_t)T * 4;
  float* gates2 = (float*)p;         p += (size_t)T * KF * 4;
  int* idx2 = (int*)p;               p += (size_t)T * KF * 4;
  int* bucket_a = (int*)p;           p += (size_t)EA * (T * KA) * 4;
  int* bucket_f = (int*)p;           p += (size_t)EF * (T * KF) * 4;
  int* counts_a = (int*)p;           p += 32 * 4;
  int* counts_f = (int*)p;           p += 32 * 4;
  float* accum = (float*)p;          p += 128 * 4;
  int* maps = (int*)p;               p += 768 * 4;
  int* totals = (int*)p;             p += 4 * 4;

  hipMemsetAsync(counts_a, 0, (32 + 32 + 128) * 4, stream);

  tcvt_kernel<<<dim3(2, 16, 24), 256, 0, stream>>>(wq, wqt, C, HD);
  tcvt_kernel<<<dim3(16, 2, 24), 256, 0, stream>>>(wo_a, woat, HD, C);
  tcvt_kernel<<<dim3(32, 16, 16), 256, 0, stream>>>(wi, wit, C, HID);
  tcvt_kernel<<<dim3(16, 32, 16), 256, 0, stream>>>(wo_m, womt, HID, C);
  tcvt_kernel<<<dim3(4, 16, 1), 256, 0, stream>>>(kvw, kvwt, C, 2 * HD);

  ln_gate_kernel<EA, KA><<<T / 16, 256, 0, stream>>>(x, n1g, n1b, gate_a, task, x1b,
                                                     probs1, lse1, gates1, idx1);
  bucket_kernel<EA><<<(T * KA + 511) / 512, 512, 0, stream>>>(idx1, T * KA, T * KA,
                                                              counts_a, bucket_a);
  build_maps_a<<<1, 64, 0, stream>>>(counts_a, maps, totals);
  qgemm_mfma<<<dim3(1, 152), 256, 0, stream>>>(x1b, wqt, bucket_a, counts_a, maps, totals, qb);
  kv_mfma<<<T / 16, 256, 0, stream>>>(x1b, kvwt, kvb, Kb, Vt);
  attn_mfma<<<dim3(NS / 64, KA, NB), 256, 0, stream>>>(qb, Kb, Vt, ob);
  oproj_mfma<<<dim3(4, 280), 256, 0, stream>>>(ob, woat, gates1, bucket_a, counts_a,
                                               maps + 256, totals + 1, y_slot);
  combine_kernel<<<T, 256, 0, stream>>>(x, y_slot, out);
  ln_gate_kernel<EF, KF><<<T / 16, 256, 0, stream>>>(out, n2g, n2b, gate_m, task, x1b,
                                                     probs2, lse2, gates2, idx2);
  bucket_kernel<EF><<<(T * KF + 511) / 512, 512, 0, stream>>>(idx2, T * KF, T * KF,
                                                              counts_f, bucket_f);
  build_maps_f<<<1, 64, 0, stream>>>(counts_f, maps, totals);
  mlp1_mfma<<<dim3(8, 80), 256, 0, stream>>>(x1b, wit, bi, bucket_f, counts_f,
                                             maps + 600, totals + 2, h);
  mlp2_mfma<<<dim3(4, 80), 256, 0, stream>>>(h, womt, bo, gates2, bucket_f, counts_f,
                                             maps + 600, totals + 2, y2_slot);
  final_kernel<<<T, 256, 0, stream>>>(y2_slot, out);
  reduce_gating<EA, KA, 64><<<T / 64, 256, 0, stream>>>(probs1, lse1, idx1, accum,
                                                        accum + 24, accum + 48);
  reduce_gating<EF, KF, 64><<<T / 64, 256, 0, stream>>>(probs2, lse2, idx2, accum + 49,
                                                        accum + 65, accum + 81);
  loss_kernel<<<1, 1, 0, stream>>>(accum, out + (size_t)T * C);
}

// Round 11
// 290.351 us; speedup vs baseline: 5.8809x; 1.0138x over previous
//
#include <hip/hip_runtime.h>
#include <math.h>

namespace {

constexpr int T   = 4096;
constexpr int C   = 512;
constexpr int NB  = 8;
constexpr int NS  = 512;
constexpr int HD  = 64;
constexpr int KA  = 8;
constexpr int EA  = 24;
constexpr int EF  = 16;
constexpr int KF  = 2;
constexpr int HID = 1024;

typedef __attribute__((ext_vector_type(8))) short bf16x8;
typedef __attribute__((ext_vector_type(4))) float f32x4;

__device__ inline unsigned short f2bf(float f) {
  unsigned u = __float_as_uint(f);
  return (unsigned short)((u + 0x7FFFu + ((u >> 16) & 1u)) >> 16);
}
__device__ inline float bf2f(unsigned short u) {
  return __uint_as_float((unsigned)u << 16);
}

// ---------------- Fused LayerNorm + Gating: 16 tokens per block ----------------
template <int E, int K>
__global__ __launch_bounds__(256) void ln_gate_kernel(
    const float* __restrict__ in, const float* __restrict__ g,
    const float* __restrict__ b, const float* __restrict__ gate_all,
    const int* __restrict__ task, unsigned short* __restrict__ outb,
    float* __restrict__ probs, float* __restrict__ lse_out,
    float* __restrict__ gates, int* __restrict__ idxs) {
  constexpr int TPB = 16;
  constexpr int XSS = 516;
  int tid = threadIdx.x, lane = tid & 63, wv = tid >> 6;
  int tb = blockIdx.x * TPB;
  __shared__ float xs[TPB][XSS];
  __shared__ float lg[TPB][E];
  __shared__ __align__(16) float Ws[C * E];
  const float* W = gate_all + (size_t)task[0] * C * E;
  for (int i = tid; i < C * E / 4; i += 256)
    *(float4*)&Ws[i * 4] = *(const float4*)&W[(size_t)i * 4];
  int c0 = lane * 8;
  const float4 g0 = *(const float4*)&g[c0], g1 = *(const float4*)&g[c0 + 4];
  const float4 b0 = *(const float4*)&b[c0], b1 = *(const float4*)&b[c0 + 4];
  #pragma unroll
  for (int i = 0; i < 4; i++) {
    int tt = wv * 4 + i;
    int t = tb + tt;
    const float* row = in + (size_t)t * C + c0;
    const float4 v0 = *(const float4*)&row[0];
    const float4 v1 = *(const float4*)&row[4];
    float s = (v0.x + v0.y) + (v0.z + v0.w) + (v1.x + v1.y) + (v1.z + v1.w);
    #pragma unroll
    for (int m = 1; m < 64; m <<= 1) s += __shfl_xor(s, m);
    float mean = s * (1.f / C);
    float d[8] = {v0.x - mean, v0.y - mean, v0.z - mean, v0.w - mean,
                  v1.x - mean, v1.y - mean, v1.z - mean, v1.w - mean};
    float vv = 0.f;
    #pragma unroll
    for (int j = 0; j < 8; j++) vv += d[j] * d[j];
    #pragma unroll
    for (int m = 1; m < 64; m <<= 1) vv += __shfl_xor(vv, m);
    float r = rsqrtf(vv * (1.f / C) + 1e-5f);
    float o[8];
    o[0] = d[0] * r * g0.x + b0.x; o[1] = d[1] * r * g0.y + b0.y;
    o[2] = d[2] * r * g0.z + b0.z; o[3] = d[3] * r * g0.w + b0.w;
    o[4] = d[4] * r * g1.x + b1.x; o[5] = d[5] * r * g1.y + b1.y;
    o[6] = d[6] * r * g1.z + b1.z; o[7] = d[7] * r * g1.w + b1.w;
    *(ushort4*)&outb[(size_t)t * C + c0] =
        make_ushort4(f2bf(o[0]), f2bf(o[1]), f2bf(o[2]), f2bf(o[3]));
    *(ushort4*)&outb[(size_t)t * C + c0 + 4] =
        make_ushort4(f2bf(o[4]), f2bf(o[5]), f2bf(o[6]), f2bf(o[7]));
    #pragma unroll
    for (int j = 0; j < 8; j++) xs[tt][c0 + j] = o[j];
  }
  __syncthreads();
  for (int p = tid; p < TPB * E; p += 256) {
    int e = p % E, tt = p / E;
    float a0 = 0.f, a1 = 0.f, a2 = 0.f, a3 = 0.f;
    #pragma unroll 8
    for (int c = 0; c < C; c += 4) {
      a0 += xs[tt][c + 0] * Ws[(c + 0) * E + e];
      a1 += xs[tt][c + 1] * Ws[(c + 1) * E + e];
      a2 += xs[tt][c + 2] * Ws[(c + 2) * E + e];
      a3 += xs[tt][c + 3] * Ws[(c + 3) * E + e];
    }
    lg[tt][e] = (a0 + a1) + (a2 + a3);
  }
  __syncthreads();
  #pragma unroll
  for (int i = 0; i < 4; i++) {
    int tt = wv * 4 + i;
    int t = tb + tt;
    float lgv = (lane < E) ? lg[tt][lane] : -3.0e38f;
    float mx = lgv;
    #pragma unroll
    for (int m = 1; m < 64; m <<= 1) mx = fmaxf(mx, __shfl_xor(mx, m));
    float pe = (lane < E) ? expf(lgv - mx) : 0.f;
    float sum = pe;
    #pragma unroll
    for (int m = 1; m < 64; m <<= 1) sum += __shfl_xor(sum, m);
    float inv = 1.f / sum;
    float prob = pe * inv;
    if (lane < E) probs[(size_t)t * E + lane] = prob;
    if (lane == 0) lse_out[t] = mx + logf(sum);
    float pv = (lane < E) ? prob : -1.f;
    float gsum = 0.f, myv = 0.f; int myi = 0;
    for (int k = 0; k < K; k++) {
      float bv = pv; int bi_ = lane;
      #pragma unroll
      for (int m = 1; m < 64; m <<= 1) {
        float ov = __shfl_xor(bv, m); int oi = __shfl_xor(bi_, m);
        if (ov > bv || (ov == bv && oi < bi_)) { bv = ov; bi_ = oi; }
      }
      gsum += bv;
      if (lane == k) { myv = bv; myi = bi_; }
      if (lane == bi_) pv = -1.f;
    }
    if (lane < K) {
      float ginv = 1.f / (gsum + 1e-6f);
      gates[(size_t)t * K + lane] = myv * ginv;
      idxs[(size_t)t * K + lane]  = myi;
    }
  }
}

// ---------------- bucket by expert ----------------
template <int E>
__global__ __launch_bounds__(512) void bucket_kernel(const int* __restrict__ idx, int nslots,
                                                     int stride, int* counts, int* bucket) {
  __shared__ int lcount[E];
  __shared__ int lbase[E];
  int tid = threadIdx.x;
  if (tid < E) lcount[tid] = 0;
  __syncthreads();
  int s = blockIdx.x * 512 + tid;
  int e = 0, lpos = 0;
  bool valid = (s < nslots);
  if (valid) {
    e = idx[s];
    lpos = atomicAdd(&lcount[e], 1);
  }
  __syncthreads();
  if (tid < E) lbase[tid] = lcount[tid] ? atomicAdd(&counts[tid], lcount[tid]) : 0;
  __syncthreads();
  if (valid) bucket[(size_t)e * stride + lbase[e] + lpos] = s;
}

// ---------------- flat (expert, tile) maps ----------------
__global__ void build_maps_a(const int* __restrict__ counts, int* __restrict__ maps,
                             int* __restrict__ totals) {
  if (threadIdx.x != 0) return;
  int n = 0;
  for (int e = 0; e < EA; e++) { int c = counts[e]; for (int t0 = 0; t0 < c; t0 += 256) maps[n++] = (e << 16) | t0; }
  totals[0] = n;
  n = 0;
  for (int e = 0; e < EA; e++) { int c = counts[e]; for (int t0 = 0; t0 < c; t0 += 128) maps[256 + n++] = (e << 16) | t0; }
  totals[1] = n;
}
__global__ void build_maps_f(const int* __restrict__ counts, int* __restrict__ maps,
                             int* __restrict__ totals) {
  if (threadIdx.x != 0) return;
  int n = 0;
  for (int e = 0; e < EF; e++) { int c = counts[e]; for (int t0 = 0; t0 < c; t0 += 64) maps[768 + n++] = (e << 16) | t0; }
  totals[3] = n;
}

// ---------------- merged transpose+cvt: all 5 weight tensors in one dispatch ----------------
// [E][K][N] f32 -> [E][N][K] bf16, 32x32 tiles, flat block id -> segment decode.
__global__ __launch_bounds__(256) void tcvt_all(
    const float* __restrict__ wq, const float* __restrict__ wo_a,
    const float* __restrict__ wi, const float* __restrict__ wo_m,
    const float* __restrict__ kvw,
    unsigned short* __restrict__ wqt, unsigned short* __restrict__ woat,
    unsigned short* __restrict__ wit, unsigned short* __restrict__ womt,
    unsigned short* __restrict__ kvwt) {
  int bid = blockIdx.x;
  const float* src; unsigned short* dst; int K, N, nx, rem;
  if (bid < 768)        { src = wq;   dst = wqt;  K = 512;  N = 64;   nx = 2;  rem = bid; }
  else if (bid < 1536)  { src = wo_a; dst = woat; K = 64;   N = 512;  nx = 16; rem = bid - 768; }
  else if (bid < 9728)  { src = wi;   dst = wit;  K = 512;  N = 1024; nx = 32; rem = bid - 1536; }
  else if (bid < 17920) { src = wo_m; dst = womt; K = 1024; N = 512;  nx = 16; rem = bid - 9728; }
  else                  { src = kvw;  dst = kvwt; K = 512;  N = 128;  nx = 4;  rem = bid - 17920; }
  int per = nx * (K / 32);
  int e = rem / per, r2 = rem % per;
  int kt = (r2 / nx) * 32, nt = (r2 % nx) * 32;
  __shared__ float tile[32][33];
  int tid = threadIdx.x;
  const float* S = src + (size_t)e * K * N;
  for (int i = tid; i < 32 * 32; i += 256) {
    int r = i >> 5, c = i & 31;
    tile[r][c] = S[(size_t)(kt + r) * N + nt + c];
  }
  __syncthreads();
  unsigned short* D = dst + (size_t)e * K * N;
  for (int i = tid; i < 32 * 8; i += 256) {
    int n = i >> 3, k4 = (i & 7) * 4;
    ushort4 v;
    v.x = f2bf(tile[k4 + 0][n]); v.y = f2bf(tile[k4 + 1][n]);
    v.z = f2bf(tile[k4 + 2][n]); v.w = f2bf(tile[k4 + 3][n]);
    *(ushort4*)&D[(size_t)(nt + n) * K + kt + k4] = v;
  }
}

// ---------------- MFMA Q GEMM: 256 slots x 64 out, K=512 -> bf16 q (pre-scaled) ----------------
__global__ __launch_bounds__(256) void qgemm_mfma(
    const unsigned short* __restrict__ xb, const unsigned short* __restrict__ wqt,
    const int* __restrict__ bucket, const int* __restrict__ counts,
    const int* __restrict__ map, const int* __restrict__ total,
    unsigned short* __restrict__ qb) {
  if ((int)blockIdx.y >= *total) return;
  int ent = map[blockIdx.y];
  int e = ent >> 16, t0 = ent & 0xFFFF;
  int cnt = counts[e];
  int tid = threadIdx.x;
  __shared__ int slots[256];
  __shared__ __align__(16) unsigned short Xb[256][72];
  __shared__ __align__(16) unsigned short Wb[64][72];
  {
    int ii = t0 + tid;
    slots[tid] = (ii < cnt) ? bucket[(size_t)e * (T * KA) + ii] : -1;
  }
  __syncthreads();
  int lane = tid & 63, wid = tid >> 6;
  int lr = lane & 15, lk = (lane >> 4) * 8, rowq = (lane >> 4) * 4;
  f32x4 acc[4][4] = {};
  for (int kc = 0; kc < C; kc += 64) {
    __syncthreads();
    #pragma unroll
    for (int it = 0; it < 8; ++it) {
      int i = it * 256 + tid;
      int r = i >> 3, c8 = (i & 7) * 8;
      int s = slots[r];
      uint4 v = make_uint4(0u, 0u, 0u, 0u);
      if (s >= 0) v = *(const uint4*)&xb[(size_t)(s >> 3) * C + kc + c8];
      *(uint4*)&Xb[r][c8] = v;
    }
    #pragma unroll
    for (int it = 0; it < 2; ++it) {
      int i = it * 256 + tid;
      int r = i >> 3, c8 = (i & 7) * 8;
      *(uint4*)&Wb[r][c8] = *(const uint4*)&wqt[((size_t)e * HD + r) * C + kc + c8];
    }
    __syncthreads();
    #pragma unroll
    for (int kk = 0; kk < 64; kk += 32) {
      bf16x8 a[4], b[4];
      #pragma unroll
      for (int nf = 0; nf < 4; nf++) a[nf] = *(const bf16x8*)&Wb[nf * 16 + lr][kk + lk];
      #pragma unroll
      for (int mf = 0; mf < 4; mf++) b[mf] = *(const bf16x8*)&Xb[wid * 64 + mf * 16 + lr][kk + lk];
      #pragma unroll
      for (int nf = 0; nf < 4; nf++)
        #pragma unroll
        for (int mf = 0; mf < 4; mf++)
          acc[nf][mf] = __builtin_amdgcn_mfma_f32_16x16x32_bf16(a[nf], b[mf], acc[nf][mf], 0, 0, 0);
    }
  }
  #pragma unroll
  for (int mf = 0; mf < 4; mf++) {
    int s = slots[wid * 64 + mf * 16 + lr];
    if (s < 0) continue;
    #pragma unroll
    for (int nf = 0; nf < 4; nf++) {
      ushort4 v = make_ushort4(f2bf(0.125f * acc[nf][mf][0]), f2bf(0.125f * acc[nf][mf][1]),
                               f2bf(0.125f * acc[nf][mf][2]), f2bf(0.125f * acc[nf][mf][3]));
      *(ushort4*)&qb[(size_t)s * HD + nf * 16 + rowq] = v;
    }
  }
}

// ---------------- MFMA KV GEMM ----------------
__global__ __launch_bounds__(256) void kv_mfma(
    const unsigned short* __restrict__ xb, const unsigned short* __restrict__ kvwt,
    const float* __restrict__ kvb, unsigned short* __restrict__ Kb,
    unsigned short* __restrict__ Vt) {
  int t0 = blockIdx.x * 16;
  int tid = threadIdx.x;
  __shared__ __align__(16) unsigned short Xs[16][72];
  __shared__ __align__(16) unsigned short Ws[128][72];
  int lane = tid & 63, w = tid >> 6;
  int lr = lane & 15, lk = (lane >> 4) * 8, rowq = (lane >> 4) * 4;
  f32x4 acc[2] = {};
  for (int kc = 0; kc < C; kc += 64) {
    __syncthreads();
    if (tid < 128) {
      int r = tid >> 3, c8 = (tid & 7) * 8;
      *(uint4*)&Xs[r][c8] = *(const uint4*)&xb[(size_t)(t0 + r) * C + kc + c8];
    }
    #pragma unroll
    for (int it = 0; it < 4; ++it) {
      int i = it * 256 + tid;
      int r = i >> 3, c8 = (i & 7) * 8;
      *(uint4*)&Ws[r][c8] = *(const uint4*)&kvwt[(size_t)r * C + kc + c8];
    }
    __syncthreads();
    #pragma unroll
    for (int kk = 0; kk < 64; kk += 32) {
      bf16x8 xf = *(const bf16x8*)&Xs[lr][kk + lk];
      #pragma unroll
      for (int cf = 0; cf < 2; cf++) {
        bf16x8 wf = *(const bf16x8*)&Ws[w * 32 + cf * 16 + lr][kk + lk];
        acc[cf] = __builtin_amdgcn_mfma_f32_16x16x32_bf16(wf, xf, acc[cf], 0, 0, 0);
      }
    }
  }
  int t = t0 + lr;
  int bb = t >> 9, n = t & (NS - 1);
  #pragma unroll
  for (int cf = 0; cf < 2; cf++) {
    #pragma unroll
    for (int r2 = 0; r2 < 4; r2++) {
      int c = w * 32 + cf * 16 + rowq + r2;
      float v = acc[cf][r2] + kvb[c];
      if (c < HD) Kb[(size_t)t * HD + c] = f2bf(v);
      else        Vt[((size_t)bb * HD + (c - HD)) * NS + n] = f2bf(v);
    }
  }
}

// ---------------- MFMA flash attention ----------------
__global__ __launch_bounds__(256) void attn_mfma(
    const unsigned short* __restrict__ qb, const unsigned short* __restrict__ Kb,
    const unsigned short* __restrict__ Vt, unsigned short* __restrict__ ob) {
  int qt = blockIdx.x, h = blockIdx.y, b = blockIdx.z;
  int tid = threadIdx.x;
  __shared__ __align__(16) unsigned short Qs[64][72];
  __shared__ __align__(16) unsigned short Ks[64][72];
  __shared__ __align__(16) unsigned short Vs[64][72];
  __shared__ __align__(16) unsigned short Ps[64][72];
  int i0 = qt * 64;
  #pragma unroll
  for (int it = 0; it < 2; ++it) {
    int i = it * 256 + tid;
    int r = i >> 3, c8 = (i & 7) * 8;
    *(uint4*)&Qs[r][c8] = *(const uint4*)&qb[(((size_t)(b * NS + i0 + r)) * KA + h) * HD + c8];
  }
  int lane = tid & 63, w = tid >> 6;
  int lr = lane & 15, lk = (lane >> 4) * 8, rowq = (lane >> 4) * 4;
  f32x4 acc_o[4] = {};
  float m_run = -3.0e38f, l_run = 0.f;
  for (int jt = 0; jt < NS / 64; ++jt) {
    __syncthreads();
    #pragma unroll
    for (int it = 0; it < 2; ++it) {
      int i = it * 256 + tid;
      int r = i >> 3, c8 = (i & 7) * 8;
      *(uint4*)&Ks[r][c8] = *(const uint4*)&Kb[((size_t)(b * NS + jt * 64 + r)) * HD + c8];
      *(uint4*)&Vs[r][c8] = *(const uint4*)&Vt[((size_t)b * HD + r) * NS + jt * 64 + c8];
    }
    __syncthreads();
    f32x4 acc_s[4] = {};
    #pragma unroll
    for (int kk = 0; kk < 64; kk += 32) {
      bf16x8 qf = *(const bf16x8*)&Qs[w * 16 + lr][kk + lk];
      #pragma unroll
      for (int kf = 0; kf < 4; kf++) {
        bf16x8 kr = *(const bf16x8*)&Ks[kf * 16 + lr][kk + lk];
        acc_s[kf] = __builtin_amdgcn_mfma_f32_16x16x32_bf16(kr, qf, acc_s[kf], 0, 0, 0);
      }
    }
    float pmax = acc_s[0][0];
    #pragma unroll
    for (int kf = 0; kf < 4; kf++)
      #pragma unroll
      for (int r = 0; r < 4; r++) pmax = fmaxf(pmax, acc_s[kf][r]);
    pmax = fmaxf(pmax, __shfl_xor(pmax, 16));
    pmax = fmaxf(pmax, __shfl_xor(pmax, 32));
    float m_new = fmaxf(m_run, pmax);
    float scl = expf(m_run - m_new);
    float rs = 0.f;
    #pragma unroll
    for (int kf = 0; kf < 4; kf++)
      #pragma unroll
      for (int r = 0; r < 4; r++) {
        float pv = expf(acc_s[kf][r] - m_new);
        rs += pv;
        Ps[w * 16 + lr][kf * 16 + rowq + r] = f2bf(pv);
      }
    rs += __shfl_xor(rs, 16);
    rs += __shfl_xor(rs, 32);
    l_run = l_run * scl + rs;
    m_run = m_new;
    __syncthreads();
    #pragma unroll
    for (int df = 0; df < 4; df++) {
      acc_o[df][0] *= scl; acc_o[df][1] *= scl;
      acc_o[df][2] *= scl; acc_o[df][3] *= scl;
    }
    #pragma unroll
    for (int kk = 0; kk < 64; kk += 32) {
      bf16x8 pf = *(const bf16x8*)&Ps[w * 16 + lr][kk + lk];
      #pragma unroll
      for (int df = 0; df < 4; df++) {
        bf16x8 vf = *(const bf16x8*)&Vs[df * 16 + lr][kk + lk];
        acc_o[df] = __builtin_amdgcn_mfma_f32_16x16x32_bf16(vf, pf, acc_o[df], 0, 0, 0);
      }
    }
  }
  float inv = 1.f / l_run;
  int token = b * NS + i0 + w * 16 + lr;
  #pragma unroll
  for (int df = 0; df < 4; df++) {
    ushort4 v = make_ushort4(f2bf(acc_o[df][0] * inv), f2bf(acc_o[df][1] * inv),
                             f2bf(acc_o[df][2] * inv), f2bf(acc_o[df][3] * inv));
    *(ushort4*)&ob[((size_t)token * KA + h) * HD + df * 16 + rowq] = v;
  }
}

// ---------------- MFMA output proj: dense per-slot bf16 (gate folded), NO atomics ----------------
__global__ __launch_bounds__(256) void oproj_mfma(
    const unsigned short* __restrict__ ob, const unsigned short* __restrict__ wot,
    const float* __restrict__ gates, const int* __restrict__ bucket,
    const int* __restrict__ counts, const int* __restrict__ map,
    const int* __restrict__ total, unsigned short* __restrict__ y_slot) {
  if ((int)blockIdx.y >= *total) return;
  int ent = map[blockIdx.y];
  int e = ent >> 16, t0 = ent & 0xFFFF;
  int c0 = blockIdx.x * 128;
  int cnt = counts[e];
  int tid = threadIdx.x;
  __shared__ int slots[128];
  __shared__ float gs[128];
  __shared__ __align__(16) unsigned short Xb[128][72];
  __shared__ __align__(16) unsigned short Wb[128][72];
  if (tid < 128) {
    int ii = t0 + tid;
    int s = (ii < cnt) ? bucket[(size_t)e * (T * KA) + ii] : -1;
    slots[tid] = s;
    gs[tid] = (s >= 0) ? gates[s] : 0.f;
  }
  __syncthreads();
  #pragma unroll
  for (int it = 0; it < 4; ++it) {
    int i = it * 256 + tid;
    int r = i >> 3, c8 = (i & 7) * 8;
    int s = slots[r];
    uint4 vo = make_uint4(0u, 0u, 0u, 0u);
    if (s >= 0) {
      float g = gs[r];
      uint4 u = *(const uint4*)&ob[(size_t)s * HD + c8];
      const unsigned short* us = (const unsigned short*)&u;
      unsigned short* vs = (unsigned short*)&vo;
      #pragma unroll
      for (int k = 0; k < 8; k++) vs[k] = f2bf(g * bf2f(us[k]));
    }
    *(uint4*)&Xb[r][c8] = vo;
  }
  #pragma unroll
  for (int it = 0; it < 4; ++it) {
    int i = it * 256 + tid;
    int r = i >> 3, c8 = (i & 7) * 8;
    *(uint4*)&Wb[r][c8] = *(const uint4*)&wot[((size_t)e * C + c0 + r) * HD + c8];
  }
  __syncthreads();
  int lane = tid & 63, wid = tid >> 6;
  int wr = wid & 1, wc = wid >> 1;
  int lr = lane & 15, lk = (lane >> 4) * 8, rowq = (lane >> 4) * 4;
  f32x4 acc[4][4] = {};
  #pragma unroll
  for (int kk = 0; kk < 64; kk += 32) {
    bf16x8 a[4], b[4];
    #pragma unroll
    for (int nf = 0; nf < 4; nf++) a[nf] = *(const bf16x8*)&Wb[wc * 64 + nf * 16 + lr][kk + lk];
    #pragma unroll
    for (int mf = 0; mf < 4; mf++) b[mf] = *(const bf16x8*)&Xb[wr * 64 + mf * 16 + lr][kk + lk];
    #pragma unroll
    for (int nf = 0; nf < 4; nf++)
      #pragma unroll
      for (int mf = 0; mf < 4; mf++)
        acc[nf][mf] = __builtin_amdgcn_mfma_f32_16x16x32_bf16(a[nf], b[mf], acc[nf][mf], 0, 0, 0);
  }
  #pragma unroll
  for (int mf = 0; mf < 4; mf++) {
    int si = wr * 64 + mf * 16 + lr;
    int s = slots[si];
    if (s < 0) continue;
    size_t base = (size_t)s * C + c0 + wc * 64;
    #pragma unroll
    for (int nf = 0; nf < 4; nf++) {
      ushort4 v = make_ushort4(f2bf(acc[nf][mf][0]), f2bf(acc[nf][mf][1]),
                               f2bf(acc[nf][mf][2]), f2bf(acc[nf][mf][3]));
      *(ushort4*)&y_slot[base + nf * 16 + rowq] = v;
    }
  }
}

// ---------------- combine: out = x + sum_k y_slot[t*8+k] ----------------
__global__ void combine_kernel(const float* __restrict__ x, const unsigned short* __restrict__ ys,
                               float* __restrict__ out) {
  int t = blockIdx.x, tid = threadIdx.x;
  int c = tid * 2;
  float s0 = 0.f, s1 = 0.f;
  #pragma unroll
  for (int k = 0; k < KA; k++) {
    unsigned u = *(const unsigned*)&ys[((size_t)t * KA + k) * C + c];
    s0 += bf2f((unsigned short)(u & 0xFFFF));
    s1 += bf2f((unsigned short)(u >> 16));
  }
  out[(size_t)t * C + c]     = x[(size_t)t * C + c] + s0;
  out[(size_t)t * C + c + 1] = x[(size_t)t * C + c + 1] + s1;
}

// ---------------- MFMA MLP1: 64-slot tile x 128 cols, gelu epilogue ----------------
__global__ __launch_bounds__(256) void mlp1_mfma(
    const unsigned short* __restrict__ xb, const unsigned short* __restrict__ wit,
    const float* __restrict__ bi, const int* __restrict__ bucket,
    const int* __restrict__ counts, const int* __restrict__ map,
    const int* __restrict__ total, unsigned short* __restrict__ h) {
  if ((int)blockIdx.y >= *total) return;
  int ent = map[blockIdx.y];
  int e = ent >> 16, t0 = ent & 0xFFFF;
  int j0 = blockIdx.x * 128;
  int cnt = counts[e];
  int tid = threadIdx.x;
  __shared__ int slots[64];
  __shared__ __align__(16) unsigned short Xb[64][72];
  __shared__ __align__(16) unsigned short Wb[128][72];
  if (tid < 64) {
    int ii = t0 + tid;
    slots[tid] = (ii < cnt) ? bucket[(size_t)e * (T * KF) + ii] : -1;
  }
  __syncthreads();
  int lane = tid & 63, w = tid >> 6;
  int lr = lane & 15, lk = (lane >> 4) * 8, rowq = (lane >> 4) * 4;
  f32x4 acc[2][4] = {};
  for (int kc = 0; kc < C; kc += 64) {
    __syncthreads();
    #pragma unroll
    for (int it = 0; it < 2; ++it) {
      int i = it * 256 + tid;
      int r = i >> 3, c8 = (i & 7) * 8;
      int s = slots[r];
      uint4 v = make_uint4(0u, 0u, 0u, 0u);
      if (s >= 0) v = *(const uint4*)&xb[(size_t)(s >> 1) * C + kc + c8];
      *(uint4*)&Xb[r][c8] = v;
    }
    #pragma unroll
    for (int it = 0; it < 4; ++it) {
      int i = it * 256 + tid;
      int r = i >> 3, c8 = (i & 7) * 8;
      *(uint4*)&Wb[r][c8] = *(const uint4*)&wit[((size_t)e * HID + j0 + r) * C + kc + c8];
    }
    __syncthreads();
    #pragma unroll
    for (int kk = 0; kk < 64; kk += 32) {
      bf16x8 a[2], b[4];
      #pragma unroll
      for (int nf = 0; nf < 2; nf++) a[nf] = *(const bf16x8*)&Wb[w * 32 + nf * 16 + lr][kk + lk];
      #pragma unroll
      for (int mf = 0; mf < 4; mf++) b[mf] = *(const bf16x8*)&Xb[mf * 16 + lr][kk + lk];
      #pragma unroll
      for (int nf = 0; nf < 2; nf++)
        #pragma unroll
        for (int mf = 0; mf < 4; mf++)
          acc[nf][mf] = __builtin_amdgcn_mfma_f32_16x16x32_bf16(a[nf], b[mf], acc[nf][mf], 0, 0, 0);
    }
  }
  #pragma unroll
  for (int mf = 0; mf < 4; mf++) {
    int s = slots[mf * 16 + lr];
    if (s < 0) continue;
    #pragma unroll
    for (int nf = 0; nf < 2; nf++) {
      int j = j0 + w * 32 + nf * 16 + rowq;
      const float4 b4 = *(const float4*)&bi[(size_t)e * HID + j];
      float v0 = acc[nf][mf][0] + b4.x, v1 = acc[nf][mf][1] + b4.y;
      float v2 = acc[nf][mf][2] + b4.z, v3 = acc[nf][mf][3] + b4.w;
      v0 = 0.5f * v0 * (1.f + erff(v0 * 0.70710678118654752f));
      v1 = 0.5f * v1 * (1.f + erff(v1 * 0.70710678118654752f));
      v2 = 0.5f * v2 * (1.f + erff(v2 * 0.70710678118654752f));
      v3 = 0.5f * v3 * (1.f + erff(v3 * 0.70710678118654752f));
      *(ushort4*)&h[(size_t)s * HID + j] = make_ushort4(f2bf(v0), f2bf(v1), f2bf(v2), f2bf(v3));
    }
  }
}

// ---------------- MFMA MLP2: 64-slot tile x 128 cols, gate+bias epilogue ----------------
__global__ __launch_bounds__(256) void mlp2_mfma(
    const unsigned short* __restrict__ h, const unsigned short* __restrict__ wot,
    const float* __restrict__ bo, const float* __restrict__ gates2,
    const int* __restrict__ bucket, const int* __restrict__ counts,
    const int* __restrict__ map, const int* __restrict__ total,
    unsigned short* __restrict__ y2) {
  if ((int)blockIdx.y >= *total) return;
  int ent = map[blockIdx.y];
  int e = ent >> 16, t0 = ent & 0xFFFF;
  int c0 = blockIdx.x * 128;
  int cnt = counts[e];
  int tid = threadIdx.x;
  __shared__ int slots[64];
  __shared__ __align__(16) unsigned short Xb[64][72];
  __shared__ __align__(16) unsigned short Wb[128][72];
  if (tid < 64) {
    int ii = t0 + tid;
    slots[tid] = (ii < cnt) ? bucket[(size_t)e * (T * KF) + ii] : -1;
  }
  __syncthreads();
  int lane = tid & 63, w = tid >> 6;
  int lr = lane & 15, lk = (lane >> 4) * 8, rowq = (lane >> 4) * 4;
  f32x4 acc[2][4] = {};
  for (int kc = 0; kc < HID; kc += 64) {
    __syncthreads();
    #pragma unroll
    for (int it = 0; it < 2; ++it) {
      int i = it * 256 + tid;
      int r = i >> 3, c8 = (i & 7) * 8;
      int s = slots[r];
      uint4 v = make_uint4(0u, 0u, 0u, 0u);
      if (s >= 0) v = *(const uint4*)&h[(size_t)s * HID + kc + c8];
      *(uint4*)&Xb[r][c8] = v;
    }
    #pragma unroll
    for (int it = 0; it < 4; ++it) {
      int i = it * 256 + tid;
      int r = i >> 3, c8 = (i & 7) * 8;
      *(uint4*)&Wb[r][c8] = *(const uint4*)&wot[((size_t)e * C + c0 + r) * HID + kc + c8];
    }
    __syncthreads();
    #pragma unroll
    for (int kk = 0; kk < 64; kk += 32) {
      bf16x8 a[2], b[4];
      #pragma unroll
      for (int nf = 0; nf < 2; nf++) a[nf] = *(const bf16x8*)&Wb[w * 32 + nf * 16 + lr][kk + lk];
      #pragma unroll
      for (int mf = 0; mf < 4; mf++) b[mf] = *(const bf16x8*)&Xb[mf * 16 + lr][kk + lk];
      #pragma unroll
      for (int nf = 0; nf < 2; nf++)
        #pragma unroll
        for (int mf = 0; mf < 4; mf++)
          acc[nf][mf] = __builtin_amdgcn_mfma_f32_16x16x32_bf16(a[nf], b[mf], acc[nf][mf], 0, 0, 0);
    }
  }
  #pragma unroll
  for (int mf = 0; mf < 4; mf++) {
    int s = slots[mf * 16 + lr];
    if (s < 0) continue;
    float g = gates2[s];
    #pragma unroll
    for (int nf = 0; nf < 2; nf++) {
      int cc = c0 + w * 32 + nf * 16 + rowq;
      const float4 b4 = *(const float4*)&bo[(size_t)e * C + cc];
      ushort4 v = make_ushort4(f2bf(g * (acc[nf][mf][0] + b4.x)),
                               f2bf(g * (acc[nf][mf][1] + b4.y)),
                               f2bf(g * (acc[nf][mf][2] + b4.z)),
                               f2bf(g * (acc[nf][mf][3] + b4.w)));
      *(ushort4*)&y2[(size_t)s * C + cc] = v;
    }
  }
}

// ---------------- Final residual add (bf16 slots) ----------------
__global__ void final_kernel(const unsigned short* __restrict__ y2, float* __restrict__ xout) {
  int t = blockIdx.x, tid = threadIdx.x;
  int c = tid * 2;
  unsigned u0 = *(const unsigned*)&y2[(size_t)(t * 2) * C + c];
  unsigned u1 = *(const unsigned*)&y2[(size_t)(t * 2 + 1) * C + c];
  xout[(size_t)t * C + c]     += bf2f((unsigned short)(u0 & 0xFFFF)) + bf2f((unsigned short)(u1 & 0xFFFF));
  xout[(size_t)t * C + c + 1] += bf2f((unsigned short)(u0 >> 16)) + bf2f((unsigned short)(u1 >> 16));
}

// ---------------- Gating statistics reduction: lane==expert ----------------
template <int E, int K, int TPB>
__global__ __launch_bounds__(256) void reduce_gating(
    const float* __restrict__ probs, const float* __restrict__ lse,
    const int* __restrict__ idxs, float* __restrict__ psum,
    float* __restrict__ freq, float* __restrict__ zsum) {
  constexpr int TPW = TPB / 4;
  int tid = threadIdx.x, lane = tid & 63, wv = tid >> 6;
  int t0 = blockIdx.x * TPB + wv * TPW;
  float ps = 0.f, fr = 0.f;
  if (lane < E) {
    for (int i = 0; i < TPW; i++) {
      int t = t0 + i;
      ps += probs[(size_t)t * E + lane];
      #pragma unroll
      for (int k = 0; k < K; k++)
        fr += (idxs[(size_t)t * K + k] == lane) ? 1.f : 0.f;
    }
  }
  float z = 0.f;
  for (int i = lane; i < TPW; i += 64) {
    float l = lse[t0 + i];
    z += l * l;
  }
  #pragma unroll
  for (int m = 1; m < 64; m <<= 1) z += __shfl_xor(z, m);
  __shared__ float sps[4][E];
  __shared__ float sfr[4][E];
  __shared__ float sz[4];
  if (lane < E) { sps[wv][lane] = ps; sfr[wv][lane] = fr; }
  if (lane == 0) sz[wv] = z;
  __syncthreads();
  if (tid < E) {
    atomicAdd(&psum[tid], sps[0][tid] + sps[1][tid] + sps[2][tid] + sps[3][tid]);
    atomicAdd(&freq[tid], sfr[0][tid] + sfr[1][tid] + sfr[2][tid] + sfr[3][tid]);
  }
  if (tid == 255) atomicAdd(zsum, sz[0] + sz[1] + sz[2] + sz[3]);
}

__global__ void loss_kernel(const float* __restrict__ acc, float* __restrict__ out) {
  const float* p1 = acc;      const float* f1 = acc + 24; float z1 = acc[48];
  const float* p2 = acc + 49; const float* f2 = acc + 65; float z2 = acc[81];
  float sp1 = 0.f, sf1 = 0.f;
  for (int e = 0; e < 24; e++) { sp1 += p1[e]; sf1 += f1[e]; }
  float sw1 = 0.f;
  for (int e = 0; e < 24; e++) sw1 += (p1[e] / sp1) * (f1[e] / sf1);
  sw1 *= 24.f;
  float sp2 = 0.f, sf2 = 0.f;
  for (int e = 0; e < 16; e++) { sp2 += p2[e]; sf2 += f2[e]; }
  float sw2 = 0.f;
  for (int e = 0; e < 16; e++) sw2 += (p2[e] / sp2) * (f2[e] / sf2);
  sw2 *= 16.f;
  out[0] = 0.01f * sw1 + 0.001f * (z1 / T) + 0.01f * sw2 + 0.001f * (z2 / T);
}

}  // namespace

extern "C" void kernel_launch(void* const* d_in, const int* in_sizes, int n_in,
                              void* d_out, int out_size, void* d_ws, size_t ws_size,
                              hipStream_t stream) {
  const float* x      = (const float*)d_in[0];
  const int*   task   = (const int*)d_in[1];
  const float* n1g    = (const float*)d_in[2];
  const float* n1b    = (const float*)d_in[3];
  const float* gate_a = (const float*)d_in[4];
  const float* wq     = (const float*)d_in[5];
  const float* wo_a   = (const float*)d_in[6];
  const float* kvw    = (const float*)d_in[7];
  const float* kvb    = (const float*)d_in[8];
  const float* n2g    = (const float*)d_in[9];
  const float* n2b    = (const float*)d_in[10];
  const float* gate_m = (const float*)d_in[11];
  const float* wi     = (const float*)d_in[12];
  const float* bi     = (const float*)d_in[13];
  const float* wo_m   = (const float*)d_in[14];
  const float* bo     = (const float*)d_in[15];
  float* out = (float*)d_out;

  char* p = (char*)d_ws;
  unsigned short* x1b = (unsigned short*)p; p += (size_t)T * C * 2;
  unsigned short* qb = (unsigned short*)p;  p += (size_t)T * KA * HD * 2;
  unsigned short* ob = (unsigned short*)p;  p += (size_t)T * KA * HD * 2;
  unsigned short* Kb = (unsigned short*)p;  p += (size_t)T * HD * 2;
  unsigned short* Vt = (unsigned short*)p;  p += (size_t)T * HD * 2;
  char* un = p;                      p += (size_t)T * KA * C * 2;
  unsigned short* y_slot  = (unsigned short*)un;
  unsigned short* h       = (unsigned short*)un;
  unsigned short* y2_slot = (unsigned short*)(un + (size_t)T * KF * HID * 2);
  unsigned short* wqt = (unsigned short*)p;  p += (size_t)EA * C * HD * 2;
  unsigned short* woat = (unsigned short*)p; p += (size_t)EA * HD * C * 2;
  unsigned short* wit = (unsigned short*)p;  p += (size_t)EF * C * HID * 2;
  unsigned short* womt = (unsigned short*)p; p += (size_t)EF * HID * C * 2;
  unsigned short* kvwt = (unsigned short*)p; p += (size_t)(2 * HD) * C * 2;
  float* probs1 = (float*)p;         p += (size_t)T * EA * 4;
  float* lse1 = (float*)p;           p += (size_t)T * 4;
  float* gates1 = (float*)p;         p += (size_t)T * KA * 4;
  int* idx1 = (int*)p;               p += (size_t)T * KA * 4;
  float* probs2 = (float*)p;         p += (size_t)T * EF * 4;
  float* lse2 = (float*)p;           p += (size_t)T * 4;
  float* gates2 = (float*)p;         p += (size_t)T * KF * 4;
  int* idx2 = (int*)p;               p += (size_t)T * KF * 4;
  int* bucket_a = (int*)p;           p += (size_t)EA * (T * KA) * 4;
  int* bucket_f = (int*)p;           p += (size_t)EF * (T * KF) * 4;
  int* counts_a = (int*)p;           p += 32 * 4;
  int* counts_f = (int*)p;           p += 32 * 4;
  float* accum = (float*)p;          p += 128 * 4;
  int* maps = (int*)p;               p += 1024 * 4;
  int* totals = (int*)p;             p += 8 * 4;

  hipMemsetAsync(counts_a, 0, (32 + 32 + 128) * 4, stream);

  tcvt_all<<<17984, 256, 0, stream>>>(wq, wo_a, wi, wo_m, kvw, wqt, woat, wit, womt, kvwt);

  ln_gate_kernel<EA, KA><<<T / 16, 256, 0, stream>>>(x, n1g, n1b, gate_a, task, x1b,
                                                     probs1, lse1, gates1, idx1);
  bucket_kernel<EA><<<(T * KA + 511) / 512, 512, 0, stream>>>(idx1, T * KA, T * KA,
                                                              counts_a, bucket_a);
  build_maps_a<<<1, 64, 0, stream>>>(counts_a, maps, totals);
  qgemm_mfma<<<dim3(1, 152), 256, 0, stream>>>(x1b, wqt, bucket_a, counts_a, maps, totals, qb);
  kv_mfma<<<T / 16, 256, 0, stream>>>(x1b, kvwt, kvb, Kb, Vt);
  attn_mfma<<<dim3(NS / 64, KA, NB), 256, 0, stream>>>(qb, Kb, Vt, ob);
  oproj_mfma<<<dim3(4, 280), 256, 0, stream>>>(ob, woat, gates1, bucket_a, counts_a,
                                               maps + 256, totals + 1, y_slot);
  combine_kernel<<<T, 256, 0, stream>>>(x, y_slot, out);
  ln_gate_kernel<EF, KF><<<T / 16, 256, 0, stream>>>(out, n2g, n2b, gate_m, task, x1b,
                                                     probs2, lse2, gates2, idx2);
  bucket_kernel<EF><<<(T * KF + 511) / 512, 512, 0, stream>>>(idx2, T * KF, T * KF,
                                                              counts_f, bucket_f);
  build_maps_f<<<1, 64, 0, stream>>>(counts_f, maps, totals);
  mlp1_mfma<<<dim3(8, 144), 256, 0, stream>>>(x1b, wit, bi, bucket_f, counts_f,
                                              maps + 768, totals + 3, h);
  mlp2_mfma<<<dim3(4, 144), 256, 0, stream>>>(h, womt, bo, gates2, bucket_f, counts_f,
                                              maps + 768, totals + 3, y2_slot);
  final_kernel<<<T, 256, 0, stream>>>(y2_slot, out);
  reduce_gating<EA, KA, 64><<<T / 64, 256, 0, stream>>>(probs1, lse1, idx1, accum,
                                                        accum + 24, accum + 48);
  reduce_gating<EF, KF, 64><<<T / 64, 256, 0, stream>>>(probs2, lse2, idx2, accum + 49,
                                                        accum + 65, accum + 81);
  loss_kernel<<<1, 1, 0, stream>>>(accum, out + (size_t)T * C);
}

// Round 12
// 252.530 us; speedup vs baseline: 6.7616x; 1.1498x over previous
//
#include <hip/hip_runtime.h>
#include <math.h>

namespace {

constexpr int T   = 4096;
constexpr int C   = 512;
constexpr int NB  = 8;
constexpr int NS  = 512;
constexpr int HD  = 64;
constexpr int KA  = 8;
constexpr int EA  = 24;
constexpr int EF  = 16;
constexpr int KF  = 2;
constexpr int HID = 1024;

typedef __attribute__((ext_vector_type(8))) short bf16x8;
typedef __attribute__((ext_vector_type(4))) float f32x4;

__device__ inline unsigned short f2bf(float f) {
  unsigned u = __float_as_uint(f);
  return (unsigned short)((u + 0x7FFFu + ((u >> 16) & 1u)) >> 16);
}
__device__ inline float bf2f(unsigned short u) {
  return __uint_as_float((unsigned)u << 16);
}

// scan counts to map flat tile id -> (expert, tile offset); returns false if past end
template <int E, int TS>
__device__ inline bool tile_from_counts(const int* counts, int tile, int& e_out, int& t0_out) {
  int e = 0;
  for (; e < E; e++) {
    int nt = (counts[e] + TS - 1) / TS;
    if (tile < nt) break;
    tile -= nt;
  }
  e_out = e; t0_out = tile * TS;
  return e < E;
}

// ---------------- Fused LayerNorm + Gating: 16 tokens per block ----------------
template <int E, int K>
__global__ __launch_bounds__(256) void ln_gate_kernel(
    const float* __restrict__ in, const float* __restrict__ g,
    const float* __restrict__ b, const float* __restrict__ gate_all,
    const int* __restrict__ task, unsigned short* __restrict__ outb,
    float* __restrict__ probs, float* __restrict__ lse_out,
    float* __restrict__ gates, int* __restrict__ idxs) {
  constexpr int TPB = 16;
  constexpr int XSS = 516;
  int tid = threadIdx.x, lane = tid & 63, wv = tid >> 6;
  int tb = blockIdx.x * TPB;
  __shared__ float xs[TPB][XSS];
  __shared__ float lg[TPB][E];
  __shared__ __align__(16) float Ws[C * E];
  const float* W = gate_all + (size_t)task[0] * C * E;
  for (int i = tid; i < C * E / 4; i += 256)
    *(float4*)&Ws[i * 4] = *(const float4*)&W[(size_t)i * 4];
  int c0 = lane * 8;
  const float4 g0 = *(const float4*)&g[c0], g1 = *(const float4*)&g[c0 + 4];
  const float4 b0 = *(const float4*)&b[c0], b1 = *(const float4*)&b[c0 + 4];
  #pragma unroll
  for (int i = 0; i < 4; i++) {
    int tt = wv * 4 + i;
    int t = tb + tt;
    const float* row = in + (size_t)t * C + c0;
    const float4 v0 = *(const float4*)&row[0];
    const float4 v1 = *(const float4*)&row[4];
    float s = (v0.x + v0.y) + (v0.z + v0.w) + (v1.x + v1.y) + (v1.z + v1.w);
    #pragma unroll
    for (int m = 1; m < 64; m <<= 1) s += __shfl_xor(s, m);
    float mean = s * (1.f / C);
    float d[8] = {v0.x - mean, v0.y - mean, v0.z - mean, v0.w - mean,
                  v1.x - mean, v1.y - mean, v1.z - mean, v1.w - mean};
    float vv = 0.f;
    #pragma unroll
    for (int j = 0; j < 8; j++) vv += d[j] * d[j];
    #pragma unroll
    for (int m = 1; m < 64; m <<= 1) vv += __shfl_xor(vv, m);
    float r = rsqrtf(vv * (1.f / C) + 1e-5f);
    float o[8];
    o[0] = d[0] * r * g0.x + b0.x; o[1] = d[1] * r * g0.y + b0.y;
    o[2] = d[2] * r * g0.z + b0.z; o[3] = d[3] * r * g0.w + b0.w;
    o[4] = d[4] * r * g1.x + b1.x; o[5] = d[5] * r * g1.y + b1.y;
    o[6] = d[6] * r * g1.z + b1.z; o[7] = d[7] * r * g1.w + b1.w;
    *(ushort4*)&outb[(size_t)t * C + c0] =
        make_ushort4(f2bf(o[0]), f2bf(o[1]), f2bf(o[2]), f2bf(o[3]));
    *(ushort4*)&outb[(size_t)t * C + c0 + 4] =
        make_ushort4(f2bf(o[4]), f2bf(o[5]), f2bf(o[6]), f2bf(o[7]));
    #pragma unroll
    for (int j = 0; j < 8; j++) xs[tt][c0 + j] = o[j];
  }
  __syncthreads();
  for (int p = tid; p < TPB * E; p += 256) {
    int e = p % E, tt = p / E;
    float a0 = 0.f, a1 = 0.f, a2 = 0.f, a3 = 0.f;
    #pragma unroll 8
    for (int c = 0; c < C; c += 4) {
      a0 += xs[tt][c + 0] * Ws[(c + 0) * E + e];
      a1 += xs[tt][c + 1] * Ws[(c + 1) * E + e];
      a2 += xs[tt][c + 2] * Ws[(c + 2) * E + e];
      a3 += xs[tt][c + 3] * Ws[(c + 3) * E + e];
    }
    lg[tt][e] = (a0 + a1) + (a2 + a3);
  }
  __syncthreads();
  #pragma unroll
  for (int i = 0; i < 4; i++) {
    int tt = wv * 4 + i;
    int t = tb + tt;
    float lgv = (lane < E) ? lg[tt][lane] : -3.0e38f;
    float mx = lgv;
    #pragma unroll
    for (int m = 1; m < 64; m <<= 1) mx = fmaxf(mx, __shfl_xor(mx, m));
    float pe = (lane < E) ? expf(lgv - mx) : 0.f;
    float sum = pe;
    #pragma unroll
    for (int m = 1; m < 64; m <<= 1) sum += __shfl_xor(sum, m);
    float inv = 1.f / sum;
    float prob = pe * inv;
    if (lane < E) probs[(size_t)t * E + lane] = prob;
    if (lane == 0) lse_out[t] = mx + logf(sum);
    float pv = (lane < E) ? prob : -1.f;
    float gsum = 0.f, myv = 0.f; int myi = 0;
    for (int k = 0; k < K; k++) {
      float bv = pv; int bi_ = lane;
      #pragma unroll
      for (int m = 1; m < 64; m <<= 1) {
        float ov = __shfl_xor(bv, m); int oi = __shfl_xor(bi_, m);
        if (ov > bv || (ov == bv && oi < bi_)) { bv = ov; bi_ = oi; }
      }
      gsum += bv;
      if (lane == k) { myv = bv; myi = bi_; }
      if (lane == bi_) pv = -1.f;
    }
    if (lane < K) {
      float ginv = 1.f / (gsum + 1e-6f);
      gates[(size_t)t * K + lane] = myv * ginv;
      idxs[(size_t)t * K + lane]  = myi;
    }
  }
}

// ---------------- bucket by expert ----------------
template <int E>
__global__ __launch_bounds__(512) void bucket_kernel(const int* __restrict__ idx, int nslots,
                                                     int stride, int* counts, int* bucket) {
  __shared__ int lcount[E];
  __shared__ int lbase[E];
  int tid = threadIdx.x;
  if (tid < E) lcount[tid] = 0;
  __syncthreads();
  int s = blockIdx.x * 512 + tid;
  int e = 0, lpos = 0;
  bool valid = (s < nslots);
  if (valid) {
    e = idx[s];
    lpos = atomicAdd(&lcount[e], 1);
  }
  __syncthreads();
  if (tid < E) lbase[tid] = lcount[tid] ? atomicAdd(&counts[tid], lcount[tid]) : 0;
  __syncthreads();
  if (valid) bucket[(size_t)e * stride + lbase[e] + lpos] = s;
}

// ---------------- merged transpose+cvt: all 5 weight tensors in one dispatch ----------------
__global__ __launch_bounds__(256) void tcvt_all(
    const float* __restrict__ wq, const float* __restrict__ wo_a,
    const float* __restrict__ wi, const float* __restrict__ wo_m,
    const float* __restrict__ kvw,
    unsigned short* __restrict__ wqt, unsigned short* __restrict__ woat,
    unsigned short* __restrict__ wit, unsigned short* __restrict__ womt,
    unsigned short* __restrict__ kvwt) {
  int bid = blockIdx.x;
  const float* src; unsigned short* dst; int K, N, nx, rem;
  if (bid < 768)        { src = wq;   dst = wqt;  K = 512;  N = 64;   nx = 2;  rem = bid; }
  else if (bid < 1536)  { src = wo_a; dst = woat; K = 64;   N = 512;  nx = 16; rem = bid - 768; }
  else if (bid < 9728)  { src = wi;   dst = wit;  K = 512;  N = 1024; nx = 32; rem = bid - 1536; }
  else if (bid < 17920) { src = wo_m; dst = womt; K = 1024; N = 512;  nx = 16; rem = bid - 9728; }
  else                  { src = kvw;  dst = kvwt; K = 512;  N = 128;  nx = 4;  rem = bid - 17920; }
  int per = nx * (K / 32);
  int e = rem / per, r2 = rem % per;
  int kt = (r2 / nx) * 32, nt = (r2 % nx) * 32;
  __shared__ float tile[32][33];
  int tid = threadIdx.x;
  const float* S = src + (size_t)e * K * N;
  for (int i = tid; i < 32 * 32; i += 256) {
    int r = i >> 5, c = i & 31;
    tile[r][c] = S[(size_t)(kt + r) * N + nt + c];
  }
  __syncthreads();
  unsigned short* D = dst + (size_t)e * K * N;
  for (int i = tid; i < 32 * 8; i += 256) {
    int n = i >> 3, k4 = (i & 7) * 4;
    ushort4 v;
    v.x = f2bf(tile[k4 + 0][n]); v.y = f2bf(tile[k4 + 1][n]);
    v.z = f2bf(tile[k4 + 2][n]); v.w = f2bf(tile[k4 + 3][n]);
    *(ushort4*)&D[(size_t)(nt + n) * K + kt + k4] = v;
  }
}

// ---------------- MFMA Q GEMM: 64 slots x 64 out, K=512 -> bf16 q (pre-scaled) ----------------
__global__ __launch_bounds__(256) void qgemm_mfma(
    const unsigned short* __restrict__ xb, const unsigned short* __restrict__ wqt,
    const int* __restrict__ bucket, const int* __restrict__ counts,
    unsigned short* __restrict__ qb) {
  __shared__ int se, st0;
  int tid = threadIdx.x;
  if (tid == 0) {
    int e, t0;
    bool ok = tile_from_counts<EA, 64>(counts, blockIdx.y, e, t0);
    se = ok ? e : -1; st0 = t0;
  }
  __syncthreads();
  if (se < 0) return;
  int e = se, t0 = st0;
  int cnt = counts[e];
  __shared__ int slots[64];
  __shared__ __align__(16) unsigned short Xb[64][72];
  __shared__ __align__(16) unsigned short Wb[64][72];
  if (tid < 64) {
    int ii = t0 + tid;
    slots[tid] = (ii < cnt) ? bucket[(size_t)e * (T * KA) + ii] : -1;
  }
  __syncthreads();
  int lane = tid & 63, w = tid >> 6;
  int lr = lane & 15, lk = (lane >> 4) * 8, rowq = (lane >> 4) * 4;
  f32x4 acc[4] = {};
  for (int kc = 0; kc < C; kc += 64) {
    __syncthreads();
    #pragma unroll
    for (int it = 0; it < 2; ++it) {
      int i = it * 256 + tid;
      int r = i >> 3, c8 = (i & 7) * 8;
      int s = slots[r];
      uint4 v = make_uint4(0u, 0u, 0u, 0u);
      if (s >= 0) v = *(const uint4*)&xb[(size_t)(s >> 3) * C + kc + c8];
      *(uint4*)&Xb[r][c8] = v;
    }
    #pragma unroll
    for (int it = 0; it < 2; ++it) {
      int i = it * 256 + tid;
      int r = i >> 3, c8 = (i & 7) * 8;
      *(uint4*)&Wb[r][c8] = *(const uint4*)&wqt[((size_t)e * HD + r) * C + kc + c8];
    }
    __syncthreads();
    #pragma unroll
    for (int kk = 0; kk < 64; kk += 32) {
      bf16x8 a = *(const bf16x8*)&Wb[w * 16 + lr][kk + lk];
      #pragma unroll
      for (int mf = 0; mf < 4; mf++) {
        bf16x8 b = *(const bf16x8*)&Xb[mf * 16 + lr][kk + lk];
        acc[mf] = __builtin_amdgcn_mfma_f32_16x16x32_bf16(a, b, acc[mf], 0, 0, 0);
      }
    }
  }
  #pragma unroll
  for (int mf = 0; mf < 4; mf++) {
    int s = slots[mf * 16 + lr];
    if (s < 0) continue;
    ushort4 v = make_ushort4(f2bf(0.125f * acc[mf][0]), f2bf(0.125f * acc[mf][1]),
                             f2bf(0.125f * acc[mf][2]), f2bf(0.125f * acc[mf][3]));
    *(ushort4*)&qb[(size_t)s * HD + w * 16 + rowq] = v;
  }
}

// ---------------- MFMA KV GEMM: 16 tokens x 128 cols per block, 256 blocks ----------------
__global__ __launch_bounds__(256) void kv_mfma(
    const unsigned short* __restrict__ xb, const unsigned short* __restrict__ kvwt,
    const float* __restrict__ kvb, unsigned short* __restrict__ Kb,
    unsigned short* __restrict__ Vt) {
  int t0 = blockIdx.x * 16;
  int tid = threadIdx.x;
  __shared__ __align__(16) unsigned short Xs[16][72];
  __shared__ __align__(16) unsigned short Ws[128][72];
  int lane = tid & 63, w = tid >> 6;
  int lr = lane & 15, lk = (lane >> 4) * 8, rowq = (lane >> 4) * 4;
  f32x4 acc[2] = {};
  for (int kc = 0; kc < C; kc += 64) {
    __syncthreads();
    if (tid < 128) {
      int r = tid >> 3, c8 = (tid & 7) * 8;
      *(uint4*)&Xs[r][c8] = *(const uint4*)&xb[(size_t)(t0 + r) * C + kc + c8];
    }
    #pragma unroll
    for (int it = 0; it < 4; ++it) {
      int i = it * 256 + tid;
      int r = i >> 3, c8 = (i & 7) * 8;
      *(uint4*)&Ws[r][c8] = *(const uint4*)&kvwt[(size_t)r * C + kc + c8];
    }
    __syncthreads();
    #pragma unroll
    for (int kk = 0; kk < 64; kk += 32) {
      bf16x8 xf = *(const bf16x8*)&Xs[lr][kk + lk];
      #pragma unroll
      for (int cf = 0; cf < 2; cf++) {
        bf16x8 wf = *(const bf16x8*)&Ws[w * 32 + cf * 16 + lr][kk + lk];
        acc[cf] = __builtin_amdgcn_mfma_f32_16x16x32_bf16(wf, xf, acc[cf], 0, 0, 0);
      }
    }
  }
  int t = t0 + lr;
  int bb = t >> 9, n = t & (NS - 1);
  #pragma unroll
  for (int cf = 0; cf < 2; cf++) {
    #pragma unroll
    for (int r2 = 0; r2 < 4; r2++) {
      int c = w * 32 + cf * 16 + rowq + r2;
      float v = acc[cf][r2] + kvb[c];
      if (c < HD) Kb[(size_t)t * HD + c] = f2bf(v);
      else        Vt[((size_t)bb * HD + (c - HD)) * NS + n] = f2bf(v);
    }
  }
}

// ---------------- MFMA flash attention ----------------
__global__ __launch_bounds__(256) void attn_mfma(
    const unsigned short* __restrict__ qb, const unsigned short* __restrict__ Kb,
    const unsigned short* __restrict__ Vt, unsigned short* __restrict__ ob) {
  int qt = blockIdx.x, h = blockIdx.y, b = blockIdx.z;
  int tid = threadIdx.x;
  __shared__ __align__(16) unsigned short Qs[64][72];
  __shared__ __align__(16) unsigned short Ks[64][72];
  __shared__ __align__(16) unsigned short Vs[64][72];
  __shared__ __align__(16) unsigned short Ps[64][72];
  int i0 = qt * 64;
  #pragma unroll
  for (int it = 0; it < 2; ++it) {
    int i = it * 256 + tid;
    int r = i >> 3, c8 = (i & 7) * 8;
    *(uint4*)&Qs[r][c8] = *(const uint4*)&qb[(((size_t)(b * NS + i0 + r)) * KA + h) * HD + c8];
  }
  int lane = tid & 63, w = tid >> 6;
  int lr = lane & 15, lk = (lane >> 4) * 8, rowq = (lane >> 4) * 4;
  f32x4 acc_o[4] = {};
  float m_run = -3.0e38f, l_run = 0.f;
  for (int jt = 0; jt < NS / 64; ++jt) {
    __syncthreads();
    #pragma unroll
    for (int it = 0; it < 2; ++it) {
      int i = it * 256 + tid;
      int r = i >> 3, c8 = (i & 7) * 8;
      *(uint4*)&Ks[r][c8] = *(const uint4*)&Kb[((size_t)(b * NS + jt * 64 + r)) * HD + c8];
      *(uint4*)&Vs[r][c8] = *(const uint4*)&Vt[((size_t)b * HD + r) * NS + jt * 64 + c8];
    }
    __syncthreads();
    f32x4 acc_s[4] = {};
    #pragma unroll
    for (int kk = 0; kk < 64; kk += 32) {
      bf16x8 qf = *(const bf16x8*)&Qs[w * 16 + lr][kk + lk];
      #pragma unroll
      for (int kf = 0; kf < 4; kf++) {
        bf16x8 kr = *(const bf16x8*)&Ks[kf * 16 + lr][kk + lk];
        acc_s[kf] = __builtin_amdgcn_mfma_f32_16x16x32_bf16(kr, qf, acc_s[kf], 0, 0, 0);
      }
    }
    float pmax = acc_s[0][0];
    #pragma unroll
    for (int kf = 0; kf < 4; kf++)
      #pragma unroll
      for (int r = 0; r < 4; r++) pmax = fmaxf(pmax, acc_s[kf][r]);
    pmax = fmaxf(pmax, __shfl_xor(pmax, 16));
    pmax = fmaxf(pmax, __shfl_xor(pmax, 32));
    float m_new = fmaxf(m_run, pmax);
    float scl = expf(m_run - m_new);
    float rs = 0.f;
    #pragma unroll
    for (int kf = 0; kf < 4; kf++)
      #pragma unroll
      for (int r = 0; r < 4; r++) {
        float pv = expf(acc_s[kf][r] - m_new);
        rs += pv;
        Ps[w * 16 + lr][kf * 16 + rowq + r] = f2bf(pv);
      }
    rs += __shfl_xor(rs, 16);
    rs += __shfl_xor(rs, 32);
    l_run = l_run * scl + rs;
    m_run = m_new;
    __syncthreads();
    #pragma unroll
    for (int df = 0; df < 4; df++) {
      acc_o[df][0] *= scl; acc_o[df][1] *= scl;
      acc_o[df][2] *= scl; acc_o[df][3] *= scl;
    }
    #pragma unroll
    for (int kk = 0; kk < 64; kk += 32) {
      bf16x8 pf = *(const bf16x8*)&Ps[w * 16 + lr][kk + lk];
      #pragma unroll
      for (int df = 0; df < 4; df++) {
        bf16x8 vf = *(const bf16x8*)&Vs[df * 16 + lr][kk + lk];
        acc_o[df] = __builtin_amdgcn_mfma_f32_16x16x32_bf16(vf, pf, acc_o[df], 0, 0, 0);
      }
    }
  }
  float inv = 1.f / l_run;
  int token = b * NS + i0 + w * 16 + lr;
  #pragma unroll
  for (int df = 0; df < 4; df++) {
    ushort4 v = make_ushort4(f2bf(acc_o[df][0] * inv), f2bf(acc_o[df][1] * inv),
                             f2bf(acc_o[df][2] * inv), f2bf(acc_o[df][3] * inv));
    *(ushort4*)&ob[((size_t)token * KA + h) * HD + df * 16 + rowq] = v;
  }
}

// ---------------- MFMA output proj: 128 slots x 128 cols, K=64, in-kernel map ----------------
__global__ __launch_bounds__(256) void oproj_mfma(
    const unsigned short* __restrict__ ob, const unsigned short* __restrict__ wot,
    const float* __restrict__ gates, const int* __restrict__ bucket,
    const int* __restrict__ counts, unsigned short* __restrict__ y_slot) {
  __shared__ int se, st0;
  int tid = threadIdx.x;
  if (tid == 0) {
    int e, t0;
    bool ok = tile_from_counts<EA, 128>(counts, blockIdx.y, e, t0);
    se = ok ? e : -1; st0 = t0;
  }
  __syncthreads();
  if (se < 0) return;
  int e = se, t0 = st0;
  int c0 = blockIdx.x * 128;
  int cnt = counts[e];
  __shared__ int slots[128];
  __shared__ float gs[128];
  __shared__ __align__(16) unsigned short Xb[128][72];
  __shared__ __align__(16) unsigned short Wb[128][72];
  if (tid < 128) {
    int ii = t0 + tid;
    int s = (ii < cnt) ? bucket[(size_t)e * (T * KA) + ii] : -1;
    slots[tid] = s;
    gs[tid] = (s >= 0) ? gates[s] : 0.f;
  }
  __syncthreads();
  #pragma unroll
  for (int it = 0; it < 4; ++it) {
    int i = it * 256 + tid;
    int r = i >> 3, c8 = (i & 7) * 8;
    int s = slots[r];
    uint4 vo = make_uint4(0u, 0u, 0u, 0u);
    if (s >= 0) {
      float g = gs[r];
      uint4 u = *(const uint4*)&ob[(size_t)s * HD + c8];
      const unsigned short* us = (const unsigned short*)&u;
      unsigned short* vs = (unsigned short*)&vo;
      #pragma unroll
      for (int k = 0; k < 8; k++) vs[k] = f2bf(g * bf2f(us[k]));
    }
    *(uint4*)&Xb[r][c8] = vo;
  }
  #pragma unroll
  for (int it = 0; it < 4; ++it) {
    int i = it * 256 + tid;
    int r = i >> 3, c8 = (i & 7) * 8;
    *(uint4*)&Wb[r][c8] = *(const uint4*)&wot[((size_t)e * C + c0 + r) * HD + c8];
  }
  __syncthreads();
  int lane = tid & 63, wid = tid >> 6;
  int wr = wid & 1, wc = wid >> 1;
  int lr = lane & 15, lk = (lane >> 4) * 8, rowq = (lane >> 4) * 4;
  f32x4 acc[4][4] = {};
  #pragma unroll
  for (int kk = 0; kk < 64; kk += 32) {
    bf16x8 a[4], b[4];
    #pragma unroll
    for (int nf = 0; nf < 4; nf++) a[nf] = *(const bf16x8*)&Wb[wc * 64 + nf * 16 + lr][kk + lk];
    #pragma unroll
    for (int mf = 0; mf < 4; mf++) b[mf] = *(const bf16x8*)&Xb[wr * 64 + mf * 16 + lr][kk + lk];
    #pragma unroll
    for (int nf = 0; nf < 4; nf++)
      #pragma unroll
      for (int mf = 0; mf < 4; mf++)
        acc[nf][mf] = __builtin_amdgcn_mfma_f32_16x16x32_bf16(a[nf], b[mf], acc[nf][mf], 0, 0, 0);
  }
  #pragma unroll
  for (int mf = 0; mf < 4; mf++) {
    int si = wr * 64 + mf * 16 + lr;
    int s = slots[si];
    if (s < 0) continue;
    size_t base = (size_t)s * C + c0 + wc * 64;
    #pragma unroll
    for (int nf = 0; nf < 4; nf++) {
      ushort4 v = make_ushort4(f2bf(acc[nf][mf][0]), f2bf(acc[nf][mf][1]),
                               f2bf(acc[nf][mf][2]), f2bf(acc[nf][mf][3]));
      *(ushort4*)&y_slot[base + nf * 16 + rowq] = v;
    }
  }
}

// ---------------- combine: out = x + sum_k y_slot[t*8+k] ----------------
__global__ void combine_kernel(const float* __restrict__ x, const unsigned short* __restrict__ ys,
                               float* __restrict__ out) {
  int t = blockIdx.x, tid = threadIdx.x;
  int c = tid * 2;
  float s0 = 0.f, s1 = 0.f;
  #pragma unroll
  for (int k = 0; k < KA; k++) {
    unsigned u = *(const unsigned*)&ys[((size_t)t * KA + k) * C + c];
    s0 += bf2f((unsigned short)(u & 0xFFFF));
    s1 += bf2f((unsigned short)(u >> 16));
  }
  out[(size_t)t * C + c]     = x[(size_t)t * C + c] + s0;
  out[(size_t)t * C + c + 1] = x[(size_t)t * C + c + 1] + s1;
}

// ---------------- MFMA MLP1: 64 slots x 64 cols, gelu epilogue, in-kernel map ----------------
__global__ __launch_bounds__(256) void mlp1_mfma(
    const unsigned short* __restrict__ xb, const unsigned short* __restrict__ wit,
    const float* __restrict__ bi, const int* __restrict__ bucket,
    const int* __restrict__ counts, unsigned short* __restrict__ h) {
  __shared__ int se, st0;
  int tid = threadIdx.x;
  if (tid == 0) {
    int e, t0;
    bool ok = tile_from_counts<EF, 64>(counts, blockIdx.y, e, t0);
    se = ok ? e : -1; st0 = t0;
  }
  __syncthreads();
  if (se < 0) return;
  int e = se, t0 = st0;
  int j0 = blockIdx.x * 64;
  int cnt = counts[e];
  __shared__ int slots[64];
  __shared__ __align__(16) unsigned short Xb[64][72];
  __shared__ __align__(16) unsigned short Wb[64][72];
  if (tid < 64) {
    int ii = t0 + tid;
    slots[tid] = (ii < cnt) ? bucket[(size_t)e * (T * KF) + ii] : -1;
  }
  __syncthreads();
  int lane = tid & 63, w = tid >> 6;
  int lr = lane & 15, lk = (lane >> 4) * 8, rowq = (lane >> 4) * 4;
  f32x4 acc[4] = {};
  for (int kc = 0; kc < C; kc += 64) {
    __syncthreads();
    #pragma unroll
    for (int it = 0; it < 2; ++it) {
      int i = it * 256 + tid;
      int r = i >> 3, c8 = (i & 7) * 8;
      int s = slots[r];
      uint4 v = make_uint4(0u, 0u, 0u, 0u);
      if (s >= 0) v = *(const uint4*)&xb[(size_t)(s >> 1) * C + kc + c8];
      *(uint4*)&Xb[r][c8] = v;
    }
    #pragma unroll
    for (int it = 0; it < 2; ++it) {
      int i = it * 256 + tid;
      int r = i >> 3, c8 = (i & 7) * 8;
      *(uint4*)&Wb[r][c8] = *(const uint4*)&wit[((size_t)e * HID + j0 + r) * C + kc + c8];
    }
    __syncthreads();
    #pragma unroll
    for (int kk = 0; kk < 64; kk += 32) {
      bf16x8 a = *(const bf16x8*)&Wb[w * 16 + lr][kk + lk];
      #pragma unroll
      for (int mf = 0; mf < 4; mf++) {
        bf16x8 b = *(const bf16x8*)&Xb[mf * 16 + lr][kk + lk];
        acc[mf] = __builtin_amdgcn_mfma_f32_16x16x32_bf16(a, b, acc[mf], 0, 0, 0);
      }
    }
  }
  #pragma unroll
  for (int mf = 0; mf < 4; mf++) {
    int s = slots[mf * 16 + lr];
    if (s < 0) continue;
    int j = j0 + w * 16 + rowq;
    const float4 b4 = *(const float4*)&bi[(size_t)e * HID + j];
    float v0 = acc[mf][0] + b4.x, v1 = acc[mf][1] + b4.y;
    float v2 = acc[mf][2] + b4.z, v3 = acc[mf][3] + b4.w;
    v0 = 0.5f * v0 * (1.f + erff(v0 * 0.70710678118654752f));
    v1 = 0.5f * v1 * (1.f + erff(v1 * 0.70710678118654752f));
    v2 = 0.5f * v2 * (1.f + erff(v2 * 0.70710678118654752f));
    v3 = 0.5f * v3 * (1.f + erff(v3 * 0.70710678118654752f));
    *(ushort4*)&h[(size_t)s * HID + j] = make_ushort4(f2bf(v0), f2bf(v1), f2bf(v2), f2bf(v3));
  }
}

// ---------------- MFMA MLP2: 64 slots x 64 cols, gate+bias epilogue, in-kernel map ----------------
__global__ __launch_bounds__(256) void mlp2_mfma(
    const unsigned short* __restrict__ h, const unsigned short* __restrict__ wot,
    const float* __restrict__ bo, const float* __restrict__ gates2,
    const int* __restrict__ bucket, const int* __restrict__ counts,
    unsigned short* __restrict__ y2) {
  __shared__ int se, st0;
  int tid = threadIdx.x;
  if (tid == 0) {
    int e, t0;
    bool ok = tile_from_counts<EF, 64>(counts, blockIdx.y, e, t0);
    se = ok ? e : -1; st0 = t0;
  }
  __syncthreads();
  if (se < 0) return;
  int e = se, t0 = st0;
  int c0 = blockIdx.x * 64;
  int cnt = counts[e];
  __shared__ int slots[64];
  __shared__ __align__(16) unsigned short Xb[64][72];
  __shared__ __align__(16) unsigned short Wb[64][72];
  if (tid < 64) {
    int ii = t0 + tid;
    slots[tid] = (ii < cnt) ? bucket[(size_t)e * (T * KF) + ii] : -1;
  }
  __syncthreads();
  int lane = tid & 63, w = tid >> 6;
  int lr = lane & 15, lk = (lane >> 4) * 8, rowq = (lane >> 4) * 4;
  f32x4 acc[4] = {};
  for (int kc = 0; kc < HID; kc += 64) {
    __syncthreads();
    #pragma unroll
    for (int it = 0; it < 2; ++it) {
      int i = it * 256 + tid;
      int r = i >> 3, c8 = (i & 7) * 8;
      int s = slots[r];
      uint4 v = make_uint4(0u, 0u, 0u, 0u);
      if (s >= 0) v = *(const uint4*)&h[(size_t)s * HID + kc + c8];
      *(uint4*)&Xb[r][c8] = v;
    }
    #pragma unroll
    for (int it = 0; it < 2; ++it) {
      int i = it * 256 + tid;
      int r = i >> 3, c8 = (i & 7) * 8;
      *(uint4*)&Wb[r][c8] = *(const uint4*)&wot[((size_t)e * C + c0 + r) * HID + kc + c8];
    }
    __syncthreads();
    #pragma unroll
    for (int kk = 0; kk < 64; kk += 32) {
      bf16x8 a = *(const bf16x8*)&Wb[w * 16 + lr][kk + lk];
      #pragma unroll
      for (int mf = 0; mf < 4; mf++) {
        bf16x8 b = *(const bf16x8*)&Xb[mf * 16 + lr][kk + lk];
        acc[mf] = __builtin_amdgcn_mfma_f32_16x16x32_bf16(a, b, acc[mf], 0, 0, 0);
      }
    }
  }
  #pragma unroll
  for (int mf = 0; mf < 4; mf++) {
    int s = slots[mf * 16 + lr];
    if (s < 0) continue;
    float g = gates2[s];
    int cc = c0 + w * 16 + rowq;
    const float4 b4 = *(const float4*)&bo[(size_t)e * C + cc];
    ushort4 v = make_ushort4(f2bf(g * (acc[mf][0] + b4.x)),
                             f2bf(g * (acc[mf][1] + b4.y)),
                             f2bf(g * (acc[mf][2] + b4.z)),
                             f2bf(g * (acc[mf][3] + b4.w)));
    *(ushort4*)&y2[(size_t)s * C + cc] = v;
  }
}

// ---------------- Final residual add (bf16 slots) ----------------
__global__ void final_kernel(const unsigned short* __restrict__ y2, float* __restrict__ xout) {
  int t = blockIdx.x, tid = threadIdx.x;
  int c = tid * 2;
  unsigned u0 = *(const unsigned*)&y2[(size_t)(t * 2) * C + c];
  unsigned u1 = *(const unsigned*)&y2[(size_t)(t * 2 + 1) * C + c];
  xout[(size_t)t * C + c]     += bf2f((unsigned short)(u0 & 0xFFFF)) + bf2f((unsigned short)(u1 & 0xFFFF));
  xout[(size_t)t * C + c + 1] += bf2f((unsigned short)(u0 >> 16)) + bf2f((unsigned short)(u1 >> 16));
}

// ---------------- Gating statistics reduction: lane==expert ----------------
template <int E, int K, int TPB>
__global__ __launch_bounds__(256) void reduce_gating(
    const float* __restrict__ probs, const float* __restrict__ lse,
    const int* __restrict__ idxs, float* __restrict__ psum,
    float* __restrict__ freq, float* __restrict__ zsum) {
  constexpr int TPW = TPB / 4;
  int tid = threadIdx.x, lane = tid & 63, wv = tid >> 6;
  int t0 = blockIdx.x * TPB + wv * TPW;
  float ps = 0.f, fr = 0.f;
  if (lane < E) {
    for (int i = 0; i < TPW; i++) {
      int t = t0 + i;
      ps += probs[(size_t)t * E + lane];
      #pragma unroll
      for (int k = 0; k < K; k++)
        fr += (idxs[(size_t)t * K + k] == lane) ? 1.f : 0.f;
    }
  }
  float z = 0.f;
  for (int i = lane; i < TPW; i += 64) {
    float l = lse[t0 + i];
    z += l * l;
  }
  #pragma unroll
  for (int m = 1; m < 64; m <<= 1) z += __shfl_xor(z, m);
  __shared__ float sps[4][E];
  __shared__ float sfr[4][E];
  __shared__ float sz[4];
  if (lane < E) { sps[wv][lane] = ps; sfr[wv][lane] = fr; }
  if (lane == 0) sz[wv] = z;
  __syncthreads();
  if (tid < E) {
    atomicAdd(&psum[tid], sps[0][tid] + sps[1][tid] + sps[2][tid] + sps[3][tid]);
    atomicAdd(&freq[tid], sfr[0][tid] + sfr[1][tid] + sfr[2][tid] + sfr[3][tid]);
  }
  if (tid == 255) atomicAdd(zsum, sz[0] + sz[1] + sz[2] + sz[3]);
}

__global__ void loss_kernel(const float* __restrict__ acc, float* __restrict__ out) {
  const float* p1 = acc;      const float* f1 = acc + 24; float z1 = acc[48];
  const float* p2 = acc + 49; const float* f2 = acc + 65; float z2 = acc[81];
  float sp1 = 0.f, sf1 = 0.f;
  for (int e = 0; e < 24; e++) { sp1 += p1[e]; sf1 += f1[e]; }
  float sw1 = 0.f;
  for (int e = 0; e < 24; e++) sw1 += (p1[e] / sp1) * (f1[e] / sf1);
  sw1 *= 24.f;
  float sp2 = 0.f, sf2 = 0.f;
  for (int e = 0; e < 16; e++) { sp2 += p2[e]; sf2 += f2[e]; }
  float sw2 = 0.f;
  for (int e = 0; e < 16; e++) sw2 += (p2[e] / sp2) * (f2[e] / sf2);
  sw2 *= 16.f;
  out[0] = 0.01f * sw1 + 0.001f * (z1 / T) + 0.01f * sw2 + 0.001f * (z2 / T);
}

}  // namespace

extern "C" void kernel_launch(void* const* d_in, const int* in_sizes, int n_in,
                              void* d_out, int out_size, void* d_ws, size_t ws_size,
                              hipStream_t stream) {
  const float* x      = (const float*)d_in[0];
  const int*   task   = (const int*)d_in[1];
  const float* n1g    = (const float*)d_in[2];
  const float* n1b    = (const float*)d_in[3];
  const float* gate_a = (const float*)d_in[4];
  const float* wq     = (const float*)d_in[5];
  const float* wo_a   = (const float*)d_in[6];
  const float* kvw    = (const float*)d_in[7];
  const float* kvb    = (const float*)d_in[8];
  const float* n2g    = (const float*)d_in[9];
  const float* n2b    = (const float*)d_in[10];
  const float* gate_m = (const float*)d_in[11];
  const float* wi     = (const float*)d_in[12];
  const float* bi     = (const float*)d_in[13];
  const float* wo_m   = (const float*)d_in[14];
  const float* bo     = (const float*)d_in[15];
  float* out = (float*)d_out;

  char* p = (char*)d_ws;
  unsigned short* x1b = (unsigned short*)p; p += (size_t)T * C * 2;
  unsigned short* qb = (unsigned short*)p;  p += (size_t)T * KA * HD * 2;
  unsigned short* ob = (unsigned short*)p;  p += (size_t)T * KA * HD * 2;
  unsigned short* Kb = (unsigned short*)p;  p += (size_t)T * HD * 2;
  unsigned short* Vt = (unsigned short*)p;  p += (size_t)T * HD * 2;
  char* un = p;                      p += (size_t)T * KA * C * 2;
  unsigned short* y_slot  = (unsigned short*)un;
  unsigned short* h       = (unsigned short*)un;
  unsigned short* y2_slot = (unsigned short*)(un + (size_t)T * KF * HID * 2);
  unsigned short* wqt = (unsigned short*)p;  p += (size_t)EA * C * HD * 2;
  unsigned short* woat = (unsigned short*)p; p += (size_t)EA * HD * C * 2;
  unsigned short* wit = (unsigned short*)p;  p += (size_t)EF * C * HID * 2;
  unsigned short* womt = (unsigned short*)p; p += (size_t)EF * HID * C * 2;
  unsigned short* kvwt = (unsigned short*)p; p += (size_t)(2 * HD) * C * 2;
  float* probs1 = (float*)p;         p += (size_t)T * EA * 4;
  float* lse1 = (float*)p;           p += (size_t)T * 4;
  float* gates1 = (float*)p;         p += (size_t)T * KA * 4;
  int* idx1 = (int*)p;               p += (size_t)T * KA * 4;
  float* probs2 = (float*)p;         p += (size_t)T * EF * 4;
  float* lse2 = (float*)p;           p += (size_t)T * 4;
  float* gates2 = (float*)p;         p += (size_t)T * KF * 4;
  int* idx2 = (int*)p;               p += (size_t)T * KF * 4;
  int* bucket_a = (int*)p;           p += (size_t)EA * (T * KA) * 4;
  int* bucket_f = (int*)p;           p += (size_t)EF * (T * KF) * 4;
  int* counts_a = (int*)p;           p += 32 * 4;
  int* counts_f = (int*)p;           p += 32 * 4;
  float* accum = (float*)p;          p += 128 * 4;

  hipMemsetAsync(counts_a, 0, (32 + 32 + 128) * 4, stream);

  tcvt_all<<<17984, 256, 0, stream>>>(wq, wo_a, wi, wo_m, kvw, wqt, woat, wit, womt, kvwt);

  ln_gate_kernel<EA, KA><<<T / 16, 256, 0, stream>>>(x, n1g, n1b, gate_a, task, x1b,
                                                     probs1, lse1, gates1, idx1);
  bucket_kernel<EA><<<(T * KA + 511) / 512, 512, 0, stream>>>(idx1, T * KA, T * KA,
                                                              counts_a, bucket_a);
  qgemm_mfma<<<dim3(1, 536), 256, 0, stream>>>(x1b, wqt, bucket_a, counts_a, qb);
  kv_mfma<<<T / 16, 256, 0, stream>>>(x1b, kvwt, kvb, Kb, Vt);
  attn_mfma<<<dim3(NS / 64, KA, NB), 256, 0, stream>>>(qb, Kb, Vt, ob);
  oproj_mfma<<<dim3(4, 280), 256, 0, stream>>>(ob, woat, gates1, bucket_a, counts_a, y_slot);
  combine_kernel<<<T, 256, 0, stream>>>(x, y_slot, out);
  ln_gate_kernel<EF, KF><<<T / 16, 256, 0, stream>>>(out, n2g, n2b, gate_m, task, x1b,
                                                     probs2, lse2, gates2, idx2);
  bucket_kernel<EF><<<(T * KF + 511) / 512, 512, 0, stream>>>(idx2, T * KF, T * KF,
                                                              counts_f, bucket_f);
  mlp1_mfma<<<dim3(16, 144), 256, 0, stream>>>(x1b, wit, bi, bucket_f, counts_f, h);
  mlp2_mfma<<<dim3(8, 144), 256, 0, stream>>>(h, womt, bo, gates2, bucket_f, counts_f, y2_slot);
  final_kernel<<<T, 256, 0, stream>>>(y2_slot, out);
  reduce_gating<EA, KA, 64><<<T / 64, 256, 0, stream>>>(probs1, lse1, idx1, accum,
                                                        accum + 24, accum + 48);
  reduce_gating<EF, KF, 64><<<T / 64, 256, 0, stream>>>(probs2, lse2, idx2, accum + 49,
                                                        accum + 65, accum + 81);
  loss_kernel<<<1, 1, 0, stream>>>(accum, out + (size_t)T * C);
}

// Round 13
// 233.491 us; speedup vs baseline: 7.3130x; 1.0815x over previous
//
#include <hip/hip_runtime.h>
#include <math.h>

namespace {

constexpr int T   = 4096;
constexpr int C   = 512;
constexpr int NB  = 8;
constexpr int NS  = 512;
constexpr int HD  = 64;
constexpr int KA  = 8;
constexpr int EA  = 24;
constexpr int EF  = 16;
constexpr int KF  = 2;
constexpr int HID = 1024;

typedef __attribute__((ext_vector_type(8))) short bf16x8;
typedef __attribute__((ext_vector_type(4))) float f32x4;

__device__ inline unsigned short f2bf(float f) {
  unsigned u = __float_as_uint(f);
  return (unsigned short)((u + 0x7FFFu + ((u >> 16) & 1u)) >> 16);
}
__device__ inline float bf2f(unsigned short u) {
  return __uint_as_float((unsigned)u << 16);
}

// scan counts to map flat tile id -> (expert, tile offset); returns false if past end
template <int E, int TS>
__device__ inline bool tile_from_counts(const int* counts, int tile, int& e_out, int& t0_out) {
  int e = 0;
  for (; e < E; e++) {
    int nt = (counts[e] + TS - 1) / TS;
    if (tile < nt) break;
    tile -= nt;
  }
  e_out = e; t0_out = tile * TS;
  return e < E;
}

// ---------------- Fused LayerNorm + Gating: 16 tokens, 512 threads ----------------
// Wt transposed in LDS (float4 logits reads); 8 waves for latency hiding.
template <int E, int K>
__global__ __launch_bounds__(512) void ln_gate_kernel(
    const float* __restrict__ in, const float* __restrict__ g,
    const float* __restrict__ b, const float* __restrict__ gate_all,
    const int* __restrict__ task, unsigned short* __restrict__ outb,
    float* __restrict__ probs, float* __restrict__ lse_out,
    float* __restrict__ gates, int* __restrict__ idxs) {
  constexpr int TPB = 16;
  constexpr int XSS = 516;
  constexpr int WSS = 516;
  int tid = threadIdx.x, lane = tid & 63, wv = tid >> 6;   // 8 waves
  int tb = blockIdx.x * TPB;
  __shared__ float xs[TPB][XSS];
  __shared__ float lg[TPB][E];
  __shared__ __align__(16) float Wt[E][WSS];
  // stage gate matrix transposed: global [c][e] coalesced -> Wt[e][c]
  const float* W = gate_all + (size_t)task[0] * C * E;
  for (int i = tid; i < C * E; i += 512) {
    int c = i / E, e = i - c * E;
    Wt[e][c] = W[i];
  }
  // LN: wave wv handles tokens wv*2 .. wv*2+1; lane covers cols lane*8..+7
  int c0 = lane * 8;
  const float4 g0 = *(const float4*)&g[c0], g1 = *(const float4*)&g[c0 + 4];
  const float4 b0 = *(const float4*)&b[c0], b1 = *(const float4*)&b[c0 + 4];
  #pragma unroll
  for (int i = 0; i < 2; i++) {
    int tt = wv * 2 + i;
    int t = tb + tt;
    const float* row = in + (size_t)t * C + c0;
    const float4 v0 = *(const float4*)&row[0];
    const float4 v1 = *(const float4*)&row[4];
    float s = (v0.x + v0.y) + (v0.z + v0.w) + (v1.x + v1.y) + (v1.z + v1.w);
    #pragma unroll
    for (int m = 1; m < 64; m <<= 1) s += __shfl_xor(s, m);
    float mean = s * (1.f / C);
    float d[8] = {v0.x - mean, v0.y - mean, v0.z - mean, v0.w - mean,
                  v1.x - mean, v1.y - mean, v1.z - mean, v1.w - mean};
    float vv = 0.f;
    #pragma unroll
    for (int j = 0; j < 8; j++) vv += d[j] * d[j];
    #pragma unroll
    for (int m = 1; m < 64; m <<= 1) vv += __shfl_xor(vv, m);
    float r = rsqrtf(vv * (1.f / C) + 1e-5f);
    float o[8];
    o[0] = d[0] * r * g0.x + b0.x; o[1] = d[1] * r * g0.y + b0.y;
    o[2] = d[2] * r * g0.z + b0.z; o[3] = d[3] * r * g0.w + b0.w;
    o[4] = d[4] * r * g1.x + b1.x; o[5] = d[5] * r * g1.y + b1.y;
    o[6] = d[6] * r * g1.z + b1.z; o[7] = d[7] * r * g1.w + b1.w;
    *(ushort4*)&outb[(size_t)t * C + c0] =
        make_ushort4(f2bf(o[0]), f2bf(o[1]), f2bf(o[2]), f2bf(o[3]));
    *(ushort4*)&outb[(size_t)t * C + c0 + 4] =
        make_ushort4(f2bf(o[4]), f2bf(o[5]), f2bf(o[6]), f2bf(o[7]));
    #pragma unroll
    for (int j = 0; j < 8; j++) xs[tt][c0 + j] = o[j];
  }
  __syncthreads();
  // logits: thread per (token, expert) pair, float4 LDS reads
  if (tid < TPB * E) {
    int e = tid % E, tt = tid / E;
    float a0 = 0.f, a1 = 0.f, a2 = 0.f, a3 = 0.f;
    float a4 = 0.f, a5 = 0.f, a6 = 0.f, a7 = 0.f;
    #pragma unroll 4
    for (int c = 0; c < C; c += 8) {
      const float4 xv0 = *(const float4*)&xs[tt][c];
      const float4 xv1 = *(const float4*)&xs[tt][c + 4];
      const float4 wv0 = *(const float4*)&Wt[e][c];
      const float4 wv1 = *(const float4*)&Wt[e][c + 4];
      a0 += xv0.x * wv0.x; a1 += xv0.y * wv0.y;
      a2 += xv0.z * wv0.z; a3 += xv0.w * wv0.w;
      a4 += xv1.x * wv1.x; a5 += xv1.y * wv1.y;
      a6 += xv1.z * wv1.z; a7 += xv1.w * wv1.w;
    }
    lg[tt][e] = ((a0 + a1) + (a2 + a3)) + ((a4 + a5) + (a6 + a7));
  }
  __syncthreads();
  // softmax + top-k: wave per token, 2 tokens per wave
  #pragma unroll
  for (int i = 0; i < 2; i++) {
    int tt = wv * 2 + i;
    int t = tb + tt;
    float lgv = (lane < E) ? lg[tt][lane] : -3.0e38f;
    float mx = lgv;
    #pragma unroll
    for (int m = 1; m < 64; m <<= 1) mx = fmaxf(mx, __shfl_xor(mx, m));
    float pe = (lane < E) ? expf(lgv - mx) : 0.f;
    float sum = pe;
    #pragma unroll
    for (int m = 1; m < 64; m <<= 1) sum += __shfl_xor(sum, m);
    float inv = 1.f / sum;
    float prob = pe * inv;
    if (lane < E) probs[(size_t)t * E + lane] = prob;
    if (lane == 0) lse_out[t] = mx + logf(sum);
    float pv = (lane < E) ? prob : -1.f;
    float gsum = 0.f, myv = 0.f; int myi = 0;
    for (int k = 0; k < K; k++) {
      float bv = pv; int bi_ = lane;
      #pragma unroll
      for (int m = 1; m < 64; m <<= 1) {
        float ov = __shfl_xor(bv, m); int oi = __shfl_xor(bi_, m);
        if (ov > bv || (ov == bv && oi < bi_)) { bv = ov; bi_ = oi; }
      }
      gsum += bv;
      if (lane == k) { myv = bv; myi = bi_; }
      if (lane == bi_) pv = -1.f;
    }
    if (lane < K) {
      float ginv = 1.f / (gsum + 1e-6f);
      gates[(size_t)t * K + lane] = myv * ginv;
      idxs[(size_t)t * K + lane]  = myi;
    }
  }
}

// ---------------- bucket by expert ----------------
template <int E>
__global__ __launch_bounds__(512) void bucket_kernel(const int* __restrict__ idx, int nslots,
                                                     int stride, int* counts, int* bucket) {
  __shared__ int lcount[E];
  __shared__ int lbase[E];
  int tid = threadIdx.x;
  if (tid < E) lcount[tid] = 0;
  __syncthreads();
  int s = blockIdx.x * 512 + tid;
  int e = 0, lpos = 0;
  bool valid = (s < nslots);
  if (valid) {
    e = idx[s];
    lpos = atomicAdd(&lcount[e], 1);
  }
  __syncthreads();
  if (tid < E) lbase[tid] = lcount[tid] ? atomicAdd(&counts[tid], lcount[tid]) : 0;
  __syncthreads();
  if (valid) bucket[(size_t)e * stride + lbase[e] + lpos] = s;
}

// ---------------- merged transpose+cvt: all 5 weight tensors in one dispatch ----------------
__global__ __launch_bounds__(256) void tcvt_all(
    const float* __restrict__ wq, const float* __restrict__ wo_a,
    const float* __restrict__ wi, const float* __restrict__ wo_m,
    const float* __restrict__ kvw,
    unsigned short* __restrict__ wqt, unsigned short* __restrict__ woat,
    unsigned short* __restrict__ wit, unsigned short* __restrict__ womt,
    unsigned short* __restrict__ kvwt) {
  int bid = blockIdx.x;
  const float* src; unsigned short* dst; int K, N, nx, rem;
  if (bid < 768)        { src = wq;   dst = wqt;  K = 512;  N = 64;   nx = 2;  rem = bid; }
  else if (bid < 1536)  { src = wo_a; dst = woat; K = 64;   N = 512;  nx = 16; rem = bid - 768; }
  else if (bid < 9728)  { src = wi;   dst = wit;  K = 512;  N = 1024; nx = 32; rem = bid - 1536; }
  else if (bid < 17920) { src = wo_m; dst = womt; K = 1024; N = 512;  nx = 16; rem = bid - 9728; }
  else                  { src = kvw;  dst = kvwt; K = 512;  N = 128;  nx = 4;  rem = bid - 17920; }
  int per = nx * (K / 32);
  int e = rem / per, r2 = rem % per;
  int kt = (r2 / nx) * 32, nt = (r2 % nx) * 32;
  __shared__ float tile[32][33];
  int tid = threadIdx.x;
  const float* S = src + (size_t)e * K * N;
  for (int i = tid; i < 32 * 32; i += 256) {
    int r = i >> 5, c = i & 31;
    tile[r][c] = S[(size_t)(kt + r) * N + nt + c];
  }
  __syncthreads();
  unsigned short* D = dst + (size_t)e * K * N;
  for (int i = tid; i < 32 * 8; i += 256) {
    int n = i >> 3, k4 = (i & 7) * 4;
    ushort4 v;
    v.x = f2bf(tile[k4 + 0][n]); v.y = f2bf(tile[k4 + 1][n]);
    v.z = f2bf(tile[k4 + 2][n]); v.w = f2bf(tile[k4 + 3][n]);
    *(ushort4*)&D[(size_t)(nt + n) * K + kt + k4] = v;
  }
}

// ---------------- MFMA Q GEMM: 64 slots x 64 out, K=512 -> bf16 q (pre-scaled) ----------------
__global__ __launch_bounds__(256) void qgemm_mfma(
    const unsigned short* __restrict__ xb, const unsigned short* __restrict__ wqt,
    const int* __restrict__ bucket, const int* __restrict__ counts,
    unsigned short* __restrict__ qb) {
  __shared__ int se, st0;
  int tid = threadIdx.x;
  if (tid == 0) {
    int e, t0;
    bool ok = tile_from_counts<EA, 64>(counts, blockIdx.y, e, t0);
    se = ok ? e : -1; st0 = t0;
  }
  __syncthreads();
  if (se < 0) return;
  int e = se, t0 = st0;
  int cnt = counts[e];
  __shared__ int slots[64];
  __shared__ __align__(16) unsigned short Xb[64][72];
  __shared__ __align__(16) unsigned short Wb[64][72];
  if (tid < 64) {
    int ii = t0 + tid;
    slots[tid] = (ii < cnt) ? bucket[(size_t)e * (T * KA) + ii] : -1;
  }
  __syncthreads();
  int lane = tid & 63, w = tid >> 6;
  int lr = lane & 15, lk = (lane >> 4) * 8, rowq = (lane >> 4) * 4;
  f32x4 acc[4] = {};
  for (int kc = 0; kc < C; kc += 64) {
    __syncthreads();
    #pragma unroll
    for (int it = 0; it < 2; ++it) {
      int i = it * 256 + tid;
      int r = i >> 3, c8 = (i & 7) * 8;
      int s = slots[r];
      uint4 v = make_uint4(0u, 0u, 0u, 0u);
      if (s >= 0) v = *(const uint4*)&xb[(size_t)(s >> 3) * C + kc + c8];
      *(uint4*)&Xb[r][c8] = v;
    }
    #pragma unroll
    for (int it = 0; it < 2; ++it) {
      int i = it * 256 + tid;
      int r = i >> 3, c8 = (i & 7) * 8;
      *(uint4*)&Wb[r][c8] = *(const uint4*)&wqt[((size_t)e * HD + r) * C + kc + c8];
    }
    __syncthreads();
    #pragma unroll
    for (int kk = 0; kk < 64; kk += 32) {
      bf16x8 a = *(const bf16x8*)&Wb[w * 16 + lr][kk + lk];
      #pragma unroll
      for (int mf = 0; mf < 4; mf++) {
        bf16x8 b = *(const bf16x8*)&Xb[mf * 16 + lr][kk + lk];
        acc[mf] = __builtin_amdgcn_mfma_f32_16x16x32_bf16(a, b, acc[mf], 0, 0, 0);
      }
    }
  }
  #pragma unroll
  for (int mf = 0; mf < 4; mf++) {
    int s = slots[mf * 16 + lr];
    if (s < 0) continue;
    ushort4 v = make_ushort4(f2bf(0.125f * acc[mf][0]), f2bf(0.125f * acc[mf][1]),
                             f2bf(0.125f * acc[mf][2]), f2bf(0.125f * acc[mf][3]));
    *(ushort4*)&qb[(size_t)s * HD + w * 16 + rowq] = v;
  }
}

// ---------------- MFMA KV GEMM: 16 tokens x 128 cols per block, 256 blocks ----------------
__global__ __launch_bounds__(256) void kv_mfma(
    const unsigned short* __restrict__ xb, const unsigned short* __restrict__ kvwt,
    const float* __restrict__ kvb, unsigned short* __restrict__ Kb,
    unsigned short* __restrict__ Vt) {
  int t0 = blockIdx.x * 16;
  int tid = threadIdx.x;
  __shared__ __align__(16) unsigned short Xs[16][72];
  __shared__ __align__(16) unsigned short Ws[128][72];
  int lane = tid & 63, w = tid >> 6;
  int lr = lane & 15, lk = (lane >> 4) * 8, rowq = (lane >> 4) * 4;
  f32x4 acc[2] = {};
  for (int kc = 0; kc < C; kc += 64) {
    __syncthreads();
    if (tid < 128) {
      int r = tid >> 3, c8 = (tid & 7) * 8;
      *(uint4*)&Xs[r][c8] = *(const uint4*)&xb[(size_t)(t0 + r) * C + kc + c8];
    }
    #pragma unroll
    for (int it = 0; it < 4; ++it) {
      int i = it * 256 + tid;
      int r = i >> 3, c8 = (i & 7) * 8;
      *(uint4*)&Ws[r][c8] = *(const uint4*)&kvwt[(size_t)r * C + kc + c8];
    }
    __syncthreads();
    #pragma unroll
    for (int kk = 0; kk < 64; kk += 32) {
      bf16x8 xf = *(const bf16x8*)&Xs[lr][kk + lk];
      #pragma unroll
      for (int cf = 0; cf < 2; cf++) {
        bf16x8 wf = *(const bf16x8*)&Ws[w * 32 + cf * 16 + lr][kk + lk];
        acc[cf] = __builtin_amdgcn_mfma_f32_16x16x32_bf16(wf, xf, acc[cf], 0, 0, 0);
      }
    }
  }
  int t = t0 + lr;
  int bb = t >> 9, n = t & (NS - 1);
  #pragma unroll
  for (int cf = 0; cf < 2; cf++) {
    #pragma unroll
    for (int r2 = 0; r2 < 4; r2++) {
      int c = w * 32 + cf * 16 + rowq + r2;
      float v = acc[cf][r2] + kvb[c];
      if (c < HD) Kb[(size_t)t * HD + c] = f2bf(v);
      else        Vt[((size_t)bb * HD + (c - HD)) * NS + n] = f2bf(v);
    }
  }
}

// ---------------- MFMA flash attention ----------------
__global__ __launch_bounds__(256) void attn_mfma(
    const unsigned short* __restrict__ qb, const unsigned short* __restrict__ Kb,
    const unsigned short* __restrict__ Vt, unsigned short* __restrict__ ob) {
  int qt = blockIdx.x, h = blockIdx.y, b = blockIdx.z;
  int tid = threadIdx.x;
  __shared__ __align__(16) unsigned short Qs[64][72];
  __shared__ __align__(16) unsigned short Ks[64][72];
  __shared__ __align__(16) unsigned short Vs[64][72];
  __shared__ __align__(16) unsigned short Ps[64][72];
  int i0 = qt * 64;
  #pragma unroll
  for (int it = 0; it < 2; ++it) {
    int i = it * 256 + tid;
    int r = i >> 3, c8 = (i & 7) * 8;
    *(uint4*)&Qs[r][c8] = *(const uint4*)&qb[(((size_t)(b * NS + i0 + r)) * KA + h) * HD + c8];
  }
  int lane = tid & 63, w = tid >> 6;
  int lr = lane & 15, lk = (lane >> 4) * 8, rowq = (lane >> 4) * 4;
  f32x4 acc_o[4] = {};
  float m_run = -3.0e38f, l_run = 0.f;
  for (int jt = 0; jt < NS / 64; ++jt) {
    __syncthreads();
    #pragma unroll
    for (int it = 0; it < 2; ++it) {
      int i = it * 256 + tid;
      int r = i >> 3, c8 = (i & 7) * 8;
      *(uint4*)&Ks[r][c8] = *(const uint4*)&Kb[((size_t)(b * NS + jt * 64 + r)) * HD + c8];
      *(uint4*)&Vs[r][c8] = *(const uint4*)&Vt[((size_t)b * HD + r) * NS + jt * 64 + c8];
    }
    __syncthreads();
    f32x4 acc_s[4] = {};
    #pragma unroll
    for (int kk = 0; kk < 64; kk += 32) {
      bf16x8 qf = *(const bf16x8*)&Qs[w * 16 + lr][kk + lk];
      #pragma unroll
      for (int kf = 0; kf < 4; kf++) {
        bf16x8 kr = *(const bf16x8*)&Ks[kf * 16 + lr][kk + lk];
        acc_s[kf] = __builtin_amdgcn_mfma_f32_16x16x32_bf16(kr, qf, acc_s[kf], 0, 0, 0);
      }
    }
    float pmax = acc_s[0][0];
    #pragma unroll
    for (int kf = 0; kf < 4; kf++)
      #pragma unroll
      for (int r = 0; r < 4; r++) pmax = fmaxf(pmax, acc_s[kf][r]);
    pmax = fmaxf(pmax, __shfl_xor(pmax, 16));
    pmax = fmaxf(pmax, __shfl_xor(pmax, 32));
    float m_new = fmaxf(m_run, pmax);
    float scl = expf(m_run - m_new);
    float rs = 0.f;
    #pragma unroll
    for (int kf = 0; kf < 4; kf++)
      #pragma unroll
      for (int r = 0; r < 4; r++) {
        float pv = expf(acc_s[kf][r] - m_new);
        rs += pv;
        Ps[w * 16 + lr][kf * 16 + rowq + r] = f2bf(pv);
      }
    rs += __shfl_xor(rs, 16);
    rs += __shfl_xor(rs, 32);
    l_run = l_run * scl + rs;
    m_run = m_new;
    __syncthreads();
    #pragma unroll
    for (int df = 0; df < 4; df++) {
      acc_o[df][0] *= scl; acc_o[df][1] *= scl;
      acc_o[df][2] *= scl; acc_o[df][3] *= scl;
    }
    #pragma unroll
    for (int kk = 0; kk < 64; kk += 32) {
      bf16x8 pf = *(const bf16x8*)&Ps[w * 16 + lr][kk + lk];
      #pragma unroll
      for (int df = 0; df < 4; df++) {
        bf16x8 vf = *(const bf16x8*)&Vs[df * 16 + lr][kk + lk];
        acc_o[df] = __builtin_amdgcn_mfma_f32_16x16x32_bf16(vf, pf, acc_o[df], 0, 0, 0);
      }
    }
  }
  float inv = 1.f / l_run;
  int token = b * NS + i0 + w * 16 + lr;
  #pragma unroll
  for (int df = 0; df < 4; df++) {
    ushort4 v = make_ushort4(f2bf(acc_o[df][0] * inv), f2bf(acc_o[df][1] * inv),
                             f2bf(acc_o[df][2] * inv), f2bf(acc_o[df][3] * inv));
    *(ushort4*)&ob[((size_t)token * KA + h) * HD + df * 16 + rowq] = v;
  }
}

// ---------------- MFMA output proj: 128 slots x 128 cols, K=64, in-kernel map ----------------
__global__ __launch_bounds__(256) void oproj_mfma(
    const unsigned short* __restrict__ ob, const unsigned short* __restrict__ wot,
    const float* __restrict__ gates, const int* __restrict__ bucket,
    const int* __restrict__ counts, unsigned short* __restrict__ y_slot) {
  __shared__ int se, st0;
  int tid = threadIdx.x;
  if (tid == 0) {
    int e, t0;
    bool ok = tile_from_counts<EA, 128>(counts, blockIdx.y, e, t0);
    se = ok ? e : -1; st0 = t0;
  }
  __syncthreads();
  if (se < 0) return;
  int e = se, t0 = st0;
  int c0 = blockIdx.x * 128;
  int cnt = counts[e];
  __shared__ int slots[128];
  __shared__ float gs[128];
  __shared__ __align__(16) unsigned short Xb[128][72];
  __shared__ __align__(16) unsigned short Wb[128][72];
  if (tid < 128) {
    int ii = t0 + tid;
    int s = (ii < cnt) ? bucket[(size_t)e * (T * KA) + ii] : -1;
    slots[tid] = s;
    gs[tid] = (s >= 0) ? gates[s] : 0.f;
  }
  __syncthreads();
  #pragma unroll
  for (int it = 0; it < 4; ++it) {
    int i = it * 256 + tid;
    int r = i >> 3, c8 = (i & 7) * 8;
    int s = slots[r];
    uint4 vo = make_uint4(0u, 0u, 0u, 0u);
    if (s >= 0) {
      float g = gs[r];
      uint4 u = *(const uint4*)&ob[(size_t)s * HD + c8];
      const unsigned short* us = (const unsigned short*)&u;
      unsigned short* vs = (unsigned short*)&vo;
      #pragma unroll
      for (int k = 0; k < 8; k++) vs[k] = f2bf(g * bf2f(us[k]));
    }
    *(uint4*)&Xb[r][c8] = vo;
  }
  #pragma unroll
  for (int it = 0; it < 4; ++it) {
    int i = it * 256 + tid;
    int r = i >> 3, c8 = (i & 7) * 8;
    *(uint4*)&Wb[r][c8] = *(const uint4*)&wot[((size_t)e * C + c0 + r) * HD + c8];
  }
  __syncthreads();
  int lane = tid & 63, wid = tid >> 6;
  int wr = wid & 1, wc = wid >> 1;
  int lr = lane & 15, lk = (lane >> 4) * 8, rowq = (lane >> 4) * 4;
  f32x4 acc[4][4] = {};
  #pragma unroll
  for (int kk = 0; kk < 64; kk += 32) {
    bf16x8 a[4], b[4];
    #pragma unroll
    for (int nf = 0; nf < 4; nf++) a[nf] = *(const bf16x8*)&Wb[wc * 64 + nf * 16 + lr][kk + lk];
    #pragma unroll
    for (int mf = 0; mf < 4; mf++) b[mf] = *(const bf16x8*)&Xb[wr * 64 + mf * 16 + lr][kk + lk];
    #pragma unroll
    for (int nf = 0; nf < 4; nf++)
      #pragma unroll
      for (int mf = 0; mf < 4; mf++)
        acc[nf][mf] = __builtin_amdgcn_mfma_f32_16x16x32_bf16(a[nf], b[mf], acc[nf][mf], 0, 0, 0);
  }
  #pragma unroll
  for (int mf = 0; mf < 4; mf++) {
    int si = wr * 64 + mf * 16 + lr;
    int s = slots[si];
    if (s < 0) continue;
    size_t base = (size_t)s * C + c0 + wc * 64;
    #pragma unroll
    for (int nf = 0; nf < 4; nf++) {
      ushort4 v = make_ushort4(f2bf(acc[nf][mf][0]), f2bf(acc[nf][mf][1]),
                               f2bf(acc[nf][mf][2]), f2bf(acc[nf][mf][3]));
      *(ushort4*)&y_slot[base + nf * 16 + rowq] = v;
    }
  }
}

// ---------------- combine: out = x + sum_k y_slot[t*8+k] ----------------
__global__ void combine_kernel(const float* __restrict__ x, const unsigned short* __restrict__ ys,
                               float* __restrict__ out) {
  int t = blockIdx.x, tid = threadIdx.x;
  int c = tid * 2;
  float s0 = 0.f, s1 = 0.f;
  #pragma unroll
  for (int k = 0; k < KA; k++) {
    unsigned u = *(const unsigned*)&ys[((size_t)t * KA + k) * C + c];
    s0 += bf2f((unsigned short)(u & 0xFFFF));
    s1 += bf2f((unsigned short)(u >> 16));
  }
  out[(size_t)t * C + c]     = x[(size_t)t * C + c] + s0;
  out[(size_t)t * C + c + 1] = x[(size_t)t * C + c + 1] + s1;
}

// ---------------- MFMA MLP1: 64 slots x 64 cols, gelu epilogue, in-kernel map ----------------
__global__ __launch_bounds__(256) void mlp1_mfma(
    const unsigned short* __restrict__ xb, const unsigned short* __restrict__ wit,
    const float* __restrict__ bi, const int* __restrict__ bucket,
    const int* __restrict__ counts, unsigned short* __restrict__ h) {
  __shared__ int se, st0;
  int tid = threadIdx.x;
  if (tid == 0) {
    int e, t0;
    bool ok = tile_from_counts<EF, 64>(counts, blockIdx.y, e, t0);
    se = ok ? e : -1; st0 = t0;
  }
  __syncthreads();
  if (se < 0) return;
  int e = se, t0 = st0;
  int j0 = blockIdx.x * 64;
  int cnt = counts[e];
  __shared__ int slots[64];
  __shared__ __align__(16) unsigned short Xb[64][72];
  __shared__ __align__(16) unsigned short Wb[64][72];
  if (tid < 64) {
    int ii = t0 + tid;
    slots[tid] = (ii < cnt) ? bucket[(size_t)e * (T * KF) + ii] : -1;
  }
  __syncthreads();
  int lane = tid & 63, w = tid >> 6;
  int lr = lane & 15, lk = (lane >> 4) * 8, rowq = (lane >> 4) * 4;
  f32x4 acc[4] = {};
  for (int kc = 0; kc < C; kc += 64) {
    __syncthreads();
    #pragma unroll
    for (int it = 0; it < 2; ++it) {
      int i = it * 256 + tid;
      int r = i >> 3, c8 = (i & 7) * 8;
      int s = slots[r];
      uint4 v = make_uint4(0u, 0u, 0u, 0u);
      if (s >= 0) v = *(const uint4*)&xb[(size_t)(s >> 1) * C + kc + c8];
      *(uint4*)&Xb[r][c8] = v;
    }
    #pragma unroll
    for (int it = 0; it < 2; ++it) {
      int i = it * 256 + tid;
      int r = i >> 3, c8 = (i & 7) * 8;
      *(uint4*)&Wb[r][c8] = *(const uint4*)&wit[((size_t)e * HID + j0 + r) * C + kc + c8];
    }
    __syncthreads();
    #pragma unroll
    for (int kk = 0; kk < 64; kk += 32) {
      bf16x8 a = *(const bf16x8*)&Wb[w * 16 + lr][kk + lk];
      #pragma unroll
      for (int mf = 0; mf < 4; mf++) {
        bf16x8 b = *(const bf16x8*)&Xb[mf * 16 + lr][kk + lk];
        acc[mf] = __builtin_amdgcn_mfma_f32_16x16x32_bf16(a, b, acc[mf], 0, 0, 0);
      }
    }
  }
  #pragma unroll
  for (int mf = 0; mf < 4; mf++) {
    int s = slots[mf * 16 + lr];
    if (s < 0) continue;
    int j = j0 + w * 16 + rowq;
    const float4 b4 = *(const float4*)&bi[(size_t)e * HID + j];
    float v0 = acc[mf][0] + b4.x, v1 = acc[mf][1] + b4.y;
    float v2 = acc[mf][2] + b4.z, v3 = acc[mf][3] + b4.w;
    v0 = 0.5f * v0 * (1.f + erff(v0 * 0.70710678118654752f));
    v1 = 0.5f * v1 * (1.f + erff(v1 * 0.70710678118654752f));
    v2 = 0.5f * v2 * (1.f + erff(v2 * 0.70710678118654752f));
    v3 = 0.5f * v3 * (1.f + erff(v3 * 0.70710678118654752f));
    *(ushort4*)&h[(size_t)s * HID + j] = make_ushort4(f2bf(v0), f2bf(v1), f2bf(v2), f2bf(v3));
  }
}

// ---------------- MFMA MLP2: 64 slots x 64 cols, gate+bias epilogue, in-kernel map ----------------
__global__ __launch_bounds__(256) void mlp2_mfma(
    const unsigned short* __restrict__ h, const unsigned short* __restrict__ wot,
    const float* __restrict__ bo, const float* __restrict__ gates2,
    const int* __restrict__ bucket, const int* __restrict__ counts,
    unsigned short* __restrict__ y2) {
  __shared__ int se, st0;
  int tid = threadIdx.x;
  if (tid == 0) {
    int e, t0;
    bool ok = tile_from_counts<EF, 64>(counts, blockIdx.y, e, t0);
    se = ok ? e : -1; st0 = t0;
  }
  __syncthreads();
  if (se < 0) return;
  int e = se, t0 = st0;
  int c0 = blockIdx.x * 64;
  int cnt = counts[e];
  __shared__ int slots[64];
  __shared__ __align__(16) unsigned short Xb[64][72];
  __shared__ __align__(16) unsigned short Wb[64][72];
  if (tid < 64) {
    int ii = t0 + tid;
    slots[tid] = (ii < cnt) ? bucket[(size_t)e * (T * KF) + ii] : -1;
  }
  __syncthreads();
  int lane = tid & 63, w = tid >> 6;
  int lr = lane & 15, lk = (lane >> 4) * 8, rowq = (lane >> 4) * 4;
  f32x4 acc[4] = {};
  for (int kc = 0; kc < HID; kc += 64) {
    __syncthreads();
    #pragma unroll
    for (int it = 0; it < 2; ++it) {
      int i = it * 256 + tid;
      int r = i >> 3, c8 = (i & 7) * 8;
      int s = slots[r];
      uint4 v = make_uint4(0u, 0u, 0u, 0u);
      if (s >= 0) v = *(const uint4*)&h[(size_t)s * HID + kc + c8];
      *(uint4*)&Xb[r][c8] = v;
    }
    #pragma unroll
    for (int it = 0; it < 2; ++it) {
      int i = it * 256 + tid;
      int r = i >> 3, c8 = (i & 7) * 8;
      *(uint4*)&Wb[r][c8] = *(const uint4*)&wot[((size_t)e * C + c0 + r) * HID + kc + c8];
    }
    __syncthreads();
    #pragma unroll
    for (int kk = 0; kk < 64; kk += 32) {
      bf16x8 a = *(const bf16x8*)&Wb[w * 16 + lr][kk + lk];
      #pragma unroll
      for (int mf = 0; mf < 4; mf++) {
        bf16x8 b = *(const bf16x8*)&Xb[mf * 16 + lr][kk + lk];
        acc[mf] = __builtin_amdgcn_mfma_f32_16x16x32_bf16(a, b, acc[mf], 0, 0, 0);
      }
    }
  }
  #pragma unroll
  for (int mf = 0; mf < 4; mf++) {
    int s = slots[mf * 16 + lr];
    if (s < 0) continue;
    float g = gates2[s];
    int cc = c0 + w * 16 + rowq;
    const float4 b4 = *(const float4*)&bo[(size_t)e * C + cc];
    ushort4 v = make_ushort4(f2bf(g * (acc[mf][0] + b4.x)),
                             f2bf(g * (acc[mf][1] + b4.y)),
                             f2bf(g * (acc[mf][2] + b4.z)),
                             f2bf(g * (acc[mf][3] + b4.w)));
    *(ushort4*)&y2[(size_t)s * C + cc] = v;
  }
}

// ---------------- Final residual add (bf16 slots) ----------------
__global__ void final_kernel(const unsigned short* __restrict__ y2, float* __restrict__ xout) {
  int t = blockIdx.x, tid = threadIdx.x;
  int c = tid * 2;
  unsigned u0 = *(const unsigned*)&y2[(size_t)(t * 2) * C + c];
  unsigned u1 = *(const unsigned*)&y2[(size_t)(t * 2 + 1) * C + c];
  xout[(size_t)t * C + c]     += bf2f((unsigned short)(u0 & 0xFFFF)) + bf2f((unsigned short)(u1 & 0xFFFF));
  xout[(size_t)t * C + c + 1] += bf2f((unsigned short)(u0 >> 16)) + bf2f((unsigned short)(u1 >> 16));
}

// ---------------- Gating statistics reduction: lane==expert ----------------
template <int E, int K, int TPB>
__global__ __launch_bounds__(256) void reduce_gating(
    const float* __restrict__ probs, const float* __restrict__ lse,
    const int* __restrict__ idxs, float* __restrict__ psum,
    float* __restrict__ freq, float* __restrict__ zsum) {
  constexpr int TPW = TPB / 4;
  int tid = threadIdx.x, lane = tid & 63, wv = tid >> 6;
  int t0 = blockIdx.x * TPB + wv * TPW;
  float ps = 0.f, fr = 0.f;
  if (lane < E) {
    for (int i = 0; i < TPW; i++) {
      int t = t0 + i;
      ps += probs[(size_t)t * E + lane];
      #pragma unroll
      for (int k = 0; k < K; k++)
        fr += (idxs[(size_t)t * K + k] == lane) ? 1.f : 0.f;
    }
  }
  float z = 0.f;
  for (int i = lane; i < TPW; i += 64) {
    float l = lse[t0 + i];
    z += l * l;
  }
  #pragma unroll
  for (int m = 1; m < 64; m <<= 1) z += __shfl_xor(z, m);
  __shared__ float sps[4][E];
  __shared__ float sfr[4][E];
  __shared__ float sz[4];
  if (lane < E) { sps[wv][lane] = ps; sfr[wv][lane] = fr; }
  if (lane == 0) sz[wv] = z;
  __syncthreads();
  if (tid < E) {
    atomicAdd(&psum[tid], sps[0][tid] + sps[1][tid] + sps[2][tid] + sps[3][tid]);
    atomicAdd(&freq[tid], sfr[0][tid] + sfr[1][tid] + sfr[2][tid] + sfr[3][tid]);
  }
  if (tid == 255) atomicAdd(zsum, sz[0] + sz[1] + sz[2] + sz[3]);
}

__global__ void loss_kernel(const float* __restrict__ acc, float* __restrict__ out) {
  const float* p1 = acc;      const float* f1 = acc + 24; float z1 = acc[48];
  const float* p2 = acc + 49; const float* f2 = acc + 65; float z2 = acc[81];
  float sp1 = 0.f, sf1 = 0.f;
  for (int e = 0; e < 24; e++) { sp1 += p1[e]; sf1 += f1[e]; }
  float sw1 = 0.f;
  for (int e = 0; e < 24; e++) sw1 += (p1[e] / sp1) * (f1[e] / sf1);
  sw1 *= 24.f;
  float sp2 = 0.f, sf2 = 0.f;
  for (int e = 0; e < 16; e++) { sp2 += p2[e]; sf2 += f2[e]; }
  float sw2 = 0.f;
  for (int e = 0; e < 16; e++) sw2 += (p2[e] / sp2) * (f2[e] / sf2);
  sw2 *= 16.f;
  out[0] = 0.01f * sw1 + 0.001f * (z1 / T) + 0.01f * sw2 + 0.001f * (z2 / T);
}

}  // namespace

extern "C" void kernel_launch(void* const* d_in, const int* in_sizes, int n_in,
                              void* d_out, int out_size, void* d_ws, size_t ws_size,
                              hipStream_t stream) {
  const float* x      = (const float*)d_in[0];
  const int*   task   = (const int*)d_in[1];
  const float* n1g    = (const float*)d_in[2];
  const float* n1b    = (const float*)d_in[3];
  const float* gate_a = (const float*)d_in[4];
  const float* wq     = (const float*)d_in[5];
  const float* wo_a   = (const float*)d_in[6];
  const float* kvw    = (const float*)d_in[7];
  const float* kvb    = (const float*)d_in[8];
  const float* n2g    = (const float*)d_in[9];
  const float* n2b    = (const float*)d_in[10];
  const float* gate_m = (const float*)d_in[11];
  const float* wi     = (const float*)d_in[12];
  const float* bi     = (const float*)d_in[13];
  const float* wo_m   = (const float*)d_in[14];
  const float* bo     = (const float*)d_in[15];
  float* out = (float*)d_out;

  char* p = (char*)d_ws;
  unsigned short* x1b = (unsigned short*)p; p += (size_t)T * C * 2;
  unsigned short* qb = (unsigned short*)p;  p += (size_t)T * KA * HD * 2;
  unsigned short* ob = (unsigned short*)p;  p += (size_t)T * KA * HD * 2;
  unsigned short* Kb = (unsigned short*)p;  p += (size_t)T * HD * 2;
  unsigned short* Vt = (unsigned short*)p;  p += (size_t)T * HD * 2;
  char* un = p;                      p += (size_t)T * KA * C * 2;
  unsigned short* y_slot  = (unsigned short*)un;
  unsigned short* h       = (unsigned short*)un;
  unsigned short* y2_slot = (unsigned short*)(un + (size_t)T * KF * HID * 2);
  unsigned short* wqt = (unsigned short*)p;  p += (size_t)EA * C * HD * 2;
  unsigned short* woat = (unsigned short*)p; p += (size_t)EA * HD * C * 2;
  unsigned short* wit = (unsigned short*)p;  p += (size_t)EF * C * HID * 2;
  unsigned short* womt = (unsigned short*)p; p += (size_t)EF * HID * C * 2;
  unsigned short* kvwt = (unsigned short*)p; p += (size_t)(2 * HD) * C * 2;
  float* probs1 = (float*)p;         p += (size_t)T * EA * 4;
  float* lse1 = (float*)p;           p += (size_t)T * 4;
  float* gates1 = (float*)p;         p += (size_t)T * KA * 4;
  int* idx1 = (int*)p;               p += (size_t)T * KA * 4;
  float* probs2 = (float*)p;         p += (size_t)T * EF * 4;
  float* lse2 = (float*)p;           p += (size_t)T * 4;
  float* gates2 = (float*)p;         p += (size_t)T * KF * 4;
  int* idx2 = (int*)p;               p += (size_t)T * KF * 4;
  int* bucket_a = (int*)p;           p += (size_t)EA * (T * KA) * 4;
  int* bucket_f = (int*)p;           p += (size_t)EF * (T * KF) * 4;
  int* counts_a = (int*)p;           p += 32 * 4;
  int* counts_f = (int*)p;           p += 32 * 4;
  float* accum = (float*)p;          p += 128 * 4;

  hipMemsetAsync(counts_a, 0, (32 + 32 + 128) * 4, stream);

  tcvt_all<<<17984, 256, 0, stream>>>(wq, wo_a, wi, wo_m, kvw, wqt, woat, wit, womt, kvwt);

  ln_gate_kernel<EA, KA><<<T / 16, 512, 0, stream>>>(x, n1g, n1b, gate_a, task, x1b,
                                                     probs1, lse1, gates1, idx1);
  bucket_kernel<EA><<<(T * KA + 511) / 512, 512, 0, stream>>>(idx1, T * KA, T * KA,
                                                              counts_a, bucket_a);
  qgemm_mfma<<<dim3(1, 536), 256, 0, stream>>>(x1b, wqt, bucket_a, counts_a, qb);
  kv_mfma<<<T / 16, 256, 0, stream>>>(x1b, kvwt, kvb, Kb, Vt);
  attn_mfma<<<dim3(NS / 64, KA, NB), 256, 0, stream>>>(qb, Kb, Vt, ob);
  oproj_mfma<<<dim3(4, 280), 256, 0, stream>>>(ob, woat, gates1, bucket_a, counts_a, y_slot);
  combine_kernel<<<T, 256, 0, stream>>>(x, y_slot, out);
  ln_gate_kernel<EF, KF><<<T / 16, 512, 0, stream>>>(out, n2g, n2b, gate_m, task, x1b,
                                                     probs2, lse2, gates2, idx2);
  bucket_kernel<EF><<<(T * KF + 511) / 512, 512, 0, stream>>>(idx2, T * KF, T * KF,
                                                              counts_f, bucket_f);
  mlp1_mfma<<<dim3(16, 144), 256, 0, stream>>>(x1b, wit, bi, bucket_f, counts_f, h);
  mlp2_mfma<<<dim3(8, 144), 256, 0, stream>>>(h, womt, bo, gates2, bucket_f, counts_f, y2_slot);
  final_kernel<<<T, 256, 0, stream>>>(y2_slot, out);
  reduce_gating<EA, KA, 64><<<T / 64, 256, 0, stream>>>(probs1, lse1, idx1, accum,
                                                        accum + 24, accum + 48);
  reduce_gating<EF, KF, 64><<<T / 64, 256, 0, stream>>>(probs2, lse2, idx2, accum + 49,
                                                        accum + 65, accum + 81);
  loss_kernel<<<1, 1, 0, stream>>>(accum, out + (size_t)T * C);
}